// Round 3
// baseline (2094.568 us; speedup 1.0000x reference)
//
#include <hip/hip_runtime.h>

// RWKV7-delta time-mix. Device: f32 in / f32 out (per reference dtypes),
// bf16 intermediates + MFMA bf16 16x16x32 compute.
// B=2 T=4096 C=2048 H=32 K=64 CHUNK=128 NC=32.

typedef unsigned short u16;
typedef unsigned int   u32;
typedef __attribute__((ext_vector_type(8))) short s16x8;
typedef __attribute__((ext_vector_type(4))) float f32x4;

#define DEV __device__ __forceinline__

DEV float b2f(u16 v){ return __uint_as_float(((u32)v) << 16); }
DEV u16 f2b(float f){ u32 u = __float_as_uint(f); return (u16)((u + 0x7fffu + ((u >> 16) & 1u)) >> 16); }
DEV float clip30(float x){ return fminf(fmaxf(x, -30.f), 30.f); }
DEV void up8(uint4 v, float* f){
  f[0]=b2f((u16)(v.x&0xffffu)); f[1]=b2f((u16)(v.x>>16));
  f[2]=b2f((u16)(v.y&0xffffu)); f[3]=b2f((u16)(v.y>>16));
  f[4]=b2f((u16)(v.z&0xffffu)); f[5]=b2f((u16)(v.z>>16));
  f[6]=b2f((u16)(v.w&0xffffu)); f[7]=b2f((u16)(v.w>>16));
}
DEV uint4 pk8(const float* f){
  uint4 v;
  v.x = (u32)f2b(f[0]) | ((u32)f2b(f[1])<<16);
  v.y = (u32)f2b(f[2]) | ((u32)f2b(f[3])<<16);
  v.z = (u32)f2b(f[4]) | ((u32)f2b(f[5])<<16);
  v.w = (u32)f2b(f[6]) | ((u32)f2b(f[7])<<16);
  return v;
}
DEV void unp16(uint4 v, u16* o){
  o[0]=(u16)(v.x&0xffffu); o[1]=(u16)(v.x>>16);
  o[2]=(u16)(v.y&0xffffu); o[3]=(u16)(v.y>>16);
  o[4]=(u16)(v.z&0xffffu); o[5]=(u16)(v.z>>16);
  o[6]=(u16)(v.w&0xffffu); o[7]=(u16)(v.w>>16);
}
#define ZF4 ((f32x4){0.f,0.f,0.f,0.f})

// ---------------------------------------------------------------- transpose f32 -> bf16
__global__ void transpose_k(const float* __restrict__ in, u16* __restrict__ out, int R, int C){
  __shared__ float tile[32][33];
  int c0 = blockIdx.x*32, r0 = blockIdx.y*32;
  int tx = threadIdx.x, ty = threadIdx.y; // (32,8)
  #pragma unroll
  for (int j=0;j<4;j++) tile[ty + j*8][tx] = in[(size_t)(r0 + ty + j*8)*C + c0 + tx];
  __syncthreads();
  #pragma unroll
  for (int j=0;j<4;j++) out[(size_t)(c0 + ty + j*8)*R + r0 + tx] = f2b(tile[tx][ty + j*8]);
}

// ---------------------------------------------------------------- prep: xmx = x + dxprev*maa_x (bf16) ; x_last (f32 out)
__global__ __launch_bounds__(256) void prep_k(const float* __restrict__ x, const float* __restrict__ shift,
    const float* __restrict__ maax, u16* __restrict__ xmx, float* __restrict__ out_xlast){
  int e8 = (blockIdx.x*256 + threadIdx.x) * 8;
  int row = e8 >> 11, col = e8 & 2047;
  int t = row & 4095, b = row >> 12;
  const float* xp = x + (size_t)row*2048 + col;
  const float* pp = t ? (x + (size_t)(row-1)*2048 + col) : (shift + (size_t)b*2048 + col);
  float xf[8], pf[8], mf[8], of[8];
  *(float4*)(xf)   = *(const float4*)(xp);
  *(float4*)(xf+4) = *(const float4*)(xp+4);
  *(float4*)(pf)   = *(const float4*)(pp);
  *(float4*)(pf+4) = *(const float4*)(pp+4);
  *(float4*)(mf)   = *(const float4*)(maax + col);
  *(float4*)(mf+4) = *(const float4*)(maax + col + 4);
  #pragma unroll
  for (int j=0;j<8;j++) of[j] = xf[j] + (pf[j]-xf[j])*mf[j];
  *(uint4*)(xmx + (size_t)row*2048 + col) = pk8(of);
  if (t == 4095){
    *(float4*)(out_xlast + (size_t)b*2048 + col)     = *(const float4*)(xf);
    *(float4*)(out_xlast + (size_t)b*2048 + col + 4) = *(const float4*)(xf+4);
  }
}

// ---------------------------------------------------------------- generic GEMM with fused epilogues
// C[M,N] = A[M,K] @ B[K,N], A/Bt bf16, Bt[N][K] (row stride ldb).
enum { EPI_STORE=0, EPI_TANH=1, EPI_SILU=2, EPI_LERP=3, EPI_ICLR=5, EPI_STORE32=6 };

template<int EPI>
__global__ __launch_bounds__(256) void gemm_k(
    const u16* __restrict__ A, int lda,
    const u16* __restrict__ Bt, int ldb,
    u16* __restrict__ Cout, float* __restrict__ Cout32, int ldc,
    int M, int N, int K,
    const float* __restrict__ e_x, const float* __restrict__ e_shift, const float* __restrict__ e_vec)
{
  __shared__ u16 As[128][40];  // +8 pad: conflict-free ds_read_b128
  __shared__ u16 Bs[128][40];
  const int tid = threadIdx.x;
  const int lane = tid & 63, wid = tid >> 6;
  const int m0 = blockIdx.x * 128, n0 = blockIdx.y * 128;
  const int wrow = (wid >> 1) * 64, wcol = (wid & 1) * 64;
  const int fr = lane & 15, kg = lane >> 4;
  const int r_c0 = tid >> 2, r_seg = tid & 3;
  const int r_c1 = r_c0 + 64;

  f32x4 acc[4][4];
  #pragma unroll
  for (int m=0;m<4;m++)
    #pragma unroll
    for (int n=0;n<4;n++) acc[m][n] = ZF4;

  for (int k0 = 0; k0 < K; k0 += 32) {
    __syncthreads();
    {
      uint4 av0 = *(const uint4*)(A + (size_t)(m0 + r_c0)*lda + k0 + r_seg*8);
      uint4 av1 = *(const uint4*)(A + (size_t)(m0 + r_c1)*lda + k0 + r_seg*8);
      *(uint4*)(&As[r_c0][r_seg*8]) = av0;
      *(uint4*)(&As[r_c1][r_seg*8]) = av1;
      uint4 z = make_uint4(0,0,0,0);
      uint4 bv0 = (n0 + r_c0 < N) ? *(const uint4*)(Bt + (size_t)(n0 + r_c0)*ldb + k0 + r_seg*8) : z;
      uint4 bv1 = (n0 + r_c1 < N) ? *(const uint4*)(Bt + (size_t)(n0 + r_c1)*ldb + k0 + r_seg*8) : z;
      *(uint4*)(&Bs[r_c0][r_seg*8]) = bv0;
      *(uint4*)(&Bs[r_c1][r_seg*8]) = bv1;
    }
    __syncthreads();
    s16x8 a[4], bb[4];
    #pragma unroll
    for (int m=0;m<4;m++) a[m] = *(const s16x8*)(&As[wrow + m*16 + fr][kg*8]);
    #pragma unroll
    for (int n=0;n<4;n++) bb[n] = *(const s16x8*)(&Bs[wcol + n*16 + fr][kg*8]);
    #pragma unroll
    for (int m=0;m<4;m++)
      #pragma unroll
      for (int n=0;n<4;n++)
        acc[m][n] = __builtin_amdgcn_mfma_f32_16x16x32_bf16(a[m], bb[n], acc[m][n], 0,0,0);
  }
  #pragma unroll
  for (int n=0;n<4;n++){
    int ccol = n0 + wcol + n*16 + fr;
    if (ccol >= N) continue;
    #pragma unroll
    for (int m=0;m<4;m++){
      #pragma unroll
      for (int q=0;q<4;q++){
        int row = m0 + wrow + m*16 + kg*4 + q;
        float v = acc[m][n][q];
        size_t oidx = (size_t)row*ldc + ccol;
        if constexpr (EPI == EPI_STORE) Cout[oidx] = f2b(v);
        else if constexpr (EPI == EPI_STORE32) Cout32[oidx] = v;
        else if constexpr (EPI == EPI_TANH) Cout[oidx] = f2b(tanhf(v));
        else if constexpr (EPI == EPI_SILU) Cout[oidx] = f2b(v / (1.f + expf(-v)));
        else if constexpr (EPI == EPI_LERP){
          float xv = e_x[(size_t)row*2048 + ccol];
          int t = row & 4095;
          float pv = t ? e_x[(size_t)(row-1)*2048 + ccol]
                       : e_shift[(size_t)(row >> 12)*2048 + ccol];
          Cout[oidx] = f2b(xv + (pv - xv) * (e_vec[ccol] + v));
        }
        else if constexpr (EPI == EPI_ICLR) Cout[oidx] = f2b(1.f / (1.f + expf(-(e_vec[ccol] + v))));
      }
    }
  }
}

// ---------------------------------------------------------------- WKV phase 1: per chunk-head
// Fused: wlog mini-gemm (t2 @ dw2 slice, -exp), kk-normalize, ICLR k-adjust.
__global__ __launch_bounds__(256, 1) void wkv1_k(
    const u16* __restrict__ r_g, const u16* __restrict__ kraw_g, const u16* __restrict__ v_g,
    const u16* __restrict__ ic_g,
    const u16* __restrict__ t2_g, const u16* __restrict__ dw2t_g, const float* __restrict__ td_g,
    const float* __restrict__ u_g, const float* __restrict__ kkk_g, const float* __restrict__ kka_g,
    u16* __restrict__ y1_g, u16* __restrict__ rw_g,
    u16* __restrict__ kvab_g, float* __restrict__ wsA_g)
{
  // LDS arena, 161792 B. Slot lifetimes (overlays always cross a __syncthreads):
  //  [0,34816)       WL f32[128][64]   -> (P3+) Abuf u16[128][136]
  //  [34816,69632)   WC f32[128][64]   -> (P4b+) kkcT u16[128][136]; tail [67584,69632): diag/offs/wsum/u/kkk/kka/td
  //  [69632,88064)   rd u16[128][72]   <- (P0: t2 stage) -> (P5a+) vT u16[64][136]
  //  [88064,106496)  ki u16[128][72]   <- (P0: dw2 stage) -> (P4a+) kkw u16[128][72]
  //  [106496,124928) kw ; [124928,143360) ka ; [143360,161792) kkb
  __shared__ __align__(16) char arena[161792];
  float* WL   = (float*)(arena);
  float* WC   = (float*)(arena + 34816);
  u16* Abuf   = (u16*)(arena);
  u16* kkcT   = (u16*)(arena + 34816);
  u16* rd_l   = (u16*)(arena + 69632);
  u16* vT_l   = (u16*)(arena + 69632);
  u16* ki_l   = (u16*)(arena + 88064);
  u16* kkw_l  = (u16*)(arena + 88064);
  u16* kw_l   = (u16*)(arena + 106496);
  u16* ka_l   = (u16*)(arena + 124928);
  u16* kkb_l  = (u16*)(arena + 143360);
  float* diag_l = (float*)(arena + 67584);  // 128
  float* offs_l = diag_l + 128;             // 64
  float* wsum_l = offs_l + 64;              // 64
  float* u_l    = wsum_l + 64;              // 64
  float* kkk_l  = u_l + 64;                 // 64
  float* kka_l  = kkk_l + 64;               // 64
  float* td_l   = kka_l + 64;               // 64 -> ends at 69632 exactly

  const int tid = threadIdx.x, lane = tid & 63, wid = tid >> 6;
  const int cb = blockIdx.x;
  const int c = cb >> 6, b = (cb >> 5) & 1, h = cb & 31;
  const size_t base = ((size_t)(b*4096 + c*128)) * 2048 + h*64;
  const int fr = lane & 15, kg = lane >> 4;

  // P0a: stage t2 chunk [128][64] and dw2t head-slice [64][64]; per-head vectors (f32 inputs)
  {
    int t = tid >> 1, jh = (tid & 1) * 32;
    const u16* t2s = t2_g + (size_t)(b*4096 + c*128 + t)*64 + jh;
    #pragma unroll
    for (int j=0;j<4;j++) *(uint4*)(&rd_l[t*72 + jh + j*8]) = *(const uint4*)(t2s + j*8);
    int n = tid >> 2, sg2 = (tid & 3) * 8;
    const u16* dws = dw2t_g + (size_t)(h*64 + n)*64;
    *(uint4*)(&ki_l[n*72 + sg2])      = *(const uint4*)(dws + sg2);
    *(uint4*)(&ki_l[n*72 + 32 + sg2]) = *(const uint4*)(dws + 32 + sg2);
  }
  if (tid < 64){
    u_l[tid]   = u_g[h*64 + tid];
    kkk_l[tid] = kkk_g[h*64 + tid];
    kka_l[tid] = kka_g[h*64 + tid];
    td_l[tid]  = td_g[h*64 + tid];
  }
  __syncthreads();
  // P0b: WL[t][k] = -exp(td[k] + t2[t,:] . dw2[:,k])   (mini-MFMA 128x64x64)
  {
    f32x4 accW[2][4];
    #pragma unroll
    for (int m=0;m<2;m++)
      #pragma unroll
      for (int n=0;n<4;n++) accW[m][n] = ZF4;
    #pragma unroll
    for (int ks=0; ks<2; ++ks){
      s16x8 af0 = *(const s16x8*)(&rd_l[(wid*32 + fr)*72 + ks*32 + kg*8]);
      s16x8 af1 = *(const s16x8*)(&rd_l[(wid*32 + 16 + fr)*72 + ks*32 + kg*8]);
      #pragma unroll
      for (int n=0;n<4;n++){
        s16x8 bf = *(const s16x8*)(&ki_l[(n*16 + fr)*72 + ks*32 + kg*8]);
        accW[0][n] = __builtin_amdgcn_mfma_f32_16x16x32_bf16(af0, bf, accW[0][n], 0,0,0);
        accW[1][n] = __builtin_amdgcn_mfma_f32_16x16x32_bf16(af1, bf, accW[1][n], 0,0,0);
      }
    }
    #pragma unroll
    for (int m=0;m<2;m++)
      #pragma unroll
      for (int n=0;n<4;n++)
        #pragma unroll
        for (int q=0;q<4;q++){
          int t = wid*32 + m*16 + kg*4 + q;
          int s = n*16 + fr;
          WL[t*64 + s] = -expf(td_l[s] + accW[m][n][q]);
        }
  }
  __syncthreads();
  // scan: inclusive cumsum over t per column k
  for (int j=0;j<16;j++){
    int k = wid*16 + j;
    float v = WL[lane*64 + k];
    #pragma unroll
    for (int d=1; d<64; d<<=1){ float o = __shfl_up(v, d); if (lane >= d) v += o; }
    WC[lane*64 + k] = v;
    float carry = __shfl(v, 63);
    float v2 = WL[(64+lane)*64 + k];
    #pragma unroll
    for (int d=1; d<64; d<<=1){ float o = __shfl_up(v2, d); if (lane >= d) v2 += o; }
    v2 += carry;
    WC[(64+lane)*64 + k] = v2;
    float tot = __shfl(v2, 63);
    if (lane == 0){ offs_l[k] = carry; wsum_l[k] = tot; wsA_g[(size_t)cb*64 + k] = expf(tot); }
  }
  __syncthreads();
  // P1: r, kadj -> rd, ki, kw (LDS), rw (global), diag
  {
    int t = tid >> 1, kh = (tid & 1) * 32;
    const u16* rs  = r_g    + base + (size_t)t*2048 + kh;
    const u16* ks_ = kraw_g + base + (size_t)t*2048 + kh;
    const u16* is_ = ic_g   + base + (size_t)t*2048 + kh;
    float dpart = 0.f;
    #pragma unroll
    for (int j=0;j<4;j++){
      float rf[8], kf[8], icf[8], rdf[8], kif[8], rwf[8], kwf[8];
      up8(*(const uint4*)(rs + j*8), rf);
      up8(*(const uint4*)(ks_ + j*8), kf);
      up8(*(const uint4*)(is_ + j*8), icf);
      #pragma unroll
      for (int e=0;e<8;e++){
        int k = kh + j*8 + e;
        float kadj = kf[e] * (1.f + (icf[e] - 1.f) * kka_l[k]);
        float wl = WL[t*64+k], wc = WC[t*64+k];
        float wcs = wc - wl;
        float off = offs_l[k], wsm = wsum_l[k];
        rdf[e] = rf[e] * expf(clip30(wcs - off));
        kif[e] = kadj  * expf(clip30(off - wc));
        rwf[e] = rf[e] * expf(clip30(wcs));
        kwf[e] = kadj  * expf(clip30(wsm - wc));
        dpart += rf[e] * u_l[k] * kadj;
      }
      *(uint4*)(&rd_l[t*72 + kh + j*8]) = pk8(rdf);
      *(uint4*)(&ki_l[t*72 + kh + j*8]) = pk8(kif);
      *(uint4*)(&kw_l[t*72 + kh + j*8]) = pk8(kwf);
      *(uint4*)(rw_g + base + (size_t)t*2048 + kh + j*8) = pk8(rwf);
    }
    dpart += __shfl_xor(dpart, 1);
    if ((tid & 1) == 0) diag_l[t] = dpart;
  }
  __syncthreads();
  // P2: raw k, iclr -> kk (normalized), ka = kk*iclr, kkb = kk
  {
    int t = tid >> 1, kh = (tid & 1) * 32;
    const u16* ks_ = kraw_g + base + (size_t)t*2048 + kh;
    const u16* is_ = ic_g   + base + (size_t)t*2048 + kh;
    float kf[32], icf[32], kkraw[32];
    #pragma unroll
    for (int j=0;j<4;j++){
      up8(*(const uint4*)(ks_ + j*8), kf + j*8);
      up8(*(const uint4*)(is_ + j*8), icf + j*8);
    }
    float ss = 0.f;
    #pragma unroll
    for (int e=0;e<32;e++){ kkraw[e] = kf[e]*kkk_l[kh+e]; ss += kkraw[e]*kkraw[e]; }
    ss += __shfl_xor(ss, 1);
    float rn = 1.f / fmaxf(sqrtf(ss), 1e-12f);
    #pragma unroll
    for (int j=0;j<4;j++){
      float kkb8[8], ka8[8];
      #pragma unroll
      for (int e=0;e<8;e++){
        float kkv = kkraw[j*8+e]*rn;
        kkb8[e] = kkv; ka8[e] = kkv*icf[j*8+e];
      }
      *(uint4*)(&kkb_l[t*72 + kh + j*8]) = pk8(kkb8);
      *(uint4*)(&ka_l [t*72 + kh + j*8]) = pk8(ka8);
    }
  }
  __syncthreads();
  // P3: A = rd @ ki^T, mask strict-lower + diag, keep in regs + write Abuf
  f32x4 accA[2][8];
  #pragma unroll
  for (int m=0;m<2;m++)
    #pragma unroll
    for (int n=0;n<8;n++) accA[m][n] = ZF4;
  #pragma unroll
  for (int ks=0; ks<2; ++ks){
    s16x8 af0 = *(const s16x8*)(&rd_l[(wid*32 + fr)*72 + ks*32 + kg*8]);
    s16x8 af1 = *(const s16x8*)(&rd_l[(wid*32 + 16 + fr)*72 + ks*32 + kg*8]);
    #pragma unroll
    for (int n=0;n<8;n++){
      s16x8 bf = *(const s16x8*)(&ki_l[(n*16 + fr)*72 + ks*32 + kg*8]);
      accA[0][n] = __builtin_amdgcn_mfma_f32_16x16x32_bf16(af0, bf, accA[0][n], 0,0,0);
      accA[1][n] = __builtin_amdgcn_mfma_f32_16x16x32_bf16(af1, bf, accA[1][n], 0,0,0);
    }
  }
  #pragma unroll
  for (int m=0;m<2;m++)
    #pragma unroll
    for (int n=0;n<8;n++)
      #pragma unroll
      for (int q=0;q<4;q++){
        int t = wid*32 + m*16 + kg*4 + q;
        int s = n*16 + fr;
        float v = accA[m][n][q];
        v = (t > s) ? v : ((t == s) ? diag_l[t] : 0.f);
        accA[m][n][q] = v;
        Abuf[t*136 + s] = f2b(v);
      }
  __syncthreads();
  // P4a: kkw = -kk * w_inter (into old ki slot)
  {
    int t = tid >> 1, kh = (tid & 1)*32;
    #pragma unroll
    for (int j=0;j<4;j++){
      float kkf[8], kwf[8];
      up8(*(const uint4*)(&kkb_l[t*72 + kh + j*8]), kkf);
      #pragma unroll
      for (int e=0;e<8;e++){
        int k = kh + j*8 + e;
        kwf[e] = -kkf[e] * expf(clip30(wsum_l[k] - WC[t*64+k]));
      }
      *(uint4*)(&kkw_l[t*72 + kh + j*8]) = pk8(kwf);
    }
  }
  __syncthreads();
  // P4b: kk_corr = ka @ kkb^T, strict-lower, write transposed kkcT[s][t]
  {
    f32x4 accC[2][8];
    #pragma unroll
    for (int m=0;m<2;m++)
      #pragma unroll
      for (int n=0;n<8;n++) accC[m][n] = ZF4;
    #pragma unroll
    for (int ks=0; ks<2; ++ks){
      s16x8 af0 = *(const s16x8*)(&ka_l[(wid*32 + fr)*72 + ks*32 + kg*8]);
      s16x8 af1 = *(const s16x8*)(&ka_l[(wid*32 + 16 + fr)*72 + ks*32 + kg*8]);
      #pragma unroll
      for (int n=0;n<8;n++){
        s16x8 bf = *(const s16x8*)(&kkb_l[(n*16 + fr)*72 + ks*32 + kg*8]);
        accC[0][n] = __builtin_amdgcn_mfma_f32_16x16x32_bf16(af0, bf, accC[0][n], 0,0,0);
        accC[1][n] = __builtin_amdgcn_mfma_f32_16x16x32_bf16(af1, bf, accC[1][n], 0,0,0);
      }
    }
    #pragma unroll
    for (int m=0;m<2;m++)
      #pragma unroll
      for (int n=0;n<8;n++)
        #pragma unroll
        for (int q=0;q<4;q++){
          int t = wid*32 + m*16 + kg*4 + q;
          int s = n*16 + fr;
          kkcT[s*136 + t] = f2b((t > s) ? accC[m][n][q] : 0.f);
        }
  }
  __syncthreads();
  // P5a: stage v transposed (vT[vd][t], into old rd slot)
  {
    int t = tid >> 1, vh = (tid & 1)*32;
    const u16* vs = v_g + base + (size_t)t*2048 + vh;
    #pragma unroll
    for (int j=0;j<4;j++){
      u16 el[8]; unp16(*(const uint4*)(vs + j*8), el);
      #pragma unroll
      for (int e=0;e<8;e++) vT_l[(vh + j*8 + e)*136 + t] = el[e];
    }
  }
  // P5b: P = Amask @ kkc ; A_total = Amask - tril(P) -> Abuf (own strip, in place)
  {
    f32x4 accP[2][8];
    #pragma unroll
    for (int m=0;m<2;m++)
      #pragma unroll
      for (int n=0;n<8;n++) accP[m][n] = ZF4;
    #pragma unroll
    for (int ks=0; ks<4; ++ks){
      s16x8 af0 = *(const s16x8*)(&Abuf[(wid*32 + fr)*136 + ks*32 + kg*8]);
      s16x8 af1 = *(const s16x8*)(&Abuf[(wid*32 + 16 + fr)*136 + ks*32 + kg*8]);
      #pragma unroll
      for (int n=0;n<8;n++){
        s16x8 bf = *(const s16x8*)(&kkcT[(n*16 + fr)*136 + ks*32 + kg*8]);
        accP[0][n] = __builtin_amdgcn_mfma_f32_16x16x32_bf16(af0, bf, accP[0][n], 0,0,0);
        accP[1][n] = __builtin_amdgcn_mfma_f32_16x16x32_bf16(af1, bf, accP[1][n], 0,0,0);
      }
    }
    #pragma unroll
    for (int m=0;m<2;m++)
      #pragma unroll
      for (int n=0;n<8;n++)
        #pragma unroll
        for (int q=0;q<4;q++){
          int t = wid*32 + m*16 + kg*4 + q;
          int s = n*16 + fr;
          float v = accA[m][n][q] - ((t >= s) ? accP[m][n][q] : 0.f);
          Abuf[t*136 + s] = f2b(v);
        }
  }
  __syncthreads();
  // P6: y_intra = A_total @ v  (write y1 global — own block's region only)
  {
    f32x4 accY[2][4];
    #pragma unroll
    for (int m=0;m<2;m++)
      #pragma unroll
      for (int n=0;n<4;n++) accY[m][n] = ZF4;
    #pragma unroll
    for (int ks=0; ks<4; ++ks){
      s16x8 af0 = *(const s16x8*)(&Abuf[(wid*32 + fr)*136 + ks*32 + kg*8]);
      s16x8 af1 = *(const s16x8*)(&Abuf[(wid*32 + 16 + fr)*136 + ks*32 + kg*8]);
      #pragma unroll
      for (int n=0;n<4;n++){
        s16x8 bf = *(const s16x8*)(&vT_l[(n*16 + fr)*136 + ks*32 + kg*8]);
        accY[0][n] = __builtin_amdgcn_mfma_f32_16x16x32_bf16(af0, bf, accY[0][n], 0,0,0);
        accY[1][n] = __builtin_amdgcn_mfma_f32_16x16x32_bf16(af1, bf, accY[1][n], 0,0,0);
      }
    }
    #pragma unroll
    for (int m=0;m<2;m++)
      #pragma unroll
      for (int n=0;n<4;n++)
        #pragma unroll
        for (int q=0;q<4;q++){
          int t = wid*32 + m*16 + kg*4 + q;
          int vd = n*16 + fr;
          y1_g[base + (size_t)t*2048 + vd] = f2b(accY[m][n][q]);
        }
  }
  // P7: kv / ab (VALU)
  {
    int kf = tid >> 2, sg = (tid & 3) * 16;
    float akv[16], aab[16];
    #pragma unroll
    for (int j=0;j<16;j++){ akv[j]=0.f; aab[j]=0.f; }
    for (int tt=0; tt<128; ++tt){
      float kwv  = b2f(kw_l[tt*72 + kf]);
      float kkwv = b2f(kkw_l[tt*72 + kf]);
      #pragma unroll
      for (int j=0;j<16;j++){
        akv[j] += kwv  * b2f(vT_l[(sg+j)*136 + tt]);
        aab[j] += kkwv * b2f(ka_l[tt*72 + sg + j]);
      }
    }
    u16* kvp = kvab_g + (size_t)cb*8192;   // [kv: 4096 u16][ab: 4096 u16]
    #pragma unroll
    for (int j=0;j<16;j++) kvp[kf*64 + sg + j] = f2b(akv[j]);
    #pragma unroll
    for (int j=0;j<16;j++) kvp[4096 + kf*64 + sg + j] = f2b(aab[j]);
  }
}

// ---------------------------------------------------------------- WKV phase 2: sequential state scan per (b,h)
__global__ __launch_bounds__(256) void wkv2_k(
   const float* __restrict__ state_in, u16* __restrict__ kvab_g,
   const float* __restrict__ wsA_g, float* __restrict__ out_state)
{
  __shared__ float S_l[64][65];
  __shared__ float ab_l[64][64];
  int tid = threadIdx.x;
  int bh = blockIdx.x; int b = bh >> 5, h = bh & 31;
  int kf = tid >> 2, sg = (tid & 3) * 16;
  #pragma unroll
  for (int j=0;j<16;j++)
    S_l[kf][sg+j] = state_in[((size_t)bh*64 + kf)*64 + sg + j];
  __syncthreads();
  for (int c=0;c<32;c++){
    int cb = (c*2 + b)*32 + h;
    u16* kvp = kvab_g + (size_t)cb*8192;
    float kvv[16], wsv[16];
    #pragma unroll
    for (int j=0;j<16;j++){
      kvv[j] = b2f(kvp[kf*64 + sg + j]);
      wsv[j] = wsA_g[(size_t)cb*64 + sg + j];
    }
    #pragma unroll
    for (int j=0;j<16;j++){
      int flat = tid*16 + j;
      ab_l[flat>>6][flat&63] = b2f(kvp[4096 + flat]);
    }
    __syncthreads();
    // overwrite kv/ab region with entry-state S_in (f32) for phase 3
    float* sip = (float*)(kvab_g + (size_t)cb*8192);
    #pragma unroll
    for (int j=0;j<16;j++) sip[kf*64 + sg + j] = S_l[kf][sg+j];
    float acc[16];
    #pragma unroll
    for (int j=0;j<16;j++) acc[j] = 0.f;
    for (int jj=0;jj<64;jj++){
      float sv = S_l[kf][jj];
      #pragma unroll
      for (int j=0;j<16;j++) acc[j] += sv * ab_l[jj][sg+j];
    }
    float nv[16];
    #pragma unroll
    for (int j=0;j<16;j++) nv[j] = S_l[kf][sg+j]*wsv[j] + acc[j] + kvv[j];
    __syncthreads();
    #pragma unroll
    for (int j=0;j<16;j++) S_l[kf][sg+j] = nv[j];
    __syncthreads();
  }
  #pragma unroll
  for (int j=0;j<16;j++)
    out_state[((size_t)bh*64 + kf)*64 + sg + j] = S_l[kf][sg+j];
}

// ---------------------------------------------------------------- WKV phase 3: y = y1 + rw@S_in, GroupNorm, *g
__global__ __launch_bounds__(256) void wkv3_k(
   const u16* __restrict__ y1_g, const u16* __restrict__ rw_g,
   const u16* __restrict__ kvab_g,
   const u16* __restrict__ g_g, const float* __restrict__ gnw, const float* __restrict__ gnb,
   u16* __restrict__ yf_g)
{
  __shared__ float S_l[64][65];
  __shared__ u16 rw_l[128][72];
  int tid = threadIdx.x;
  int cb = blockIdx.x; int c = cb>>6, b = (cb>>5)&1, h = cb&31;
  size_t base = ((size_t)(b*4096 + c*128))*2048 + h*64;
  const float* sip = (const float*)(kvab_g + (size_t)cb*8192);
  #pragma unroll
  for (int j=0;j<16;j++){ int flat = tid*16+j; S_l[flat>>6][flat&63] = sip[flat]; }
  {
    int t = tid>>1, kh = (tid&1)*32;
    const u16* rs = rw_g + base + (size_t)t*2048 + kh;
    #pragma unroll
    for (int j=0;j<4;j++) *(uint4*)(&rw_l[t][kh+j*8]) = *(const uint4*)(rs + j*8);
  }
  __syncthreads();
  int t = tid>>1, vh = (tid&1)*32;
  float acc[32];
  #pragma unroll
  for (int j=0;j<32;j++) acc[j] = 0.f;
  for (int kf2=0; kf2<64; kf2++){
    float rv = b2f(rw_l[t][kf2]);
    #pragma unroll
    for (int j=0;j<32;j++) acc[j] += rv * S_l[kf2][vh+j];
  }
  float sum=0.f, sq=0.f;
  float yv[32];
  #pragma unroll
  for (int j=0;j<32;j++){
    yv[j] = acc[j] + b2f(y1_g[base + (size_t)t*2048 + vh + j]);
    sum += yv[j]; sq += yv[j]*yv[j];
  }
  sum += __shfl_xor(sum, 1); sq += __shfl_xor(sq, 1);
  float mean = sum * (1.f/64.f);
  float var = sq * (1.f/64.f) - mean*mean;
  float rstd = rsqrtf(fmaxf(var, 0.f) + 6.4e-4f);
  size_t bt = (size_t)(b*4096 + c*128 + t);
  #pragma unroll
  for (int j=0;j<32;j++){
    int ch = h*64 + vh + j;
    float val = (yv[j]-mean)*rstd * gnw[ch] + gnb[ch];
    val *= b2f(g_g[bt*2048 + ch]);
    yf_g[base + (size_t)t*2048 + vh + j] = f2b(val);
  }
}

// ---------------------------------------------------------------- host
// ws layout (bytes), peak 252444672 (~241 MB)
#define O_WTR   0ull              /* 4x8MB big-W transposed; rw reuses [0,32MB) */
#define O_WTK   8388608ull
#define O_WTV   16777216ull
#define O_WTG   25165824ull
#define O_WTO   33554432ull       /* 8MB, persists to final gemm */
#define O_W1T   41943040ull
#define O_W2T   42729472ull
#define O_DW1T  43515904ull
#define O_DW2T  43778048ull
#define O_A1T   44040192ull
#define O_A2T   44433408ull
#define O_XXX   44826624ull       /* 3MB */
#define O_T2    47972352ull       /* 1MB */
#define O_T3    49020928ull       /* 1.5MB */
#define O_WSA   50593792ull       /* 0.5MB f32 */
#define O_XMX   51118080ull       /* 32MB: xmx -> g */
#define O_A     84672512ull       /* 32MB: lerp staging -> kvab/S_in */
#define O_I     118226944ull      /* 32MB: iclr */
#define O_R     151781376ull      /* 32MB: r */
#define O_K     185335808ull      /* 32MB: raw k -> y1 -> yf */
#define O_V     218890240ull      /* 32MB: v */
#define WS_NEEDED 252444672ull

extern "C" void kernel_launch(void* const* d_in, const int* in_sizes, int n_in,
                              void* d_out, int out_size, void* d_ws, size_t ws_size,
                              hipStream_t stream)
{
  (void)in_sizes; (void)n_in; (void)out_size;
  if (ws_size < WS_NEEDED) return;  // diagnostic: leaves d_out zeroed -> absmax == max|ref|
  const float* x     = (const float*)d_in[0];
  const float* shift = (const float*)d_in[1];
  const float* st_in = (const float*)d_in[2];
  const float* maax  = (const float*)d_in[3];
  const float* maas[6] = {(const float*)d_in[4],(const float*)d_in[5],(const float*)d_in[6],
                          (const float*)d_in[7],(const float*)d_in[8],(const float*)d_in[9]};
  const float* w1    = (const float*)d_in[10];
  const float* w2    = (const float*)d_in[11];
  const float* td    = (const float*)d_in[12];
  const float* dw1   = (const float*)d_in[13];
  const float* dw2   = (const float*)d_in[14];
  const float* faaaa = (const float*)d_in[15];
  const float* a0v   = (const float*)d_in[16];
  const float* a1w   = (const float*)d_in[17];
  const float* a2w   = (const float*)d_in[18];
  const float* kkk   = (const float*)d_in[19];
  const float* kka   = (const float*)d_in[20];
  const float* Wr    = (const float*)d_in[21];
  const float* Wk    = (const float*)d_in[22];
  const float* Wv    = (const float*)d_in[23];
  const float* Wg    = (const float*)d_in[24];
  const float* Wo    = (const float*)d_in[25];
  const float* gnw   = (const float*)d_in[26];
  const float* gnb   = (const float*)d_in[27];
  float* out = (float*)d_out;
  char* ws = (char*)d_ws;
  #define WSP(o) ((u16*)(ws + (o)))

  u16 *wtR=WSP(O_WTR), *wtK=WSP(O_WTK), *wtV=WSP(O_WTV), *wtG=WSP(O_WTG), *wtO=WSP(O_WTO);
  u16 *w1t=WSP(O_W1T), *w2t=WSP(O_W2T), *dw1t=WSP(O_DW1T), *dw2t=WSP(O_DW2T), *a1t=WSP(O_A1T), *a2t=WSP(O_A2T);
  u16 *xxx=WSP(O_XXX), *t2b=WSP(O_T2), *t3b=WSP(O_T3);
  u16 *xmx=WSP(O_XMX), *Ab=WSP(O_A), *Ib=WSP(O_I), *Rb=WSP(O_R), *Kb=WSP(O_K), *Vb=WSP(O_V);
  u16 *rw = WSP(O_WTR);       // reuses dead big-W region
  u16 *kvab = WSP(O_A);       // reuses dead staging region
  u16 *gbuf = WSP(O_XMX);     // reuses dead xmx region
  float* wsA = (float*)(ws + O_WSA);
  float* out_xlast = out + 16777216;
  float* out_state = out + 16781312;

  dim3 tb(32,8);
  transpose_k<<<dim3(64,64), tb, 0, stream>>>(Wr, wtR, 2048, 2048);
  transpose_k<<<dim3(64,64), tb, 0, stream>>>(Wk, wtK, 2048, 2048);
  transpose_k<<<dim3(64,64), tb, 0, stream>>>(Wv, wtV, 2048, 2048);
  transpose_k<<<dim3(64,64), tb, 0, stream>>>(Wg, wtG, 2048, 2048);
  transpose_k<<<dim3(64,64), tb, 0, stream>>>(Wo, wtO, 2048, 2048);
  transpose_k<<<dim3(6,64),  tb, 0, stream>>>(w1, w1t, 2048, 192);
  transpose_k<<<dim3(64,6),  tb, 0, stream>>>(w2, w2t, 192, 2048);
  transpose_k<<<dim3(2,64),  tb, 0, stream>>>(dw1, dw1t, 2048, 64);
  transpose_k<<<dim3(64,2),  tb, 0, stream>>>(dw2, dw2t, 64, 2048);
  transpose_k<<<dim3(3,64),  tb, 0, stream>>>(a1w, a1t, 2048, 96);
  transpose_k<<<dim3(64,3),  tb, 0, stream>>>(a2w, a2t, 96, 2048);

  prep_k<<<8192, 256, 0, stream>>>(x, shift, maax, xmx, out_xlast);

  // xxx = tanh(xmx @ w1)
  gemm_k<EPI_TANH><<<dim3(64,2), 256, 0, stream>>>(xmx, 2048, w1t, 2048, xxx, nullptr, 192, 8192, 192, 2048, nullptr, nullptr, nullptr);
  // xw -> Ab ; t2 = tanh(xw @ dw1)
  gemm_k<EPI_LERP><<<dim3(64,16), 256, 0, stream>>>(xxx + 0*32, 192, w2t + 0*32, 192, Ab, nullptr, 2048, 8192, 2048, 32, x, shift, maas[0]);
  gemm_k<EPI_TANH><<<dim3(64,1), 256, 0, stream>>>(Ab, 2048, dw1t, 2048, t2b, nullptr, 64, 8192, 64, 2048, nullptr, nullptr, nullptr);
  // xa -> Ab ; t3 = xa @ a1 ; iclr = sigmoid(a0 + t3 @ a2)
  gemm_k<EPI_LERP><<<dim3(64,16), 256, 0, stream>>>(xxx + 5*32, 192, w2t + 5*32, 192, Ab, nullptr, 2048, 8192, 2048, 32, x, shift, maas[5]);
  gemm_k<EPI_STORE><<<dim3(64,1), 256, 0, stream>>>(Ab, 2048, a1t, 2048, t3b, nullptr, 96, 8192, 96, 2048, nullptr, nullptr, nullptr);
  gemm_k<EPI_ICLR><<<dim3(64,16), 256, 0, stream>>>(t3b, 96, a2t, 96, Ib, nullptr, 2048, 8192, 2048, 96, nullptr, nullptr, a0v);
  // xr -> Ab ; r = xr @ Wr
  gemm_k<EPI_LERP><<<dim3(64,16), 256, 0, stream>>>(xxx + 3*32, 192, w2t + 3*32, 192, Ab, nullptr, 2048, 8192, 2048, 32, x, shift, maas[3]);
  gemm_k<EPI_STORE><<<dim3(64,16), 256, 0, stream>>>(Ab, 2048, wtR, 2048, Rb, nullptr, 2048, 8192, 2048, 2048, nullptr, nullptr, nullptr);
  // xk -> Ab ; k(raw) = xk @ Wk
  gemm_k<EPI_LERP><<<dim3(64,16), 256, 0, stream>>>(xxx + 1*32, 192, w2t + 1*32, 192, Ab, nullptr, 2048, 8192, 2048, 32, x, shift, maas[1]);
  gemm_k<EPI_STORE><<<dim3(64,16), 256, 0, stream>>>(Ab, 2048, wtK, 2048, Kb, nullptr, 2048, 8192, 2048, 2048, nullptr, nullptr, nullptr);
  // xv -> Ab ; v = xv @ Wv
  gemm_k<EPI_LERP><<<dim3(64,16), 256, 0, stream>>>(xxx + 2*32, 192, w2t + 2*32, 192, Ab, nullptr, 2048, 8192, 2048, 32, x, shift, maas[2]);
  gemm_k<EPI_STORE><<<dim3(64,16), 256, 0, stream>>>(Ab, 2048, wtV, 2048, Vb, nullptr, 2048, 8192, 2048, 2048, nullptr, nullptr, nullptr);
  // xg -> Ab ; g = silu(xg @ Wg)  -> xmx region
  gemm_k<EPI_LERP><<<dim3(64,16), 256, 0, stream>>>(xxx + 4*32, 192, w2t + 4*32, 192, Ab, nullptr, 2048, 8192, 2048, 32, x, shift, maas[4]);
  gemm_k<EPI_SILU><<<dim3(64,16), 256, 0, stream>>>(Ab, 2048, wtG, 2048, gbuf, nullptr, 2048, 8192, 2048, 2048, nullptr, nullptr, nullptr);
  // wkv (wlog + kk + k-adjust fused into wkv1)
  wkv1_k<<<2048, 256, 0, stream>>>(Rb, Kb, Vb, Ib, t2b, dw2t, td, faaaa, kkk, kka,
                                   Kb /*y1 overwrites raw k*/, rw, kvab, wsA);
  wkv2_k<<<64, 256, 0, stream>>>(st_in, kvab, wsA, out_state);
  wkv3_k<<<2048, 256, 0, stream>>>(Kb /*y1*/, rw, kvab /*S_in*/, gbuf, gnw, gnb, Kb /*yf in place*/);
  // out = yf @ W_o  (f32 store to d_out)
  gemm_k<EPI_STORE32><<<dim3(64,16), 256, 0, stream>>>(Kb, 2048, wtO, 2048, nullptr, out, 2048, 8192, 2048, 2048, nullptr, nullptr, nullptr);
}

// Round 4
// 1869.641 us; speedup vs baseline: 1.1203x; 1.1203x over previous
//
#include <hip/hip_runtime.h>

// RWKV7-delta time-mix. f32 in/out, bf16 intermediates + MFMA bf16 16x16x32.
// B=2 T=4096 C=2048 H=32 K=64 CHUNK=128 NC=32.

typedef unsigned short u16;
typedef unsigned int   u32;
typedef __attribute__((ext_vector_type(8))) short s16x8;
typedef __attribute__((ext_vector_type(4))) float f32x4;

#define DEV __device__ __forceinline__

DEV float b2f(u16 v){ return __uint_as_float(((u32)v) << 16); }
DEV u16 f2b(float f){ u32 u = __float_as_uint(f); return (u16)((u + 0x7fffu + ((u >> 16) & 1u)) >> 16); }
DEV float clip30(float x){ return fminf(fmaxf(x, -30.f), 30.f); }
DEV void up8(uint4 v, float* f){
  f[0]=b2f((u16)(v.x&0xffffu)); f[1]=b2f((u16)(v.x>>16));
  f[2]=b2f((u16)(v.y&0xffffu)); f[3]=b2f((u16)(v.y>>16));
  f[4]=b2f((u16)(v.z&0xffffu)); f[5]=b2f((u16)(v.z>>16));
  f[6]=b2f((u16)(v.w&0xffffu)); f[7]=b2f((u16)(v.w>>16));
}
DEV uint4 pk8(const float* f){
  uint4 v;
  v.x = (u32)f2b(f[0]) | ((u32)f2b(f[1])<<16);
  v.y = (u32)f2b(f[2]) | ((u32)f2b(f[3])<<16);
  v.z = (u32)f2b(f[4]) | ((u32)f2b(f[5])<<16);
  v.w = (u32)f2b(f[6]) | ((u32)f2b(f[7])<<16);
  return v;
}
DEV void unp16(uint4 v, u16* o){
  o[0]=(u16)(v.x&0xffffu); o[1]=(u16)(v.x>>16);
  o[2]=(u16)(v.y&0xffffu); o[3]=(u16)(v.y>>16);
  o[4]=(u16)(v.z&0xffffu); o[5]=(u16)(v.z>>16);
  o[6]=(u16)(v.w&0xffffu); o[7]=(u16)(v.w>>16);
}
DEV void gload16(const u16* g, u16* l){
  __builtin_amdgcn_global_load_lds(
      (const __attribute__((address_space(1))) u32*)g,
      (__attribute__((address_space(3))) u32*)l, 16, 0, 0);
}
#define ZF4 ((f32x4){0.f,0.f,0.f,0.f})

// ---------------------------------------------------------------- transpose f32 -> bf16
__global__ void transpose_k(const float* __restrict__ in, u16* __restrict__ out, int R, int C){
  __shared__ float tile[32][33];
  int c0 = blockIdx.x*32, r0 = blockIdx.y*32;
  int tx = threadIdx.x, ty = threadIdx.y; // (32,8)
  #pragma unroll
  for (int j=0;j<4;j++) tile[ty + j*8][tx] = in[(size_t)(r0 + ty + j*8)*C + c0 + tx];
  __syncthreads();
  #pragma unroll
  for (int j=0;j<4;j++) out[(size_t)(c0 + ty + j*8)*R + r0 + tx] = f2b(tile[tx][ty + j*8]);
}

// ---------------------------------------------------------------- prep: xmx bf16, dxprev bf16, x_last f32
__global__ __launch_bounds__(256) void prep_k(const float* __restrict__ x, const float* __restrict__ shift,
    const float* __restrict__ maax, u16* __restrict__ xmx, u16* __restrict__ dxp, float* __restrict__ out_xlast){
  int e8 = (blockIdx.x*256 + threadIdx.x) * 8;
  int row = e8 >> 11, col = e8 & 2047;
  int t = row & 4095, b = row >> 12;
  const float* xp = x + (size_t)row*2048 + col;
  const float* pp = t ? (x + (size_t)(row-1)*2048 + col) : (shift + (size_t)b*2048 + col);
  float xf[8], pf[8], mf[8], of[8], df[8];
  *(float4*)(xf)   = *(const float4*)(xp);
  *(float4*)(xf+4) = *(const float4*)(xp+4);
  *(float4*)(pf)   = *(const float4*)(pp);
  *(float4*)(pf+4) = *(const float4*)(pp+4);
  *(float4*)(mf)   = *(const float4*)(maax + col);
  *(float4*)(mf+4) = *(const float4*)(maax + col + 4);
  #pragma unroll
  for (int j=0;j<8;j++){ df[j] = pf[j]-xf[j]; of[j] = xf[j] + df[j]*mf[j]; }
  *(uint4*)(xmx + (size_t)row*2048 + col) = pk8(of);
  *(uint4*)(dxp + (size_t)row*2048 + col) = pk8(df);
  if (t == 4095){
    *(float4*)(out_xlast + (size_t)b*2048 + col)     = *(const float4*)(xf);
    *(float4*)(out_xlast + (size_t)b*2048 + col + 4) = *(const float4*)(xf+4);
  }
}

// ---------------------------------------------------------------- generic GEMM with fused epilogues
// C[M,N] = A[M,K] @ B[K,N], Bt[N][K]. ASYNC: global_load_lds path (requires N%128==0, K%32==0, aligned).
enum { EPI_STORE=0, EPI_TANH=1, EPI_SILU=2, EPI_LERP=3, EPI_ICLR=5, EPI_STORE32=6 };

template<int EPI, bool ASYNC>
__global__ __launch_bounds__(256) void gemm_k(
    const u16* __restrict__ A, int lda,
    const u16* __restrict__ Bt, int ldb,
    u16* __restrict__ Cout, float* __restrict__ Cout32, int ldc,
    int M, int N, int K,
    const float* __restrict__ e_x, const u16* __restrict__ e_dxp, const float* __restrict__ e_vec)
{
  constexpr int LDW = ASYNC ? 32 : 40;   // linear for global_load_lds; +8 pad for sync path
  __shared__ u16 As[128][LDW];
  __shared__ u16 Bs[128][LDW];
  const int tid = threadIdx.x;
  const int lane = tid & 63, wid = tid >> 6;
  const int m0 = blockIdx.x * 128, n0 = blockIdx.y * 128;
  const int wrow = (wid >> 1) * 64, wcol = (wid & 1) * 64;
  const int fr = lane & 15, kg = lane >> 4;
  const int r_c0 = tid >> 2, r_seg = tid & 3;
  const int r_c1 = r_c0 + 64;

  f32x4 acc[4][4];
  #pragma unroll
  for (int m=0;m<4;m++)
    #pragma unroll
    for (int n=0;n<4;n++) acc[m][n] = ZF4;

  for (int k0 = 0; k0 < K; k0 += 32) {
    __syncthreads();
    if constexpr (ASYNC) {
      const int w4 = __builtin_amdgcn_readfirstlane(wid);
      const int rr = lane >> 2, seg8 = (lane & 3) * 8;
      #pragma unroll
      for (int i=0;i<2;i++){
        int row = w4*32 + i*16 + rr;
        gload16(A  + (size_t)(m0 + row)*lda + k0 + seg8, &As[w4*32 + i*16][0]);
        gload16(Bt + (size_t)(n0 + row)*ldb + k0 + seg8, &Bs[w4*32 + i*16][0]);
      }
    } else {
      uint4 av0 = *(const uint4*)(A + (size_t)(m0 + r_c0)*lda + k0 + r_seg*8);
      uint4 av1 = *(const uint4*)(A + (size_t)(m0 + r_c1)*lda + k0 + r_seg*8);
      *(uint4*)(&As[r_c0][r_seg*8]) = av0;
      *(uint4*)(&As[r_c1][r_seg*8]) = av1;
      uint4 z = make_uint4(0,0,0,0);
      uint4 bv0 = (n0 + r_c0 < N) ? *(const uint4*)(Bt + (size_t)(n0 + r_c0)*ldb + k0 + r_seg*8) : z;
      uint4 bv1 = (n0 + r_c1 < N) ? *(const uint4*)(Bt + (size_t)(n0 + r_c1)*ldb + k0 + r_seg*8) : z;
      *(uint4*)(&Bs[r_c0][r_seg*8]) = bv0;
      *(uint4*)(&Bs[r_c1][r_seg*8]) = bv1;
    }
    __syncthreads();
    s16x8 a[4], bb[4];
    #pragma unroll
    for (int m=0;m<4;m++) a[m] = *(const s16x8*)(&As[wrow + m*16 + fr][kg*8]);
    #pragma unroll
    for (int n=0;n<4;n++) bb[n] = *(const s16x8*)(&Bs[wcol + n*16 + fr][kg*8]);
    #pragma unroll
    for (int m=0;m<4;m++)
      #pragma unroll
      for (int n=0;n<4;n++)
        acc[m][n] = __builtin_amdgcn_mfma_f32_16x16x32_bf16(a[m], bb[n], acc[m][n], 0,0,0);
  }
  #pragma unroll
  for (int n=0;n<4;n++){
    int ccol = n0 + wcol + n*16 + fr;
    if (ccol >= N) continue;
    #pragma unroll
    for (int m=0;m<4;m++){
      #pragma unroll
      for (int q=0;q<4;q++){
        int row = m0 + wrow + m*16 + kg*4 + q;
        float v = acc[m][n][q];
        size_t oidx = (size_t)row*ldc + ccol;
        if constexpr (EPI == EPI_STORE) Cout[oidx] = f2b(v);
        else if constexpr (EPI == EPI_STORE32) Cout32[oidx] = v;
        else if constexpr (EPI == EPI_TANH) Cout[oidx] = f2b(tanhf(v));
        else if constexpr (EPI == EPI_SILU) Cout[oidx] = f2b(v / (1.f + expf(-v)));
        else if constexpr (EPI == EPI_LERP){
          float xv = e_x[(size_t)row*2048 + ccol];
          float dx = b2f(e_dxp[(size_t)row*2048 + ccol]);
          Cout[oidx] = f2b(xv + dx * (e_vec[ccol] + v));
        }
        else if constexpr (EPI == EPI_ICLR) Cout[oidx] = f2b(1.f / (1.f + expf(-(e_vec[ccol] + v))));
      }
    }
  }
}

// ---------------------------------------------------------------- WKV phase 1: per chunk-head
__global__ __launch_bounds__(256, 1) void wkv1_k(
    const u16* __restrict__ r_g, const u16* __restrict__ kraw_g, const u16* __restrict__ v_g,
    const u16* __restrict__ ic_g,
    const u16* __restrict__ t2_g, const u16* __restrict__ dw2t_g, const float* __restrict__ td_g,
    const float* __restrict__ u_g, const float* __restrict__ kkk_g, const float* __restrict__ kka_g,
    u16* __restrict__ y1_g, u16* __restrict__ rw_g,
    u16* __restrict__ kvab_g, float* __restrict__ wsA_g)
{
  // LDS arena, 161792 B. Slot lifetimes (overlays cross a barrier):
  //  S0 [0,34816)       WL f32[128][64]   -> (P3+) Abuf u16[128][136]
  //  S1 [34816,69632)   WC f32[128][64]   -> (P4b+) kkcT u16[128][136]; tail [67584,69632): diag/offs/wsum/u/kkk/kka/td
  //  S2 [69632,88064)   rd u16[128][72]   <- (P0: t2 stage) -> (P5a+) vT u16[64][136]
  //  S3 [88064,106496)  ki u16[128][72]   <- (P0: dw2 stage) -> (P4a+) kkwT u16[64][136]
  //  S4 [106496,124928) kwT u16[64][136]
  //  S5 [124928,143360) ka u16[128][72]
  //  S6 [143360,161792) kkb u16[128][72]  -> (P5a+) kaT u16[64][136]
  __shared__ __align__(16) char arena[161792];
  float* WL   = (float*)(arena);
  float* WC   = (float*)(arena + 34816);
  u16* Abuf   = (u16*)(arena);
  u16* kkcT   = (u16*)(arena + 34816);
  u16* rd_l   = (u16*)(arena + 69632);
  u16* vT_l   = (u16*)(arena + 69632);
  u16* ki_l   = (u16*)(arena + 88064);
  u16* kkwT_l = (u16*)(arena + 88064);
  u16* kwT_l  = (u16*)(arena + 106496);
  u16* ka_l   = (u16*)(arena + 124928);
  u16* kkb_l  = (u16*)(arena + 143360);
  u16* kaT_l  = (u16*)(arena + 143360);
  float* diag_l = (float*)(arena + 67584);  // 128
  float* offs_l = diag_l + 128;             // 64
  float* wsum_l = offs_l + 64;              // 64
  float* u_l    = wsum_l + 64;              // 64
  float* kkk_l  = u_l + 64;                 // 64
  float* kka_l  = kkk_l + 64;               // 64
  float* td_l   = kka_l + 64;               // 64 -> ends at 69632

  const int tid = threadIdx.x, lane = tid & 63, wid = tid >> 6;
  const int cb = blockIdx.x;
  const int c = cb >> 6, b = (cb >> 5) & 1, h = cb & 31;
  const size_t base = ((size_t)(b*4096 + c*128)) * 2048 + h*64;
  const int fr = lane & 15, kg = lane >> 4;

  // P0a: stage t2 chunk [128][64] + dw2t head-slice [64][64]; per-head vectors
  {
    int t = tid >> 1, jh = (tid & 1) * 32;
    const u16* t2s = t2_g + (size_t)(b*4096 + c*128 + t)*64 + jh;
    #pragma unroll
    for (int j=0;j<4;j++) *(uint4*)(&rd_l[t*72 + jh + j*8]) = *(const uint4*)(t2s + j*8);
    int n = tid >> 2, sg2 = (tid & 3) * 8;
    const u16* dws = dw2t_g + (size_t)(h*64 + n)*64;
    *(uint4*)(&ki_l[n*72 + sg2])      = *(const uint4*)(dws + sg2);
    *(uint4*)(&ki_l[n*72 + 32 + sg2]) = *(const uint4*)(dws + 32 + sg2);
  }
  if (tid < 64){
    u_l[tid]   = u_g[h*64 + tid];
    kkk_l[tid] = kkk_g[h*64 + tid];
    kka_l[tid] = kka_g[h*64 + tid];
    td_l[tid]  = td_g[h*64 + tid];
  }
  __syncthreads();
  // P0b: WL[t][k] = -exp(td[k] + t2[t,:] . dw2[:,k])
  {
    f32x4 accW[2][4];
    #pragma unroll
    for (int m=0;m<2;m++)
      #pragma unroll
      for (int n=0;n<4;n++) accW[m][n] = ZF4;
    #pragma unroll
    for (int ks=0; ks<2; ++ks){
      s16x8 af0 = *(const s16x8*)(&rd_l[(wid*32 + fr)*72 + ks*32 + kg*8]);
      s16x8 af1 = *(const s16x8*)(&rd_l[(wid*32 + 16 + fr)*72 + ks*32 + kg*8]);
      #pragma unroll
      for (int n=0;n<4;n++){
        s16x8 bf = *(const s16x8*)(&ki_l[(n*16 + fr)*72 + ks*32 + kg*8]);
        accW[0][n] = __builtin_amdgcn_mfma_f32_16x16x32_bf16(af0, bf, accW[0][n], 0,0,0);
        accW[1][n] = __builtin_amdgcn_mfma_f32_16x16x32_bf16(af1, bf, accW[1][n], 0,0,0);
      }
    }
    #pragma unroll
    for (int m=0;m<2;m++)
      #pragma unroll
      for (int n=0;n<4;n++)
        #pragma unroll
        for (int q=0;q<4;q++){
          int t = wid*32 + m*16 + kg*4 + q;
          int s = n*16 + fr;
          WL[t*64 + s] = -expf(td_l[s] + accW[m][n][q]);
        }
  }
  __syncthreads();
  // scan: inclusive cumsum over t per column k
  for (int j=0;j<16;j++){
    int k = wid*16 + j;
    float v = WL[lane*64 + k];
    #pragma unroll
    for (int d=1; d<64; d<<=1){ float o = __shfl_up(v, d); if (lane >= d) v += o; }
    WC[lane*64 + k] = v;
    float carry = __shfl(v, 63);
    float v2 = WL[(64+lane)*64 + k];
    #pragma unroll
    for (int d=1; d<64; d<<=1){ float o = __shfl_up(v2, d); if (lane >= d) v2 += o; }
    v2 += carry;
    WC[(64+lane)*64 + k] = v2;
    float tot = __shfl(v2, 63);
    if (lane == 0){ offs_l[k] = carry; wsum_l[k] = tot; wsA_g[(size_t)cb*64 + k] = expf(tot); }
  }
  __syncthreads();
  // P1: r, kadj -> rd, ki (natural), kwT (transposed), rw (global), diag
  {
    int t = tid >> 1, kh = (tid & 1) * 32;
    const u16* rs  = r_g    + base + (size_t)t*2048 + kh;
    const u16* ks_ = kraw_g + base + (size_t)t*2048 + kh;
    const u16* is_ = ic_g   + base + (size_t)t*2048 + kh;
    float dpart = 0.f;
    #pragma unroll
    for (int j=0;j<4;j++){
      float rf[8], kf[8], icf[8], rdf[8], kif[8], rwf[8];
      up8(*(const uint4*)(rs + j*8), rf);
      up8(*(const uint4*)(ks_ + j*8), kf);
      up8(*(const uint4*)(is_ + j*8), icf);
      #pragma unroll
      for (int e=0;e<8;e++){
        int k = kh + j*8 + e;
        float kadj = kf[e] * (1.f + (icf[e] - 1.f) * kka_l[k]);
        float wl = WL[t*64+k], wc = WC[t*64+k];
        float wcs = wc - wl;
        float off = offs_l[k], wsm = wsum_l[k];
        rdf[e] = rf[e] * expf(clip30(wcs - off));
        kif[e] = kadj  * expf(clip30(off - wc));
        rwf[e] = rf[e] * expf(clip30(wcs));
        kwT_l[k*136 + t] = f2b(kadj * expf(clip30(wsm - wc)));
        dpart += rf[e] * u_l[k] * kadj;
      }
      *(uint4*)(&rd_l[t*72 + kh + j*8]) = pk8(rdf);
      *(uint4*)(&ki_l[t*72 + kh + j*8]) = pk8(kif);
      *(uint4*)(rw_g + base + (size_t)t*2048 + kh + j*8) = pk8(rwf);
    }
    dpart += __shfl_xor(dpart, 1);
    if ((tid & 1) == 0) diag_l[t] = dpart;
  }
  __syncthreads();
  // P2: raw k, iclr -> ka = kk*iclr, kkb = kk (normalized)
  {
    int t = tid >> 1, kh = (tid & 1) * 32;
    const u16* ks_ = kraw_g + base + (size_t)t*2048 + kh;
    const u16* is_ = ic_g   + base + (size_t)t*2048 + kh;
    float kf[32], icf[32], kkraw[32];
    #pragma unroll
    for (int j=0;j<4;j++){
      up8(*(const uint4*)(ks_ + j*8), kf + j*8);
      up8(*(const uint4*)(is_ + j*8), icf + j*8);
    }
    float ss = 0.f;
    #pragma unroll
    for (int e=0;e<32;e++){ kkraw[e] = kf[e]*kkk_l[kh+e]; ss += kkraw[e]*kkraw[e]; }
    ss += __shfl_xor(ss, 1);
    float rn = 1.f / fmaxf(sqrtf(ss), 1e-12f);
    #pragma unroll
    for (int j=0;j<4;j++){
      float kkb8[8], ka8[8];
      #pragma unroll
      for (int e=0;e<8;e++){
        float kkv = kkraw[j*8+e]*rn;
        kkb8[e] = kkv; ka8[e] = kkv*icf[j*8+e];
      }
      *(uint4*)(&kkb_l[t*72 + kh + j*8]) = pk8(kkb8);
      *(uint4*)(&ka_l [t*72 + kh + j*8]) = pk8(ka8);
    }
  }
  __syncthreads();
  // P3: A = rd @ ki^T, mask strict-lower + diag, keep in regs + write Abuf
  f32x4 accA[2][8];
  #pragma unroll
  for (int m=0;m<2;m++)
    #pragma unroll
    for (int n=0;n<8;n++) accA[m][n] = ZF4;
  #pragma unroll
  for (int ks=0; ks<2; ++ks){
    s16x8 af0 = *(const s16x8*)(&rd_l[(wid*32 + fr)*72 + ks*32 + kg*8]);
    s16x8 af1 = *(const s16x8*)(&rd_l[(wid*32 + 16 + fr)*72 + ks*32 + kg*8]);
    #pragma unroll
    for (int n=0;n<8;n++){
      s16x8 bf = *(const s16x8*)(&ki_l[(n*16 + fr)*72 + ks*32 + kg*8]);
      accA[0][n] = __builtin_amdgcn_mfma_f32_16x16x32_bf16(af0, bf, accA[0][n], 0,0,0);
      accA[1][n] = __builtin_amdgcn_mfma_f32_16x16x32_bf16(af1, bf, accA[1][n], 0,0,0);
    }
  }
  #pragma unroll
  for (int m=0;m<2;m++)
    #pragma unroll
    for (int n=0;n<8;n++)
      #pragma unroll
      for (int q=0;q<4;q++){
        int t = wid*32 + m*16 + kg*4 + q;
        int s = n*16 + fr;
        float v = accA[m][n][q];
        v = (t > s) ? v : ((t == s) ? diag_l[t] : 0.f);
        accA[m][n][q] = v;
        Abuf[t*136 + s] = f2b(v);
      }
  __syncthreads();
  // P4a: kkwT[k][t] = -kk * w_inter  (transposed, into old ki slot)
  {
    int t = tid >> 1, kh = (tid & 1)*32;
    #pragma unroll
    for (int j=0;j<4;j++){
      float kkf[8];
      up8(*(const uint4*)(&kkb_l[t*72 + kh + j*8]), kkf);
      #pragma unroll
      for (int e=0;e<8;e++){
        int k = kh + j*8 + e;
        kkwT_l[k*136 + t] = f2b(-kkf[e] * expf(clip30(wsum_l[k] - WC[t*64+k])));
      }
    }
  }
  __syncthreads();
  // P4b: kk_corr = ka @ kkb^T, strict-lower, write transposed kkcT[s][t]
  {
    f32x4 accC[2][8];
    #pragma unroll
    for (int m=0;m<2;m++)
      #pragma unroll
      for (int n=0;n<8;n++) accC[m][n] = ZF4;
    #pragma unroll
    for (int ks=0; ks<2; ++ks){
      s16x8 af0 = *(const s16x8*)(&ka_l[(wid*32 + fr)*72 + ks*32 + kg*8]);
      s16x8 af1 = *(const s16x8*)(&ka_l[(wid*32 + 16 + fr)*72 + ks*32 + kg*8]);
      #pragma unroll
      for (int n=0;n<8;n++){
        s16x8 bf = *(const s16x8*)(&kkb_l[(n*16 + fr)*72 + ks*32 + kg*8]);
        accC[0][n] = __builtin_amdgcn_mfma_f32_16x16x32_bf16(af0, bf, accC[0][n], 0,0,0);
        accC[1][n] = __builtin_amdgcn_mfma_f32_16x16x32_bf16(af1, bf, accC[1][n], 0,0,0);
      }
    }
    #pragma unroll
    for (int m=0;m<2;m++)
      #pragma unroll
      for (int n=0;n<8;n++)
        #pragma unroll
        for (int q=0;q<4;q++){
          int t = wid*32 + m*16 + kg*4 + q;
          int s = n*16 + fr;
          kkcT[s*136 + t] = f2b((t > s) ? accC[m][n][q] : 0.f);
        }
  }
  __syncthreads();
  // P5a: stage v transposed (vT[vd][t]) + kaT[j][t] (over dead kkb)
  {
    int t = tid >> 1, vh = (tid & 1)*32;
    const u16* vs = v_g + base + (size_t)t*2048 + vh;
    #pragma unroll
    for (int j=0;j<4;j++){
      u16 el[8]; unp16(*(const uint4*)(vs + j*8), el);
      #pragma unroll
      for (int e=0;e<8;e++) vT_l[(vh + j*8 + e)*136 + t] = el[e];
    }
    #pragma unroll
    for (int j=0;j<4;j++){
      u16 el[8]; unp16(*(const uint4*)(&ka_l[t*72 + vh + j*8]), el);
      #pragma unroll
      for (int e=0;e<8;e++) kaT_l[(vh + j*8 + e)*136 + t] = el[e];
    }
  }
  // P5b: P = Amask @ kkc ; A_total = Amask - tril(P) -> Abuf (own strip, in place)
  {
    f32x4 accP[2][8];
    #pragma unroll
    for (int m=0;m<2;m++)
      #pragma unroll
      for (int n=0;n<8;n++) accP[m][n] = ZF4;
    #pragma unroll
    for (int ks=0; ks<4; ++ks){
      s16x8 af0 = *(const s16x8*)(&Abuf[(wid*32 + fr)*136 + ks*32 + kg*8]);
      s16x8 af1 = *(const s16x8*)(&Abuf[(wid*32 + 16 + fr)*136 + ks*32 + kg*8]);
      #pragma unroll
      for (int n=0;n<8;n++){
        s16x8 bf = *(const s16x8*)(&kkcT[(n*16 + fr)*136 + ks*32 + kg*8]);
        accP[0][n] = __builtin_amdgcn_mfma_f32_16x16x32_bf16(af0, bf, accP[0][n], 0,0,0);
        accP[1][n] = __builtin_amdgcn_mfma_f32_16x16x32_bf16(af1, bf, accP[1][n], 0,0,0);
      }
    }
    #pragma unroll
    for (int m=0;m<2;m++)
      #pragma unroll
      for (int n=0;n<8;n++)
        #pragma unroll
        for (int q=0;q<4;q++){
          int t = wid*32 + m*16 + kg*4 + q;
          int s = n*16 + fr;
          float v = accA[m][n][q] - ((t >= s) ? accP[m][n][q] : 0.f);
          Abuf[t*136 + s] = f2b(v);
        }
  }
  __syncthreads();
  // P6: y_intra = A_total @ v  (write y1 global)
  {
    f32x4 accY[2][4];
    #pragma unroll
    for (int m=0;m<2;m++)
      #pragma unroll
      for (int n=0;n<4;n++) accY[m][n] = ZF4;
    #pragma unroll
    for (int ks=0; ks<4; ++ks){
      s16x8 af0 = *(const s16x8*)(&Abuf[(wid*32 + fr)*136 + ks*32 + kg*8]);
      s16x8 af1 = *(const s16x8*)(&Abuf[(wid*32 + 16 + fr)*136 + ks*32 + kg*8]);
      #pragma unroll
      for (int n=0;n<4;n++){
        s16x8 bf = *(const s16x8*)(&vT_l[(n*16 + fr)*136 + ks*32 + kg*8]);
        accY[0][n] = __builtin_amdgcn_mfma_f32_16x16x32_bf16(af0, bf, accY[0][n], 0,0,0);
        accY[1][n] = __builtin_amdgcn_mfma_f32_16x16x32_bf16(af1, bf, accY[1][n], 0,0,0);
      }
    }
    #pragma unroll
    for (int m=0;m<2;m++)
      #pragma unroll
      for (int n=0;n<4;n++)
        #pragma unroll
        for (int q=0;q<4;q++){
          int t = wid*32 + m*16 + kg*4 + q;
          int vd = n*16 + fr;
          y1_g[base + (size_t)t*2048 + vd] = f2b(accY[m][n][q]);
        }
  }
  // P7: kv = kwT @ vT^T ; ab = kkwT @ kaT^T  (MFMA, 64x64, K=128)
  {
    f32x4 akv[4], aab[4];
    #pragma unroll
    for (int n=0;n<4;n++){ akv[n] = ZF4; aab[n] = ZF4; }
    #pragma unroll
    for (int ks=0; ks<4; ++ks){
      s16x8 a1 = *(const s16x8*)(&kwT_l [(wid*16 + fr)*136 + ks*32 + kg*8]);
      s16x8 a2 = *(const s16x8*)(&kkwT_l[(wid*16 + fr)*136 + ks*32 + kg*8]);
      #pragma unroll
      for (int n=0;n<4;n++){
        s16x8 bv = *(const s16x8*)(&vT_l [(n*16 + fr)*136 + ks*32 + kg*8]);
        s16x8 ba = *(const s16x8*)(&kaT_l[(n*16 + fr)*136 + ks*32 + kg*8]);
        akv[n] = __builtin_amdgcn_mfma_f32_16x16x32_bf16(a1, bv, akv[n], 0,0,0);
        aab[n] = __builtin_amdgcn_mfma_f32_16x16x32_bf16(a2, ba, aab[n], 0,0,0);
      }
    }
    u16* kvp = kvab_g + (size_t)cb*8192;   // [kv: 4096][ab: 4096]
    #pragma unroll
    for (int n=0;n<4;n++)
      #pragma unroll
      for (int q=0;q<4;q++){
        int kd = wid*16 + kg*4 + q, vd = n*16 + fr;
        kvp[kd*64 + vd]        = f2b(akv[n][q]);
        kvp[4096 + kd*64 + vd] = f2b(aab[n][q]);
      }
  }
}

// ---------------------------------------------------------------- WKV phase 2: sequential state scan per (b,h)
__global__ __launch_bounds__(256) void wkv2_k(
   const float* __restrict__ state_in, u16* __restrict__ kvab_g,
   const float* __restrict__ wsA_g, float* __restrict__ out_state)
{
  __shared__ float S_l[64][65];
  __shared__ float ab_l[64][64];
  int tid = threadIdx.x;
  int bh = blockIdx.x; int b = bh >> 5, h = bh & 31;
  int kf = tid >> 2, sg = (tid & 3) * 16;
  #pragma unroll
  for (int j=0;j<16;j++)
    S_l[kf][sg+j] = state_in[((size_t)bh*64 + kf)*64 + sg + j];
  __syncthreads();
  for (int c=0;c<32;c++){
    int cb = (c*2 + b)*32 + h;
    u16* kvp = kvab_g + (size_t)cb*8192;
    float kvv[16], wsv[16];
    #pragma unroll
    for (int j=0;j<16;j++){
      kvv[j] = b2f(kvp[kf*64 + sg + j]);
      wsv[j] = wsA_g[(size_t)cb*64 + sg + j];
    }
    #pragma unroll
    for (int j=0;j<16;j++){
      int flat = tid*16 + j;
      ab_l[flat>>6][flat&63] = b2f(kvp[4096 + flat]);
    }
    __syncthreads();
    float* sip = (float*)(kvab_g + (size_t)cb*8192);
    #pragma unroll
    for (int j=0;j<16;j++) sip[kf*64 + sg + j] = S_l[kf][sg+j];
    float acc[16];
    #pragma unroll
    for (int j=0;j<16;j++) acc[j] = 0.f;
    for (int jj=0;jj<64;jj++){
      float sv = S_l[kf][jj];
      #pragma unroll
      for (int j=0;j<16;j++) acc[j] += sv * ab_l[jj][sg+j];
    }
    float nv[16];
    #pragma unroll
    for (int j=0;j<16;j++) nv[j] = S_l[kf][sg+j]*wsv[j] + acc[j] + kvv[j];
    __syncthreads();
    #pragma unroll
    for (int j=0;j<16;j++) S_l[kf][sg+j] = nv[j];
    __syncthreads();
  }
  #pragma unroll
  for (int j=0;j<16;j++)
    out_state[((size_t)bh*64 + kf)*64 + sg + j] = S_l[kf][sg+j];
}

// ---------------------------------------------------------------- WKV phase 3: y = y1 + rw@S_in, GroupNorm, *g
__global__ __launch_bounds__(256) void wkv3_k(
   const u16* __restrict__ y1_g, const u16* __restrict__ rw_g,
   const u16* __restrict__ kvab_g,
   const u16* __restrict__ g_g, const float* __restrict__ gnw, const float* __restrict__ gnb,
   u16* __restrict__ yf_g)
{
  __shared__ float S_l[64][65];
  __shared__ u16 rw_l[128][72];
  int tid = threadIdx.x;
  int cb = blockIdx.x; int c = cb>>6, b = (cb>>5)&1, h = cb&31;
  size_t base = ((size_t)(b*4096 + c*128))*2048 + h*64;
  const float* sip = (const float*)(kvab_g + (size_t)cb*8192);
  #pragma unroll
  for (int j=0;j<16;j++){ int flat = tid*16+j; S_l[flat>>6][flat&63] = sip[flat]; }
  {
    int t = tid>>1, kh = (tid&1)*32;
    const u16* rs = rw_g + base + (size_t)t*2048 + kh;
    #pragma unroll
    for (int j=0;j<4;j++) *(uint4*)(&rw_l[t][kh+j*8]) = *(const uint4*)(rs + j*8);
  }
  __syncthreads();
  int t = tid>>1, vh = (tid&1)*32;
  float acc[32];
  #pragma unroll
  for (int j=0;j<32;j++) acc[j] = 0.f;
  for (int kf2=0; kf2<64; kf2++){
    float rv = b2f(rw_l[t][kf2]);
    #pragma unroll
    for (int j=0;j<32;j++) acc[j] += rv * S_l[kf2][vh+j];
  }
  float sum=0.f, sq=0.f;
  float yv[32];
  #pragma unroll
  for (int j=0;j<32;j++){
    yv[j] = acc[j] + b2f(y1_g[base + (size_t)t*2048 + vh + j]);
    sum += yv[j]; sq += yv[j]*yv[j];
  }
  sum += __shfl_xor(sum, 1); sq += __shfl_xor(sq, 1);
  float mean = sum * (1.f/64.f);
  float var = sq * (1.f/64.f) - mean*mean;
  float rstd = rsqrtf(fmaxf(var, 0.f) + 6.4e-4f);
  size_t bt = (size_t)(b*4096 + c*128 + t);
  #pragma unroll
  for (int j=0;j<32;j++){
    int ch = h*64 + vh + j;
    float val = (yv[j]-mean)*rstd * gnw[ch] + gnb[ch];
    val *= b2f(g_g[bt*2048 + ch]);
    yf_g[base + (size_t)t*2048 + vh + j] = f2b(val);
  }
}

// ---------------------------------------------------------------- host
#define O_WTR   0ull
#define O_WTK   8388608ull
#define O_WTV   16777216ull
#define O_WTG   25165824ull
#define O_WTO   33554432ull
#define O_W1T   41943040ull
#define O_W2T   42729472ull
#define O_DW1T  43515904ull
#define O_DW2T  43778048ull
#define O_A1T   44040192ull
#define O_A2T   44433408ull
#define O_XXX   44826624ull
#define O_T2    47972352ull
#define O_T3    49020928ull
#define O_WSA   50593792ull
#define O_XMX   51118080ull       /* 32MB: xmx -> g */
#define O_A     84672512ull       /* 32MB: lerp staging -> kvab/S_in */
#define O_I     118226944ull      /* 32MB: dxprev -> iclr */
#define O_R     151781376ull
#define O_K     185335808ull      /* raw k -> y1 -> yf */
#define O_V     218890240ull
#define WS_NEEDED 252444672ull

extern "C" void kernel_launch(void* const* d_in, const int* in_sizes, int n_in,
                              void* d_out, int out_size, void* d_ws, size_t ws_size,
                              hipStream_t stream)
{
  (void)in_sizes; (void)n_in; (void)out_size;
  if (ws_size < WS_NEEDED) return;
  const float* x     = (const float*)d_in[0];
  const float* shift = (const float*)d_in[1];
  const float* st_in = (const float*)d_in[2];
  const float* maax  = (const float*)d_in[3];
  const float* maas[6] = {(const float*)d_in[4],(const float*)d_in[5],(const float*)d_in[6],
                          (const float*)d_in[7],(const float*)d_in[8],(const float*)d_in[9]};
  const float* w1    = (const float*)d_in[10];
  const float* w2    = (const float*)d_in[11];
  const float* td    = (const float*)d_in[12];
  const float* dw1   = (const float*)d_in[13];
  const float* dw2   = (const float*)d_in[14];
  const float* faaaa = (const float*)d_in[15];
  const float* a0v   = (const float*)d_in[16];
  const float* a1w   = (const float*)d_in[17];
  const float* a2w   = (const float*)d_in[18];
  const float* kkk   = (const float*)d_in[19];
  const float* kka   = (const float*)d_in[20];
  const float* Wr    = (const float*)d_in[21];
  const float* Wk    = (const float*)d_in[22];
  const float* Wv    = (const float*)d_in[23];
  const float* Wg    = (const float*)d_in[24];
  const float* Wo    = (const float*)d_in[25];
  const float* gnw   = (const float*)d_in[26];
  const float* gnb   = (const float*)d_in[27];
  float* out = (float*)d_out;
  char* ws = (char*)d_ws;
  #define WSP(o) ((u16*)(ws + (o)))

  u16 *wtR=WSP(O_WTR), *wtK=WSP(O_WTK), *wtV=WSP(O_WTV), *wtG=WSP(O_WTG), *wtO=WSP(O_WTO);
  u16 *w1t=WSP(O_W1T), *w2t=WSP(O_W2T), *dw1t=WSP(O_DW1T), *dw2t=WSP(O_DW2T), *a1t=WSP(O_A1T), *a2t=WSP(O_A2T);
  u16 *xxx=WSP(O_XXX), *t2b=WSP(O_T2), *t3b=WSP(O_T3);
  u16 *xmx=WSP(O_XMX), *Ab=WSP(O_A), *Ib=WSP(O_I), *Rb=WSP(O_R), *Kb=WSP(O_K), *Vb=WSP(O_V);
  u16 *rw = WSP(O_WTR);       // reuses dead big-W region
  u16 *kvab = WSP(O_A);       // reuses dead staging region
  u16 *gbuf = WSP(O_XMX);     // reuses dead xmx region
  u16 *dxp  = WSP(O_I);       // dxprev bf16; dead once ICLR overwrites
  float* wsA = (float*)(ws + O_WSA);
  float* out_xlast = out + 16777216;
  float* out_state = out + 16781312;

  dim3 tb(32,8);
  transpose_k<<<dim3(64,64), tb, 0, stream>>>(Wr, wtR, 2048, 2048);
  transpose_k<<<dim3(64,64), tb, 0, stream>>>(Wk, wtK, 2048, 2048);
  transpose_k<<<dim3(64,64), tb, 0, stream>>>(Wv, wtV, 2048, 2048);
  transpose_k<<<dim3(64,64), tb, 0, stream>>>(Wg, wtG, 2048, 2048);
  transpose_k<<<dim3(64,64), tb, 0, stream>>>(Wo, wtO, 2048, 2048);
  transpose_k<<<dim3(6,64),  tb, 0, stream>>>(w1, w1t, 2048, 192);
  transpose_k<<<dim3(64,6),  tb, 0, stream>>>(w2, w2t, 192, 2048);
  transpose_k<<<dim3(2,64),  tb, 0, stream>>>(dw1, dw1t, 2048, 64);
  transpose_k<<<dim3(64,2),  tb, 0, stream>>>(dw2, dw2t, 64, 2048);
  transpose_k<<<dim3(3,64),  tb, 0, stream>>>(a1w, a1t, 2048, 96);
  transpose_k<<<dim3(64,3),  tb, 0, stream>>>(a2w, a2t, 96, 2048);

  prep_k<<<8192, 256, 0, stream>>>(x, shift, maax, xmx, dxp, out_xlast);

  // xxx = tanh(xmx @ w1)   (N=192 -> sync path)
  gemm_k<EPI_TANH,false><<<dim3(64,2), 256, 0, stream>>>(xmx, 2048, w1t, 2048, xxx, nullptr, 192, 8192, 192, 2048, nullptr, nullptr, nullptr);
  // xw -> Ab ; t2 = tanh(xw @ dw1)
  gemm_k<EPI_LERP,true><<<dim3(64,16), 256, 0, stream>>>(xxx + 0*32, 192, w2t + 0*32, 192, Ab, nullptr, 2048, 8192, 2048, 32, x, dxp, maas[0]);
  gemm_k<EPI_TANH,false><<<dim3(64,1), 256, 0, stream>>>(Ab, 2048, dw1t, 2048, t2b, nullptr, 64, 8192, 64, 2048, nullptr, nullptr, nullptr);
  // xa -> Ab ; t3 = xa @ a1
  gemm_k<EPI_LERP,true><<<dim3(64,16), 256, 0, stream>>>(xxx + 5*32, 192, w2t + 5*32, 192, Ab, nullptr, 2048, 8192, 2048, 32, x, dxp, maas[5]);
  gemm_k<EPI_STORE,false><<<dim3(64,1), 256, 0, stream>>>(Ab, 2048, a1t, 2048, t3b, nullptr, 96, 8192, 96, 2048, nullptr, nullptr, nullptr);
  // xr -> Ab ; r = xr @ Wr
  gemm_k<EPI_LERP,true><<<dim3(64,16), 256, 0, stream>>>(xxx + 3*32, 192, w2t + 3*32, 192, Ab, nullptr, 2048, 8192, 2048, 32, x, dxp, maas[3]);
  gemm_k<EPI_STORE,true><<<dim3(64,16), 256, 0, stream>>>(Ab, 2048, wtR, 2048, Rb, nullptr, 2048, 8192, 2048, 2048, nullptr, nullptr, nullptr);
  // xk -> Ab ; k(raw) = xk @ Wk
  gemm_k<EPI_LERP,true><<<dim3(64,16), 256, 0, stream>>>(xxx + 1*32, 192, w2t + 1*32, 192, Ab, nullptr, 2048, 8192, 2048, 32, x, dxp, maas[1]);
  gemm_k<EPI_STORE,true><<<dim3(64,16), 256, 0, stream>>>(Ab, 2048, wtK, 2048, Kb, nullptr, 2048, 8192, 2048, 2048, nullptr, nullptr, nullptr);
  // xv -> Ab ; v = xv @ Wv
  gemm_k<EPI_LERP,true><<<dim3(64,16), 256, 0, stream>>>(xxx + 2*32, 192, w2t + 2*32, 192, Ab, nullptr, 2048, 8192, 2048, 32, x, dxp, maas[2]);
  gemm_k<EPI_STORE,true><<<dim3(64,16), 256, 0, stream>>>(Ab, 2048, wtV, 2048, Vb, nullptr, 2048, 8192, 2048, 2048, nullptr, nullptr, nullptr);
  // xg -> Ab ; g = silu(xg @ Wg)
  gemm_k<EPI_LERP,true><<<dim3(64,16), 256, 0, stream>>>(xxx + 4*32, 192, w2t + 4*32, 192, Ab, nullptr, 2048, 8192, 2048, 32, x, dxp, maas[4]);
  gemm_k<EPI_SILU,true><<<dim3(64,16), 256, 0, stream>>>(Ab, 2048, wtG, 2048, gbuf, nullptr, 2048, 8192, 2048, 2048, nullptr, nullptr, nullptr);
  // iclr = sigmoid(a0 + t3 @ a2)  (after all lerps: overwrites dxp region)
  gemm_k<EPI_ICLR,true><<<dim3(64,16), 256, 0, stream>>>(t3b, 96, a2t, 96, Ib, nullptr, 2048, 8192, 2048, 96, nullptr, nullptr, a0v);
  // wkv
  wkv1_k<<<2048, 256, 0, stream>>>(Rb, Kb, Vb, Ib, t2b, dw2t, td, faaaa, kkk, kka,
                                   Kb /*y1 overwrites raw k*/, rw, kvab, wsA);
  wkv2_k<<<64, 256, 0, stream>>>(st_in, kvab, wsA, out_state);
  wkv3_k<<<2048, 256, 0, stream>>>(Kb /*y1*/, rw, kvab /*S_in*/, gbuf, gnw, gnb, Kb /*yf in place*/);
  // out = yf @ W_o  (f32 store)
  gemm_k<EPI_STORE32,true><<<dim3(64,16), 256, 0, stream>>>(Kb, 2048, wtO, 2048, nullptr, out, 2048, 8192, 2048, 2048, nullptr, nullptr, nullptr);
}

// Round 5
// 1737.747 us; speedup vs baseline: 1.2053x; 1.0759x over previous
//
#include <hip/hip_runtime.h>

// RWKV7-delta time-mix. f32 in/out, bf16 intermediates + MFMA bf16 16x16x32.
// B=2 T=4096 C=2048 H=32 K=64 CHUNK=128 NC=32.

typedef unsigned short u16;
typedef unsigned int   u32;
typedef __attribute__((ext_vector_type(8))) short s16x8;
typedef __attribute__((ext_vector_type(4))) float f32x4;

#define DEV __device__ __forceinline__

DEV float b2f(u16 v){ return __uint_as_float(((u32)v) << 16); }
DEV u16 f2b(float f){ u32 u = __float_as_uint(f); return (u16)((u + 0x7fffu + ((u >> 16) & 1u)) >> 16); }
DEV float clip30(float x){ return fminf(fmaxf(x, -30.f), 30.f); }
DEV void up8(uint4 v, float* f){
  f[0]=b2f((u16)(v.x&0xffffu)); f[1]=b2f((u16)(v.x>>16));
  f[2]=b2f((u16)(v.y&0xffffu)); f[3]=b2f((u16)(v.y>>16));
  f[4]=b2f((u16)(v.z&0xffffu)); f[5]=b2f((u16)(v.z>>16));
  f[6]=b2f((u16)(v.w&0xffffu)); f[7]=b2f((u16)(v.w>>16));
}
DEV uint4 pk8(const float* f){
  uint4 v;
  v.x = (u32)f2b(f[0]) | ((u32)f2b(f[1])<<16);
  v.y = (u32)f2b(f[2]) | ((u32)f2b(f[3])<<16);
  v.z = (u32)f2b(f[4]) | ((u32)f2b(f[5])<<16);
  v.w = (u32)f2b(f[6]) | ((u32)f2b(f[7])<<16);
  return v;
}
DEV void unp16(uint4 v, u16* o){
  o[0]=(u16)(v.x&0xffffu); o[1]=(u16)(v.x>>16);
  o[2]=(u16)(v.y&0xffffu); o[3]=(u16)(v.y>>16);
  o[4]=(u16)(v.z&0xffffu); o[5]=(u16)(v.z>>16);
  o[6]=(u16)(v.w&0xffffu); o[7]=(u16)(v.w>>16);
}
DEV void gload16(const u16* g, u16* l){
  __builtin_amdgcn_global_load_lds(
      (const __attribute__((address_space(1))) u32*)g,
      (__attribute__((address_space(3))) u32*)l, 16, 0, 0);
}
#define ZF4 ((f32x4){0.f,0.f,0.f,0.f})

// ---------------------------------------------------------------- transpose f32 -> bf16
__global__ void transpose_k(const float* __restrict__ in, u16* __restrict__ out, int R, int C){
  __shared__ float tile[32][33];
  int c0 = blockIdx.x*32, r0 = blockIdx.y*32;
  int tx = threadIdx.x, ty = threadIdx.y; // (32,8)
  #pragma unroll
  for (int j=0;j<4;j++) tile[ty + j*8][tx] = in[(size_t)(r0 + ty + j*8)*C + c0 + tx];
  __syncthreads();
  #pragma unroll
  for (int j=0;j<4;j++) out[(size_t)(c0 + ty + j*8)*R + r0 + tx] = f2b(tile[tx][ty + j*8]);
}

// ---------------------------------------------------------------- prep: xmx bf16, dxprev bf16, x_last f32
__global__ __launch_bounds__(256) void prep_k(const float* __restrict__ x, const float* __restrict__ shift,
    const float* __restrict__ maax, u16* __restrict__ xmx, u16* __restrict__ dxp, float* __restrict__ out_xlast){
  int e8 = (blockIdx.x*256 + threadIdx.x) * 8;
  int row = e8 >> 11, col = e8 & 2047;
  int t = row & 4095, b = row >> 12;
  const float* xp = x + (size_t)row*2048 + col;
  const float* pp = t ? (x + (size_t)(row-1)*2048 + col) : (shift + (size_t)b*2048 + col);
  float xf[8], pf[8], mf[8], of[8], df[8];
  *(float4*)(xf)   = *(const float4*)(xp);
  *(float4*)(xf+4) = *(const float4*)(xp+4);
  *(float4*)(pf)   = *(const float4*)(pp);
  *(float4*)(pf+4) = *(const float4*)(pp+4);
  *(float4*)(mf)   = *(const float4*)(maax + col);
  *(float4*)(mf+4) = *(const float4*)(maax + col + 4);
  #pragma unroll
  for (int j=0;j<8;j++){ df[j] = pf[j]-xf[j]; of[j] = xf[j] + df[j]*mf[j]; }
  *(uint4*)(xmx + (size_t)row*2048 + col) = pk8(of);
  *(uint4*)(dxp + (size_t)row*2048 + col) = pk8(df);
  if (t == 4095){
    *(float4*)(out_xlast + (size_t)b*2048 + col)     = *(const float4*)(xf);
    *(float4*)(out_xlast + (size_t)b*2048 + col + 4) = *(const float4*)(xf+4);
  }
}

// ---------------------------------------------------------------- generic 128x128 GEMM with fused epilogues
enum { EPI_STORE=0, EPI_TANH=1, EPI_SILU=2, EPI_LERP=3, EPI_ICLR=5, EPI_STORE32=6 };

template<int EPI, bool ASYNC, bool SWZ>
__global__ __launch_bounds__(256) void gemm_k(
    const u16* __restrict__ A, int lda,
    const u16* __restrict__ Bt, int ldb,
    u16* __restrict__ Cout, float* __restrict__ Cout32, int ldc,
    int M, int N, int K,
    const float* __restrict__ e_x, const u16* __restrict__ e_dxp, const float* __restrict__ e_vec)
{
  constexpr int LDW = ASYNC ? 32 : 40;
  __shared__ u16 As[128][LDW];
  __shared__ u16 Bs[128][LDW];
  const int tid = threadIdx.x;
  const int lane = tid & 63, wid = tid >> 6;
  int bxx = blockIdx.x, byy = blockIdx.y;
  if constexpr (SWZ){
    int nwg = gridDim.x * gridDim.y;
    if ((nwg & 7) == 0){
      int bid = byy * gridDim.x + bxx;
      int cpx = nwg >> 3;
      int swz = (bid & 7) * cpx + (bid >> 3);
      bxx = swz % gridDim.x; byy = swz / gridDim.x;
    }
  }
  const int m0 = bxx * 128, n0 = byy * 128;
  const int wrow = (wid >> 1) * 64, wcol = (wid & 1) * 64;
  const int fr = lane & 15, kg = lane >> 4;
  const int r_c0 = tid >> 2, r_seg = tid & 3;
  const int r_c1 = r_c0 + 64;

  f32x4 acc[4][4];
  #pragma unroll
  for (int m=0;m<4;m++)
    #pragma unroll
    for (int n=0;n<4;n++) acc[m][n] = ZF4;

  for (int k0 = 0; k0 < K; k0 += 32) {
    __syncthreads();
    if constexpr (ASYNC) {
      const int w4 = __builtin_amdgcn_readfirstlane(wid);
      const int rr = lane >> 2, seg8 = (lane & 3) * 8;
      #pragma unroll
      for (int i=0;i<2;i++){
        int row = w4*32 + i*16 + rr;
        gload16(A  + (size_t)(m0 + row)*lda + k0 + seg8, &As[w4*32 + i*16][0]);
        gload16(Bt + (size_t)(n0 + row)*ldb + k0 + seg8, &Bs[w4*32 + i*16][0]);
      }
    } else {
      uint4 av0 = *(const uint4*)(A + (size_t)(m0 + r_c0)*lda + k0 + r_seg*8);
      uint4 av1 = *(const uint4*)(A + (size_t)(m0 + r_c1)*lda + k0 + r_seg*8);
      *(uint4*)(&As[r_c0][r_seg*8]) = av0;
      *(uint4*)(&As[r_c1][r_seg*8]) = av1;
      uint4 z = make_uint4(0,0,0,0);
      uint4 bv0 = (n0 + r_c0 < N) ? *(const uint4*)(Bt + (size_t)(n0 + r_c0)*ldb + k0 + r_seg*8) : z;
      uint4 bv1 = (n0 + r_c1 < N) ? *(const uint4*)(Bt + (size_t)(n0 + r_c1)*ldb + k0 + r_seg*8) : z;
      *(uint4*)(&Bs[r_c0][r_seg*8]) = bv0;
      *(uint4*)(&Bs[r_c1][r_seg*8]) = bv1;
    }
    __syncthreads();
    s16x8 a[4], bb[4];
    #pragma unroll
    for (int m=0;m<4;m++) a[m] = *(const s16x8*)(&As[wrow + m*16 + fr][kg*8]);
    #pragma unroll
    for (int n=0;n<4;n++) bb[n] = *(const s16x8*)(&Bs[wcol + n*16 + fr][kg*8]);
    #pragma unroll
    for (int m=0;m<4;m++)
      #pragma unroll
      for (int n=0;n<4;n++)
        acc[m][n] = __builtin_amdgcn_mfma_f32_16x16x32_bf16(a[m], bb[n], acc[m][n], 0,0,0);
  }
  #pragma unroll
  for (int n=0;n<4;n++){
    int ccol = n0 + wcol + n*16 + fr;
    if (ccol >= N) continue;
    #pragma unroll
    for (int m=0;m<4;m++){
      #pragma unroll
      for (int q=0;q<4;q++){
        int row = m0 + wrow + m*16 + kg*4 + q;
        float v = acc[m][n][q];
        size_t oidx = (size_t)row*ldc + ccol;
        if constexpr (EPI == EPI_STORE) Cout[oidx] = f2b(v);
        else if constexpr (EPI == EPI_STORE32) Cout32[oidx] = v;
        else if constexpr (EPI == EPI_TANH) Cout[oidx] = f2b(tanhf(v));
        else if constexpr (EPI == EPI_SILU) Cout[oidx] = f2b(v / (1.f + expf(-v)));
        else if constexpr (EPI == EPI_LERP){
          float xv = e_x[(size_t)row*2048 + ccol];
          float dx = b2f(e_dxp[(size_t)row*2048 + ccol]);
          Cout[oidx] = f2b(xv + dx * (e_vec[ccol] + v));
        }
        else if constexpr (EPI == EPI_ICLR) Cout[oidx] = f2b(1.f / (1.f + expf(-(e_vec[ccol] + v))));
      }
    }
  }
}

// ---------------------------------------------------------------- thin GEMM: 64x64 tile, for small N (more blocks)
template<int EPI>
__global__ __launch_bounds__(256) void gemm_thin_k(
    const u16* __restrict__ A, int lda,
    const u16* __restrict__ Bt, int ldb,
    u16* __restrict__ Cout, int ldc, int N, int K)
{
  __shared__ u16 As[64][40];
  __shared__ u16 Bs[64][40];
  const int tid = threadIdx.x;
  const int lane = tid & 63, wid = tid >> 6;
  const int m0 = blockIdx.x * 64, n0 = blockIdx.y * 64;
  const int wrow = (wid >> 1) * 32, wcol = (wid & 1) * 32;
  const int fr = lane & 15, kg = lane >> 4;
  const int r_c = tid >> 2, r_seg = tid & 3;

  f32x4 acc[2][2];
  #pragma unroll
  for (int m=0;m<2;m++)
    #pragma unroll
    for (int n=0;n<2;n++) acc[m][n] = ZF4;

  for (int k0 = 0; k0 < K; k0 += 32) {
    __syncthreads();
    {
      uint4 av = *(const uint4*)(A + (size_t)(m0 + r_c)*lda + k0 + r_seg*8);
      *(uint4*)(&As[r_c][r_seg*8]) = av;
      uint4 z = make_uint4(0,0,0,0);
      uint4 bv = (n0 + r_c < N) ? *(const uint4*)(Bt + (size_t)(n0 + r_c)*ldb + k0 + r_seg*8) : z;
      *(uint4*)(&Bs[r_c][r_seg*8]) = bv;
    }
    __syncthreads();
    s16x8 a[2], bb[2];
    #pragma unroll
    for (int m=0;m<2;m++) a[m] = *(const s16x8*)(&As[wrow + m*16 + fr][kg*8]);
    #pragma unroll
    for (int n=0;n<2;n++) bb[n] = *(const s16x8*)(&Bs[wcol + n*16 + fr][kg*8]);
    #pragma unroll
    for (int m=0;m<2;m++)
      #pragma unroll
      for (int n=0;n<2;n++)
        acc[m][n] = __builtin_amdgcn_mfma_f32_16x16x32_bf16(a[m], bb[n], acc[m][n], 0,0,0);
  }
  #pragma unroll
  for (int n=0;n<2;n++){
    int ccol = n0 + wcol + n*16 + fr;
    if (ccol >= N) continue;
    #pragma unroll
    for (int m=0;m<2;m++){
      #pragma unroll
      for (int q=0;q<4;q++){
        int row = m0 + wrow + m*16 + kg*4 + q;
        float v = acc[m][n][q];
        size_t oidx = (size_t)row*ldc + ccol;
        if constexpr (EPI == EPI_TANH) Cout[oidx] = f2b(tanhf(v));
        else Cout[oidx] = f2b(v);
      }
    }
  }
}

// ---------------------------------------------------------------- WKV phase 1: per chunk-head, 512 threads / 8 waves
__global__ __launch_bounds__(512, 1) void wkv1_k(
    const u16* __restrict__ r_g, const u16* __restrict__ kraw_g, const u16* __restrict__ v_g,
    const u16* __restrict__ ic_g,
    const u16* __restrict__ t2_g, const u16* __restrict__ dw2t_g, const float* __restrict__ td_g,
    const float* __restrict__ u_g, const float* __restrict__ kkk_g, const float* __restrict__ kka_g,
    u16* __restrict__ y1_g, u16* __restrict__ rw_g,
    u16* __restrict__ kvab_g, float* __restrict__ wsA_g)
{
  // LDS arena, 161792 B. Slot lifetimes (overlays cross a barrier):
  //  S0 [0,34816)       WL f32[128][64]   -> (P3+) Abuf u16[128][136]
  //  S1 [34816,69632)   WC f32[128][64]   -> (P4b+) kkcT u16[128][136]; tail [67584,69632): diag/offs/wsum/u/kkk/kka/td
  //  S2 [69632,88064)   rd u16[128][72]   <- (P0: t2 stage) -> (P5a+) vT u16[64][136]
  //  S3 [88064,106496)  ki u16[128][72]   <- (P0: dw2 stage) -> (P4a+) kkwT u16[64][136]
  //  S4 [106496,124928) kwT u16[64][136]
  //  S5 [124928,143360) ka u16[128][72]
  //  S6 [143360,161792) kkb u16[128][72]  -> (P5a+) kaT u16[64][136]
  __shared__ __align__(16) char arena[161792];
  float* WL   = (float*)(arena);
  float* WC   = (float*)(arena + 34816);
  u16* Abuf   = (u16*)(arena);
  u16* kkcT   = (u16*)(arena + 34816);
  u16* rd_l   = (u16*)(arena + 69632);
  u16* vT_l   = (u16*)(arena + 69632);
  u16* ki_l   = (u16*)(arena + 88064);
  u16* kkwT_l = (u16*)(arena + 88064);
  u16* kwT_l  = (u16*)(arena + 106496);
  u16* ka_l   = (u16*)(arena + 124928);
  u16* kkb_l  = (u16*)(arena + 143360);
  u16* kaT_l  = (u16*)(arena + 143360);
  float* diag_l = (float*)(arena + 67584);  // 128
  float* offs_l = diag_l + 128;             // 64
  float* wsum_l = offs_l + 64;              // 64
  float* u_l    = wsum_l + 64;              // 64
  float* kkk_l  = u_l + 64;                 // 64
  float* kka_l  = kkk_l + 64;               // 64
  float* td_l   = kka_l + 64;               // 64 -> ends at 69632

  const int tid = threadIdx.x, lane = tid & 63, wid = tid >> 6;  // wid 0..7
  const int cb = blockIdx.x;
  const int c = cb >> 6, b = (cb >> 5) & 1, h = cb & 31;
  const size_t base = ((size_t)(b*4096 + c*128)) * 2048 + h*64;
  const int fr = lane & 15, kg = lane >> 4;
  const int tq = tid >> 2, kh = (tid & 3) * 16;   // 4 threads per row, 16 cols each

  // P0a: stage t2 [128][64] + dw2t head-slice [64][64]; per-head vectors
  {
    const u16* t2s = t2_g + (size_t)(b*4096 + c*128 + tq)*64 + kh;
    *(uint4*)(&rd_l[tq*72 + kh])     = *(const uint4*)(t2s);
    *(uint4*)(&rd_l[tq*72 + kh + 8]) = *(const uint4*)(t2s + 8);
    int n = tid >> 3, sg2 = (tid & 7) * 8;
    *(uint4*)(&ki_l[n*72 + sg2]) = *(const uint4*)(dw2t_g + (size_t)(h*64 + n)*64 + sg2);
  }
  if (tid < 64){
    u_l[tid]   = u_g[h*64 + tid];
    kkk_l[tid] = kkk_g[h*64 + tid];
    kka_l[tid] = kka_g[h*64 + tid];
    td_l[tid]  = td_g[h*64 + tid];
  }
  __syncthreads();
  // P0b: WL[t][k] = -exp(td[k] + t2[t,:] . dw2[:,k])  — wave w owns m-tile w (16 rows)
  {
    f32x4 accW[4];
    #pragma unroll
    for (int n=0;n<4;n++) accW[n] = ZF4;
    #pragma unroll
    for (int ks=0; ks<2; ++ks){
      s16x8 af = *(const s16x8*)(&rd_l[(wid*16 + fr)*72 + ks*32 + kg*8]);
      #pragma unroll
      for (int n=0;n<4;n++){
        s16x8 bf = *(const s16x8*)(&ki_l[(n*16 + fr)*72 + ks*32 + kg*8]);
        accW[n] = __builtin_amdgcn_mfma_f32_16x16x32_bf16(af, bf, accW[n], 0,0,0);
      }
    }
    #pragma unroll
    for (int n=0;n<4;n++)
      #pragma unroll
      for (int q=0;q<4;q++){
        int t = wid*16 + kg*4 + q;
        int s = n*16 + fr;
        WL[t*64 + s] = -expf(td_l[s] + accW[n][q]);
      }
  }
  __syncthreads();
  // scan: inclusive cumsum over t per column k — 8 cols per wave
  for (int j=0;j<8;j++){
    int k = wid*8 + j;
    float v = WL[lane*64 + k];
    #pragma unroll
    for (int d=1; d<64; d<<=1){ float o = __shfl_up(v, d); if (lane >= d) v += o; }
    WC[lane*64 + k] = v;
    float carry = __shfl(v, 63);
    float v2 = WL[(64+lane)*64 + k];
    #pragma unroll
    for (int d=1; d<64; d<<=1){ float o = __shfl_up(v2, d); if (lane >= d) v2 += o; }
    v2 += carry;
    WC[(64+lane)*64 + k] = v2;
    float tot = __shfl(v2, 63);
    if (lane == 0){ offs_l[k] = carry; wsum_l[k] = tot; wsA_g[(size_t)cb*64 + k] = expf(tot); }
  }
  __syncthreads();
  // P1: r, kadj -> rd, ki (natural), kwT (transposed), rw (global), diag
  {
    const u16* rs  = r_g    + base + (size_t)tq*2048 + kh;
    const u16* ks_ = kraw_g + base + (size_t)tq*2048 + kh;
    const u16* is_ = ic_g   + base + (size_t)tq*2048 + kh;
    float dpart = 0.f;
    #pragma unroll
    for (int j=0;j<2;j++){
      float rf[8], kf[8], icf[8], rdf[8], kif[8], rwf[8];
      up8(*(const uint4*)(rs + j*8), rf);
      up8(*(const uint4*)(ks_ + j*8), kf);
      up8(*(const uint4*)(is_ + j*8), icf);
      #pragma unroll
      for (int e=0;e<8;e++){
        int k = kh + j*8 + e;
        float kadj = kf[e] * (1.f + (icf[e] - 1.f) * kka_l[k]);
        float wl = WL[tq*64+k], wc = WC[tq*64+k];
        float wcs = wc - wl;
        float off = offs_l[k], wsm = wsum_l[k];
        rdf[e] = rf[e] * expf(clip30(wcs - off));
        kif[e] = kadj  * expf(clip30(off - wc));
        rwf[e] = rf[e] * expf(clip30(wcs));
        kwT_l[k*136 + tq] = f2b(kadj * expf(clip30(wsm - wc)));
        dpart += rf[e] * u_l[k] * kadj;
      }
      *(uint4*)(&rd_l[tq*72 + kh + j*8]) = pk8(rdf);
      *(uint4*)(&ki_l[tq*72 + kh + j*8]) = pk8(kif);
      *(uint4*)(rw_g + base + (size_t)tq*2048 + kh + j*8) = pk8(rwf);
    }
    dpart += __shfl_xor(dpart, 1);
    dpart += __shfl_xor(dpart, 2);
    if ((tid & 3) == 0) diag_l[tq] = dpart;
  }
  __syncthreads();
  // P2: raw k, iclr -> ka = kk*iclr, kkb = kk (normalized)
  {
    const u16* ks_ = kraw_g + base + (size_t)tq*2048 + kh;
    const u16* is_ = ic_g   + base + (size_t)tq*2048 + kh;
    float kf[16], icf[16], kkraw[16];
    #pragma unroll
    for (int j=0;j<2;j++){
      up8(*(const uint4*)(ks_ + j*8), kf + j*8);
      up8(*(const uint4*)(is_ + j*8), icf + j*8);
    }
    float ss = 0.f;
    #pragma unroll
    for (int e=0;e<16;e++){ kkraw[e] = kf[e]*kkk_l[kh+e]; ss += kkraw[e]*kkraw[e]; }
    ss += __shfl_xor(ss, 1);
    ss += __shfl_xor(ss, 2);
    float rn = 1.f / fmaxf(sqrtf(ss), 1e-12f);
    #pragma unroll
    for (int j=0;j<2;j++){
      float kkb8[8], ka8[8];
      #pragma unroll
      for (int e=0;e<8;e++){
        float kkv = kkraw[j*8+e]*rn;
        kkb8[e] = kkv; ka8[e] = kkv*icf[j*8+e];
      }
      *(uint4*)(&kkb_l[tq*72 + kh + j*8]) = pk8(kkb8);
      *(uint4*)(&ka_l [tq*72 + kh + j*8]) = pk8(ka8);
    }
  }
  __syncthreads();
  // P3: A = rd @ ki^T (wave w -> m-tile w), mask strict-lower + diag, keep in regs + write Abuf
  f32x4 accA[8];
  #pragma unroll
  for (int n=0;n<8;n++) accA[n] = ZF4;
  #pragma unroll
  for (int ks=0; ks<2; ++ks){
    s16x8 af = *(const s16x8*)(&rd_l[(wid*16 + fr)*72 + ks*32 + kg*8]);
    #pragma unroll
    for (int n=0;n<8;n++){
      s16x8 bf = *(const s16x8*)(&ki_l[(n*16 + fr)*72 + ks*32 + kg*8]);
      accA[n] = __builtin_amdgcn_mfma_f32_16x16x32_bf16(af, bf, accA[n], 0,0,0);
    }
  }
  #pragma unroll
  for (int n=0;n<8;n++)
    #pragma unroll
    for (int q=0;q<4;q++){
      int t = wid*16 + kg*4 + q;
      int s = n*16 + fr;
      float v = accA[n][q];
      v = (t > s) ? v : ((t == s) ? diag_l[t] : 0.f);
      accA[n][q] = v;
      Abuf[t*136 + s] = f2b(v);
    }
  __syncthreads();
  // P4a: kkwT[k][t] = -kk * w_inter
  {
    #pragma unroll
    for (int j=0;j<2;j++){
      float kkf[8];
      up8(*(const uint4*)(&kkb_l[tq*72 + kh + j*8]), kkf);
      #pragma unroll
      for (int e=0;e<8;e++){
        int k = kh + j*8 + e;
        kkwT_l[k*136 + tq] = f2b(-kkf[e] * expf(clip30(wsum_l[k] - WC[tq*64+k])));
      }
    }
  }
  __syncthreads();
  // P4b: kk_corr = ka @ kkb^T, strict-lower, write transposed kkcT[s][t]
  {
    f32x4 accC[8];
    #pragma unroll
    for (int n=0;n<8;n++) accC[n] = ZF4;
    #pragma unroll
    for (int ks=0; ks<2; ++ks){
      s16x8 af = *(const s16x8*)(&ka_l[(wid*16 + fr)*72 + ks*32 + kg*8]);
      #pragma unroll
      for (int n=0;n<8;n++){
        s16x8 bf = *(const s16x8*)(&kkb_l[(n*16 + fr)*72 + ks*32 + kg*8]);
        accC[n] = __builtin_amdgcn_mfma_f32_16x16x32_bf16(af, bf, accC[n], 0,0,0);
      }
    }
    #pragma unroll
    for (int n=0;n<8;n++)
      #pragma unroll
      for (int q=0;q<4;q++){
        int t = wid*16 + kg*4 + q;
        int s = n*16 + fr;
        kkcT[s*136 + t] = f2b((t > s) ? accC[n][q] : 0.f);
      }
  }
  __syncthreads();
  // P5a: stage v transposed (vT[vd][t]) + kaT[j][t] (over dead kkb)
  {
    const u16* vs = v_g + base + (size_t)tq*2048 + kh;
    #pragma unroll
    for (int j=0;j<2;j++){
      u16 el[8]; unp16(*(const uint4*)(vs + j*8), el);
      #pragma unroll
      for (int e=0;e<8;e++) vT_l[(kh + j*8 + e)*136 + tq] = el[e];
    }
    #pragma unroll
    for (int j=0;j<2;j++){
      u16 el[8]; unp16(*(const uint4*)(&ka_l[tq*72 + kh + j*8]), el);
      #pragma unroll
      for (int e=0;e<8;e++) kaT_l[(kh + j*8 + e)*136 + tq] = el[e];
    }
  }
  // P5b: P = Amask @ kkc ; A_total = Amask - tril(P) -> Abuf (own m-tile rows, in place)
  {
    f32x4 accP[8];
    #pragma unroll
    for (int n=0;n<8;n++) accP[n] = ZF4;
    #pragma unroll
    for (int ks=0; ks<4; ++ks){
      s16x8 af = *(const s16x8*)(&Abuf[(wid*16 + fr)*136 + ks*32 + kg*8]);
      #pragma unroll
      for (int n=0;n<8;n++){
        s16x8 bf = *(const s16x8*)(&kkcT[(n*16 + fr)*136 + ks*32 + kg*8]);
        accP[n] = __builtin_amdgcn_mfma_f32_16x16x32_bf16(af, bf, accP[n], 0,0,0);
      }
    }
    #pragma unroll
    for (int n=0;n<8;n++)
      #pragma unroll
      for (int q=0;q<4;q++){
        int t = wid*16 + kg*4 + q;
        int s = n*16 + fr;
        float v = accA[n][q] - ((t >= s) ? accP[n][q] : 0.f);
        Abuf[t*136 + s] = f2b(v);
      }
  }
  __syncthreads();
  // P6: y_intra = A_total @ v  (wave w -> m-tile w)
  {
    f32x4 accY[4];
    #pragma unroll
    for (int n=0;n<4;n++) accY[n] = ZF4;
    #pragma unroll
    for (int ks=0; ks<4; ++ks){
      s16x8 af = *(const s16x8*)(&Abuf[(wid*16 + fr)*136 + ks*32 + kg*8]);
      #pragma unroll
      for (int n=0;n<4;n++){
        s16x8 bf = *(const s16x8*)(&vT_l[(n*16 + fr)*136 + ks*32 + kg*8]);
        accY[n] = __builtin_amdgcn_mfma_f32_16x16x32_bf16(af, bf, accY[n], 0,0,0);
      }
    }
    #pragma unroll
    for (int n=0;n<4;n++)
      #pragma unroll
      for (int q=0;q<4;q++){
        int t = wid*16 + kg*4 + q;
        int vd = n*16 + fr;
        y1_g[base + (size_t)t*2048 + vd] = f2b(accY[n][q]);
      }
  }
  // P7: kv = kwT @ vT^T (waves 0-3) ; ab = kkwT @ kaT^T (waves 4-7)
  {
    const int isAB = wid >> 2, mrow = (wid & 3) * 16;
    const u16* Amat = isAB ? kkwT_l : kwT_l;
    const u16* Bmat = isAB ? kaT_l  : vT_l;
    f32x4 acc2[4];
    #pragma unroll
    for (int n=0;n<4;n++) acc2[n] = ZF4;
    #pragma unroll
    for (int ks=0; ks<4; ++ks){
      s16x8 af = *(const s16x8*)(&Amat[(mrow + fr)*136 + ks*32 + kg*8]);
      #pragma unroll
      for (int n=0;n<4;n++){
        s16x8 bf = *(const s16x8*)(&Bmat[(n*16 + fr)*136 + ks*32 + kg*8]);
        acc2[n] = __builtin_amdgcn_mfma_f32_16x16x32_bf16(af, bf, acc2[n], 0,0,0);
      }
    }
    u16* kvp = kvab_g + (size_t)cb*8192 + isAB*4096;
    #pragma unroll
    for (int n=0;n<4;n++)
      #pragma unroll
      for (int q=0;q<4;q++){
        int kd = mrow + kg*4 + q, vd = n*16 + fr;
        kvp[kd*64 + vd] = f2b(acc2[n][q]);
      }
  }
}

// ---------------------------------------------------------------- WKV phase 2: sequential state scan per (b,h)
__global__ __launch_bounds__(256) void wkv2_k(
   const float* __restrict__ state_in, u16* __restrict__ kvab_g,
   const float* __restrict__ wsA_g, float* __restrict__ out_state)
{
  __shared__ float S_l[64][65];
  __shared__ float ab_l[64][64];
  int tid = threadIdx.x;
  int bh = blockIdx.x; int b = bh >> 5, h = bh & 31;
  int kf = tid >> 2, sg = (tid & 3) * 16;
  #pragma unroll
  for (int j=0;j<16;j++)
    S_l[kf][sg+j] = state_in[((size_t)bh*64 + kf)*64 + sg + j];
  __syncthreads();
  for (int c=0;c<32;c++){
    int cb = (c*2 + b)*32 + h;
    u16* kvp = kvab_g + (size_t)cb*8192;
    float kvv[16], wsv[16];
    #pragma unroll
    for (int j=0;j<16;j++){
      kvv[j] = b2f(kvp[kf*64 + sg + j]);
      wsv[j] = wsA_g[(size_t)cb*64 + sg + j];
    }
    #pragma unroll
    for (int j=0;j<16;j++){
      int flat = tid*16 + j;
      ab_l[flat>>6][flat&63] = b2f(kvp[4096 + flat]);
    }
    __syncthreads();
    float* sip = (float*)(kvab_g + (size_t)cb*8192);
    #pragma unroll
    for (int j=0;j<16;j++) sip[kf*64 + sg + j] = S_l[kf][sg+j];
    float acc[16];
    #pragma unroll
    for (int j=0;j<16;j++) acc[j] = 0.f;
    for (int jj=0;jj<64;jj++){
      float sv = S_l[kf][jj];
      #pragma unroll
      for (int j=0;j<16;j++) acc[j] += sv * ab_l[jj][sg+j];
    }
    float nv[16];
    #pragma unroll
    for (int j=0;j<16;j++) nv[j] = S_l[kf][sg+j]*wsv[j] + acc[j] + kvv[j];
    __syncthreads();
    #pragma unroll
    for (int j=0;j<16;j++) S_l[kf][sg+j] = nv[j];
    __syncthreads();
  }
  #pragma unroll
  for (int j=0;j<16;j++)
    out_state[((size_t)bh*64 + kf)*64 + sg + j] = S_l[kf][sg+j];
}

// ---------------------------------------------------------------- WKV phase 3: y = y1 + rw@S_in, GroupNorm, *g
__global__ __launch_bounds__(256) void wkv3_k(
   const u16* __restrict__ y1_g, const u16* __restrict__ rw_g,
   const u16* __restrict__ kvab_g,
   const u16* __restrict__ g_g, const float* __restrict__ gnw, const float* __restrict__ gnb,
   u16* __restrict__ yf_g)
{
  __shared__ float S_l[64][65];
  __shared__ u16 rw_l[128][72];
  int tid = threadIdx.x;
  int cb = blockIdx.x; int c = cb>>6, b = (cb>>5)&1, h = cb&31;
  size_t base = ((size_t)(b*4096 + c*128))*2048 + h*64;
  const float* sip = (const float*)(kvab_g + (size_t)cb*8192);
  #pragma unroll
  for (int j=0;j<16;j++){ int flat = tid*16+j; S_l[flat>>6][flat&63] = sip[flat]; }
  {
    int t = tid>>1, kh = (tid&1)*32;
    const u16* rs = rw_g + base + (size_t)t*2048 + kh;
    #pragma unroll
    for (int j=0;j<4;j++) *(uint4*)(&rw_l[t][kh+j*8]) = *(const uint4*)(rs + j*8);
  }
  __syncthreads();
  int t = tid>>1, vh = (tid&1)*32;
  float acc[32];
  #pragma unroll
  for (int j=0;j<32;j++) acc[j] = 0.f;
  for (int kf2=0; kf2<64; kf2++){
    float rv = b2f(rw_l[t][kf2]);
    #pragma unroll
    for (int j=0;j<32;j++) acc[j] += rv * S_l[kf2][vh+j];
  }
  float sum=0.f, sq=0.f;
  float yv[32];
  #pragma unroll
  for (int j=0;j<32;j++){
    yv[j] = acc[j] + b2f(y1_g[base + (size_t)t*2048 + vh + j]);
    sum += yv[j]; sq += yv[j]*yv[j];
  }
  sum += __shfl_xor(sum, 1); sq += __shfl_xor(sq, 1);
  float mean = sum * (1.f/64.f);
  float var = sq * (1.f/64.f) - mean*mean;
  float rstd = rsqrtf(fmaxf(var, 0.f) + 6.4e-4f);
  size_t bt = (size_t)(b*4096 + c*128 + t);
  #pragma unroll
  for (int j=0;j<32;j++){
    int ch = h*64 + vh + j;
    float val = (yv[j]-mean)*rstd * gnw[ch] + gnb[ch];
    val *= b2f(g_g[bt*2048 + ch]);
    yf_g[base + (size_t)t*2048 + vh + j] = f2b(val);
  }
}

// ---------------------------------------------------------------- host
#define O_WTR   0ull
#define O_WTK   8388608ull
#define O_WTV   16777216ull
#define O_WTG   25165824ull
#define O_WTO   33554432ull
#define O_W1T   41943040ull
#define O_W2T   42729472ull
#define O_DW1T  43515904ull
#define O_DW2T  43778048ull
#define O_A1T   44040192ull
#define O_A2T   44433408ull
#define O_XXX   44826624ull
#define O_T2    47972352ull
#define O_T3    49020928ull
#define O_WSA   50593792ull
#define O_XMX   51118080ull       /* 32MB: xmx -> g */
#define O_A     84672512ull       /* 32MB: lerp staging -> kvab/S_in */
#define O_I     118226944ull      /* 32MB: dxprev -> iclr */
#define O_R     151781376ull
#define O_K     185335808ull      /* raw k -> y1 -> yf */
#define O_V     218890240ull
#define WS_NEEDED 252444672ull

extern "C" void kernel_launch(void* const* d_in, const int* in_sizes, int n_in,
                              void* d_out, int out_size, void* d_ws, size_t ws_size,
                              hipStream_t stream)
{
  (void)in_sizes; (void)n_in; (void)out_size;
  if (ws_size < WS_NEEDED) return;
  const float* x     = (const float*)d_in[0];
  const float* shift = (const float*)d_in[1];
  const float* st_in = (const float*)d_in[2];
  const float* maax  = (const float*)d_in[3];
  const float* maas[6] = {(const float*)d_in[4],(const float*)d_in[5],(const float*)d_in[6],
                          (const float*)d_in[7],(const float*)d_in[8],(const float*)d_in[9]};
  const float* w1    = (const float*)d_in[10];
  const float* w2    = (const float*)d_in[11];
  const float* td    = (const float*)d_in[12];
  const float* dw1   = (const float*)d_in[13];
  const float* dw2   = (const float*)d_in[14];
  const float* faaaa = (const float*)d_in[15];
  const float* a0v   = (const float*)d_in[16];
  const float* a1w   = (const float*)d_in[17];
  const float* a2w   = (const float*)d_in[18];
  const float* kkk   = (const float*)d_in[19];
  const float* kka   = (const float*)d_in[20];
  const float* Wr    = (const float*)d_in[21];
  const float* Wk    = (const float*)d_in[22];
  const float* Wv    = (const float*)d_in[23];
  const float* Wg    = (const float*)d_in[24];
  const float* Wo    = (const float*)d_in[25];
  const float* gnw   = (const float*)d_in[26];
  const float* gnb   = (const float*)d_in[27];
  float* out = (float*)d_out;
  char* ws = (char*)d_ws;
  #define WSP(o) ((u16*)(ws + (o)))

  u16 *wtR=WSP(O_WTR), *wtK=WSP(O_WTK), *wtV=WSP(O_WTV), *wtG=WSP(O_WTG), *wtO=WSP(O_WTO);
  u16 *w1t=WSP(O_W1T), *w2t=WSP(O_W2T), *dw1t=WSP(O_DW1T), *dw2t=WSP(O_DW2T), *a1t=WSP(O_A1T), *a2t=WSP(O_A2T);
  u16 *xxx=WSP(O_XXX), *t2b=WSP(O_T2), *t3b=WSP(O_T3);
  u16 *xmx=WSP(O_XMX), *Ab=WSP(O_A), *Ib=WSP(O_I), *Rb=WSP(O_R), *Kb=WSP(O_K), *Vb=WSP(O_V);
  u16 *rw = WSP(O_WTR);
  u16 *kvab = WSP(O_A);
  u16 *gbuf = WSP(O_XMX);
  u16 *dxp  = WSP(O_I);
  float* wsA = (float*)(ws + O_WSA);
  float* out_xlast = out + 16777216;
  float* out_state = out + 16781312;

  dim3 tb(32,8);
  transpose_k<<<dim3(64,64), tb, 0, stream>>>(Wr, wtR, 2048, 2048);
  transpose_k<<<dim3(64,64), tb, 0, stream>>>(Wk, wtK, 2048, 2048);
  transpose_k<<<dim3(64,64), tb, 0, stream>>>(Wv, wtV, 2048, 2048);
  transpose_k<<<dim3(64,64), tb, 0, stream>>>(Wg, wtG, 2048, 2048);
  transpose_k<<<dim3(64,64), tb, 0, stream>>>(Wo, wtO, 2048, 2048);
  transpose_k<<<dim3(6,64),  tb, 0, stream>>>(w1, w1t, 2048, 192);
  transpose_k<<<dim3(64,6),  tb, 0, stream>>>(w2, w2t, 192, 2048);
  transpose_k<<<dim3(2,64),  tb, 0, stream>>>(dw1, dw1t, 2048, 64);
  transpose_k<<<dim3(64,2),  tb, 0, stream>>>(dw2, dw2t, 64, 2048);
  transpose_k<<<dim3(3,64),  tb, 0, stream>>>(a1w, a1t, 2048, 96);
  transpose_k<<<dim3(64,3),  tb, 0, stream>>>(a2w, a2t, 96, 2048);

  prep_k<<<8192, 256, 0, stream>>>(x, shift, maax, xmx, dxp, out_xlast);

  // xxx = tanh(xmx @ w1)   (thin: 128x3 = 384 blocks)
  gemm_thin_k<EPI_TANH><<<dim3(128,3), 256, 0, stream>>>(xmx, 2048, w1t, 2048, xxx, 192, 192, 2048);
  // xw -> Ab ; t2 = tanh(xw @ dw1)  (thin: 128 blocks)
  gemm_k<EPI_LERP,true,true><<<dim3(64,16), 256, 0, stream>>>(xxx + 0*32, 192, w2t + 0*32, 192, Ab, nullptr, 2048, 8192, 2048, 32, x, dxp, maas[0]);
  gemm_thin_k<EPI_TANH><<<dim3(128,1), 256, 0, stream>>>(Ab, 2048, dw1t, 2048, t2b, 64, 64, 2048);
  // xa -> Ab ; t3 = xa @ a1  (thin: 256 blocks)
  gemm_k<EPI_LERP,true,true><<<dim3(64,16), 256, 0, stream>>>(xxx + 5*32, 192, w2t + 5*32, 192, Ab, nullptr, 2048, 8192, 2048, 32, x, dxp, maas[5]);
  gemm_thin_k<EPI_STORE><<<dim3(128,2), 256, 0, stream>>>(Ab, 2048, a1t, 2048, t3b, 96, 96, 2048);
  // xr -> Ab ; r = xr @ Wr
  gemm_k<EPI_LERP,true,true><<<dim3(64,16), 256, 0, stream>>>(xxx + 3*32, 192, w2t + 3*32, 192, Ab, nullptr, 2048, 8192, 2048, 32, x, dxp, maas[3]);
  gemm_k<EPI_STORE,true,true><<<dim3(64,16), 256, 0, stream>>>(Ab, 2048, wtR, 2048, Rb, nullptr, 2048, 8192, 2048, 2048, nullptr, nullptr, nullptr);
  // xk -> Ab ; k(raw) = xk @ Wk
  gemm_k<EPI_LERP,true,true><<<dim3(64,16), 256, 0, stream>>>(xxx + 1*32, 192, w2t + 1*32, 192, Ab, nullptr, 2048, 8192, 2048, 32, x, dxp, maas[1]);
  gemm_k<EPI_STORE,true,true><<<dim3(64,16), 256, 0, stream>>>(Ab, 2048, wtK, 2048, Kb, nullptr, 2048, 8192, 2048, 2048, nullptr, nullptr, nullptr);
  // xv -> Ab ; v = xv @ Wv
  gemm_k<EPI_LERP,true,true><<<dim3(64,16), 256, 0, stream>>>(xxx + 2*32, 192, w2t + 2*32, 192, Ab, nullptr, 2048, 8192, 2048, 32, x, dxp, maas[2]);
  gemm_k<EPI_STORE,true,true><<<dim3(64,16), 256, 0, stream>>>(Ab, 2048, wtV, 2048, Vb, nullptr, 2048, 8192, 2048, 2048, nullptr, nullptr, nullptr);
  // xg -> Ab ; g = silu(xg @ Wg)
  gemm_k<EPI_LERP,true,true><<<dim3(64,16), 256, 0, stream>>>(xxx + 4*32, 192, w2t + 4*32, 192, Ab, nullptr, 2048, 8192, 2048, 32, x, dxp, maas[4]);
  gemm_k<EPI_SILU,true,true><<<dim3(64,16), 256, 0, stream>>>(Ab, 2048, wtG, 2048, gbuf, nullptr, 2048, 8192, 2048, 2048, nullptr, nullptr, nullptr);
  // iclr = sigmoid(a0 + t3 @ a2)  (after all lerps: overwrites dxp region)
  gemm_k<EPI_ICLR,true,true><<<dim3(64,16), 256, 0, stream>>>(t3b, 96, a2t, 96, Ib, nullptr, 2048, 8192, 2048, 96, nullptr, nullptr, a0v);
  // wkv
  wkv1_k<<<2048, 512, 0, stream>>>(Rb, Kb, Vb, Ib, t2b, dw2t, td, faaaa, kkk, kka,
                                   Kb /*y1 overwrites raw k*/, rw, kvab, wsA);
  wkv2_k<<<64, 256, 0, stream>>>(st_in, kvab, wsA, out_state);
  wkv3_k<<<2048, 256, 0, stream>>>(Kb /*y1*/, rw, kvab /*S_in*/, gbuf, gnw, gnb, Kb /*yf in place*/);
  // out = yf @ W_o  (f32 store)
  gemm_k<EPI_STORE32,true,true><<<dim3(64,16), 256, 0, stream>>>(Kb, 2048, wtO, 2048, nullptr, out, 2048, 8192, 2048, 2048, nullptr, nullptr, nullptr);
}

// Round 6
// 1534.414 us; speedup vs baseline: 1.3651x; 1.1325x over previous
//
#include <hip/hip_runtime.h>

// RWKV7-delta time-mix. f32 in/out, bf16 intermediates + MFMA bf16 16x16x32.
// B=2 T=4096 C=2048 H=32 K=64 CHUNK=128 NC=32.

typedef unsigned short u16;
typedef unsigned int   u32;
typedef __attribute__((ext_vector_type(8))) short s16x8;
typedef __attribute__((ext_vector_type(4))) float f32x4;

#define DEV __device__ __forceinline__

DEV float b2f(u16 v){ return __uint_as_float(((u32)v) << 16); }
DEV u16 f2b(float f){ u32 u = __float_as_uint(f); return (u16)((u + 0x7fffu + ((u >> 16) & 1u)) >> 16); }
DEV float clip30(float x){ return fminf(fmaxf(x, -30.f), 30.f); }
DEV void up8(uint4 v, float* f){
  f[0]=b2f((u16)(v.x&0xffffu)); f[1]=b2f((u16)(v.x>>16));
  f[2]=b2f((u16)(v.y&0xffffu)); f[3]=b2f((u16)(v.y>>16));
  f[4]=b2f((u16)(v.z&0xffffu)); f[5]=b2f((u16)(v.z>>16));
  f[6]=b2f((u16)(v.w&0xffffu)); f[7]=b2f((u16)(v.w>>16));
}
DEV uint4 pk8(const float* f){
  uint4 v;
  v.x = (u32)f2b(f[0]) | ((u32)f2b(f[1])<<16);
  v.y = (u32)f2b(f[2]) | ((u32)f2b(f[3])<<16);
  v.z = (u32)f2b(f[4]) | ((u32)f2b(f[5])<<16);
  v.w = (u32)f2b(f[6]) | ((u32)f2b(f[7])<<16);
  return v;
}
DEV void unp16(uint4 v, u16* o){
  o[0]=(u16)(v.x&0xffffu); o[1]=(u16)(v.x>>16);
  o[2]=(u16)(v.y&0xffffu); o[3]=(u16)(v.y>>16);
  o[4]=(u16)(v.z&0xffffu); o[5]=(u16)(v.z>>16);
  o[6]=(u16)(v.w&0xffffu); o[7]=(u16)(v.w>>16);
}
DEV void gload16(const u16* g, u16* l){
  __builtin_amdgcn_global_load_lds(
      (const __attribute__((address_space(1))) u32*)g,
      (__attribute__((address_space(3))) u32*)l, 16, 0, 0);
}
#define ZF4 ((f32x4){0.f,0.f,0.f,0.f})

// ---------------------------------------------------------------- transpose f32 -> bf16
__global__ void transpose_k(const float* __restrict__ in, u16* __restrict__ out, int R, int C){
  __shared__ float tile[32][33];
  int c0 = blockIdx.x*32, r0 = blockIdx.y*32;
  int tx = threadIdx.x, ty = threadIdx.y; // (32,8)
  #pragma unroll
  for (int j=0;j<4;j++) tile[ty + j*8][tx] = in[(size_t)(r0 + ty + j*8)*C + c0 + tx];
  __syncthreads();
  #pragma unroll
  for (int j=0;j<4;j++) out[(size_t)(c0 + ty + j*8)*R + r0 + tx] = f2b(tile[tx][ty + j*8]);
}

// ---------------------------------------------------------------- prep: xmx bf16, dxprev bf16, x_last f32
__global__ __launch_bounds__(256) void prep_k(const float* __restrict__ x, const float* __restrict__ shift,
    const float* __restrict__ maax, u16* __restrict__ xmx, u16* __restrict__ dxp, float* __restrict__ out_xlast){
  int e8 = (blockIdx.x*256 + threadIdx.x) * 8;
  int row = e8 >> 11, col = e8 & 2047;
  int t = row & 4095, b = row >> 12;
  const float* xp = x + (size_t)row*2048 + col;
  const float* pp = t ? (x + (size_t)(row-1)*2048 + col) : (shift + (size_t)b*2048 + col);
  float xf[8], pf[8], mf[8], of[8], df[8];
  *(float4*)(xf)   = *(const float4*)(xp);
  *(float4*)(xf+4) = *(const float4*)(xp+4);
  *(float4*)(pf)   = *(const float4*)(pp);
  *(float4*)(pf+4) = *(const float4*)(pp+4);
  *(float4*)(mf)   = *(const float4*)(maax + col);
  *(float4*)(mf+4) = *(const float4*)(maax + col + 4);
  #pragma unroll
  for (int j=0;j<8;j++){ df[j] = pf[j]-xf[j]; of[j] = xf[j] + df[j]*mf[j]; }
  *(uint4*)(xmx + (size_t)row*2048 + col) = pk8(of);
  *(uint4*)(dxp + (size_t)row*2048 + col) = pk8(df);
  if (t == 4095){
    *(float4*)(out_xlast + (size_t)b*2048 + col)     = *(const float4*)(xf);
    *(float4*)(out_xlast + (size_t)b*2048 + col + 4) = *(const float4*)(xf+4);
  }
}

// ---------------------------------------------------------------- generic 128x128 GEMM with fused epilogues
enum { EPI_STORE=0, EPI_TANH=1, EPI_SILU=2, EPI_LERP=3, EPI_ICLR=5, EPI_STORE32=6 };

template<int EPI, bool ASYNC, bool SWZ>
__global__ __launch_bounds__(256) void gemm_k(
    const u16* __restrict__ A, int lda,
    const u16* __restrict__ Bt, int ldb,
    u16* __restrict__ Cout, float* __restrict__ Cout32, int ldc,
    int M, int N, int K,
    const float* __restrict__ e_x, const u16* __restrict__ e_dxp, const float* __restrict__ e_vec)
{
  constexpr int LDW = ASYNC ? 32 : 40;
  __shared__ u16 As[128][LDW];
  __shared__ u16 Bs[128][LDW];
  const int tid = threadIdx.x;
  const int lane = tid & 63, wid = tid >> 6;
  int bxx = blockIdx.x, byy = blockIdx.y;
  if constexpr (SWZ){
    int nwg = gridDim.x * gridDim.y;
    if ((nwg & 7) == 0){
      int bid = byy * gridDim.x + bxx;
      int cpx = nwg >> 3;
      int swz = (bid & 7) * cpx + (bid >> 3);
      bxx = swz % gridDim.x; byy = swz / gridDim.x;
    }
  }
  const int m0 = bxx * 128, n0 = byy * 128;
  const int wrow = (wid >> 1) * 64, wcol = (wid & 1) * 64;
  const int fr = lane & 15, kg = lane >> 4;
  const int r_c0 = tid >> 2, r_seg = tid & 3;
  const int r_c1 = r_c0 + 64;

  f32x4 acc[4][4];
  #pragma unroll
  for (int m=0;m<4;m++)
    #pragma unroll
    for (int n=0;n<4;n++) acc[m][n] = ZF4;

  for (int k0 = 0; k0 < K; k0 += 32) {
    __syncthreads();
    if constexpr (ASYNC) {
      const int w4 = __builtin_amdgcn_readfirstlane(wid);
      const int rr = lane >> 2, seg8 = (lane & 3) * 8;
      #pragma unroll
      for (int i=0;i<2;i++){
        int row = w4*32 + i*16 + rr;
        gload16(A  + (size_t)(m0 + row)*lda + k0 + seg8, &As[w4*32 + i*16][0]);
        gload16(Bt + (size_t)(n0 + row)*ldb + k0 + seg8, &Bs[w4*32 + i*16][0]);
      }
    } else {
      uint4 av0 = *(const uint4*)(A + (size_t)(m0 + r_c0)*lda + k0 + r_seg*8);
      uint4 av1 = *(const uint4*)(A + (size_t)(m0 + r_c1)*lda + k0 + r_seg*8);
      *(uint4*)(&As[r_c0][r_seg*8]) = av0;
      *(uint4*)(&As[r_c1][r_seg*8]) = av1;
      uint4 z = make_uint4(0,0,0,0);
      uint4 bv0 = (n0 + r_c0 < N) ? *(const uint4*)(Bt + (size_t)(n0 + r_c0)*ldb + k0 + r_seg*8) : z;
      uint4 bv1 = (n0 + r_c1 < N) ? *(const uint4*)(Bt + (size_t)(n0 + r_c1)*ldb + k0 + r_seg*8) : z;
      *(uint4*)(&Bs[r_c0][r_seg*8]) = bv0;
      *(uint4*)(&Bs[r_c1][r_seg*8]) = bv1;
    }
    __syncthreads();
    s16x8 a[4], bb[4];
    #pragma unroll
    for (int m=0;m<4;m++) a[m] = *(const s16x8*)(&As[wrow + m*16 + fr][kg*8]);
    #pragma unroll
    for (int n=0;n<4;n++) bb[n] = *(const s16x8*)(&Bs[wcol + n*16 + fr][kg*8]);
    #pragma unroll
    for (int m=0;m<4;m++)
      #pragma unroll
      for (int n=0;n<4;n++)
        acc[m][n] = __builtin_amdgcn_mfma_f32_16x16x32_bf16(a[m], bb[n], acc[m][n], 0,0,0);
  }
  #pragma unroll
  for (int n=0;n<4;n++){
    int ccol = n0 + wcol + n*16 + fr;
    if (ccol >= N) continue;
    #pragma unroll
    for (int m=0;m<4;m++){
      #pragma unroll
      for (int q=0;q<4;q++){
        int row = m0 + wrow + m*16 + kg*4 + q;
        float v = acc[m][n][q];
        size_t oidx = (size_t)row*ldc + ccol;
        if constexpr (EPI == EPI_STORE) Cout[oidx] = f2b(v);
        else if constexpr (EPI == EPI_STORE32) Cout32[oidx] = v;
        else if constexpr (EPI == EPI_TANH) Cout[oidx] = f2b(tanhf(v));
        else if constexpr (EPI == EPI_SILU) Cout[oidx] = f2b(v / (1.f + expf(-v)));
        else if constexpr (EPI == EPI_LERP){
          float xv = e_x[(size_t)row*2048 + ccol];
          float dx = b2f(e_dxp[(size_t)row*2048 + ccol]);
          Cout[oidx] = f2b(xv + dx * (e_vec[ccol] + v));
        }
        else if constexpr (EPI == EPI_ICLR) Cout[oidx] = f2b(1.f / (1.f + expf(-(e_vec[ccol] + v))));
      }
    }
  }
}

// ---------------------------------------------------------------- thin GEMM: 64x64 tile, for small N (more blocks)
template<int EPI>
__global__ __launch_bounds__(256) void gemm_thin_k(
    const u16* __restrict__ A, int lda,
    const u16* __restrict__ Bt, int ldb,
    u16* __restrict__ Cout, int ldc, int N, int K)
{
  __shared__ u16 As[64][40];
  __shared__ u16 Bs[64][40];
  const int tid = threadIdx.x;
  const int lane = tid & 63, wid = tid >> 6;
  const int m0 = blockIdx.x * 64, n0 = blockIdx.y * 64;
  const int wrow = (wid >> 1) * 32, wcol = (wid & 1) * 32;
  const int fr = lane & 15, kg = lane >> 4;
  const int r_c = tid >> 2, r_seg = tid & 3;

  f32x4 acc[2][2];
  #pragma unroll
  for (int m=0;m<2;m++)
    #pragma unroll
    for (int n=0;n<2;n++) acc[m][n] = ZF4;

  for (int k0 = 0; k0 < K; k0 += 32) {
    __syncthreads();
    {
      uint4 av = *(const uint4*)(A + (size_t)(m0 + r_c)*lda + k0 + r_seg*8);
      *(uint4*)(&As[r_c][r_seg*8]) = av;
      uint4 z = make_uint4(0,0,0,0);
      uint4 bv = (n0 + r_c < N) ? *(const uint4*)(Bt + (size_t)(n0 + r_c)*ldb + k0 + r_seg*8) : z;
      *(uint4*)(&Bs[r_c][r_seg*8]) = bv;
    }
    __syncthreads();
    s16x8 a[2], bb[2];
    #pragma unroll
    for (int m=0;m<2;m++) a[m] = *(const s16x8*)(&As[wrow + m*16 + fr][kg*8]);
    #pragma unroll
    for (int n=0;n<2;n++) bb[n] = *(const s16x8*)(&Bs[wcol + n*16 + fr][kg*8]);
    #pragma unroll
    for (int m=0;m<2;m++)
      #pragma unroll
      for (int n=0;n<2;n++)
        acc[m][n] = __builtin_amdgcn_mfma_f32_16x16x32_bf16(a[m], bb[n], acc[m][n], 0,0,0);
  }
  #pragma unroll
  for (int n=0;n<2;n++){
    int ccol = n0 + wcol + n*16 + fr;
    if (ccol >= N) continue;
    #pragma unroll
    for (int m=0;m<2;m++){
      #pragma unroll
      for (int q=0;q<4;q++){
        int row = m0 + wrow + m*16 + kg*4 + q;
        float v = acc[m][n][q];
        size_t oidx = (size_t)row*ldc + ccol;
        if constexpr (EPI == EPI_TANH) Cout[oidx] = f2b(tanhf(v));
        else Cout[oidx] = f2b(v);
      }
    }
  }
}

// ---------------------------------------------------------------- WKV phase 1: per chunk-head, 512 threads / 8 waves
__global__ __launch_bounds__(512, 1) void wkv1_k(
    const u16* __restrict__ r_g, const u16* __restrict__ kraw_g, const u16* __restrict__ v_g,
    const u16* __restrict__ ic_g,
    const u16* __restrict__ t2_g, const u16* __restrict__ dw2t_g, const float* __restrict__ td_g,
    const float* __restrict__ u_g, const float* __restrict__ kkk_g, const float* __restrict__ kka_g,
    u16* __restrict__ y1_g, u16* __restrict__ rw_g,
    u16* __restrict__ kvab_g, float* __restrict__ wsA_g)
{
  __shared__ __align__(16) char arena[161792];
  float* WL   = (float*)(arena);
  float* WC   = (float*)(arena + 34816);
  u16* Abuf   = (u16*)(arena);
  u16* kkcT   = (u16*)(arena + 34816);
  u16* rd_l   = (u16*)(arena + 69632);
  u16* vT_l   = (u16*)(arena + 69632);
  u16* ki_l   = (u16*)(arena + 88064);
  u16* kkwT_l = (u16*)(arena + 88064);
  u16* kwT_l  = (u16*)(arena + 106496);
  u16* ka_l   = (u16*)(arena + 124928);
  u16* kkb_l  = (u16*)(arena + 143360);
  u16* kaT_l  = (u16*)(arena + 143360);
  float* diag_l = (float*)(arena + 67584);  // 128
  float* offs_l = diag_l + 128;             // 64
  float* wsum_l = offs_l + 64;              // 64
  float* u_l    = wsum_l + 64;              // 64
  float* kkk_l  = u_l + 64;                 // 64
  float* kka_l  = kkk_l + 64;               // 64
  float* td_l   = kka_l + 64;               // 64 -> ends at 69632

  const int tid = threadIdx.x, lane = tid & 63, wid = tid >> 6;  // wid 0..7
  const int cb = blockIdx.x;
  const int c = cb >> 6, b = (cb >> 5) & 1, h = cb & 31;
  const size_t base = ((size_t)(b*4096 + c*128)) * 2048 + h*64;
  const int fr = lane & 15, kg = lane >> 4;
  const int tq = tid >> 2, kh = (tid & 3) * 16;   // 4 threads per row, 16 cols each

  // P0a: stage t2 [128][64] + dw2t head-slice [64][64]; per-head vectors
  {
    const u16* t2s = t2_g + (size_t)(b*4096 + c*128 + tq)*64 + kh;
    *(uint4*)(&rd_l[tq*72 + kh])     = *(const uint4*)(t2s);
    *(uint4*)(&rd_l[tq*72 + kh + 8]) = *(const uint4*)(t2s + 8);
    int n = tid >> 3, sg2 = (tid & 7) * 8;
    *(uint4*)(&ki_l[n*72 + sg2]) = *(const uint4*)(dw2t_g + (size_t)(h*64 + n)*64 + sg2);
  }
  if (tid < 64){
    u_l[tid]   = u_g[h*64 + tid];
    kkk_l[tid] = kkk_g[h*64 + tid];
    kka_l[tid] = kka_g[h*64 + tid];
    td_l[tid]  = td_g[h*64 + tid];
  }
  __syncthreads();
  // P0b: WL[t][k] = -exp(td[k] + t2[t,:] . dw2[:,k])
  {
    f32x4 accW[4];
    #pragma unroll
    for (int n=0;n<4;n++) accW[n] = ZF4;
    #pragma unroll
    for (int ks=0; ks<2; ++ks){
      s16x8 af = *(const s16x8*)(&rd_l[(wid*16 + fr)*72 + ks*32 + kg*8]);
      #pragma unroll
      for (int n=0;n<4;n++){
        s16x8 bf = *(const s16x8*)(&ki_l[(n*16 + fr)*72 + ks*32 + kg*8]);
        accW[n] = __builtin_amdgcn_mfma_f32_16x16x32_bf16(af, bf, accW[n], 0,0,0);
      }
    }
    #pragma unroll
    for (int n=0;n<4;n++)
      #pragma unroll
      for (int q=0;q<4;q++){
        int t = wid*16 + kg*4 + q;
        int s = n*16 + fr;
        WL[t*64 + s] = -expf(td_l[s] + accW[n][q]);
      }
  }
  __syncthreads();
  // scan: inclusive cumsum over t per column k — 8 cols per wave
  for (int j=0;j<8;j++){
    int k = wid*8 + j;
    float v = WL[lane*64 + k];
    #pragma unroll
    for (int d=1; d<64; d<<=1){ float o = __shfl_up(v, d); if (lane >= d) v += o; }
    WC[lane*64 + k] = v;
    float carry = __shfl(v, 63);
    float v2 = WL[(64+lane)*64 + k];
    #pragma unroll
    for (int d=1; d<64; d<<=1){ float o = __shfl_up(v2, d); if (lane >= d) v2 += o; }
    v2 += carry;
    WC[(64+lane)*64 + k] = v2;
    float tot = __shfl(v2, 63);
    if (lane == 0){ offs_l[k] = carry; wsum_l[k] = tot; wsA_g[(size_t)cb*64 + k] = expf(tot); }
  }
  __syncthreads();
  // P1: r, kadj -> rd, ki (natural), kwT (transposed), rw (global), diag
  {
    const u16* rs  = r_g    + base + (size_t)tq*2048 + kh;
    const u16* ks_ = kraw_g + base + (size_t)tq*2048 + kh;
    const u16* is_ = ic_g   + base + (size_t)tq*2048 + kh;
    float dpart = 0.f;
    #pragma unroll
    for (int j=0;j<2;j++){
      float rf[8], kf[8], icf[8], rdf[8], kif[8], rwf[8];
      up8(*(const uint4*)(rs + j*8), rf);
      up8(*(const uint4*)(ks_ + j*8), kf);
      up8(*(const uint4*)(is_ + j*8), icf);
      #pragma unroll
      for (int e=0;e<8;e++){
        int k = kh + j*8 + e;
        float kadj = kf[e] * (1.f + (icf[e] - 1.f) * kka_l[k]);
        float wl = WL[tq*64+k], wc = WC[tq*64+k];
        float wcs = wc - wl;
        float off = offs_l[k], wsm = wsum_l[k];
        rdf[e] = rf[e] * expf(clip30(wcs - off));
        kif[e] = kadj  * expf(clip30(off - wc));
        rwf[e] = rf[e] * expf(clip30(wcs));
        kwT_l[k*136 + tq] = f2b(kadj * expf(clip30(wsm - wc)));
        dpart += rf[e] * u_l[k] * kadj;
      }
      *(uint4*)(&rd_l[tq*72 + kh + j*8]) = pk8(rdf);
      *(uint4*)(&ki_l[tq*72 + kh + j*8]) = pk8(kif);
      *(uint4*)(rw_g + base + (size_t)tq*2048 + kh + j*8) = pk8(rwf);
    }
    dpart += __shfl_xor(dpart, 1);
    dpart += __shfl_xor(dpart, 2);
    if ((tid & 3) == 0) diag_l[tq] = dpart;
  }
  __syncthreads();
  // P2: raw k, iclr -> ka = kk*iclr, kkb = kk (normalized)
  {
    const u16* ks_ = kraw_g + base + (size_t)tq*2048 + kh;
    const u16* is_ = ic_g   + base + (size_t)tq*2048 + kh;
    float kf[16], icf[16], kkraw[16];
    #pragma unroll
    for (int j=0;j<2;j++){
      up8(*(const uint4*)(ks_ + j*8), kf + j*8);
      up8(*(const uint4*)(is_ + j*8), icf + j*8);
    }
    float ss = 0.f;
    #pragma unroll
    for (int e=0;e<16;e++){ kkraw[e] = kf[e]*kkk_l[kh+e]; ss += kkraw[e]*kkraw[e]; }
    ss += __shfl_xor(ss, 1);
    ss += __shfl_xor(ss, 2);
    float rn = 1.f / fmaxf(sqrtf(ss), 1e-12f);
    #pragma unroll
    for (int j=0;j<2;j++){
      float kkb8[8], ka8[8];
      #pragma unroll
      for (int e=0;e<8;e++){
        float kkv = kkraw[j*8+e]*rn;
        kkb8[e] = kkv; ka8[e] = kkv*icf[j*8+e];
      }
      *(uint4*)(&kkb_l[tq*72 + kh + j*8]) = pk8(kkb8);
      *(uint4*)(&ka_l [tq*72 + kh + j*8]) = pk8(ka8);
    }
  }
  __syncthreads();
  // P3: A = rd @ ki^T (wave w -> m-tile w), mask strict-lower + diag
  f32x4 accA[8];
  #pragma unroll
  for (int n=0;n<8;n++) accA[n] = ZF4;
  #pragma unroll
  for (int ks=0; ks<2; ++ks){
    s16x8 af = *(const s16x8*)(&rd_l[(wid*16 + fr)*72 + ks*32 + kg*8]);
    #pragma unroll
    for (int n=0;n<8;n++){
      s16x8 bf = *(const s16x8*)(&ki_l[(n*16 + fr)*72 + ks*32 + kg*8]);
      accA[n] = __builtin_amdgcn_mfma_f32_16x16x32_bf16(af, bf, accA[n], 0,0,0);
    }
  }
  #pragma unroll
  for (int n=0;n<8;n++)
    #pragma unroll
    for (int q=0;q<4;q++){
      int t = wid*16 + kg*4 + q;
      int s = n*16 + fr;
      float v = accA[n][q];
      v = (t > s) ? v : ((t == s) ? diag_l[t] : 0.f);
      accA[n][q] = v;
      Abuf[t*136 + s] = f2b(v);
    }
  __syncthreads();
  // P4a: kkwT[k][t] = -kk * w_inter
  {
    #pragma unroll
    for (int j=0;j<2;j++){
      float kkf[8];
      up8(*(const uint4*)(&kkb_l[tq*72 + kh + j*8]), kkf);
      #pragma unroll
      for (int e=0;e<8;e++){
        int k = kh + j*8 + e;
        kkwT_l[k*136 + tq] = f2b(-kkf[e] * expf(clip30(wsum_l[k] - WC[tq*64+k])));
      }
    }
  }
  __syncthreads();
  // P4b: kk_corr = ka @ kkb^T, strict-lower, write transposed kkcT[s][t]
  {
    f32x4 accC[8];
    #pragma unroll
    for (int n=0;n<8;n++) accC[n] = ZF4;
    #pragma unroll
    for (int ks=0; ks<2; ++ks){
      s16x8 af = *(const s16x8*)(&ka_l[(wid*16 + fr)*72 + ks*32 + kg*8]);
      #pragma unroll
      for (int n=0;n<8;n++){
        s16x8 bf = *(const s16x8*)(&kkb_l[(n*16 + fr)*72 + ks*32 + kg*8]);
        accC[n] = __builtin_amdgcn_mfma_f32_16x16x32_bf16(af, bf, accC[n], 0,0,0);
      }
    }
    #pragma unroll
    for (int n=0;n<8;n++)
      #pragma unroll
      for (int q=0;q<4;q++){
        int t = wid*16 + kg*4 + q;
        int s = n*16 + fr;
        kkcT[s*136 + t] = f2b((t > s) ? accC[n][q] : 0.f);
      }
  }
  __syncthreads();
  // P5a: stage v transposed (vT[vd][t]) + kaT[j][t] (over dead kkb)
  {
    const u16* vs = v_g + base + (size_t)tq*2048 + kh;
    #pragma unroll
    for (int j=0;j<2;j++){
      u16 el[8]; unp16(*(const uint4*)(vs + j*8), el);
      #pragma unroll
      for (int e=0;e<8;e++) vT_l[(kh + j*8 + e)*136 + tq] = el[e];
    }
    #pragma unroll
    for (int j=0;j<2;j++){
      u16 el[8]; unp16(*(const uint4*)(&ka_l[tq*72 + kh + j*8]), el);
      #pragma unroll
      for (int e=0;e<8;e++) kaT_l[(kh + j*8 + e)*136 + tq] = el[e];
    }
  }
  // P5b: P = Amask @ kkc ; A_total = Amask - tril(P) -> Abuf
  {
    f32x4 accP[8];
    #pragma unroll
    for (int n=0;n<8;n++) accP[n] = ZF4;
    #pragma unroll
    for (int ks=0; ks<4; ++ks){
      s16x8 af = *(const s16x8*)(&Abuf[(wid*16 + fr)*136 + ks*32 + kg*8]);
      #pragma unroll
      for (int n=0;n<8;n++){
        s16x8 bf = *(const s16x8*)(&kkcT[(n*16 + fr)*136 + ks*32 + kg*8]);
        accP[n] = __builtin_amdgcn_mfma_f32_16x16x32_bf16(af, bf, accP[n], 0,0,0);
      }
    }
    #pragma unroll
    for (int n=0;n<8;n++)
      #pragma unroll
      for (int q=0;q<4;q++){
        int t = wid*16 + kg*4 + q;
        int s = n*16 + fr;
        float v = accA[n][q] - ((t >= s) ? accP[n][q] : 0.f);
        Abuf[t*136 + s] = f2b(v);
      }
  }
  __syncthreads();
  // P6: y_intra = A_total @ v
  {
    f32x4 accY[4];
    #pragma unroll
    for (int n=0;n<4;n++) accY[n] = ZF4;
    #pragma unroll
    for (int ks=0; ks<4; ++ks){
      s16x8 af = *(const s16x8*)(&Abuf[(wid*16 + fr)*136 + ks*32 + kg*8]);
      #pragma unroll
      for (int n=0;n<4;n++){
        s16x8 bf = *(const s16x8*)(&vT_l[(n*16 + fr)*136 + ks*32 + kg*8]);
        accY[n] = __builtin_amdgcn_mfma_f32_16x16x32_bf16(af, bf, accY[n], 0,0,0);
      }
    }
    #pragma unroll
    for (int n=0;n<4;n++)
      #pragma unroll
      for (int q=0;q<4;q++){
        int t = wid*16 + kg*4 + q;
        int vd = n*16 + fr;
        y1_g[base + (size_t)t*2048 + vd] = f2b(accY[n][q]);
      }
  }
  // P7: kv = kwT @ vT^T (waves 0-3, row-major) ; ab = kkwT @ kaT^T (waves 4-7, stored TRANSPOSED for wkv2)
  {
    const int isAB = wid >> 2, mrow = (wid & 3) * 16;
    const u16* Amat = isAB ? kkwT_l : kwT_l;
    const u16* Bmat = isAB ? kaT_l  : vT_l;
    f32x4 acc2[4];
    #pragma unroll
    for (int n=0;n<4;n++) acc2[n] = ZF4;
    #pragma unroll
    for (int ks=0; ks<4; ++ks){
      s16x8 af = *(const s16x8*)(&Amat[(mrow + fr)*136 + ks*32 + kg*8]);
      #pragma unroll
      for (int n=0;n<4;n++){
        s16x8 bf = *(const s16x8*)(&Bmat[(n*16 + fr)*136 + ks*32 + kg*8]);
        acc2[n] = __builtin_amdgcn_mfma_f32_16x16x32_bf16(af, bf, acc2[n], 0,0,0);
      }
    }
    u16* kvp = kvab_g + (size_t)cb*8192 + isAB*4096;
    #pragma unroll
    for (int n=0;n<4;n++)
      #pragma unroll
      for (int q=0;q<4;q++){
        int kd = mrow + kg*4 + q, vd = n*16 + fr;
        if (isAB) kvp[vd*64 + kd] = f2b(acc2[n][q]);   // abT[v][k] for wkv2 B-operand
        else      kvp[kd*64 + vd] = f2b(acc2[n][q]);   // kv[k][v]
      }
  }
}

// ---------------------------------------------------------------- WKV phase 2: MFMA state scan per (b,h), reg prefetch
__global__ __launch_bounds__(256) void wkv2_k(
   const float* __restrict__ state_in, u16* __restrict__ kvab_g,
   const float* __restrict__ wsA_g, float* __restrict__ out_state)
{
  __shared__ u16 Sb[64][72];    // bf16 S (A-operand); only the S@ab input is rounded
  __shared__ u16 abT[64][72];   // abT[v_out][k_contract]
  const int tid = threadIdx.x, lane = tid & 63, wid = tid >> 6;
  const int bh = blockIdx.x, b = bh >> 5, h = bh & 31;
  const int fr = lane & 15, kg = lane >> 4;
  const int r0 = wid*16 + kg*4;                     // thread's 4 rows (C-layout)
  const int vrow = tid >> 2, jc = (tid & 3) * 16;   // abT staging ownership

  f32x4 S[4];   // n-frags: S[n][q] = S[r0+q][n*16+fr], f32 across the whole scan
  #pragma unroll
  for (int n=0;n<4;n++)
    #pragma unroll
    for (int q=0;q<4;q++)
      S[n][q] = state_in[(size_t)bh*4096 + (size_t)(r0+q)*64 + n*16+fr];

  uint4 pf_ab0, pf_ab1; u16 pf_kv[16]; float pf_ws[4];
  {
    int cb = b*32 + h;   // chunk 0
    const u16* kvp = kvab_g + (size_t)cb*8192;
    pf_ab0 = *(const uint4*)(kvp + 4096 + vrow*64 + jc);
    pf_ab1 = *(const uint4*)(kvp + 4096 + vrow*64 + jc + 8);
    #pragma unroll
    for (int n=0;n<4;n++)
      #pragma unroll
      for (int q=0;q<4;q++)
        pf_kv[n*4+q] = kvp[(r0+q)*64 + n*16+fr];
    #pragma unroll
    for (int n=0;n<4;n++) pf_ws[n] = wsA_g[(size_t)cb*64 + n*16+fr];
  }

  for (int c=0;c<32;c++){
    int cb = (c*2+b)*32 + h;
    // stage LDS from prefetched regs + current S (bf16)
    *(uint4*)(&abT[vrow][jc])   = pf_ab0;
    *(uint4*)(&abT[vrow][jc+8]) = pf_ab1;
    #pragma unroll
    for (int n=0;n<4;n++)
      #pragma unroll
      for (int q=0;q<4;q++)
        Sb[r0+q][n*16+fr] = f2b(S[n][q]);
    float kvf[16], wsf[4];
    #pragma unroll
    for (int i=0;i<16;i++) kvf[i] = b2f(pf_kv[i]);
    #pragma unroll
    for (int n=0;n<4;n++) wsf[n] = pf_ws[n];
    // write entry-state S_in (f32) for wkv3 — overwrites this chunk's kv/abT (already consumed)
    float* sip = (float*)(kvab_g + (size_t)cb*8192);
    #pragma unroll
    for (int n=0;n<4;n++)
      #pragma unroll
      for (int q=0;q<4;q++)
        sip[(r0+q)*64 + n*16+fr] = S[n][q];
    __syncthreads();
    // prefetch chunk c+1 (hidden under MFMA + update)
    if (c < 31){
      int cb2 = ((c+1)*2+b)*32 + h;
      const u16* kvp2 = kvab_g + (size_t)cb2*8192;
      pf_ab0 = *(const uint4*)(kvp2 + 4096 + vrow*64 + jc);
      pf_ab1 = *(const uint4*)(kvp2 + 4096 + vrow*64 + jc + 8);
      #pragma unroll
      for (int n=0;n<4;n++)
        #pragma unroll
        for (int q=0;q<4;q++)
          pf_kv[n*4+q] = kvp2[(r0+q)*64 + n*16+fr];
      #pragma unroll
      for (int n=0;n<4;n++) pf_ws[n] = wsA_g[(size_t)cb2*64 + n*16+fr];
    }
    // acc = S @ ab  (MFMA; contraction over S columns)
    f32x4 acc[4];
    #pragma unroll
    for (int n=0;n<4;n++) acc[n] = ZF4;
    #pragma unroll
    for (int ks=0; ks<2; ++ks){
      s16x8 a = *(const s16x8*)(&Sb[wid*16 + fr][ks*32 + kg*8]);
      #pragma unroll
      for (int n=0;n<4;n++){
        s16x8 bb = *(const s16x8*)(&abT[n*16 + fr][ks*32 + kg*8]);
        acc[n] = __builtin_amdgcn_mfma_f32_16x16x32_bf16(a, bb, acc[n], 0,0,0);
      }
    }
    // S = S*ws + acc + kv   (f32)
    #pragma unroll
    for (int n=0;n<4;n++)
      #pragma unroll
      for (int q=0;q<4;q++)
        S[n][q] = S[n][q]*wsf[n] + acc[n][q] + kvf[n*4+q];
    __syncthreads();
  }
  #pragma unroll
  for (int n=0;n<4;n++)
    #pragma unroll
    for (int q=0;q<4;q++)
      out_state[(size_t)bh*4096 + (size_t)(r0+q)*64 + n*16+fr] = S[n][q];
}

// ---------------------------------------------------------------- WKV phase 3: y = y1 + rw@S_in, GroupNorm, *g
__global__ __launch_bounds__(256) void wkv3_k(
   const u16* __restrict__ y1_g, const u16* __restrict__ rw_g,
   const u16* __restrict__ kvab_g,
   const u16* __restrict__ g_g, const float* __restrict__ gnw, const float* __restrict__ gnb,
   u16* __restrict__ yf_g)
{
  __shared__ float S_l[64][65];
  __shared__ u16 rw_l[128][72];
  int tid = threadIdx.x;
  int cb = blockIdx.x; int c = cb>>6, b = (cb>>5)&1, h = cb&31;
  size_t base = ((size_t)(b*4096 + c*128))*2048 + h*64;
  const float* sip = (const float*)(kvab_g + (size_t)cb*8192);
  #pragma unroll
  for (int j=0;j<16;j++){ int flat = tid*16+j; S_l[flat>>6][flat&63] = sip[flat]; }
  {
    int t = tid>>1, kh = (tid&1)*32;
    const u16* rs = rw_g + base + (size_t)t*2048 + kh;
    #pragma unroll
    for (int j=0;j<4;j++) *(uint4*)(&rw_l[t][kh+j*8]) = *(const uint4*)(rs + j*8);
  }
  __syncthreads();
  int t = tid>>1, vh = (tid&1)*32;
  float acc[32];
  #pragma unroll
  for (int j=0;j<32;j++) acc[j] = 0.f;
  for (int kf2=0; kf2<64; kf2++){
    float rv = b2f(rw_l[t][kf2]);
    #pragma unroll
    for (int j=0;j<32;j++) acc[j] += rv * S_l[kf2][vh+j];
  }
  float sum=0.f, sq=0.f;
  float yv[32];
  #pragma unroll
  for (int j=0;j<32;j++){
    yv[j] = acc[j] + b2f(y1_g[base + (size_t)t*2048 + vh + j]);
    sum += yv[j]; sq += yv[j]*yv[j];
  }
  sum += __shfl_xor(sum, 1); sq += __shfl_xor(sq, 1);
  float mean = sum * (1.f/64.f);
  float var = sq * (1.f/64.f) - mean*mean;
  float rstd = rsqrtf(fmaxf(var, 0.f) + 6.4e-4f);
  size_t bt = (size_t)(b*4096 + c*128 + t);
  #pragma unroll
  for (int j=0;j<32;j++){
    int ch = h*64 + vh + j;
    float val = (yv[j]-mean)*rstd * gnw[ch] + gnb[ch];
    val *= b2f(g_g[bt*2048 + ch]);
    yf_g[base + (size_t)t*2048 + vh + j] = f2b(val);
  }
}

// ---------------------------------------------------------------- host
#define O_WTR   0ull
#define O_WTK   8388608ull
#define O_WTV   16777216ull
#define O_WTG   25165824ull
#define O_WTO   33554432ull
#define O_W1T   41943040ull
#define O_W2T   42729472ull
#define O_DW1T  43515904ull
#define O_DW2T  43778048ull
#define O_A1T   44040192ull
#define O_A2T   44433408ull
#define O_XXX   44826624ull
#define O_T2    47972352ull
#define O_T3    49020928ull
#define O_WSA   50593792ull
#define O_XMX   51118080ull       /* 32MB: xmx -> g */
#define O_A     84672512ull       /* 32MB: lerp staging -> kvab/S_in */
#define O_I     118226944ull      /* 32MB: dxprev -> iclr */
#define O_R     151781376ull
#define O_K     185335808ull      /* raw k -> y1 -> yf */
#define O_V     218890240ull
#define WS_NEEDED 252444672ull

extern "C" void kernel_launch(void* const* d_in, const int* in_sizes, int n_in,
                              void* d_out, int out_size, void* d_ws, size_t ws_size,
                              hipStream_t stream)
{
  (void)in_sizes; (void)n_in; (void)out_size;
  if (ws_size < WS_NEEDED) return;
  const float* x     = (const float*)d_in[0];
  const float* shift = (const float*)d_in[1];
  const float* st_in = (const float*)d_in[2];
  const float* maax  = (const float*)d_in[3];
  const float* maas[6] = {(const float*)d_in[4],(const float*)d_in[5],(const float*)d_in[6],
                          (const float*)d_in[7],(const float*)d_in[8],(const float*)d_in[9]};
  const float* w1    = (const float*)d_in[10];
  const float* w2    = (const float*)d_in[11];
  const float* td    = (const float*)d_in[12];
  const float* dw1   = (const float*)d_in[13];
  const float* dw2   = (const float*)d_in[14];
  const float* faaaa = (const float*)d_in[15];
  const float* a0v   = (const float*)d_in[16];
  const float* a1w   = (const float*)d_in[17];
  const float* a2w   = (const float*)d_in[18];
  const float* kkk   = (const float*)d_in[19];
  const float* kka   = (const float*)d_in[20];
  const float* Wr    = (const float*)d_in[21];
  const float* Wk    = (const float*)d_in[22];
  const float* Wv    = (const float*)d_in[23];
  const float* Wg    = (const float*)d_in[24];
  const float* Wo    = (const float*)d_in[25];
  const float* gnw   = (const float*)d_in[26];
  const float* gnb   = (const float*)d_in[27];
  float* out = (float*)d_out;
  char* ws = (char*)d_ws;
  #define WSP(o) ((u16*)(ws + (o)))

  u16 *wtR=WSP(O_WTR), *wtK=WSP(O_WTK), *wtV=WSP(O_WTV), *wtG=WSP(O_WTG), *wtO=WSP(O_WTO);
  u16 *w1t=WSP(O_W1T), *w2t=WSP(O_W2T), *dw1t=WSP(O_DW1T), *dw2t=WSP(O_DW2T), *a1t=WSP(O_A1T), *a2t=WSP(O_A2T);
  u16 *xxx=WSP(O_XXX), *t2b=WSP(O_T2), *t3b=WSP(O_T3);
  u16 *xmx=WSP(O_XMX), *Ab=WSP(O_A), *Ib=WSP(O_I), *Rb=WSP(O_R), *Kb=WSP(O_K), *Vb=WSP(O_V);
  u16 *rw = WSP(O_WTR);
  u16 *kvab = WSP(O_A);
  u16 *gbuf = WSP(O_XMX);
  u16 *dxp  = WSP(O_I);
  float* wsA = (float*)(ws + O_WSA);
  float* out_xlast = out + 16777216;
  float* out_state = out + 16781312;

  dim3 tb(32,8);
  transpose_k<<<dim3(64,64), tb, 0, stream>>>(Wr, wtR, 2048, 2048);
  transpose_k<<<dim3(64,64), tb, 0, stream>>>(Wk, wtK, 2048, 2048);
  transpose_k<<<dim3(64,64), tb, 0, stream>>>(Wv, wtV, 2048, 2048);
  transpose_k<<<dim3(64,64), tb, 0, stream>>>(Wg, wtG, 2048, 2048);
  transpose_k<<<dim3(64,64), tb, 0, stream>>>(Wo, wtO, 2048, 2048);
  transpose_k<<<dim3(6,64),  tb, 0, stream>>>(w1, w1t, 2048, 192);
  transpose_k<<<dim3(64,6),  tb, 0, stream>>>(w2, w2t, 192, 2048);
  transpose_k<<<dim3(2,64),  tb, 0, stream>>>(dw1, dw1t, 2048, 64);
  transpose_k<<<dim3(64,2),  tb, 0, stream>>>(dw2, dw2t, 64, 2048);
  transpose_k<<<dim3(3,64),  tb, 0, stream>>>(a1w, a1t, 2048, 96);
  transpose_k<<<dim3(64,3),  tb, 0, stream>>>(a2w, a2t, 96, 2048);

  prep_k<<<8192, 256, 0, stream>>>(x, shift, maax, xmx, dxp, out_xlast);

  // xxx = tanh(xmx @ w1)
  gemm_thin_k<EPI_TANH><<<dim3(128,3), 256, 0, stream>>>(xmx, 2048, w1t, 2048, xxx, 192, 192, 2048);
  // xw -> Ab ; t2 = tanh(xw @ dw1)
  gemm_k<EPI_LERP,true,true><<<dim3(64,16), 256, 0, stream>>>(xxx + 0*32, 192, w2t + 0*32, 192, Ab, nullptr, 2048, 8192, 2048, 32, x, dxp, maas[0]);
  gemm_thin_k<EPI_TANH><<<dim3(128,1), 256, 0, stream>>>(Ab, 2048, dw1t, 2048, t2b, 64, 64, 2048);
  // xa -> Ab ; t3 = xa @ a1
  gemm_k<EPI_LERP,true,true><<<dim3(64,16), 256, 0, stream>>>(xxx + 5*32, 192, w2t + 5*32, 192, Ab, nullptr, 2048, 8192, 2048, 32, x, dxp, maas[5]);
  gemm_thin_k<EPI_STORE><<<dim3(128,2), 256, 0, stream>>>(Ab, 2048, a1t, 2048, t3b, 96, 96, 2048);
  // xr -> Ab ; r = xr @ Wr
  gemm_k<EPI_LERP,true,true><<<dim3(64,16), 256, 0, stream>>>(xxx + 3*32, 192, w2t + 3*32, 192, Ab, nullptr, 2048, 8192, 2048, 32, x, dxp, maas[3]);
  gemm_k<EPI_STORE,true,true><<<dim3(64,16), 256, 0, stream>>>(Ab, 2048, wtR, 2048, Rb, nullptr, 2048, 8192, 2048, 2048, nullptr, nullptr, nullptr);
  // xk -> Ab ; k(raw) = xk @ Wk
  gemm_k<EPI_LERP,true,true><<<dim3(64,16), 256, 0, stream>>>(xxx + 1*32, 192, w2t + 1*32, 192, Ab, nullptr, 2048, 8192, 2048, 32, x, dxp, maas[1]);
  gemm_k<EPI_STORE,true,true><<<dim3(64,16), 256, 0, stream>>>(Ab, 2048, wtK, 2048, Kb, nullptr, 2048, 8192, 2048, 2048, nullptr, nullptr, nullptr);
  // xv -> Ab ; v = xv @ Wv
  gemm_k<EPI_LERP,true,true><<<dim3(64,16), 256, 0, stream>>>(xxx + 2*32, 192, w2t + 2*32, 192, Ab, nullptr, 2048, 8192, 2048, 32, x, dxp, maas[2]);
  gemm_k<EPI_STORE,true,true><<<dim3(64,16), 256, 0, stream>>>(Ab, 2048, wtV, 2048, Vb, nullptr, 2048, 8192, 2048, 2048, nullptr, nullptr, nullptr);
  // xg -> Ab ; g = silu(xg @ Wg)
  gemm_k<EPI_LERP,true,true><<<dim3(64,16), 256, 0, stream>>>(xxx + 4*32, 192, w2t + 4*32, 192, Ab, nullptr, 2048, 8192, 2048, 32, x, dxp, maas[4]);
  gemm_k<EPI_SILU,true,true><<<dim3(64,16), 256, 0, stream>>>(Ab, 2048, wtG, 2048, gbuf, nullptr, 2048, 8192, 2048, 2048, nullptr, nullptr, nullptr);
  // iclr = sigmoid(a0 + t3 @ a2)
  gemm_k<EPI_ICLR,true,true><<<dim3(64,16), 256, 0, stream>>>(t3b, 96, a2t, 96, Ib, nullptr, 2048, 8192, 2048, 96, nullptr, nullptr, a0v);
  // wkv
  wkv1_k<<<2048, 512, 0, stream>>>(Rb, Kb, Vb, Ib, t2b, dw2t, td, faaaa, kkk, kka,
                                   Kb /*y1 overwrites raw k*/, rw, kvab, wsA);
  wkv2_k<<<64, 256, 0, stream>>>(st_in, kvab, wsA, out_state);
  wkv3_k<<<2048, 256, 0, stream>>>(Kb /*y1*/, rw, kvab /*S_in*/, gbuf, gnw, gnb, Kb /*yf in place*/);
  // out = yf @ W_o  (f32 store)
  gemm_k<EPI_STORE32,true,true><<<dim3(64,16), 256, 0, stream>>>(Kb, 2048, wtO, 2048, nullptr, out, 2048, 8192, 2048, 2048, nullptr, nullptr, nullptr);
}

// Round 7
// 1300.583 us; speedup vs baseline: 1.6105x; 1.1798x over previous
//
#include <hip/hip_runtime.h>

// RWKV7-delta time-mix. f32 in/out, bf16 intermediates + MFMA bf16 16x16x32.
// B=2 T=4096 C=2048 H=32 K=64 CHUNK=128 NC=32.

typedef unsigned short u16;
typedef unsigned int   u32;
typedef __attribute__((ext_vector_type(8))) short s16x8;
typedef __attribute__((ext_vector_type(4))) float f32x4;

#define DEV __device__ __forceinline__

DEV float b2f(u16 v){ return __uint_as_float(((u32)v) << 16); }
DEV u16 f2b(float f){ u32 u = __float_as_uint(f); return (u16)((u + 0x7fffu + ((u >> 16) & 1u)) >> 16); }
DEV float clip30(float x){ return fminf(fmaxf(x, -30.f), 30.f); }
DEV void up8(uint4 v, float* f){
  f[0]=b2f((u16)(v.x&0xffffu)); f[1]=b2f((u16)(v.x>>16));
  f[2]=b2f((u16)(v.y&0xffffu)); f[3]=b2f((u16)(v.y>>16));
  f[4]=b2f((u16)(v.z&0xffffu)); f[5]=b2f((u16)(v.z>>16));
  f[6]=b2f((u16)(v.w&0xffffu)); f[7]=b2f((u16)(v.w>>16));
}
DEV uint4 pk8(const float* f){
  uint4 v;
  v.x = (u32)f2b(f[0]) | ((u32)f2b(f[1])<<16);
  v.y = (u32)f2b(f[2]) | ((u32)f2b(f[3])<<16);
  v.z = (u32)f2b(f[4]) | ((u32)f2b(f[5])<<16);
  v.w = (u32)f2b(f[6]) | ((u32)f2b(f[7])<<16);
  return v;
}
DEV void unp16(uint4 v, u16* o){
  o[0]=(u16)(v.x&0xffffu); o[1]=(u16)(v.x>>16);
  o[2]=(u16)(v.y&0xffffu); o[3]=(u16)(v.y>>16);
  o[4]=(u16)(v.z&0xffffu); o[5]=(u16)(v.z>>16);
  o[6]=(u16)(v.w&0xffffu); o[7]=(u16)(v.w>>16);
}
DEV void gload16(const u16* g, u16* l){
  __builtin_amdgcn_global_load_lds(
      (const __attribute__((address_space(1))) u32*)g,
      (__attribute__((address_space(3))) u32*)l, 16, 0, 0);
}
#define ZF4 ((f32x4){0.f,0.f,0.f,0.f})

// ---------------------------------------------------------------- transpose f32 -> bf16
__global__ void transpose_k(const float* __restrict__ in, u16* __restrict__ out, int R, int C){
  __shared__ float tile[32][33];
  int c0 = blockIdx.x*32, r0 = blockIdx.y*32;
  int tx = threadIdx.x, ty = threadIdx.y; // (32,8)
  #pragma unroll
  for (int j=0;j<4;j++) tile[ty + j*8][tx] = in[(size_t)(r0 + ty + j*8)*C + c0 + tx];
  __syncthreads();
  #pragma unroll
  for (int j=0;j<4;j++) out[(size_t)(c0 + ty + j*8)*R + r0 + tx] = f2b(tile[tx][ty + j*8]);
}

// ---------------------------------------------------------------- prep: xmx bf16, dxprev bf16, x_last f32
__global__ __launch_bounds__(256) void prep_k(const float* __restrict__ x, const float* __restrict__ shift,
    const float* __restrict__ maax, u16* __restrict__ xmx, u16* __restrict__ dxp, float* __restrict__ out_xlast){
  int e8 = (blockIdx.x*256 + threadIdx.x) * 8;
  int row = e8 >> 11, col = e8 & 2047;
  int t = row & 4095, b = row >> 12;
  const float* xp = x + (size_t)row*2048 + col;
  const float* pp = t ? (x + (size_t)(row-1)*2048 + col) : (shift + (size_t)b*2048 + col);
  float xf[8], pf[8], mf[8], of[8], df[8];
  *(float4*)(xf)   = *(const float4*)(xp);
  *(float4*)(xf+4) = *(const float4*)(xp+4);
  *(float4*)(pf)   = *(const float4*)(pp);
  *(float4*)(pf+4) = *(const float4*)(pp+4);
  *(float4*)(mf)   = *(const float4*)(maax + col);
  *(float4*)(mf+4) = *(const float4*)(maax + col + 4);
  #pragma unroll
  for (int j=0;j<8;j++){ df[j] = pf[j]-xf[j]; of[j] = xf[j] + df[j]*mf[j]; }
  *(uint4*)(xmx + (size_t)row*2048 + col) = pk8(of);
  *(uint4*)(dxp + (size_t)row*2048 + col) = pk8(df);
  if (t == 4095){
    *(float4*)(out_xlast + (size_t)b*2048 + col)     = *(const float4*)(xf);
    *(float4*)(out_xlast + (size_t)b*2048 + col + 4) = *(const float4*)(xf+4);
  }
}

// ---------------------------------------------------------------- epilogue ids
enum { EPI_STORE=0, EPI_TANH=1, EPI_SILU=2, EPI_LERP=3, EPI_ICLR=5, EPI_STORE32=6 };

// ---------------------------------------------------------------- 256x256 BK=32 counted-vmcnt GEMM (big GEMMs)
// C[M,N] = A[M,K] @ Bt[N,K]^T. Requires M%256==0, N%256==0, K%32==0, lda=ldb=K, ldc=N.
template<int EPI>
__global__ __launch_bounds__(512, 2) void gemm256_k(
    const u16* __restrict__ A, const u16* __restrict__ Bt,
    u16* __restrict__ Cout, float* __restrict__ Cout32,
    int M, int N, int K)
{
  __shared__ __align__(16) u16 lds[4*16384];   // 4 bufs x (A[256][32] + B[256][32]) = 128 KiB
  const int tid = threadIdx.x, lane = tid & 63;
  int bxx = blockIdx.x, byy = blockIdx.y;
  {
    int nwg = gridDim.x * gridDim.y;
    if ((nwg & 7) == 0){
      int bid = byy * gridDim.x + bxx;
      int cpx = nwg >> 3;
      int swz = (bid & 7) * cpx + (bid >> 3);
      bxx = swz % gridDim.x; byy = swz / gridDim.x;
    }
  }
  const int m0 = bxx * 256, n0 = byy * 256;
  const int wid = tid >> 6;
  const int wm = wid >> 2, wn = wid & 3;       // 2 x 4 wave grid; wave tile 128x64
  const int fr = lane & 15, kg = lane >> 4;    // kg = k-slot (8 bf16 each)
  const int NT = K >> 5;
  const int chunk0 = __builtin_amdgcn_readfirstlane(wid) * 2;  // 2 chunks of 16 rows per wave
  const int lr = lane >> 2, lsl = lane & 3;    // staging: row-in-chunk, 16B slot

  f32x4 acc[8][4];
  #pragma unroll
  for (int m=0;m<8;m++)
    #pragma unroll
    for (int n=0;n<4;n++) acc[m][n] = ZF4;

  auto STAGE = [&](int t){
    u16* ab = lds + (t & 3) * 16384;
    u16* bb = ab + 8192;
    int k0 = t << 5;
    #pragma unroll
    for (int i=0;i<2;i++){
      int c = chunk0 + i;
      int r = c*16 + lr;
      int gc = k0 + lsl*8;
      gload16(A  + (size_t)(m0 + r)*K + gc, ab + c*512);
      gload16(Bt + (size_t)(n0 + r)*K + gc, bb + c*512);
    }
  };

  STAGE(0); STAGE(1); STAGE(2);
  for (int t=0; t<NT; ++t){
    asm volatile("s_waitcnt vmcnt(4)" ::: "memory");
    __builtin_amdgcn_s_barrier();
    __builtin_amdgcn_sched_barrier(0);
    if (t+3 < NT) STAGE(t+3);
    const u16* ab = lds + (t & 3) * 16384;
    const u16* bb = ab + 8192;
    s16x8 af[8], bf[4];
    #pragma unroll
    for (int m=0;m<8;m++){
      int r = wm*128 + m*16 + fr;
      af[m] = *(const s16x8*)(ab + r*32 + kg*8);
    }
    #pragma unroll
    for (int n=0;n<4;n++){
      int r = wn*64 + n*16 + fr;
      bf[n] = *(const s16x8*)(bb + r*32 + kg*8);
    }
    __builtin_amdgcn_s_setprio(1);
    #pragma unroll
    for (int m=0;m<8;m++)
      #pragma unroll
      for (int n=0;n<4;n++)
        acc[m][n] = __builtin_amdgcn_mfma_f32_16x16x32_bf16(af[m], bf[n], acc[m][n], 0,0,0);
    __builtin_amdgcn_s_setprio(0);
  }

  #pragma unroll
  for (int n=0;n<4;n++){
    int ccol = n0 + wn*64 + n*16 + fr;
    #pragma unroll
    for (int m=0;m<8;m++){
      #pragma unroll
      for (int q=0;q<4;q++){
        int row = m0 + wm*128 + m*16 + kg*4 + q;
        float v = acc[m][n][q];
        size_t oidx = (size_t)row*N + ccol;
        if constexpr (EPI == EPI_STORE) Cout[oidx] = f2b(v);
        else if constexpr (EPI == EPI_STORE32) Cout32[oidx] = v;
        else if constexpr (EPI == EPI_SILU) Cout[oidx] = f2b(v / (1.f + expf(-v)));
      }
    }
  }
}

// ---------------------------------------------------------------- generic 128x128 GEMM with fused epilogues
template<int EPI, bool ASYNC, bool SWZ>
__global__ __launch_bounds__(256) void gemm_k(
    const u16* __restrict__ A, int lda,
    const u16* __restrict__ Bt, int ldb,
    u16* __restrict__ Cout, float* __restrict__ Cout32, int ldc,
    int M, int N, int K,
    const float* __restrict__ e_x, const u16* __restrict__ e_dxp, const float* __restrict__ e_vec)
{
  constexpr int LDW = ASYNC ? 32 : 40;
  __shared__ u16 As[128][LDW];
  __shared__ u16 Bs[128][LDW];
  const int tid = threadIdx.x;
  const int lane = tid & 63, wid = tid >> 6;
  int bxx = blockIdx.x, byy = blockIdx.y;
  if constexpr (SWZ){
    int nwg = gridDim.x * gridDim.y;
    if ((nwg & 7) == 0){
      int bid = byy * gridDim.x + bxx;
      int cpx = nwg >> 3;
      int swz = (bid & 7) * cpx + (bid >> 3);
      bxx = swz % gridDim.x; byy = swz / gridDim.x;
    }
  }
  const int m0 = bxx * 128, n0 = byy * 128;
  const int wrow = (wid >> 1) * 64, wcol = (wid & 1) * 64;
  const int fr = lane & 15, kg = lane >> 4;
  const int r_c0 = tid >> 2, r_seg = tid & 3;
  const int r_c1 = r_c0 + 64;

  f32x4 acc[4][4];
  #pragma unroll
  for (int m=0;m<4;m++)
    #pragma unroll
    for (int n=0;n<4;n++) acc[m][n] = ZF4;

  for (int k0 = 0; k0 < K; k0 += 32) {
    __syncthreads();
    if constexpr (ASYNC) {
      const int w4 = __builtin_amdgcn_readfirstlane(wid);
      const int rr = lane >> 2, seg8 = (lane & 3) * 8;
      #pragma unroll
      for (int i=0;i<2;i++){
        int row = w4*32 + i*16 + rr;
        gload16(A  + (size_t)(m0 + row)*lda + k0 + seg8, &As[w4*32 + i*16][0]);
        gload16(Bt + (size_t)(n0 + row)*ldb + k0 + seg8, &Bs[w4*32 + i*16][0]);
      }
    } else {
      uint4 av0 = *(const uint4*)(A + (size_t)(m0 + r_c0)*lda + k0 + r_seg*8);
      uint4 av1 = *(const uint4*)(A + (size_t)(m0 + r_c1)*lda + k0 + r_seg*8);
      *(uint4*)(&As[r_c0][r_seg*8]) = av0;
      *(uint4*)(&As[r_c1][r_seg*8]) = av1;
      uint4 z = make_uint4(0,0,0,0);
      uint4 bv0 = (n0 + r_c0 < N) ? *(const uint4*)(Bt + (size_t)(n0 + r_c0)*ldb + k0 + r_seg*8) : z;
      uint4 bv1 = (n0 + r_c1 < N) ? *(const uint4*)(Bt + (size_t)(n0 + r_c1)*ldb + k0 + r_seg*8) : z;
      *(uint4*)(&Bs[r_c0][r_seg*8]) = bv0;
      *(uint4*)(&Bs[r_c1][r_seg*8]) = bv1;
    }
    __syncthreads();
    s16x8 a[4], bb[4];
    #pragma unroll
    for (int m=0;m<4;m++) a[m] = *(const s16x8*)(&As[wrow + m*16 + fr][kg*8]);
    #pragma unroll
    for (int n=0;n<4;n++) bb[n] = *(const s16x8*)(&Bs[wcol + n*16 + fr][kg*8]);
    #pragma unroll
    for (int m=0;m<4;m++)
      #pragma unroll
      for (int n=0;n<4;n++)
        acc[m][n] = __builtin_amdgcn_mfma_f32_16x16x32_bf16(a[m], bb[n], acc[m][n], 0,0,0);
  }
  #pragma unroll
  for (int n=0;n<4;n++){
    int ccol = n0 + wcol + n*16 + fr;
    if (ccol >= N) continue;
    #pragma unroll
    for (int m=0;m<4;m++){
      #pragma unroll
      for (int q=0;q<4;q++){
        int row = m0 + wrow + m*16 + kg*4 + q;
        float v = acc[m][n][q];
        size_t oidx = (size_t)row*ldc + ccol;
        if constexpr (EPI == EPI_STORE) Cout[oidx] = f2b(v);
        else if constexpr (EPI == EPI_STORE32) Cout32[oidx] = v;
        else if constexpr (EPI == EPI_TANH) Cout[oidx] = f2b(tanhf(v));
        else if constexpr (EPI == EPI_SILU) Cout[oidx] = f2b(v / (1.f + expf(-v)));
        else if constexpr (EPI == EPI_LERP){
          float xv = e_x[(size_t)row*2048 + ccol];
          float dx = b2f(e_dxp[(size_t)row*2048 + ccol]);
          Cout[oidx] = f2b(xv + dx * (e_vec[ccol] + v));
        }
        else if constexpr (EPI == EPI_ICLR) Cout[oidx] = f2b(1.f / (1.f + expf(-(e_vec[ccol] + v))));
      }
    }
  }
}

// ---------------------------------------------------------------- thin GEMM: 64x64 tile, for small N
template<int EPI>
__global__ __launch_bounds__(256) void gemm_thin_k(
    const u16* __restrict__ A, int lda,
    const u16* __restrict__ Bt, int ldb,
    u16* __restrict__ Cout, int ldc, int N, int K)
{
  __shared__ u16 As[64][40];
  __shared__ u16 Bs[64][40];
  const int tid = threadIdx.x;
  const int lane = tid & 63, wid = tid >> 6;
  const int m0 = blockIdx.x * 64, n0 = blockIdx.y * 64;
  const int wrow = (wid >> 1) * 32, wcol = (wid & 1) * 32;
  const int fr = lane & 15, kg = lane >> 4;
  const int r_c = tid >> 2, r_seg = tid & 3;

  f32x4 acc[2][2];
  #pragma unroll
  for (int m=0;m<2;m++)
    #pragma unroll
    for (int n=0;n<2;n++) acc[m][n] = ZF4;

  for (int k0 = 0; k0 < K; k0 += 32) {
    __syncthreads();
    {
      uint4 av = *(const uint4*)(A + (size_t)(m0 + r_c)*lda + k0 + r_seg*8);
      *(uint4*)(&As[r_c][r_seg*8]) = av;
      uint4 z = make_uint4(0,0,0,0);
      uint4 bv = (n0 + r_c < N) ? *(const uint4*)(Bt + (size_t)(n0 + r_c)*ldb + k0 + r_seg*8) : z;
      *(uint4*)(&Bs[r_c][r_seg*8]) = bv;
    }
    __syncthreads();
    s16x8 a[2], bb[2];
    #pragma unroll
    for (int m=0;m<2;m++) a[m] = *(const s16x8*)(&As[wrow + m*16 + fr][kg*8]);
    #pragma unroll
    for (int n=0;n<2;n++) bb[n] = *(const s16x8*)(&Bs[wcol + n*16 + fr][kg*8]);
    #pragma unroll
    for (int m=0;m<2;m++)
      #pragma unroll
      for (int n=0;n<2;n++)
        acc[m][n] = __builtin_amdgcn_mfma_f32_16x16x32_bf16(a[m], bb[n], acc[m][n], 0,0,0);
  }
  #pragma unroll
  for (int n=0;n<2;n++){
    int ccol = n0 + wcol + n*16 + fr;
    if (ccol >= N) continue;
    #pragma unroll
    for (int m=0;m<2;m++){
      #pragma unroll
      for (int q=0;q<4;q++){
        int row = m0 + wrow + m*16 + kg*4 + q;
        float v = acc[m][n][q];
        size_t oidx = (size_t)row*ldc + ccol;
        if constexpr (EPI == EPI_TANH) Cout[oidx] = f2b(tanhf(v));
        else Cout[oidx] = f2b(v);
      }
    }
  }
}

// ---------------------------------------------------------------- WKV phase 1: per chunk-head, 512 threads / 8 waves
__global__ __launch_bounds__(512, 1) void wkv1_k(
    const u16* __restrict__ r_g, const u16* __restrict__ kraw_g, const u16* __restrict__ v_g,
    const u16* __restrict__ ic_g,
    const u16* __restrict__ t2_g, const u16* __restrict__ dw2t_g, const float* __restrict__ td_g,
    const float* __restrict__ u_g, const float* __restrict__ kkk_g, const float* __restrict__ kka_g,
    u16* __restrict__ y1_g, u16* __restrict__ rw_g,
    u16* __restrict__ kvab_g, float* __restrict__ wsA_g)
{
  __shared__ __align__(16) char arena[161792];
  float* WL   = (float*)(arena);
  float* WC   = (float*)(arena + 34816);
  u16* Abuf   = (u16*)(arena);
  u16* kkcT   = (u16*)(arena + 34816);
  u16* rd_l   = (u16*)(arena + 69632);
  u16* vT_l   = (u16*)(arena + 69632);
  u16* ki_l   = (u16*)(arena + 88064);
  u16* kkwT_l = (u16*)(arena + 88064);
  u16* kwT_l  = (u16*)(arena + 106496);
  u16* ka_l   = (u16*)(arena + 124928);
  u16* kkb_l  = (u16*)(arena + 143360);
  u16* kaT_l  = (u16*)(arena + 143360);
  float* diag_l = (float*)(arena + 67584);  // 128
  float* offs_l = diag_l + 128;             // 64
  float* wsum_l = offs_l + 64;              // 64
  float* u_l    = wsum_l + 64;              // 64
  float* kkk_l  = u_l + 64;                 // 64
  float* kka_l  = kkk_l + 64;               // 64
  float* td_l   = kka_l + 64;               // 64 -> ends at 69632

  const int tid = threadIdx.x, lane = tid & 63, wid = tid >> 6;  // wid 0..7
  const int cb = blockIdx.x;
  const int c = cb >> 6, b = (cb >> 5) & 1, h = cb & 31;
  const size_t base = ((size_t)(b*4096 + c*128)) * 2048 + h*64;
  const int fr = lane & 15, kg = lane >> 4;
  const int tq = tid >> 2, kh = (tid & 3) * 16;   // 4 threads per row, 16 cols each

  // P0a: stage t2 [128][64] + dw2t head-slice [64][64]; per-head vectors
  {
    const u16* t2s = t2_g + (size_t)(b*4096 + c*128 + tq)*64 + kh;
    *(uint4*)(&rd_l[tq*72 + kh])     = *(const uint4*)(t2s);
    *(uint4*)(&rd_l[tq*72 + kh + 8]) = *(const uint4*)(t2s + 8);
    int n = tid >> 3, sg2 = (tid & 7) * 8;
    *(uint4*)(&ki_l[n*72 + sg2]) = *(const uint4*)(dw2t_g + (size_t)(h*64 + n)*64 + sg2);
  }
  if (tid < 64){
    u_l[tid]   = u_g[h*64 + tid];
    kkk_l[tid] = kkk_g[h*64 + tid];
    kka_l[tid] = kka_g[h*64 + tid];
    td_l[tid]  = td_g[h*64 + tid];
  }
  __syncthreads();
  // P0b: WL[t][k] = -exp(td[k] + t2[t,:] . dw2[:,k])
  {
    f32x4 accW[4];
    #pragma unroll
    for (int n=0;n<4;n++) accW[n] = ZF4;
    #pragma unroll
    for (int ks=0; ks<2; ++ks){
      s16x8 af = *(const s16x8*)(&rd_l[(wid*16 + fr)*72 + ks*32 + kg*8]);
      #pragma unroll
      for (int n=0;n<4;n++){
        s16x8 bf = *(const s16x8*)(&ki_l[(n*16 + fr)*72 + ks*32 + kg*8]);
        accW[n] = __builtin_amdgcn_mfma_f32_16x16x32_bf16(af, bf, accW[n], 0,0,0);
      }
    }
    #pragma unroll
    for (int n=0;n<4;n++)
      #pragma unroll
      for (int q=0;q<4;q++){
        int t = wid*16 + kg*4 + q;
        int s = n*16 + fr;
        WL[t*64 + s] = -expf(td_l[s] + accW[n][q]);
      }
  }
  __syncthreads();
  // scan: inclusive cumsum over t per column k — 8 cols per wave
  for (int j=0;j<8;j++){
    int k = wid*8 + j;
    float v = WL[lane*64 + k];
    #pragma unroll
    for (int d=1; d<64; d<<=1){ float o = __shfl_up(v, d); if (lane >= d) v += o; }
    WC[lane*64 + k] = v;
    float carry = __shfl(v, 63);
    float v2 = WL[(64+lane)*64 + k];
    #pragma unroll
    for (int d=1; d<64; d<<=1){ float o = __shfl_up(v2, d); if (lane >= d) v2 += o; }
    v2 += carry;
    WC[(64+lane)*64 + k] = v2;
    float tot = __shfl(v2, 63);
    if (lane == 0){ offs_l[k] = carry; wsum_l[k] = tot; wsA_g[(size_t)cb*64 + k] = expf(tot); }
  }
  __syncthreads();
  // P1: r, kadj -> rd, ki (natural), kwT (transposed), rw (global), diag
  {
    const u16* rs  = r_g    + base + (size_t)tq*2048 + kh;
    const u16* ks_ = kraw_g + base + (size_t)tq*2048 + kh;
    const u16* is_ = ic_g   + base + (size_t)tq*2048 + kh;
    float dpart = 0.f;
    #pragma unroll
    for (int j=0;j<2;j++){
      float rf[8], kf[8], icf[8], rdf[8], kif[8], rwf[8];
      up8(*(const uint4*)(rs + j*8), rf);
      up8(*(const uint4*)(ks_ + j*8), kf);
      up8(*(const uint4*)(is_ + j*8), icf);
      #pragma unroll
      for (int e=0;e<8;e++){
        int k = kh + j*8 + e;
        float kadj = kf[e] * (1.f + (icf[e] - 1.f) * kka_l[k]);
        float wl = WL[tq*64+k], wc = WC[tq*64+k];
        float wcs = wc - wl;
        float off = offs_l[k], wsm = wsum_l[k];
        rdf[e] = rf[e] * expf(clip30(wcs - off));
        kif[e] = kadj  * expf(clip30(off - wc));
        rwf[e] = rf[e] * expf(clip30(wcs));
        kwT_l[k*136 + tq] = f2b(kadj * expf(clip30(wsm - wc)));
        dpart += rf[e] * u_l[k] * kadj;
      }
      *(uint4*)(&rd_l[tq*72 + kh + j*8]) = pk8(rdf);
      *(uint4*)(&ki_l[tq*72 + kh + j*8]) = pk8(kif);
      *(uint4*)(rw_g + base + (size_t)tq*2048 + kh + j*8) = pk8(rwf);
    }
    dpart += __shfl_xor(dpart, 1);
    dpart += __shfl_xor(dpart, 2);
    if ((tid & 3) == 0) diag_l[tq] = dpart;
  }
  __syncthreads();
  // P2: raw k, iclr -> ka = kk*iclr, kkb = kk (normalized)
  {
    const u16* ks_ = kraw_g + base + (size_t)tq*2048 + kh;
    const u16* is_ = ic_g   + base + (size_t)tq*2048 + kh;
    float kf[16], icf[16], kkraw[16];
    #pragma unroll
    for (int j=0;j<2;j++){
      up8(*(const uint4*)(ks_ + j*8), kf + j*8);
      up8(*(const uint4*)(is_ + j*8), icf + j*8);
    }
    float ss = 0.f;
    #pragma unroll
    for (int e=0;e<16;e++){ kkraw[e] = kf[e]*kkk_l[kh+e]; ss += kkraw[e]*kkraw[e]; }
    ss += __shfl_xor(ss, 1);
    ss += __shfl_xor(ss, 2);
    float rn = 1.f / fmaxf(sqrtf(ss), 1e-12f);
    #pragma unroll
    for (int j=0;j<2;j++){
      float kkb8[8], ka8[8];
      #pragma unroll
      for (int e=0;e<8;e++){
        float kkv = kkraw[j*8+e]*rn;
        kkb8[e] = kkv; ka8[e] = kkv*icf[j*8+e];
      }
      *(uint4*)(&kkb_l[tq*72 + kh + j*8]) = pk8(kkb8);
      *(uint4*)(&ka_l [tq*72 + kh + j*8]) = pk8(ka8);
    }
  }
  __syncthreads();
  // P3: A = rd @ ki^T (wave w -> m-tile w), mask strict-lower + diag
  f32x4 accA[8];
  #pragma unroll
  for (int n=0;n<8;n++) accA[n] = ZF4;
  #pragma unroll
  for (int ks=0; ks<2; ++ks){
    s16x8 af = *(const s16x8*)(&rd_l[(wid*16 + fr)*72 + ks*32 + kg*8]);
    #pragma unroll
    for (int n=0;n<8;n++){
      s16x8 bf = *(const s16x8*)(&ki_l[(n*16 + fr)*72 + ks*32 + kg*8]);
      accA[n] = __builtin_amdgcn_mfma_f32_16x16x32_bf16(af, bf, accA[n], 0,0,0);
    }
  }
  #pragma unroll
  for (int n=0;n<8;n++)
    #pragma unroll
    for (int q=0;q<4;q++){
      int t = wid*16 + kg*4 + q;
      int s = n*16 + fr;
      float v = accA[n][q];
      v = (t > s) ? v : ((t == s) ? diag_l[t] : 0.f);
      accA[n][q] = v;
      Abuf[t*136 + s] = f2b(v);
    }
  __syncthreads();
  // P4a: kkwT[k][t] = -kk * w_inter
  {
    #pragma unroll
    for (int j=0;j<2;j++){
      float kkf[8];
      up8(*(const uint4*)(&kkb_l[tq*72 + kh + j*8]), kkf);
      #pragma unroll
      for (int e=0;e<8;e++){
        int k = kh + j*8 + e;
        kkwT_l[k*136 + tq] = f2b(-kkf[e] * expf(clip30(wsum_l[k] - WC[tq*64+k])));
      }
    }
  }
  __syncthreads();
  // P4b: kk_corr = ka @ kkb^T, strict-lower, write transposed kkcT[s][t]
  {
    f32x4 accC[8];
    #pragma unroll
    for (int n=0;n<8;n++) accC[n] = ZF4;
    #pragma unroll
    for (int ks=0; ks<2; ++ks){
      s16x8 af = *(const s16x8*)(&ka_l[(wid*16 + fr)*72 + ks*32 + kg*8]);
      #pragma unroll
      for (int n=0;n<8;n++){
        s16x8 bf = *(const s16x8*)(&kkb_l[(n*16 + fr)*72 + ks*32 + kg*8]);
        accC[n] = __builtin_amdgcn_mfma_f32_16x16x32_bf16(af, bf, accC[n], 0,0,0);
      }
    }
    #pragma unroll
    for (int n=0;n<8;n++)
      #pragma unroll
      for (int q=0;q<4;q++){
        int t = wid*16 + kg*4 + q;
        int s = n*16 + fr;
        kkcT[s*136 + t] = f2b((t > s) ? accC[n][q] : 0.f);
      }
  }
  __syncthreads();
  // P5a: stage v transposed (vT[vd][t]) + kaT[j][t] (over dead kkb)
  {
    const u16* vs = v_g + base + (size_t)tq*2048 + kh;
    #pragma unroll
    for (int j=0;j<2;j++){
      u16 el[8]; unp16(*(const uint4*)(vs + j*8), el);
      #pragma unroll
      for (int e=0;e<8;e++) vT_l[(kh + j*8 + e)*136 + tq] = el[e];
    }
    #pragma unroll
    for (int j=0;j<2;j++){
      u16 el[8]; unp16(*(const uint4*)(&ka_l[tq*72 + kh + j*8]), el);
      #pragma unroll
      for (int e=0;e<8;e++) kaT_l[(kh + j*8 + e)*136 + tq] = el[e];
    }
  }
  // P5b: P = Amask @ kkc ; A_total = Amask - tril(P) -> Abuf
  {
    f32x4 accP[8];
    #pragma unroll
    for (int n=0;n<8;n++) accP[n] = ZF4;
    #pragma unroll
    for (int ks=0; ks<4; ++ks){
      s16x8 af = *(const s16x8*)(&Abuf[(wid*16 + fr)*136 + ks*32 + kg*8]);
      #pragma unroll
      for (int n=0;n<8;n++){
        s16x8 bf = *(const s16x8*)(&kkcT[(n*16 + fr)*136 + ks*32 + kg*8]);
        accP[n] = __builtin_amdgcn_mfma_f32_16x16x32_bf16(af, bf, accP[n], 0,0,0);
      }
    }
    #pragma unroll
    for (int n=0;n<8;n++)
      #pragma unroll
      for (int q=0;q<4;q++){
        int t = wid*16 + kg*4 + q;
        int s = n*16 + fr;
        float v = accA[n][q] - ((t >= s) ? accP[n][q] : 0.f);
        Abuf[t*136 + s] = f2b(v);
      }
  }
  __syncthreads();
  // P6: y_intra = A_total @ v
  {
    f32x4 accY[4];
    #pragma unroll
    for (int n=0;n<4;n++) accY[n] = ZF4;
    #pragma unroll
    for (int ks=0; ks<4; ++ks){
      s16x8 af = *(const s16x8*)(&Abuf[(wid*16 + fr)*136 + ks*32 + kg*8]);
      #pragma unroll
      for (int n=0;n<4;n++){
        s16x8 bf = *(const s16x8*)(&vT_l[(n*16 + fr)*136 + ks*32 + kg*8]);
        accY[n] = __builtin_amdgcn_mfma_f32_16x16x32_bf16(af, bf, accY[n], 0,0,0);
      }
    }
    #pragma unroll
    for (int n=0;n<4;n++)
      #pragma unroll
      for (int q=0;q<4;q++){
        int t = wid*16 + kg*4 + q;
        int vd = n*16 + fr;
        y1_g[base + (size_t)t*2048 + vd] = f2b(accY[n][q]);
      }
  }
  // P7: kv = kwT @ vT^T (waves 0-3, row-major) ; ab = kkwT @ kaT^T (waves 4-7, stored TRANSPOSED for wkv2)
  {
    const int isAB = wid >> 2, mrow = (wid & 3) * 16;
    const u16* Amat = isAB ? kkwT_l : kwT_l;
    const u16* Bmat = isAB ? kaT_l  : vT_l;
    f32x4 acc2[4];
    #pragma unroll
    for (int n=0;n<4;n++) acc2[n] = ZF4;
    #pragma unroll
    for (int ks=0; ks<4; ++ks){
      s16x8 af = *(const s16x8*)(&Amat[(mrow + fr)*136 + ks*32 + kg*8]);
      #pragma unroll
      for (int n=0;n<4;n++){
        s16x8 bf = *(const s16x8*)(&Bmat[(n*16 + fr)*136 + ks*32 + kg*8]);
        acc2[n] = __builtin_amdgcn_mfma_f32_16x16x32_bf16(af, bf, acc2[n], 0,0,0);
      }
    }
    u16* kvp = kvab_g + (size_t)cb*8192 + isAB*4096;
    #pragma unroll
    for (int n=0;n<4;n++)
      #pragma unroll
      for (int q=0;q<4;q++){
        int kd = mrow + kg*4 + q, vd = n*16 + fr;
        if (isAB) kvp[vd*64 + kd] = f2b(acc2[n][q]);   // abT[v][k] for wkv2 B-operand
        else      kvp[kd*64 + vd] = f2b(acc2[n][q]);   // kv[k][v]
      }
  }
}

// ---------------------------------------------------------------- WKV phase 2: MFMA state scan per (b,h), reg prefetch
__global__ __launch_bounds__(256) void wkv2_k(
   const float* __restrict__ state_in, u16* __restrict__ kvab_g,
   const float* __restrict__ wsA_g, float* __restrict__ out_state)
{
  __shared__ u16 Sb[64][72];    // bf16 S (A-operand); only the S@ab input is rounded
  __shared__ u16 abT[64][72];   // abT[v_out][k_contract]
  const int tid = threadIdx.x, lane = tid & 63, wid = tid >> 6;
  const int bh = blockIdx.x, b = bh >> 5, h = bh & 31;
  const int fr = lane & 15, kg = lane >> 4;
  const int r0 = wid*16 + kg*4;                     // thread's 4 rows (C-layout)
  const int vrow = tid >> 2, jc = (tid & 3) * 16;   // abT staging ownership

  f32x4 S[4];   // S[n][q] = S[r0+q][n*16+fr], f32 across the whole scan
  #pragma unroll
  for (int n=0;n<4;n++)
    #pragma unroll
    for (int q=0;q<4;q++)
      S[n][q] = state_in[(size_t)bh*4096 + (size_t)(r0+q)*64 + n*16+fr];

  uint4 pf_ab0, pf_ab1; u16 pf_kv[16]; float pf_ws[4];
  {
    int cb = b*32 + h;   // chunk 0
    const u16* kvp = kvab_g + (size_t)cb*8192;
    pf_ab0 = *(const uint4*)(kvp + 4096 + vrow*64 + jc);
    pf_ab1 = *(const uint4*)(kvp + 4096 + vrow*64 + jc + 8);
    #pragma unroll
    for (int n=0;n<4;n++)
      #pragma unroll
      for (int q=0;q<4;q++)
        pf_kv[n*4+q] = kvp[(r0+q)*64 + n*16+fr];
    #pragma unroll
    for (int n=0;n<4;n++) pf_ws[n] = wsA_g[(size_t)cb*64 + n*16+fr];
  }

  for (int c=0;c<32;c++){
    int cb = (c*2+b)*32 + h;
    *(uint4*)(&abT[vrow][jc])   = pf_ab0;
    *(uint4*)(&abT[vrow][jc+8]) = pf_ab1;
    #pragma unroll
    for (int n=0;n<4;n++)
      #pragma unroll
      for (int q=0;q<4;q++)
        Sb[r0+q][n*16+fr] = f2b(S[n][q]);
    float kvf[16], wsf[4];
    #pragma unroll
    for (int i=0;i<16;i++) kvf[i] = b2f(pf_kv[i]);
    #pragma unroll
    for (int n=0;n<4;n++) wsf[n] = pf_ws[n];
    float* sip = (float*)(kvab_g + (size_t)cb*8192);
    #pragma unroll
    for (int n=0;n<4;n++)
      #pragma unroll
      for (int q=0;q<4;q++)
        sip[(r0+q)*64 + n*16+fr] = S[n][q];
    __syncthreads();
    if (c < 31){
      int cb2 = ((c+1)*2+b)*32 + h;
      const u16* kvp2 = kvab_g + (size_t)cb2*8192;
      pf_ab0 = *(const uint4*)(kvp2 + 4096 + vrow*64 + jc);
      pf_ab1 = *(const uint4*)(kvp2 + 4096 + vrow*64 + jc + 8);
      #pragma unroll
      for (int n=0;n<4;n++)
        #pragma unroll
        for (int q=0;q<4;q++)
          pf_kv[n*4+q] = kvp2[(r0+q)*64 + n*16+fr];
      #pragma unroll
      for (int n=0;n<4;n++) pf_ws[n] = wsA_g[(size_t)cb2*64 + n*16+fr];
    }
    f32x4 acc[4];
    #pragma unroll
    for (int n=0;n<4;n++) acc[n] = ZF4;
    #pragma unroll
    for (int ks=0; ks<2; ++ks){
      s16x8 a = *(const s16x8*)(&Sb[wid*16 + fr][ks*32 + kg*8]);
      #pragma unroll
      for (int n=0;n<4;n++){
        s16x8 bb = *(const s16x8*)(&abT[n*16 + fr][ks*32 + kg*8]);
        acc[n] = __builtin_amdgcn_mfma_f32_16x16x32_bf16(a, bb, acc[n], 0,0,0);
      }
    }
    #pragma unroll
    for (int n=0;n<4;n++)
      #pragma unroll
      for (int q=0;q<4;q++)
        S[n][q] = S[n][q]*wsf[n] + acc[n][q] + kvf[n*4+q];
    __syncthreads();
  }
  #pragma unroll
  for (int n=0;n<4;n++)
    #pragma unroll
    for (int q=0;q<4;q++)
      out_state[(size_t)bh*4096 + (size_t)(r0+q)*64 + n*16+fr] = S[n][q];
}

// ---------------------------------------------------------------- WKV phase 3: y = y1 + rw@S_in, GroupNorm, *g
__global__ __launch_bounds__(256) void wkv3_k(
   const u16* __restrict__ y1_g, const u16* __restrict__ rw_g,
   const u16* __restrict__ kvab_g,
   const u16* __restrict__ g_g, const float* __restrict__ gnw, const float* __restrict__ gnb,
   u16* __restrict__ yf_g)
{
  __shared__ float S_l[64][65];
  __shared__ u16 rw_l[128][72];
  int tid = threadIdx.x;
  int cb = blockIdx.x; int c = cb>>6, b = (cb>>5)&1, h = cb&31;
  size_t base = ((size_t)(b*4096 + c*128))*2048 + h*64;
  const float* sip = (const float*)(kvab_g + (size_t)cb*8192);
  #pragma unroll
  for (int j=0;j<16;j++){ int flat = tid*16+j; S_l[flat>>6][flat&63] = sip[flat]; }
  {
    int t = tid>>1, kh = (tid&1)*32;
    const u16* rs = rw_g + base + (size_t)t*2048 + kh;
    #pragma unroll
    for (int j=0;j<4;j++) *(uint4*)(&rw_l[t][kh+j*8]) = *(const uint4*)(rs + j*8);
  }
  __syncthreads();
  int t = tid>>1, vh = (tid&1)*32;
  float acc[32];
  #pragma unroll
  for (int j=0;j<32;j++) acc[j] = 0.f;
  for (int kf2=0; kf2<64; kf2++){
    float rv = b2f(rw_l[t][kf2]);
    #pragma unroll
    for (int j=0;j<32;j++) acc[j] += rv * S_l[kf2][vh+j];
  }
  float sum=0.f, sq=0.f;
  float yv[32];
  #pragma unroll
  for (int j=0;j<32;j++){
    yv[j] = acc[j] + b2f(y1_g[base + (size_t)t*2048 + vh + j]);
    sum += yv[j]; sq += yv[j]*yv[j];
  }
  sum += __shfl_xor(sum, 1); sq += __shfl_xor(sq, 1);
  float mean = sum * (1.f/64.f);
  float var = sq * (1.f/64.f) - mean*mean;
  float rstd = rsqrtf(fmaxf(var, 0.f) + 6.4e-4f);
  size_t bt = (size_t)(b*4096 + c*128 + t);
  #pragma unroll
  for (int j=0;j<32;j++){
    int ch = h*64 + vh + j;
    float val = (yv[j]-mean)*rstd * gnw[ch] + gnb[ch];
    val *= b2f(g_g[bt*2048 + ch]);
    yf_g[base + (size_t)t*2048 + vh + j] = f2b(val);
  }
}

// ---------------------------------------------------------------- host
#define O_WTR   0ull
#define O_WTK   8388608ull
#define O_WTV   16777216ull
#define O_WTG   25165824ull
#define O_WTO   33554432ull
#define O_W1T   41943040ull
#define O_W2T   42729472ull
#define O_DW1T  43515904ull
#define O_DW2T  43778048ull
#define O_A1T   44040192ull
#define O_A2T   44433408ull
#define O_XXX   44826624ull
#define O_T2    47972352ull
#define O_T3    49020928ull
#define O_WSA   50593792ull
#define O_XMX   51118080ull       /* 32MB: xmx -> g */
#define O_A     84672512ull       /* 32MB: lerp staging -> kvab/S_in */
#define O_I     118226944ull      /* 32MB: dxprev -> iclr */
#define O_R     151781376ull
#define O_K     185335808ull      /* raw k -> y1 -> yf */
#define O_V     218890240ull
#define WS_NEEDED 252444672ull

extern "C" void kernel_launch(void* const* d_in, const int* in_sizes, int n_in,
                              void* d_out, int out_size, void* d_ws, size_t ws_size,
                              hipStream_t stream)
{
  (void)in_sizes; (void)n_in; (void)out_size;
  if (ws_size < WS_NEEDED) return;
  const float* x     = (const float*)d_in[0];
  const float* shift = (const float*)d_in[1];
  const float* st_in = (const float*)d_in[2];
  const float* maax  = (const float*)d_in[3];
  const float* maas[6] = {(const float*)d_in[4],(const float*)d_in[5],(const float*)d_in[6],
                          (const float*)d_in[7],(const float*)d_in[8],(const float*)d_in[9]};
  const float* w1    = (const float*)d_in[10];
  const float* w2    = (const float*)d_in[11];
  const float* td    = (const float*)d_in[12];
  const float* dw1   = (const float*)d_in[13];
  const float* dw2   = (const float*)d_in[14];
  const float* faaaa = (const float*)d_in[15];
  const float* a0v   = (const float*)d_in[16];
  const float* a1w   = (const float*)d_in[17];
  const float* a2w   = (const float*)d_in[18];
  const float* kkk   = (const float*)d_in[19];
  const float* kka   = (const float*)d_in[20];
  const float* Wr    = (const float*)d_in[21];
  const float* Wk    = (const float*)d_in[22];
  const float* Wv    = (const float*)d_in[23];
  const float* Wg    = (const float*)d_in[24];
  const float* Wo    = (const float*)d_in[25];
  const float* gnw   = (const float*)d_in[26];
  const float* gnb   = (const float*)d_in[27];
  float* out = (float*)d_out;
  char* ws = (char*)d_ws;
  #define WSP(o) ((u16*)(ws + (o)))

  u16 *wtR=WSP(O_WTR), *wtK=WSP(O_WTK), *wtV=WSP(O_WTV), *wtG=WSP(O_WTG), *wtO=WSP(O_WTO);
  u16 *w1t=WSP(O_W1T), *w2t=WSP(O_W2T), *dw1t=WSP(O_DW1T), *dw2t=WSP(O_DW2T), *a1t=WSP(O_A1T), *a2t=WSP(O_A2T);
  u16 *xxx=WSP(O_XXX), *t2b=WSP(O_T2), *t3b=WSP(O_T3);
  u16 *xmx=WSP(O_XMX), *Ab=WSP(O_A), *Ib=WSP(O_I), *Rb=WSP(O_R), *Kb=WSP(O_K), *Vb=WSP(O_V);
  u16 *rw = WSP(O_WTR);
  u16 *kvab = WSP(O_A);
  u16 *gbuf = WSP(O_XMX);
  u16 *dxp  = WSP(O_I);
  float* wsA = (float*)(ws + O_WSA);
  float* out_xlast = out + 16777216;
  float* out_state = out + 16781312;

  dim3 tb(32,8);
  transpose_k<<<dim3(64,64), tb, 0, stream>>>(Wr, wtR, 2048, 2048);
  transpose_k<<<dim3(64,64), tb, 0, stream>>>(Wk, wtK, 2048, 2048);
  transpose_k<<<dim3(64,64), tb, 0, stream>>>(Wv, wtV, 2048, 2048);
  transpose_k<<<dim3(64,64), tb, 0, stream>>>(Wg, wtG, 2048, 2048);
  transpose_k<<<dim3(64,64), tb, 0, stream>>>(Wo, wtO, 2048, 2048);
  transpose_k<<<dim3(6,64),  tb, 0, stream>>>(w1, w1t, 2048, 192);
  transpose_k<<<dim3(64,6),  tb, 0, stream>>>(w2, w2t, 192, 2048);
  transpose_k<<<dim3(2,64),  tb, 0, stream>>>(dw1, dw1t, 2048, 64);
  transpose_k<<<dim3(64,2),  tb, 0, stream>>>(dw2, dw2t, 64, 2048);
  transpose_k<<<dim3(3,64),  tb, 0, stream>>>(a1w, a1t, 2048, 96);
  transpose_k<<<dim3(64,3),  tb, 0, stream>>>(a2w, a2t, 96, 2048);

  prep_k<<<8192, 256, 0, stream>>>(x, shift, maax, xmx, dxp, out_xlast);

  // xxx = tanh(xmx @ w1)
  gemm_thin_k<EPI_TANH><<<dim3(128,3), 256, 0, stream>>>(xmx, 2048, w1t, 2048, xxx, 192, 192, 2048);
  // xw -> Ab ; t2 = tanh(xw @ dw1)
  gemm_k<EPI_LERP,true,true><<<dim3(64,16), 256, 0, stream>>>(xxx + 0*32, 192, w2t + 0*32, 192, Ab, nullptr, 2048, 8192, 2048, 32, x, dxp, maas[0]);
  gemm_thin_k<EPI_TANH><<<dim3(128,1), 256, 0, stream>>>(Ab, 2048, dw1t, 2048, t2b, 64, 64, 2048);
  // xa -> Ab ; t3 = xa @ a1
  gemm_k<EPI_LERP,true,true><<<dim3(64,16), 256, 0, stream>>>(xxx + 5*32, 192, w2t + 5*32, 192, Ab, nullptr, 2048, 8192, 2048, 32, x, dxp, maas[5]);
  gemm_thin_k<EPI_STORE><<<dim3(128,2), 256, 0, stream>>>(Ab, 2048, a1t, 2048, t3b, 96, 96, 2048);
  // xr -> Ab ; r = xr @ Wr
  gemm_k<EPI_LERP,true,true><<<dim3(64,16), 256, 0, stream>>>(xxx + 3*32, 192, w2t + 3*32, 192, Ab, nullptr, 2048, 8192, 2048, 32, x, dxp, maas[3]);
  gemm256_k<EPI_STORE><<<dim3(32,8), 512, 0, stream>>>(Ab, wtR, Rb, nullptr, 8192, 2048, 2048);
  // xk -> Ab ; k(raw) = xk @ Wk
  gemm_k<EPI_LERP,true,true><<<dim3(64,16), 256, 0, stream>>>(xxx + 1*32, 192, w2t + 1*32, 192, Ab, nullptr, 2048, 8192, 2048, 32, x, dxp, maas[1]);
  gemm256_k<EPI_STORE><<<dim3(32,8), 512, 0, stream>>>(Ab, wtK, Kb, nullptr, 8192, 2048, 2048);
  // xv -> Ab ; v = xv @ Wv
  gemm_k<EPI_LERP,true,true><<<dim3(64,16), 256, 0, stream>>>(xxx + 2*32, 192, w2t + 2*32, 192, Ab, nullptr, 2048, 8192, 2048, 32, x, dxp, maas[2]);
  gemm256_k<EPI_STORE><<<dim3(32,8), 512, 0, stream>>>(Ab, wtV, Vb, nullptr, 8192, 2048, 2048);
  // xg -> Ab ; g = silu(xg @ Wg)
  gemm_k<EPI_LERP,true,true><<<dim3(64,16), 256, 0, stream>>>(xxx + 4*32, 192, w2t + 4*32, 192, Ab, nullptr, 2048, 8192, 2048, 32, x, dxp, maas[4]);
  gemm256_k<EPI_SILU><<<dim3(32,8), 512, 0, stream>>>(Ab, wtG, gbuf, nullptr, 8192, 2048, 2048);
  // iclr = sigmoid(a0 + t3 @ a2)
  gemm_k<EPI_ICLR,true,true><<<dim3(64,16), 256, 0, stream>>>(t3b, 96, a2t, 96, Ib, nullptr, 2048, 8192, 2048, 96, nullptr, nullptr, a0v);
  // wkv
  wkv1_k<<<2048, 512, 0, stream>>>(Rb, Kb, Vb, Ib, t2b, dw2t, td, faaaa, kkk, kka,
                                   Kb /*y1 overwrites raw k*/, rw, kvab, wsA);
  wkv2_k<<<64, 256, 0, stream>>>(st_in, kvab, wsA, out_state);
  wkv3_k<<<2048, 256, 0, stream>>>(Kb /*y1*/, rw, kvab /*S_in*/, gbuf, gnw, gnb, Kb /*yf in place*/);
  // out = yf @ W_o  (f32 store)
  gemm256_k<EPI_STORE32><<<dim3(32,8), 512, 0, stream>>>(Kb, wtO, nullptr, out, 8192, 2048, 2048);
}

// Round 8
// 1230.001 us; speedup vs baseline: 1.7029x; 1.0574x over previous
//
#include <hip/hip_runtime.h>

// RWKV7-delta time-mix. f32 in/out, bf16 intermediates + MFMA bf16 16x16x32.
// B=2 T=4096 C=2048 H=32 K=64 CHUNK=128 NC=32.

typedef unsigned short u16;
typedef unsigned int   u32;
typedef __attribute__((ext_vector_type(8))) short s16x8;
typedef __attribute__((ext_vector_type(4))) float f32x4;

#define DEV __device__ __forceinline__

DEV float b2f(u16 v){ return __uint_as_float(((u32)v) << 16); }
DEV u16 f2b(float f){ u32 u = __float_as_uint(f); return (u16)((u + 0x7fffu + ((u >> 16) & 1u)) >> 16); }
DEV float clip30(float x){ return fminf(fmaxf(x, -30.f), 30.f); }
DEV void up8(uint4 v, float* f){
  f[0]=b2f((u16)(v.x&0xffffu)); f[1]=b2f((u16)(v.x>>16));
  f[2]=b2f((u16)(v.y&0xffffu)); f[3]=b2f((u16)(v.y>>16));
  f[4]=b2f((u16)(v.z&0xffffu)); f[5]=b2f((u16)(v.z>>16));
  f[6]=b2f((u16)(v.w&0xffffu)); f[7]=b2f((u16)(v.w>>16));
}
DEV uint4 pk8(const float* f){
  uint4 v;
  v.x = (u32)f2b(f[0]) | ((u32)f2b(f[1])<<16);
  v.y = (u32)f2b(f[2]) | ((u32)f2b(f[3])<<16);
  v.z = (u32)f2b(f[4]) | ((u32)f2b(f[5])<<16);
  v.w = (u32)f2b(f[6]) | ((u32)f2b(f[7])<<16);
  return v;
}
DEV void unp16(uint4 v, u16* o){
  o[0]=(u16)(v.x&0xffffu); o[1]=(u16)(v.x>>16);
  o[2]=(u16)(v.y&0xffffu); o[3]=(u16)(v.y>>16);
  o[4]=(u16)(v.z&0xffffu); o[5]=(u16)(v.z>>16);
  o[6]=(u16)(v.w&0xffffu); o[7]=(u16)(v.w>>16);
}
DEV void gload16(const u16* g, u16* l){
  __builtin_amdgcn_global_load_lds(
      (const __attribute__((address_space(1))) u32*)g,
      (__attribute__((address_space(3))) u32*)l, 16, 0, 0);
}
#define ZF4 ((f32x4){0.f,0.f,0.f,0.f})

// ---------------------------------------------------------------- transpose f32 -> bf16
__global__ void transpose_k(const float* __restrict__ in, u16* __restrict__ out, int R, int C){
  __shared__ float tile[32][33];
  int c0 = blockIdx.x*32, r0 = blockIdx.y*32;
  int tx = threadIdx.x, ty = threadIdx.y; // (32,8)
  #pragma unroll
  for (int j=0;j<4;j++) tile[ty + j*8][tx] = in[(size_t)(r0 + ty + j*8)*C + c0 + tx];
  __syncthreads();
  #pragma unroll
  for (int j=0;j<4;j++) out[(size_t)(c0 + ty + j*8)*R + r0 + tx] = f2b(tile[tx][ty + j*8]);
}

// ---------------------------------------------------------------- prep: xmx bf16, dxprev bf16, x_last f32
__global__ __launch_bounds__(256) void prep_k(const float* __restrict__ x, const float* __restrict__ shift,
    const float* __restrict__ maax, u16* __restrict__ xmx, u16* __restrict__ dxp, float* __restrict__ out_xlast){
  int e8 = (blockIdx.x*256 + threadIdx.x) * 8;
  int row = e8 >> 11, col = e8 & 2047;
  int t = row & 4095, b = row >> 12;
  const float* xp = x + (size_t)row*2048 + col;
  const float* pp = t ? (x + (size_t)(row-1)*2048 + col) : (shift + (size_t)b*2048 + col);
  float xf[8], pf[8], mf[8], of[8], df[8];
  *(float4*)(xf)   = *(const float4*)(xp);
  *(float4*)(xf+4) = *(const float4*)(xp+4);
  *(float4*)(pf)   = *(const float4*)(pp);
  *(float4*)(pf+4) = *(const float4*)(pp+4);
  *(float4*)(mf)   = *(const float4*)(maax + col);
  *(float4*)(mf+4) = *(const float4*)(maax + col + 4);
  #pragma unroll
  for (int j=0;j<8;j++){ df[j] = pf[j]-xf[j]; of[j] = xf[j] + df[j]*mf[j]; }
  *(uint4*)(xmx + (size_t)row*2048 + col) = pk8(of);
  *(uint4*)(dxp + (size_t)row*2048 + col) = pk8(df);
  if (t == 4095){
    *(float4*)(out_xlast + (size_t)b*2048 + col)     = *(const float4*)(xf);
    *(float4*)(out_xlast + (size_t)b*2048 + col + 4) = *(const float4*)(xf+4);
  }
}

// ---------------------------------------------------------------- epilogue ids
enum { EPI_STORE=0, EPI_TANH=1, EPI_SILU=2, EPI_LERP=3, EPI_ICLR=5, EPI_STORE32=6 };

// ---------------------------------------------------------------- 256x256 BK=32 counted-vmcnt GEMM (big GEMMs)
// C[M,N] = A[M,K] @ Bt[N,K]^T. Requires M%256==0, N%256==0, K%32==0, lda=ldb=K, ldc=N.
// XCD chunk map (grid 32x8): each XCD owns 4(m) x 8(n) blocks -> A-tiles fetched ~once, B-panels from XCD L2.
template<int EPI>
__global__ __launch_bounds__(512, 2) void gemm256_k(
    const u16* __restrict__ A, const u16* __restrict__ Bt,
    u16* __restrict__ Cout, float* __restrict__ Cout32,
    int M, int N, int K)
{
  __shared__ __align__(16) u16 lds[4*16384];   // 4 bufs x (A[256][32] + B[256][32]) = 128 KiB
  const int tid = threadIdx.x, lane = tid & 63;
  int bxx = blockIdx.x, byy = blockIdx.y;
  if (gridDim.x == 32 && gridDim.y == 8){
    int bid = byy * 32 + bxx;
    int xcd = bid & 7, idx = bid >> 3;       // idx 0..31
    bxx = xcd*4 + (idx & 3);                 // 4 m-columns per XCD chunk
    byy = idx >> 2;                          // all 8 n-rows inside chunk
  } else {
    int nwg = gridDim.x * gridDim.y;
    if ((nwg & 7) == 0){
      int bid = byy * gridDim.x + bxx;
      int cpx = nwg >> 3;
      int swz = (bid & 7) * cpx + (bid >> 3);
      bxx = swz % gridDim.x; byy = swz / gridDim.x;
    }
  }
  const int m0 = bxx * 256, n0 = byy * 256;
  const int wid = tid >> 6;
  const int wm = wid >> 2, wn = wid & 3;       // 2 x 4 wave grid; wave tile 128x64
  const int fr = lane & 15, kg = lane >> 4;    // kg = k-slot (8 bf16 each)
  const int NT = K >> 5;
  const int chunk0 = __builtin_amdgcn_readfirstlane(wid) * 2;  // 2 chunks of 16 rows per wave
  const int lr = lane >> 2, lsl = lane & 3;    // staging: row-in-chunk, 16B slot

  f32x4 acc[8][4];
  #pragma unroll
  for (int m=0;m<8;m++)
    #pragma unroll
    for (int n=0;n<4;n++) acc[m][n] = ZF4;

  auto STAGE = [&](int t){
    u16* ab = lds + (t & 3) * 16384;
    u16* bb = ab + 8192;
    int k0 = t << 5;
    #pragma unroll
    for (int i=0;i<2;i++){
      int c = chunk0 + i;
      int r = c*16 + lr;
      int gc = k0 + lsl*8;
      gload16(A  + (size_t)(m0 + r)*K + gc, ab + c*512);
      gload16(Bt + (size_t)(n0 + r)*K + gc, bb + c*512);
    }
  };

  STAGE(0); STAGE(1); STAGE(2);
  for (int t=0; t<NT; ++t){
    asm volatile("s_waitcnt vmcnt(4)" ::: "memory");
    __builtin_amdgcn_s_barrier();
    __builtin_amdgcn_sched_barrier(0);
    if (t+3 < NT) STAGE(t+3);
    const u16* ab = lds + (t & 3) * 16384;
    const u16* bb = ab + 8192;
    s16x8 af[8], bf[4];
    #pragma unroll
    for (int m=0;m<8;m++){
      int r = wm*128 + m*16 + fr;
      af[m] = *(const s16x8*)(ab + r*32 + kg*8);
    }
    #pragma unroll
    for (int n=0;n<4;n++){
      int r = wn*64 + n*16 + fr;
      bf[n] = *(const s16x8*)(bb + r*32 + kg*8);
    }
    __builtin_amdgcn_s_setprio(1);
    #pragma unroll
    for (int m=0;m<8;m++)
      #pragma unroll
      for (int n=0;n<4;n++)
        acc[m][n] = __builtin_amdgcn_mfma_f32_16x16x32_bf16(af[m], bf[n], acc[m][n], 0,0,0);
    __builtin_amdgcn_s_setprio(0);
  }

  #pragma unroll
  for (int n=0;n<4;n++){
    int ccol = n0 + wn*64 + n*16 + fr;
    #pragma unroll
    for (int m=0;m<8;m++){
      #pragma unroll
      for (int q=0;q<4;q++){
        int row = m0 + wm*128 + m*16 + kg*4 + q;
        float v = acc[m][n][q];
        size_t oidx = (size_t)row*N + ccol;
        if constexpr (EPI == EPI_STORE) Cout[oidx] = f2b(v);
        else if constexpr (EPI == EPI_STORE32) Cout32[oidx] = v;
        else if constexpr (EPI == EPI_SILU) Cout[oidx] = f2b(v / (1.f + expf(-v)));
      }
    }
  }
}

// ---------------------------------------------------------------- generic 128x128 GEMM with fused epilogues
template<int EPI, bool ASYNC, bool SWZ>
__global__ __launch_bounds__(256) void gemm_k(
    const u16* __restrict__ A, int lda,
    const u16* __restrict__ Bt, int ldb,
    u16* __restrict__ Cout, float* __restrict__ Cout32, int ldc,
    int M, int N, int K,
    const float* __restrict__ e_x, const u16* __restrict__ e_dxp, const float* __restrict__ e_vec)
{
  constexpr int LDW = ASYNC ? 32 : 40;
  __shared__ u16 As[128][LDW];
  __shared__ u16 Bs[128][LDW];
  const int tid = threadIdx.x;
  const int lane = tid & 63, wid = tid >> 6;
  int bxx = blockIdx.x, byy = blockIdx.y;
  if constexpr (SWZ){
    int nwg = gridDim.x * gridDim.y;
    if ((nwg & 7) == 0){
      int bid = byy * gridDim.x + bxx;
      int cpx = nwg >> 3;
      int swz = (bid & 7) * cpx + (bid >> 3);
      bxx = swz % gridDim.x; byy = swz / gridDim.x;
    }
  }
  const int m0 = bxx * 128, n0 = byy * 128;
  const int wrow = (wid >> 1) * 64, wcol = (wid & 1) * 64;
  const int fr = lane & 15, kg = lane >> 4;
  const int r_c0 = tid >> 2, r_seg = tid & 3;
  const int r_c1 = r_c0 + 64;

  f32x4 acc[4][4];
  #pragma unroll
  for (int m=0;m<4;m++)
    #pragma unroll
    for (int n=0;n<4;n++) acc[m][n] = ZF4;

  for (int k0 = 0; k0 < K; k0 += 32) {
    __syncthreads();
    if constexpr (ASYNC) {
      const int w4 = __builtin_amdgcn_readfirstlane(wid);
      const int rr = lane >> 2, seg8 = (lane & 3) * 8;
      #pragma unroll
      for (int i=0;i<2;i++){
        int row = w4*32 + i*16 + rr;
        gload16(A  + (size_t)(m0 + row)*lda + k0 + seg8, &As[w4*32 + i*16][0]);
        gload16(Bt + (size_t)(n0 + row)*ldb + k0 + seg8, &Bs[w4*32 + i*16][0]);
      }
    } else {
      uint4 av0 = *(const uint4*)(A + (size_t)(m0 + r_c0)*lda + k0 + r_seg*8);
      uint4 av1 = *(const uint4*)(A + (size_t)(m0 + r_c1)*lda + k0 + r_seg*8);
      *(uint4*)(&As[r_c0][r_seg*8]) = av0;
      *(uint4*)(&As[r_c1][r_seg*8]) = av1;
      uint4 z = make_uint4(0,0,0,0);
      uint4 bv0 = (n0 + r_c0 < N) ? *(const uint4*)(Bt + (size_t)(n0 + r_c0)*ldb + k0 + r_seg*8) : z;
      uint4 bv1 = (n0 + r_c1 < N) ? *(const uint4*)(Bt + (size_t)(n0 + r_c1)*ldb + k0 + r_seg*8) : z;
      *(uint4*)(&Bs[r_c0][r_seg*8]) = bv0;
      *(uint4*)(&Bs[r_c1][r_seg*8]) = bv1;
    }
    __syncthreads();
    s16x8 a[4], bb[4];
    #pragma unroll
    for (int m=0;m<4;m++) a[m] = *(const s16x8*)(&As[wrow + m*16 + fr][kg*8]);
    #pragma unroll
    for (int n=0;n<4;n++) bb[n] = *(const s16x8*)(&Bs[wcol + n*16 + fr][kg*8]);
    #pragma unroll
    for (int m=0;m<4;m++)
      #pragma unroll
      for (int n=0;n<4;n++)
        acc[m][n] = __builtin_amdgcn_mfma_f32_16x16x32_bf16(a[m], bb[n], acc[m][n], 0,0,0);
  }
  #pragma unroll
  for (int n=0;n<4;n++){
    int ccol = n0 + wcol + n*16 + fr;
    if (ccol >= N) continue;
    #pragma unroll
    for (int m=0;m<4;m++){
      #pragma unroll
      for (int q=0;q<4;q++){
        int row = m0 + wrow + m*16 + kg*4 + q;
        float v = acc[m][n][q];
        size_t oidx = (size_t)row*ldc + ccol;
        if constexpr (EPI == EPI_STORE) Cout[oidx] = f2b(v);
        else if constexpr (EPI == EPI_STORE32) Cout32[oidx] = v;
        else if constexpr (EPI == EPI_TANH) Cout[oidx] = f2b(tanhf(v));
        else if constexpr (EPI == EPI_SILU) Cout[oidx] = f2b(v / (1.f + expf(-v)));
        else if constexpr (EPI == EPI_LERP){
          float xv = e_x[(size_t)row*2048 + ccol];
          float dx = b2f(e_dxp[(size_t)row*2048 + ccol]);
          Cout[oidx] = f2b(xv + dx * (e_vec[ccol] + v));
        }
        else if constexpr (EPI == EPI_ICLR) Cout[oidx] = f2b(1.f / (1.f + expf(-(e_vec[ccol] + v))));
      }
    }
  }
}

// ---------------------------------------------------------------- thin GEMM: 64x64 tile, for small N
template<int EPI>
__global__ __launch_bounds__(256) void gemm_thin_k(
    const u16* __restrict__ A, int lda,
    const u16* __restrict__ Bt, int ldb,
    u16* __restrict__ Cout, int ldc, int N, int K)
{
  __shared__ u16 As[64][40];
  __shared__ u16 Bs[64][40];
  const int tid = threadIdx.x;
  const int lane = tid & 63, wid = tid >> 6;
  const int m0 = blockIdx.x * 64, n0 = blockIdx.y * 64;
  const int wrow = (wid >> 1) * 32, wcol = (wid & 1) * 32;
  const int fr = lane & 15, kg = lane >> 4;
  const int r_c = tid >> 2, r_seg = tid & 3;

  f32x4 acc[2][2];
  #pragma unroll
  for (int m=0;m<2;m++)
    #pragma unroll
    for (int n=0;n<2;n++) acc[m][n] = ZF4;

  for (int k0 = 0; k0 < K; k0 += 32) {
    __syncthreads();
    {
      uint4 av = *(const uint4*)(A + (size_t)(m0 + r_c)*lda + k0 + r_seg*8);
      *(uint4*)(&As[r_c][r_seg*8]) = av;
      uint4 z = make_uint4(0,0,0,0);
      uint4 bv = (n0 + r_c < N) ? *(const uint4*)(Bt + (size_t)(n0 + r_c)*ldb + k0 + r_seg*8) : z;
      *(uint4*)(&Bs[r_c][r_seg*8]) = bv;
    }
    __syncthreads();
    s16x8 a[2], bb[2];
    #pragma unroll
    for (int m=0;m<2;m++) a[m] = *(const s16x8*)(&As[wrow + m*16 + fr][kg*8]);
    #pragma unroll
    for (int n=0;n<2;n++) bb[n] = *(const s16x8*)(&Bs[wcol + n*16 + fr][kg*8]);
    #pragma unroll
    for (int m=0;m<2;m++)
      #pragma unroll
      for (int n=0;n<2;n++)
        acc[m][n] = __builtin_amdgcn_mfma_f32_16x16x32_bf16(a[m], bb[n], acc[m][n], 0,0,0);
  }
  #pragma unroll
  for (int n=0;n<2;n++){
    int ccol = n0 + wcol + n*16 + fr;
    if (ccol >= N) continue;
    #pragma unroll
    for (int m=0;m<2;m++){
      #pragma unroll
      for (int q=0;q<4;q++){
        int row = m0 + wrow + m*16 + kg*4 + q;
        float v = acc[m][n][q];
        size_t oidx = (size_t)row*ldc + ccol;
        if constexpr (EPI == EPI_TANH) Cout[oidx] = f2b(tanhf(v));
        else Cout[oidx] = f2b(v);
      }
    }
  }
}

// ---------------------------------------------------------------- WKV phase 1: per chunk-head, 512 threads / 8 waves
// WL/WC stride 65 f32 (bank-conflict-free scan: bank=(lane+k)%32; P1/P4a reads 2-way).
__global__ __launch_bounds__(512, 1) void wkv1_k(
    const u16* __restrict__ r_g, const u16* __restrict__ kraw_g, const u16* __restrict__ v_g,
    const u16* __restrict__ ic_g,
    const u16* __restrict__ t2_g, const u16* __restrict__ dw2t_g, const float* __restrict__ td_g,
    const float* __restrict__ u_g, const float* __restrict__ kkk_g, const float* __restrict__ kka_g,
    u16* __restrict__ y1_g, u16* __restrict__ rw_g,
    u16* __restrict__ kvab_g, float* __restrict__ wsA_g)
{
  // Arena 162304 B. Slots:
  //  [0,33280)       WL f32[128][65]   -> (P3+) Abuf u16[128][136] @0..34816
  //  [34816,68096)   WC f32[128][65]   -> (P4b+) kkcT u16[128][136] @34816..69632
  //  [68096,70144)   tail: diag(128f)/offs/wsum/u/kkk/kka/td  (kkcT overlays diag..kkk, all dead by P4b)
  //  [70144,88576)   rd u16[128][72]   -> (P5a+) vT u16[64][136]
  //  [88576,107008)  ki u16[128][72]   -> (P4a+) kkwT u16[64][136]
  //  [107008,125440) kwT u16[64][136]
  //  [125440,143872) ka u16[128][72]
  //  [143872,162304) kkb u16[128][72]  -> (P5a+) kaT u16[64][136]
  __shared__ __align__(16) char arena[162304];
  float* WL   = (float*)(arena);
  float* WC   = (float*)(arena + 34816);
  u16* Abuf   = (u16*)(arena);
  u16* kkcT   = (u16*)(arena + 34816);
  float* diag_l = (float*)(arena + 68096);  // 128
  float* offs_l = diag_l + 128;             // 64
  float* wsum_l = offs_l + 64;              // 64
  float* u_l    = wsum_l + 64;              // 64
  float* kkk_l  = u_l + 64;                 // 64
  float* kka_l  = kkk_l + 64;               // 64
  float* td_l   = kka_l + 64;               // 64 -> ends 70144
  u16* rd_l   = (u16*)(arena + 70144);
  u16* vT_l   = (u16*)(arena + 70144);
  u16* ki_l   = (u16*)(arena + 88576);
  u16* kkwT_l = (u16*)(arena + 88576);
  u16* kwT_l  = (u16*)(arena + 107008);
  u16* ka_l   = (u16*)(arena + 125440);
  u16* kkb_l  = (u16*)(arena + 143872);
  u16* kaT_l  = (u16*)(arena + 143872);

  const int tid = threadIdx.x, lane = tid & 63, wid = tid >> 6;  // wid 0..7
  const int cb = blockIdx.x;
  const int c = cb >> 6, b = (cb >> 5) & 1, h = cb & 31;
  const size_t base = ((size_t)(b*4096 + c*128)) * 2048 + h*64;
  const int fr = lane & 15, kg = lane >> 4;
  const int tq = tid >> 2, kh = (tid & 3) * 16;   // 4 threads per row, 16 cols each

  // P0a: stage t2 [128][64] + dw2t head-slice [64][64]; per-head vectors
  {
    const u16* t2s = t2_g + (size_t)(b*4096 + c*128 + tq)*64 + kh;
    *(uint4*)(&rd_l[tq*72 + kh])     = *(const uint4*)(t2s);
    *(uint4*)(&rd_l[tq*72 + kh + 8]) = *(const uint4*)(t2s + 8);
    int n = tid >> 3, sg2 = (tid & 7) * 8;
    *(uint4*)(&ki_l[n*72 + sg2]) = *(const uint4*)(dw2t_g + (size_t)(h*64 + n)*64 + sg2);
  }
  if (tid < 64){
    u_l[tid]   = u_g[h*64 + tid];
    kkk_l[tid] = kkk_g[h*64 + tid];
    kka_l[tid] = kka_g[h*64 + tid];
    td_l[tid]  = td_g[h*64 + tid];
  }
  __syncthreads();
  // P0b: WL[t][k] = -exp(td[k] + t2[t,:] . dw2[:,k])
  {
    f32x4 accW[4];
    #pragma unroll
    for (int n=0;n<4;n++) accW[n] = ZF4;
    #pragma unroll
    for (int ks=0; ks<2; ++ks){
      s16x8 af = *(const s16x8*)(&rd_l[(wid*16 + fr)*72 + ks*32 + kg*8]);
      #pragma unroll
      for (int n=0;n<4;n++){
        s16x8 bf = *(const s16x8*)(&ki_l[(n*16 + fr)*72 + ks*32 + kg*8]);
        accW[n] = __builtin_amdgcn_mfma_f32_16x16x32_bf16(af, bf, accW[n], 0,0,0);
      }
    }
    #pragma unroll
    for (int n=0;n<4;n++)
      #pragma unroll
      for (int q=0;q<4;q++){
        int t = wid*16 + kg*4 + q;
        int s = n*16 + fr;
        WL[t*65 + s] = -expf(td_l[s] + accW[n][q]);
      }
  }
  __syncthreads();
  // scan: inclusive cumsum over t per column k — 8 cols per wave (stride-65: conflict-free)
  for (int j=0;j<8;j++){
    int k = wid*8 + j;
    float v = WL[lane*65 + k];
    #pragma unroll
    for (int d=1; d<64; d<<=1){ float o = __shfl_up(v, d); if (lane >= d) v += o; }
    WC[lane*65 + k] = v;
    float carry = __shfl(v, 63);
    float v2 = WL[(64+lane)*65 + k];
    #pragma unroll
    for (int d=1; d<64; d<<=1){ float o = __shfl_up(v2, d); if (lane >= d) v2 += o; }
    v2 += carry;
    WC[(64+lane)*65 + k] = v2;
    float tot = __shfl(v2, 63);
    if (lane == 0){ offs_l[k] = carry; wsum_l[k] = tot; wsA_g[(size_t)cb*64 + k] = expf(tot); }
  }
  __syncthreads();
  // P1: r, kadj -> rd, ki (natural), kwT (transposed), rw (global), diag
  {
    const u16* rs  = r_g    + base + (size_t)tq*2048 + kh;
    const u16* ks_ = kraw_g + base + (size_t)tq*2048 + kh;
    const u16* is_ = ic_g   + base + (size_t)tq*2048 + kh;
    float dpart = 0.f;
    #pragma unroll
    for (int j=0;j<2;j++){
      float rf[8], kf[8], icf[8], rdf[8], kif[8], rwf[8];
      up8(*(const uint4*)(rs + j*8), rf);
      up8(*(const uint4*)(ks_ + j*8), kf);
      up8(*(const uint4*)(is_ + j*8), icf);
      #pragma unroll
      for (int e=0;e<8;e++){
        int k = kh + j*8 + e;
        float kadj = kf[e] * (1.f + (icf[e] - 1.f) * kka_l[k]);
        float wl = WL[tq*65+k], wc = WC[tq*65+k];
        float wcs = wc - wl;
        float off = offs_l[k], wsm = wsum_l[k];
        rdf[e] = rf[e] * expf(clip30(wcs - off));
        kif[e] = kadj  * expf(clip30(off - wc));
        rwf[e] = rf[e] * expf(clip30(wcs));
        kwT_l[k*136 + tq] = f2b(kadj * expf(clip30(wsm - wc)));
        dpart += rf[e] * u_l[k] * kadj;
      }
      *(uint4*)(&rd_l[tq*72 + kh + j*8]) = pk8(rdf);
      *(uint4*)(&ki_l[tq*72 + kh + j*8]) = pk8(kif);
      *(uint4*)(rw_g + base + (size_t)tq*2048 + kh + j*8) = pk8(rwf);
    }
    dpart += __shfl_xor(dpart, 1);
    dpart += __shfl_xor(dpart, 2);
    if ((tid & 3) == 0) diag_l[tq] = dpart;
  }
  __syncthreads();
  // P2: raw k, iclr -> ka = kk*iclr, kkb = kk (normalized)
  {
    const u16* ks_ = kraw_g + base + (size_t)tq*2048 + kh;
    const u16* is_ = ic_g   + base + (size_t)tq*2048 + kh;
    float kf[16], icf[16], kkraw[16];
    #pragma unroll
    for (int j=0;j<2;j++){
      up8(*(const uint4*)(ks_ + j*8), kf + j*8);
      up8(*(const uint4*)(is_ + j*8), icf + j*8);
    }
    float ss = 0.f;
    #pragma unroll
    for (int e=0;e<16;e++){ kkraw[e] = kf[e]*kkk_l[kh+e]; ss += kkraw[e]*kkraw[e]; }
    ss += __shfl_xor(ss, 1);
    ss += __shfl_xor(ss, 2);
    float rn = 1.f / fmaxf(sqrtf(ss), 1e-12f);
    #pragma unroll
    for (int j=0;j<2;j++){
      float kkb8[8], ka8[8];
      #pragma unroll
      for (int e=0;e<8;e++){
        float kkv = kkraw[j*8+e]*rn;
        kkb8[e] = kkv; ka8[e] = kkv*icf[j*8+e];
      }
      *(uint4*)(&kkb_l[tq*72 + kh + j*8]) = pk8(kkb8);
      *(uint4*)(&ka_l [tq*72 + kh + j*8]) = pk8(ka8);
    }
  }
  __syncthreads();
  // P3: A = rd @ ki^T (wave w -> m-tile w), mask strict-lower + diag
  f32x4 accA[8];
  #pragma unroll
  for (int n=0;n<8;n++) accA[n] = ZF4;
  #pragma unroll
  for (int ks=0; ks<2; ++ks){
    s16x8 af = *(const s16x8*)(&rd_l[(wid*16 + fr)*72 + ks*32 + kg*8]);
    #pragma unroll
    for (int n=0;n<8;n++){
      s16x8 bf = *(const s16x8*)(&ki_l[(n*16 + fr)*72 + ks*32 + kg*8]);
      accA[n] = __builtin_amdgcn_mfma_f32_16x16x32_bf16(af, bf, accA[n], 0,0,0);
    }
  }
  #pragma unroll
  for (int n=0;n<8;n++)
    #pragma unroll
    for (int q=0;q<4;q++){
      int t = wid*16 + kg*4 + q;
      int s = n*16 + fr;
      float v = accA[n][q];
      v = (t > s) ? v : ((t == s) ? diag_l[t] : 0.f);
      accA[n][q] = v;
      Abuf[t*136 + s] = f2b(v);
    }
  __syncthreads();
  // P4a: kkwT[k][t] = -kk * w_inter
  {
    #pragma unroll
    for (int j=0;j<2;j++){
      float kkf[8];
      up8(*(const uint4*)(&kkb_l[tq*72 + kh + j*8]), kkf);
      #pragma unroll
      for (int e=0;e<8;e++){
        int k = kh + j*8 + e;
        kkwT_l[k*136 + tq] = f2b(-kkf[e] * expf(clip30(wsum_l[k] - WC[tq*65+k])));
      }
    }
  }
  __syncthreads();
  // P4b: kk_corr = ka @ kkb^T, strict-lower, write transposed kkcT[s][t]
  {
    f32x4 accC[8];
    #pragma unroll
    for (int n=0;n<8;n++) accC[n] = ZF4;
    #pragma unroll
    for (int ks=0; ks<2; ++ks){
      s16x8 af = *(const s16x8*)(&ka_l[(wid*16 + fr)*72 + ks*32 + kg*8]);
      #pragma unroll
      for (int n=0;n<8;n++){
        s16x8 bf = *(const s16x8*)(&kkb_l[(n*16 + fr)*72 + ks*32 + kg*8]);
        accC[n] = __builtin_amdgcn_mfma_f32_16x16x32_bf16(af, bf, accC[n], 0,0,0);
      }
    }
    #pragma unroll
    for (int n=0;n<8;n++)
      #pragma unroll
      for (int q=0;q<4;q++){
        int t = wid*16 + kg*4 + q;
        int s = n*16 + fr;
        kkcT[s*136 + t] = f2b((t > s) ? accC[n][q] : 0.f);
      }
  }
  __syncthreads();
  // P5a: stage v transposed (vT[vd][t]) + kaT[j][t] (over dead kkb)
  {
    const u16* vs = v_g + base + (size_t)tq*2048 + kh;
    #pragma unroll
    for (int j=0;j<2;j++){
      u16 el[8]; unp16(*(const uint4*)(vs + j*8), el);
      #pragma unroll
      for (int e=0;e<8;e++) vT_l[(kh + j*8 + e)*136 + tq] = el[e];
    }
    #pragma unroll
    for (int j=0;j<2;j++){
      u16 el[8]; unp16(*(const uint4*)(&ka_l[tq*72 + kh + j*8]), el);
      #pragma unroll
      for (int e=0;e<8;e++) kaT_l[(kh + j*8 + e)*136 + tq] = el[e];
    }
  }
  // P5b: P = Amask @ kkc ; A_total = Amask - tril(P) -> Abuf
  {
    f32x4 accP[8];
    #pragma unroll
    for (int n=0;n<8;n++) accP[n] = ZF4;
    #pragma unroll
    for (int ks=0; ks<4; ++ks){
      s16x8 af = *(const s16x8*)(&Abuf[(wid*16 + fr)*136 + ks*32 + kg*8]);
      #pragma unroll
      for (int n=0;n<8;n++){
        s16x8 bf = *(const s16x8*)(&kkcT[(n*16 + fr)*136 + ks*32 + kg*8]);
        accP[n] = __builtin_amdgcn_mfma_f32_16x16x32_bf16(af, bf, accP[n], 0,0,0);
      }
    }
    #pragma unroll
    for (int n=0;n<8;n++)
      #pragma unroll
      for (int q=0;q<4;q++){
        int t = wid*16 + kg*4 + q;
        int s = n*16 + fr;
        float v = accA[n][q] - ((t >= s) ? accP[n][q] : 0.f);
        Abuf[t*136 + s] = f2b(v);
      }
  }
  __syncthreads();
  // P6: y_intra = A_total @ v
  {
    f32x4 accY[4];
    #pragma unroll
    for (int n=0;n<4;n++) accY[n] = ZF4;
    #pragma unroll
    for (int ks=0; ks<4; ++ks){
      s16x8 af = *(const s16x8*)(&Abuf[(wid*16 + fr)*136 + ks*32 + kg*8]);
      #pragma unroll
      for (int n=0;n<4;n++){
        s16x8 bf = *(const s16x8*)(&vT_l[(n*16 + fr)*136 + ks*32 + kg*8]);
        accY[n] = __builtin_amdgcn_mfma_f32_16x16x32_bf16(af, bf, accY[n], 0,0,0);
      }
    }
    #pragma unroll
    for (int n=0;n<4;n++)
      #pragma unroll
      for (int q=0;q<4;q++){
        int t = wid*16 + kg*4 + q;
        int vd = n*16 + fr;
        y1_g[base + (size_t)t*2048 + vd] = f2b(accY[n][q]);
      }
  }
  // P7: kv = kwT @ vT^T (waves 0-3, row-major) ; ab = kkwT @ kaT^T (waves 4-7, stored TRANSPOSED for wkv2)
  {
    const int isAB = wid >> 2, mrow = (wid & 3) * 16;
    const u16* Amat = isAB ? kkwT_l : kwT_l;
    const u16* Bmat = isAB ? kaT_l  : vT_l;
    f32x4 acc2[4];
    #pragma unroll
    for (int n=0;n<4;n++) acc2[n] = ZF4;
    #pragma unroll
    for (int ks=0; ks<4; ++ks){
      s16x8 af = *(const s16x8*)(&Amat[(mrow + fr)*136 + ks*32 + kg*8]);
      #pragma unroll
      for (int n=0;n<4;n++){
        s16x8 bf = *(const s16x8*)(&Bmat[(n*16 + fr)*136 + ks*32 + kg*8]);
        acc2[n] = __builtin_amdgcn_mfma_f32_16x16x32_bf16(af, bf, acc2[n], 0,0,0);
      }
    }
    u16* kvp = kvab_g + (size_t)cb*8192 + isAB*4096;
    #pragma unroll
    for (int n=0;n<4;n++)
      #pragma unroll
      for (int q=0;q<4;q++){
        int kd = mrow + kg*4 + q, vd = n*16 + fr;
        if (isAB) kvp[vd*64 + kd] = f2b(acc2[n][q]);   // abT[v][k] for wkv2 B-operand
        else      kvp[kd*64 + vd] = f2b(acc2[n][q]);   // kv[k][v]
      }
  }
}

// ---------------------------------------------------------------- WKV phase 2: MFMA state scan per (b,h), reg prefetch
__global__ __launch_bounds__(256) void wkv2_k(
   const float* __restrict__ state_in, u16* __restrict__ kvab_g,
   const float* __restrict__ wsA_g, float* __restrict__ out_state)
{
  __shared__ u16 Sb[64][72];    // bf16 S (A-operand); only the S@ab input is rounded
  __shared__ u16 abT[64][72];   // abT[v_out][k_contract]
  const int tid = threadIdx.x, lane = tid & 63, wid = tid >> 6;
  const int bh = blockIdx.x, b = bh >> 5, h = bh & 31;
  const int fr = lane & 15, kg = lane >> 4;
  const int r0 = wid*16 + kg*4;                     // thread's 4 rows (C-layout)
  const int vrow = tid >> 2, jc = (tid & 3) * 16;   // abT staging ownership

  f32x4 S[4];   // S[n][q] = S[r0+q][n*16+fr], f32 across the whole scan
  #pragma unroll
  for (int n=0;n<4;n++)
    #pragma unroll
    for (int q=0;q<4;q++)
      S[n][q] = state_in[(size_t)bh*4096 + (size_t)(r0+q)*64 + n*16+fr];

  uint4 pf_ab0, pf_ab1; u16 pf_kv[16]; float pf_ws[4];
  {
    int cb = b*32 + h;   // chunk 0
    const u16* kvp = kvab_g + (size_t)cb*8192;
    pf_ab0 = *(const uint4*)(kvp + 4096 + vrow*64 + jc);
    pf_ab1 = *(const uint4*)(kvp + 4096 + vrow*64 + jc + 8);
    #pragma unroll
    for (int n=0;n<4;n++)
      #pragma unroll
      for (int q=0;q<4;q++)
        pf_kv[n*4+q] = kvp[(r0+q)*64 + n*16+fr];
    #pragma unroll
    for (int n=0;n<4;n++) pf_ws[n] = wsA_g[(size_t)cb*64 + n*16+fr];
  }

  for (int c=0;c<32;c++){
    int cb = (c*2+b)*32 + h;
    *(uint4*)(&abT[vrow][jc])   = pf_ab0;
    *(uint4*)(&abT[vrow][jc+8]) = pf_ab1;
    #pragma unroll
    for (int n=0;n<4;n++)
      #pragma unroll
      for (int q=0;q<4;q++)
        Sb[r0+q][n*16+fr] = f2b(S[n][q]);
    float kvf[16], wsf[4];
    #pragma unroll
    for (int i=0;i<16;i++) kvf[i] = b2f(pf_kv[i]);
    #pragma unroll
    for (int n=0;n<4;n++) wsf[n] = pf_ws[n];
    float* sip = (float*)(kvab_g + (size_t)cb*8192);
    #pragma unroll
    for (int n=0;n<4;n++)
      #pragma unroll
      for (int q=0;q<4;q++)
        sip[(r0+q)*64 + n*16+fr] = S[n][q];
    __syncthreads();
    if (c < 31){
      int cb2 = ((c+1)*2+b)*32 + h;
      const u16* kvp2 = kvab_g + (size_t)cb2*8192;
      pf_ab0 = *(const uint4*)(kvp2 + 4096 + vrow*64 + jc);
      pf_ab1 = *(const uint4*)(kvp2 + 4096 + vrow*64 + jc + 8);
      #pragma unroll
      for (int n=0;n<4;n++)
        #pragma unroll
        for (int q=0;q<4;q++)
          pf_kv[n*4+q] = kvp2[(r0+q)*64 + n*16+fr];
      #pragma unroll
      for (int n=0;n<4;n++) pf_ws[n] = wsA_g[(size_t)cb2*64 + n*16+fr];
    }
    f32x4 acc[4];
    #pragma unroll
    for (int n=0;n<4;n++) acc[n] = ZF4;
    #pragma unroll
    for (int ks=0; ks<2; ++ks){
      s16x8 a = *(const s16x8*)(&Sb[wid*16 + fr][ks*32 + kg*8]);
      #pragma unroll
      for (int n=0;n<4;n++){
        s16x8 bb = *(const s16x8*)(&abT[n*16 + fr][ks*32 + kg*8]);
        acc[n] = __builtin_amdgcn_mfma_f32_16x16x32_bf16(a, bb, acc[n], 0,0,0);
      }
    }
    #pragma unroll
    for (int n=0;n<4;n++)
      #pragma unroll
      for (int q=0;q<4;q++)
        S[n][q] = S[n][q]*wsf[n] + acc[n][q] + kvf[n*4+q];
    __syncthreads();
  }
  #pragma unroll
  for (int n=0;n<4;n++)
    #pragma unroll
    for (int q=0;q<4;q++)
      out_state[(size_t)bh*4096 + (size_t)(r0+q)*64 + n*16+fr] = S[n][q];
}

// ---------------------------------------------------------------- WKV phase 3: y = y1 + rw@S_in, GroupNorm, *g
__global__ __launch_bounds__(256) void wkv3_k(
   const u16* __restrict__ y1_g, const u16* __restrict__ rw_g,
   const u16* __restrict__ kvab_g,
   const u16* __restrict__ g_g, const float* __restrict__ gnw, const float* __restrict__ gnb,
   u16* __restrict__ yf_g)
{
  __shared__ float S_l[64][65];
  __shared__ u16 rw_l[128][72];
  int tid = threadIdx.x;
  int cb = blockIdx.x; int c = cb>>6, b = (cb>>5)&1, h = cb&31;
  size_t base = ((size_t)(b*4096 + c*128))*2048 + h*64;
  const float* sip = (const float*)(kvab_g + (size_t)cb*8192);
  #pragma unroll
  for (int j=0;j<16;j++){ int flat = tid*16+j; S_l[flat>>6][flat&63] = sip[flat]; }
  {
    int t = tid>>1, kh = (tid&1)*32;
    const u16* rs = rw_g + base + (size_t)t*2048 + kh;
    #pragma unroll
    for (int j=0;j<4;j++) *(uint4*)(&rw_l[t][kh+j*8]) = *(const uint4*)(rs + j*8);
  }
  __syncthreads();
  int t = tid>>1, vh = (tid&1)*32;
  float acc[32];
  #pragma unroll
  for (int j=0;j<32;j++) acc[j] = 0.f;
  for (int kf2=0; kf2<64; kf2++){
    float rv = b2f(rw_l[t][kf2]);
    #pragma unroll
    for (int j=0;j<32;j++) acc[j] += rv * S_l[kf2][vh+j];
  }
  float sum=0.f, sq=0.f;
  float yv[32];
  #pragma unroll
  for (int j=0;j<32;j++){
    yv[j] = acc[j] + b2f(y1_g[base + (size_t)t*2048 + vh + j]);
    sum += yv[j]; sq += yv[j]*yv[j];
  }
  sum += __shfl_xor(sum, 1); sq += __shfl_xor(sq, 1);
  float mean = sum * (1.f/64.f);
  float var = sq * (1.f/64.f) - mean*mean;
  float rstd = rsqrtf(fmaxf(var, 0.f) + 6.4e-4f);
  size_t bt = (size_t)(b*4096 + c*128 + t);
  #pragma unroll
  for (int j=0;j<32;j++){
    int ch = h*64 + vh + j;
    float val = (yv[j]-mean)*rstd * gnw[ch] + gnb[ch];
    val *= b2f(g_g[bt*2048 + ch]);
    yf_g[base + (size_t)t*2048 + vh + j] = f2b(val);
  }
}

// ---------------------------------------------------------------- host
#define O_WTR   0ull
#define O_WTK   8388608ull
#define O_WTV   16777216ull
#define O_WTG   25165824ull
#define O_WTO   33554432ull
#define O_W1T   41943040ull
#define O_W2T   42729472ull
#define O_DW1T  43515904ull
#define O_DW2T  43778048ull
#define O_A1T   44040192ull
#define O_A2T   44433408ull
#define O_XXX   44826624ull
#define O_T2    47972352ull
#define O_T3    49020928ull
#define O_WSA   50593792ull
#define O_XMX   51118080ull       /* 32MB: xmx -> g */
#define O_A     84672512ull       /* 32MB: lerp staging -> kvab/S_in */
#define O_I     118226944ull      /* 32MB: dxprev -> iclr */
#define O_R     151781376ull
#define O_K     185335808ull      /* raw k -> y1 -> yf */
#define O_V     218890240ull
#define WS_NEEDED 252444672ull

extern "C" void kernel_launch(void* const* d_in, const int* in_sizes, int n_in,
                              void* d_out, int out_size, void* d_ws, size_t ws_size,
                              hipStream_t stream)
{
  (void)in_sizes; (void)n_in; (void)out_size;
  if (ws_size < WS_NEEDED) return;
  const float* x     = (const float*)d_in[0];
  const float* shift = (const float*)d_in[1];
  const float* st_in = (const float*)d_in[2];
  const float* maax  = (const float*)d_in[3];
  const float* maas[6] = {(const float*)d_in[4],(const float*)d_in[5],(const float*)d_in[6],
                          (const float*)d_in[7],(const float*)d_in[8],(const float*)d_in[9]};
  const float* w1    = (const float*)d_in[10];
  const float* w2    = (const float*)d_in[11];
  const float* td    = (const float*)d_in[12];
  const float* dw1   = (const float*)d_in[13];
  const float* dw2   = (const float*)d_in[14];
  const float* faaaa = (const float*)d_in[15];
  const float* a0v   = (const float*)d_in[16];
  const float* a1w   = (const float*)d_in[17];
  const float* a2w   = (const float*)d_in[18];
  const float* kkk   = (const float*)d_in[19];
  const float* kka   = (const float*)d_in[20];
  const float* Wr    = (const float*)d_in[21];
  const float* Wk    = (const float*)d_in[22];
  const float* Wv    = (const float*)d_in[23];
  const float* Wg    = (const float*)d_in[24];
  const float* Wo    = (const float*)d_in[25];
  const float* gnw   = (const float*)d_in[26];
  const float* gnb   = (const float*)d_in[27];
  float* out = (float*)d_out;
  char* ws = (char*)d_ws;
  #define WSP(o) ((u16*)(ws + (o)))

  u16 *wtR=WSP(O_WTR), *wtK=WSP(O_WTK), *wtV=WSP(O_WTV), *wtG=WSP(O_WTG), *wtO=WSP(O_WTO);
  u16 *w1t=WSP(O_W1T), *w2t=WSP(O_W2T), *dw1t=WSP(O_DW1T), *dw2t=WSP(O_DW2T), *a1t=WSP(O_A1T), *a2t=WSP(O_A2T);
  u16 *xxx=WSP(O_XXX), *t2b=WSP(O_T2), *t3b=WSP(O_T3);
  u16 *xmx=WSP(O_XMX), *Ab=WSP(O_A), *Ib=WSP(O_I), *Rb=WSP(O_R), *Kb=WSP(O_K), *Vb=WSP(O_V);
  u16 *rw = WSP(O_WTR);
  u16 *kvab = WSP(O_A);
  u16 *gbuf = WSP(O_XMX);
  u16 *dxp  = WSP(O_I);
  float* wsA = (float*)(ws + O_WSA);
  float* out_xlast = out + 16777216;
  float* out_state = out + 16781312;

  dim3 tb(32,8);
  transpose_k<<<dim3(64,64), tb, 0, stream>>>(Wr, wtR, 2048, 2048);
  transpose_k<<<dim3(64,64), tb, 0, stream>>>(Wk, wtK, 2048, 2048);
  transpose_k<<<dim3(64,64), tb, 0, stream>>>(Wv, wtV, 2048, 2048);
  transpose_k<<<dim3(64,64), tb, 0, stream>>>(Wg, wtG, 2048, 2048);
  transpose_k<<<dim3(64,64), tb, 0, stream>>>(Wo, wtO, 2048, 2048);
  transpose_k<<<dim3(6,64),  tb, 0, stream>>>(w1, w1t, 2048, 192);
  transpose_k<<<dim3(64,6),  tb, 0, stream>>>(w2, w2t, 192, 2048);
  transpose_k<<<dim3(2,64),  tb, 0, stream>>>(dw1, dw1t, 2048, 64);
  transpose_k<<<dim3(64,2),  tb, 0, stream>>>(dw2, dw2t, 64, 2048);
  transpose_k<<<dim3(3,64),  tb, 0, stream>>>(a1w, a1t, 2048, 96);
  transpose_k<<<dim3(64,3),  tb, 0, stream>>>(a2w, a2t, 96, 2048);

  prep_k<<<8192, 256, 0, stream>>>(x, shift, maax, xmx, dxp, out_xlast);

  // xxx = tanh(xmx @ w1)
  gemm_thin_k<EPI_TANH><<<dim3(128,3), 256, 0, stream>>>(xmx, 2048, w1t, 2048, xxx, 192, 192, 2048);
  // xw -> Ab ; t2 = tanh(xw @ dw1)
  gemm_k<EPI_LERP,true,true><<<dim3(64,16), 256, 0, stream>>>(xxx + 0*32, 192, w2t + 0*32, 192, Ab, nullptr, 2048, 8192, 2048, 32, x, dxp, maas[0]);
  gemm_thin_k<EPI_TANH><<<dim3(128,1), 256, 0, stream>>>(Ab, 2048, dw1t, 2048, t2b, 64, 64, 2048);
  // xa -> Ab ; t3 = xa @ a1
  gemm_k<EPI_LERP,true,true><<<dim3(64,16), 256, 0, stream>>>(xxx + 5*32, 192, w2t + 5*32, 192, Ab, nullptr, 2048, 8192, 2048, 32, x, dxp, maas[5]);
  gemm_thin_k<EPI_STORE><<<dim3(128,2), 256, 0, stream>>>(Ab, 2048, a1t, 2048, t3b, 96, 96, 2048);
  // xr -> Ab ; r = xr @ Wr
  gemm_k<EPI_LERP,true,true><<<dim3(64,16), 256, 0, stream>>>(xxx + 3*32, 192, w2t + 3*32, 192, Ab, nullptr, 2048, 8192, 2048, 32, x, dxp, maas[3]);
  gemm256_k<EPI_STORE><<<dim3(32,8), 512, 0, stream>>>(Ab, wtR, Rb, nullptr, 8192, 2048, 2048);
  // xk -> Ab ; k(raw) = xk @ Wk
  gemm_k<EPI_LERP,true,true><<<dim3(64,16), 256, 0, stream>>>(xxx + 1*32, 192, w2t + 1*32, 192, Ab, nullptr, 2048, 8192, 2048, 32, x, dxp, maas[1]);
  gemm256_k<EPI_STORE><<<dim3(32,8), 512, 0, stream>>>(Ab, wtK, Kb, nullptr, 8192, 2048, 2048);
  // xv -> Ab ; v = xv @ Wv
  gemm_k<EPI_LERP,true,true><<<dim3(64,16), 256, 0, stream>>>(xxx + 2*32, 192, w2t + 2*32, 192, Ab, nullptr, 2048, 8192, 2048, 32, x, dxp, maas[2]);
  gemm256_k<EPI_STORE><<<dim3(32,8), 512, 0, stream>>>(Ab, wtV, Vb, nullptr, 8192, 2048, 2048);
  // xg -> Ab ; g = silu(xg @ Wg)
  gemm_k<EPI_LERP,true,true><<<dim3(64,16), 256, 0, stream>>>(xxx + 4*32, 192, w2t + 4*32, 192, Ab, nullptr, 2048, 8192, 2048, 32, x, dxp, maas[4]);
  gemm256_k<EPI_SILU><<<dim3(32,8), 512, 0, stream>>>(Ab, wtG, gbuf, nullptr, 8192, 2048, 2048);
  // iclr = sigmoid(a0 + t3 @ a2)
  gemm_k<EPI_ICLR,true,true><<<dim3(64,16), 256, 0, stream>>>(t3b, 96, a2t, 96, Ib, nullptr, 2048, 8192, 2048, 96, nullptr, nullptr, a0v);
  // wkv
  wkv1_k<<<2048, 512, 0, stream>>>(Rb, Kb, Vb, Ib, t2b, dw2t, td, faaaa, kkk, kka,
                                   Kb /*y1 overwrites raw k*/, rw, kvab, wsA);
  wkv2_k<<<64, 256, 0, stream>>>(st_in, kvab, wsA, out_state);
  wkv3_k<<<2048, 256, 0, stream>>>(Kb /*y1*/, rw, kvab /*S_in*/, gbuf, gnw, gnb, Kb /*yf in place*/);
  // out = yf @ W_o  (f32 store)
  gemm256_k<EPI_STORE32><<<dim3(32,8), 512, 0, stream>>>(Kb, wtO, nullptr, out, 8192, 2048, 2048);
}

// Round 9
// 1023.830 us; speedup vs baseline: 2.0458x; 1.2014x over previous
//
#include <hip/hip_runtime.h>

// RWKV7-delta time-mix. f32 in/out, bf16 intermediates + MFMA bf16 16x16x32.
// B=2 T=4096 C=2048 H=32 K=64 CHUNK=128 NC=32.

typedef unsigned short u16;
typedef unsigned int   u32;
typedef __attribute__((ext_vector_type(8))) short s16x8;
typedef __attribute__((ext_vector_type(4))) float f32x4;

#define DEV __device__ __forceinline__

DEV float b2f(u16 v){ return __uint_as_float(((u32)v) << 16); }
DEV u16 f2b(float f){ u32 u = __float_as_uint(f); return (u16)((u + 0x7fffu + ((u >> 16) & 1u)) >> 16); }
DEV float clip30(float x){ return fminf(fmaxf(x, -30.f), 30.f); }
DEV void up8(uint4 v, float* f){
  f[0]=b2f((u16)(v.x&0xffffu)); f[1]=b2f((u16)(v.x>>16));
  f[2]=b2f((u16)(v.y&0xffffu)); f[3]=b2f((u16)(v.y>>16));
  f[4]=b2f((u16)(v.z&0xffffu)); f[5]=b2f((u16)(v.z>>16));
  f[6]=b2f((u16)(v.w&0xffffu)); f[7]=b2f((u16)(v.w>>16));
}
DEV uint4 pk8(const float* f){
  uint4 v;
  v.x = (u32)f2b(f[0]) | ((u32)f2b(f[1])<<16);
  v.y = (u32)f2b(f[2]) | ((u32)f2b(f[3])<<16);
  v.z = (u32)f2b(f[4]) | ((u32)f2b(f[5])<<16);
  v.w = (u32)f2b(f[6]) | ((u32)f2b(f[7])<<16);
  return v;
}
DEV void unp16(uint4 v, u16* o){
  o[0]=(u16)(v.x&0xffffu); o[1]=(u16)(v.x>>16);
  o[2]=(u16)(v.y&0xffffu); o[3]=(u16)(v.y>>16);
  o[4]=(u16)(v.z&0xffffu); o[5]=(u16)(v.z>>16);
  o[6]=(u16)(v.w&0xffffu); o[7]=(u16)(v.w>>16);
}
DEV void gload16(const u16* g, u16* l){
  __builtin_amdgcn_global_load_lds(
      (const __attribute__((address_space(1))) u32*)g,
      (__attribute__((address_space(3))) u32*)l, 16, 0, 0);
}
#define ZF4 ((f32x4){0.f,0.f,0.f,0.f})

// ---------------------------------------------------------------- transpose f32 -> bf16
__global__ void transpose_k(const float* __restrict__ in, u16* __restrict__ out, int R, int C){
  __shared__ float tile[32][33];
  int c0 = blockIdx.x*32, r0 = blockIdx.y*32;
  int tx = threadIdx.x, ty = threadIdx.y; // (32,8)
  #pragma unroll
  for (int j=0;j<4;j++) tile[ty + j*8][tx] = in[(size_t)(r0 + ty + j*8)*C + c0 + tx];
  __syncthreads();
  #pragma unroll
  for (int j=0;j<4;j++) out[(size_t)(c0 + ty + j*8)*R + r0 + tx] = f2b(tile[tx][ty + j*8]);
}

// ---------------------------------------------------------------- prep: xmx bf16, dxprev bf16, x_last f32
__global__ __launch_bounds__(256) void prep_k(const float* __restrict__ x, const float* __restrict__ shift,
    const float* __restrict__ maax, u16* __restrict__ xmx, u16* __restrict__ dxp, float* __restrict__ out_xlast){
  int e8 = (blockIdx.x*256 + threadIdx.x) * 8;
  int row = e8 >> 11, col = e8 & 2047;
  int t = row & 4095, b = row >> 12;
  const float* xp = x + (size_t)row*2048 + col;
  const float* pp = t ? (x + (size_t)(row-1)*2048 + col) : (shift + (size_t)b*2048 + col);
  float xf[8], pf[8], mf[8], of[8], df[8];
  *(float4*)(xf)   = *(const float4*)(xp);
  *(float4*)(xf+4) = *(const float4*)(xp+4);
  *(float4*)(pf)   = *(const float4*)(pp);
  *(float4*)(pf+4) = *(const float4*)(pp+4);
  *(float4*)(mf)   = *(const float4*)(maax + col);
  *(float4*)(mf+4) = *(const float4*)(maax + col + 4);
  #pragma unroll
  for (int j=0;j<8;j++){ df[j] = pf[j]-xf[j]; of[j] = xf[j] + df[j]*mf[j]; }
  *(uint4*)(xmx + (size_t)row*2048 + col) = pk8(of);
  *(uint4*)(dxp + (size_t)row*2048 + col) = pk8(df);
  if (t == 4095){
    *(float4*)(out_xlast + (size_t)b*2048 + col)     = *(const float4*)(xf);
    *(float4*)(out_xlast + (size_t)b*2048 + col + 4) = *(const float4*)(xf+4);
  }
}

// ---------------------------------------------------------------- epilogue ids
enum { EPI_STORE=0, EPI_TANH=1, EPI_SILU=2, EPI_LERP=3, EPI_ICLR=5, EPI_STORE32=6 };

// ---------------------------------------------------------------- fused 6-way token-shift lerp
// o_s = x + dxp*(maa_s + xxx[:,s*32:(s+1)*32] @ w2t_s), s=0..5. x/dxp read ONCE per element.
__global__ __launch_bounds__(256) void lerp6_k(
    const u16* __restrict__ xxx, const u16* __restrict__ w2t,
    const float* __restrict__ x, const u16* __restrict__ dxp,
    const float* __restrict__ ma0, const float* __restrict__ ma1, const float* __restrict__ ma2,
    const float* __restrict__ ma3, const float* __restrict__ ma4, const float* __restrict__ ma5,
    u16* __restrict__ o0, u16* __restrict__ o1, u16* __restrict__ o2,
    u16* __restrict__ o3, u16* __restrict__ o4, u16* __restrict__ o5)
{
  __shared__ u16 As[128][40];
  __shared__ u16 Bs[128][40];
  const int tid = threadIdx.x, lane = tid & 63, wid = tid >> 6;
  const int m0 = blockIdx.x*128, n0 = blockIdx.y*128;
  const int wrow = (wid>>1)*64, wcol = (wid&1)*64;
  const int fr = lane&15, kg = lane>>4;
  const int r_c0 = tid>>2, r_seg = tid&3, r_c1 = r_c0+64;
  const float* maap[6] = {ma0,ma1,ma2,ma3,ma4,ma5};
  u16* outs[6] = {o0,o1,o2,o3,o4,o5};

  // preload x (f32) + dxp (bf16->f32) for this thread's 64 output elements
  float xv_[4][4][4], dxv_[4][4][4];
  #pragma unroll
  for (int m=0;m<4;m++)
    #pragma unroll
    for (int n=0;n<4;n++)
      #pragma unroll
      for (int q=0;q<4;q++){
        int row = m0 + wrow + m*16 + kg*4 + q;
        int col = n0 + wcol + n*16 + fr;
        xv_[m][n][q]  = x[(size_t)row*2048 + col];
        dxv_[m][n][q] = b2f(dxp[(size_t)row*2048 + col]);
      }

  #pragma unroll
  for (int s=0;s<6;s++){
    __syncthreads();
    *(uint4*)(&As[r_c0][r_seg*8]) = *(const uint4*)(xxx + (size_t)(m0+r_c0)*192 + s*32 + r_seg*8);
    *(uint4*)(&As[r_c1][r_seg*8]) = *(const uint4*)(xxx + (size_t)(m0+r_c1)*192 + s*32 + r_seg*8);
    *(uint4*)(&Bs[r_c0][r_seg*8]) = *(const uint4*)(w2t + (size_t)(n0+r_c0)*192 + s*32 + r_seg*8);
    *(uint4*)(&Bs[r_c1][r_seg*8]) = *(const uint4*)(w2t + (size_t)(n0+r_c1)*192 + s*32 + r_seg*8);
    __syncthreads();
    s16x8 a[4], bb[4];
    #pragma unroll
    for (int m=0;m<4;m++) a[m] = *(const s16x8*)(&As[wrow + m*16 + fr][kg*8]);
    #pragma unroll
    for (int n=0;n<4;n++) bb[n] = *(const s16x8*)(&Bs[wcol + n*16 + fr][kg*8]);
    f32x4 acc[4][4];
    #pragma unroll
    for (int m=0;m<4;m++)
      #pragma unroll
      for (int n=0;n<4;n++) acc[m][n] = ZF4;
    #pragma unroll
    for (int m=0;m<4;m++)
      #pragma unroll
      for (int n=0;n<4;n++)
        acc[m][n] = __builtin_amdgcn_mfma_f32_16x16x32_bf16(a[m], bb[n], acc[m][n], 0,0,0);
    #pragma unroll
    for (int n=0;n<4;n++){
      int col = n0 + wcol + n*16 + fr;
      float mv = maap[s][col];
      #pragma unroll
      for (int m=0;m<4;m++)
        #pragma unroll
        for (int q=0;q<4;q++){
          int row = m0 + wrow + m*16 + kg*4 + q;
          outs[s][(size_t)row*2048 + col] = f2b(xv_[m][n][q] + dxv_[m][n][q]*(mv + acc[m][n][q]));
        }
    }
  }
}

// ---------------------------------------------------------------- 256x256 BK=32 counted-vmcnt GEMM (big GEMMs)
template<int EPI>
__global__ __launch_bounds__(512, 2) void gemm256_k(
    const u16* __restrict__ A, const u16* __restrict__ Bt,
    u16* __restrict__ Cout, float* __restrict__ Cout32,
    int M, int N, int K)
{
  __shared__ __align__(16) u16 lds[4*16384];   // 4 bufs x (A[256][32] + B[256][32]) = 128 KiB
  const int tid = threadIdx.x, lane = tid & 63;
  int bxx = blockIdx.x, byy = blockIdx.y;
  if (gridDim.x == 32 && gridDim.y == 8){
    int bid = byy * 32 + bxx;
    int xcd = bid & 7, idx = bid >> 3;
    bxx = xcd*4 + (idx & 3);
    byy = idx >> 2;
  } else {
    int nwg = gridDim.x * gridDim.y;
    if ((nwg & 7) == 0){
      int bid = byy * gridDim.x + bxx;
      int cpx = nwg >> 3;
      int swz = (bid & 7) * cpx + (bid >> 3);
      bxx = swz % gridDim.x; byy = swz / gridDim.x;
    }
  }
  const int m0 = bxx * 256, n0 = byy * 256;
  const int wid = tid >> 6;
  const int wm = wid >> 2, wn = wid & 3;
  const int fr = lane & 15, kg = lane >> 4;
  const int NT = K >> 5;
  const int chunk0 = __builtin_amdgcn_readfirstlane(wid) * 2;
  const int lr = lane >> 2, lsl = lane & 3;

  f32x4 acc[8][4];
  #pragma unroll
  for (int m=0;m<8;m++)
    #pragma unroll
    for (int n=0;n<4;n++) acc[m][n] = ZF4;

  auto STAGE = [&](int t){
    u16* ab = lds + (t & 3) * 16384;
    u16* bb = ab + 8192;
    int k0 = t << 5;
    #pragma unroll
    for (int i=0;i<2;i++){
      int c = chunk0 + i;
      int r = c*16 + lr;
      int gc = k0 + lsl*8;
      gload16(A  + (size_t)(m0 + r)*K + gc, ab + c*512);
      gload16(Bt + (size_t)(n0 + r)*K + gc, bb + c*512);
    }
  };

  STAGE(0); STAGE(1); STAGE(2);
  for (int t=0; t<NT; ++t){
    asm volatile("s_waitcnt vmcnt(8)" ::: "memory");   // tiles <= t complete; t+1,t+2(,t+3) in flight
    __builtin_amdgcn_s_barrier();
    __builtin_amdgcn_sched_barrier(0);
    if (t+3 < NT) STAGE(t+3);
    const u16* ab = lds + (t & 3) * 16384;
    const u16* bb = ab + 8192;
    s16x8 af[8], bf[4];
    #pragma unroll
    for (int m=0;m<8;m++){
      int r = wm*128 + m*16 + fr;
      af[m] = *(const s16x8*)(ab + r*32 + kg*8);
    }
    #pragma unroll
    for (int n=0;n<4;n++){
      int r = wn*64 + n*16 + fr;
      bf[n] = *(const s16x8*)(bb + r*32 + kg*8);
    }
    __builtin_amdgcn_s_setprio(1);
    #pragma unroll
    for (int m=0;m<8;m++)
      #pragma unroll
      for (int n=0;n<4;n++)
        acc[m][n] = __builtin_amdgcn_mfma_f32_16x16x32_bf16(af[m], bf[n], acc[m][n], 0,0,0);
    __builtin_amdgcn_s_setprio(0);
  }

  #pragma unroll
  for (int n=0;n<4;n++){
    int ccol = n0 + wn*64 + n*16 + fr;
    #pragma unroll
    for (int m=0;m<8;m++){
      #pragma unroll
      for (int q=0;q<4;q++){
        int row = m0 + wm*128 + m*16 + kg*4 + q;
        float v = acc[m][n][q];
        size_t oidx = (size_t)row*N + ccol;
        if constexpr (EPI == EPI_STORE) Cout[oidx] = f2b(v);
        else if constexpr (EPI == EPI_STORE32) Cout32[oidx] = v;
        else if constexpr (EPI == EPI_SILU) Cout[oidx] = f2b(v / (1.f + expf(-v)));
      }
    }
  }
}

// ---------------------------------------------------------------- generic 128x128 GEMM with fused epilogues
template<int EPI, bool ASYNC, bool SWZ>
__global__ __launch_bounds__(256) void gemm_k(
    const u16* __restrict__ A, int lda,
    const u16* __restrict__ Bt, int ldb,
    u16* __restrict__ Cout, float* __restrict__ Cout32, int ldc,
    int M, int N, int K,
    const float* __restrict__ e_x, const u16* __restrict__ e_dxp, const float* __restrict__ e_vec)
{
  constexpr int LDW = ASYNC ? 32 : 40;
  __shared__ u16 As[128][LDW];
  __shared__ u16 Bs[128][LDW];
  const int tid = threadIdx.x;
  const int lane = tid & 63, wid = tid >> 6;
  int bxx = blockIdx.x, byy = blockIdx.y;
  if constexpr (SWZ){
    int nwg = gridDim.x * gridDim.y;
    if ((nwg & 7) == 0){
      int bid = byy * gridDim.x + bxx;
      int cpx = nwg >> 3;
      int swz = (bid & 7) * cpx + (bid >> 3);
      bxx = swz % gridDim.x; byy = swz / gridDim.x;
    }
  }
  const int m0 = bxx * 128, n0 = byy * 128;
  const int wrow = (wid >> 1) * 64, wcol = (wid & 1) * 64;
  const int fr = lane & 15, kg = lane >> 4;
  const int r_c0 = tid >> 2, r_seg = tid & 3;
  const int r_c1 = r_c0 + 64;

  f32x4 acc[4][4];
  #pragma unroll
  for (int m=0;m<4;m++)
    #pragma unroll
    for (int n=0;n<4;n++) acc[m][n] = ZF4;

  for (int k0 = 0; k0 < K; k0 += 32) {
    __syncthreads();
    if constexpr (ASYNC) {
      const int w4 = __builtin_amdgcn_readfirstlane(wid);
      const int rr = lane >> 2, seg8 = (lane & 3) * 8;
      #pragma unroll
      for (int i=0;i<2;i++){
        int row = w4*32 + i*16 + rr;
        gload16(A  + (size_t)(m0 + row)*lda + k0 + seg8, &As[w4*32 + i*16][0]);
        gload16(Bt + (size_t)(n0 + row)*ldb + k0 + seg8, &Bs[w4*32 + i*16][0]);
      }
    } else {
      uint4 av0 = *(const uint4*)(A + (size_t)(m0 + r_c0)*lda + k0 + r_seg*8);
      uint4 av1 = *(const uint4*)(A + (size_t)(m0 + r_c1)*lda + k0 + r_seg*8);
      *(uint4*)(&As[r_c0][r_seg*8]) = av0;
      *(uint4*)(&As[r_c1][r_seg*8]) = av1;
      uint4 z = make_uint4(0,0,0,0);
      uint4 bv0 = (n0 + r_c0 < N) ? *(const uint4*)(Bt + (size_t)(n0 + r_c0)*ldb + k0 + r_seg*8) : z;
      uint4 bv1 = (n0 + r_c1 < N) ? *(const uint4*)(Bt + (size_t)(n0 + r_c1)*ldb + k0 + r_seg*8) : z;
      *(uint4*)(&Bs[r_c0][r_seg*8]) = bv0;
      *(uint4*)(&Bs[r_c1][r_seg*8]) = bv1;
    }
    __syncthreads();
    s16x8 a[4], bb[4];
    #pragma unroll
    for (int m=0;m<4;m++) a[m] = *(const s16x8*)(&As[wrow + m*16 + fr][kg*8]);
    #pragma unroll
    for (int n=0;n<4;n++) bb[n] = *(const s16x8*)(&Bs[wcol + n*16 + fr][kg*8]);
    #pragma unroll
    for (int m=0;m<4;m++)
      #pragma unroll
      for (int n=0;n<4;n++)
        acc[m][n] = __builtin_amdgcn_mfma_f32_16x16x32_bf16(a[m], bb[n], acc[m][n], 0,0,0);
  }
  #pragma unroll
  for (int n=0;n<4;n++){
    int ccol = n0 + wcol + n*16 + fr;
    if (ccol >= N) continue;
    #pragma unroll
    for (int m=0;m<4;m++){
      #pragma unroll
      for (int q=0;q<4;q++){
        int row = m0 + wrow + m*16 + kg*4 + q;
        float v = acc[m][n][q];
        size_t oidx = (size_t)row*ldc + ccol;
        if constexpr (EPI == EPI_STORE) Cout[oidx] = f2b(v);
        else if constexpr (EPI == EPI_STORE32) Cout32[oidx] = v;
        else if constexpr (EPI == EPI_TANH) Cout[oidx] = f2b(tanhf(v));
        else if constexpr (EPI == EPI_SILU) Cout[oidx] = f2b(v / (1.f + expf(-v)));
        else if constexpr (EPI == EPI_LERP){
          float xv = e_x[(size_t)row*2048 + ccol];
          float dx = b2f(e_dxp[(size_t)row*2048 + ccol]);
          Cout[oidx] = f2b(xv + dx * (e_vec[ccol] + v));
        }
        else if constexpr (EPI == EPI_ICLR) Cout[oidx] = f2b(1.f / (1.f + expf(-(e_vec[ccol] + v))));
      }
    }
  }
}

// ---------------------------------------------------------------- thin GEMM: 64x64 tile, for small N
template<int EPI>
__global__ __launch_bounds__(256) void gemm_thin_k(
    const u16* __restrict__ A, int lda,
    const u16* __restrict__ Bt, int ldb,
    u16* __restrict__ Cout, int ldc, int N, int K)
{
  __shared__ u16 As[64][40];
  __shared__ u16 Bs[64][40];
  const int tid = threadIdx.x;
  const int lane = tid & 63, wid = tid >> 6;
  const int m0 = blockIdx.x * 64, n0 = blockIdx.y * 64;
  const int wrow = (wid >> 1) * 32, wcol = (wid & 1) * 32;
  const int fr = lane & 15, kg = lane >> 4;
  const int r_c = tid >> 2, r_seg = tid & 3;

  f32x4 acc[2][2];
  #pragma unroll
  for (int m=0;m<2;m++)
    #pragma unroll
    for (int n=0;n<2;n++) acc[m][n] = ZF4;

  for (int k0 = 0; k0 < K; k0 += 32) {
    __syncthreads();
    {
      uint4 av = *(const uint4*)(A + (size_t)(m0 + r_c)*lda + k0 + r_seg*8);
      *(uint4*)(&As[r_c][r_seg*8]) = av;
      uint4 z = make_uint4(0,0,0,0);
      uint4 bv = (n0 + r_c < N) ? *(const uint4*)(Bt + (size_t)(n0 + r_c)*ldb + k0 + r_seg*8) : z;
      *(uint4*)(&Bs[r_c][r_seg*8]) = bv;
    }
    __syncthreads();
    s16x8 a[2], bb[2];
    #pragma unroll
    for (int m=0;m<2;m++) a[m] = *(const s16x8*)(&As[wrow + m*16 + fr][kg*8]);
    #pragma unroll
    for (int n=0;n<2;n++) bb[n] = *(const s16x8*)(&Bs[wcol + n*16 + fr][kg*8]);
    #pragma unroll
    for (int m=0;m<2;m++)
      #pragma unroll
      for (int n=0;n<2;n++)
        acc[m][n] = __builtin_amdgcn_mfma_f32_16x16x32_bf16(a[m], bb[n], acc[m][n], 0,0,0);
  }
  #pragma unroll
  for (int n=0;n<2;n++){
    int ccol = n0 + wcol + n*16 + fr;
    if (ccol >= N) continue;
    #pragma unroll
    for (int m=0;m<2;m++){
      #pragma unroll
      for (int q=0;q<4;q++){
        int row = m0 + wrow + m*16 + kg*4 + q;
        float v = acc[m][n][q];
        size_t oidx = (size_t)row*ldc + ccol;
        if constexpr (EPI == EPI_TANH) Cout[oidx] = f2b(tanhf(v));
        else Cout[oidx] = f2b(v);
      }
    }
  }
}

// ---------------------------------------------------------------- WKV phase 1: per chunk-head, 512 threads / 8 waves
__global__ __launch_bounds__(512, 1) void wkv1_k(
    const u16* __restrict__ r_g, const u16* __restrict__ kraw_g, const u16* __restrict__ v_g,
    const u16* __restrict__ ic_g,
    const u16* __restrict__ t2_g, const u16* __restrict__ dw2t_g, const float* __restrict__ td_g,
    const float* __restrict__ u_g, const float* __restrict__ kkk_g, const float* __restrict__ kka_g,
    u16* __restrict__ y1_g, u16* __restrict__ rw_g,
    u16* __restrict__ kvab_g, float* __restrict__ wsA_g)
{
  __shared__ __align__(16) char arena[162304];
  float* WL   = (float*)(arena);
  float* WC   = (float*)(arena + 34816);
  u16* Abuf   = (u16*)(arena);
  u16* kkcT   = (u16*)(arena + 34816);
  float* diag_l = (float*)(arena + 68096);  // 128
  float* offs_l = diag_l + 128;             // 64
  float* wsum_l = offs_l + 64;              // 64
  float* u_l    = wsum_l + 64;              // 64
  float* kkk_l  = u_l + 64;                 // 64
  float* kka_l  = kkk_l + 64;               // 64
  float* td_l   = kka_l + 64;               // 64 -> ends 70144
  u16* rd_l   = (u16*)(arena + 70144);
  u16* vT_l   = (u16*)(arena + 70144);
  u16* ki_l   = (u16*)(arena + 88576);
  u16* kkwT_l = (u16*)(arena + 88576);
  u16* kwT_l  = (u16*)(arena + 107008);
  u16* ka_l   = (u16*)(arena + 125440);
  u16* kkb_l  = (u16*)(arena + 143872);
  u16* kaT_l  = (u16*)(arena + 143872);

  const int tid = threadIdx.x, lane = tid & 63, wid = tid >> 6;
  const int cb = blockIdx.x;
  const int c = cb >> 6, b = (cb >> 5) & 1, h = cb & 31;
  const size_t base = ((size_t)(b*4096 + c*128)) * 2048 + h*64;
  const int fr = lane & 15, kg = lane >> 4;
  const int tq = tid >> 2, kh = (tid & 3) * 16;

  // P0a
  {
    const u16* t2s = t2_g + (size_t)(b*4096 + c*128 + tq)*64 + kh;
    *(uint4*)(&rd_l[tq*72 + kh])     = *(const uint4*)(t2s);
    *(uint4*)(&rd_l[tq*72 + kh + 8]) = *(const uint4*)(t2s + 8);
    int n = tid >> 3, sg2 = (tid & 7) * 8;
    *(uint4*)(&ki_l[n*72 + sg2]) = *(const uint4*)(dw2t_g + (size_t)(h*64 + n)*64 + sg2);
  }
  if (tid < 64){
    u_l[tid]   = u_g[h*64 + tid];
    kkk_l[tid] = kkk_g[h*64 + tid];
    kka_l[tid] = kka_g[h*64 + tid];
    td_l[tid]  = td_g[h*64 + tid];
  }
  __syncthreads();
  // P0b
  {
    f32x4 accW[4];
    #pragma unroll
    for (int n=0;n<4;n++) accW[n] = ZF4;
    #pragma unroll
    for (int ks=0; ks<2; ++ks){
      s16x8 af = *(const s16x8*)(&rd_l[(wid*16 + fr)*72 + ks*32 + kg*8]);
      #pragma unroll
      for (int n=0;n<4;n++){
        s16x8 bf = *(const s16x8*)(&ki_l[(n*16 + fr)*72 + ks*32 + kg*8]);
        accW[n] = __builtin_amdgcn_mfma_f32_16x16x32_bf16(af, bf, accW[n], 0,0,0);
      }
    }
    #pragma unroll
    for (int n=0;n<4;n++)
      #pragma unroll
      for (int q=0;q<4;q++){
        int t = wid*16 + kg*4 + q;
        int s = n*16 + fr;
        WL[t*65 + s] = -__expf(td_l[s] + accW[n][q]);
      }
  }
  __syncthreads();
  // scan
  for (int j=0;j<8;j++){
    int k = wid*8 + j;
    float v = WL[lane*65 + k];
    #pragma unroll
    for (int d=1; d<64; d<<=1){ float o = __shfl_up(v, d); if (lane >= d) v += o; }
    WC[lane*65 + k] = v;
    float carry = __shfl(v, 63);
    float v2 = WL[(64+lane)*65 + k];
    #pragma unroll
    for (int d=1; d<64; d<<=1){ float o = __shfl_up(v2, d); if (lane >= d) v2 += o; }
    v2 += carry;
    WC[(64+lane)*65 + k] = v2;
    float tot = __shfl(v2, 63);
    if (lane == 0){ offs_l[k] = carry; wsum_l[k] = tot; wsA_g[(size_t)cb*64 + k] = __expf(tot); }
  }
  __syncthreads();
  // P1
  {
    const u16* rs  = r_g    + base + (size_t)tq*2048 + kh;
    const u16* ks_ = kraw_g + base + (size_t)tq*2048 + kh;
    const u16* is_ = ic_g   + base + (size_t)tq*2048 + kh;
    float dpart = 0.f;
    #pragma unroll
    for (int j=0;j<2;j++){
      float rf[8], kf[8], icf[8], rdf[8], kif[8], rwf[8];
      up8(*(const uint4*)(rs + j*8), rf);
      up8(*(const uint4*)(ks_ + j*8), kf);
      up8(*(const uint4*)(is_ + j*8), icf);
      #pragma unroll
      for (int e=0;e<8;e++){
        int k = kh + j*8 + e;
        float kadj = kf[e] * (1.f + (icf[e] - 1.f) * kka_l[k]);
        float wl = WL[tq*65+k], wc = WC[tq*65+k];
        float wcs = wc - wl;
        float off = offs_l[k], wsm = wsum_l[k];
        rdf[e] = rf[e] * __expf(clip30(wcs - off));
        kif[e] = kadj  * __expf(clip30(off - wc));
        rwf[e] = rf[e] * __expf(clip30(wcs));
        kwT_l[k*136 + tq] = f2b(kadj * __expf(clip30(wsm - wc)));
        dpart += rf[e] * u_l[k] * kadj;
      }
      *(uint4*)(&rd_l[tq*72 + kh + j*8]) = pk8(rdf);
      *(uint4*)(&ki_l[tq*72 + kh + j*8]) = pk8(kif);
      *(uint4*)(rw_g + base + (size_t)tq*2048 + kh + j*8) = pk8(rwf);
    }
    dpart += __shfl_xor(dpart, 1);
    dpart += __shfl_xor(dpart, 2);
    if ((tid & 3) == 0) diag_l[tq] = dpart;
  }
  __syncthreads();
  // P2
  {
    const u16* ks_ = kraw_g + base + (size_t)tq*2048 + kh;
    const u16* is_ = ic_g   + base + (size_t)tq*2048 + kh;
    float kf[16], icf[16], kkraw[16];
    #pragma unroll
    for (int j=0;j<2;j++){
      up8(*(const uint4*)(ks_ + j*8), kf + j*8);
      up8(*(const uint4*)(is_ + j*8), icf + j*8);
    }
    float ss = 0.f;
    #pragma unroll
    for (int e=0;e<16;e++){ kkraw[e] = kf[e]*kkk_l[kh+e]; ss += kkraw[e]*kkraw[e]; }
    ss += __shfl_xor(ss, 1);
    ss += __shfl_xor(ss, 2);
    float rn = 1.f / fmaxf(sqrtf(ss), 1e-12f);
    #pragma unroll
    for (int j=0;j<2;j++){
      float kkb8[8], ka8[8];
      #pragma unroll
      for (int e=0;e<8;e++){
        float kkv = kkraw[j*8+e]*rn;
        kkb8[e] = kkv; ka8[e] = kkv*icf[j*8+e];
      }
      *(uint4*)(&kkb_l[tq*72 + kh + j*8]) = pk8(kkb8);
      *(uint4*)(&ka_l [tq*72 + kh + j*8]) = pk8(ka8);
    }
  }
  __syncthreads();
  // P3
  f32x4 accA[8];
  #pragma unroll
  for (int n=0;n<8;n++) accA[n] = ZF4;
  #pragma unroll
  for (int ks=0; ks<2; ++ks){
    s16x8 af = *(const s16x8*)(&rd_l[(wid*16 + fr)*72 + ks*32 + kg*8]);
    #pragma unroll
    for (int n=0;n<8;n++){
      s16x8 bf = *(const s16x8*)(&ki_l[(n*16 + fr)*72 + ks*32 + kg*8]);
      accA[n] = __builtin_amdgcn_mfma_f32_16x16x32_bf16(af, bf, accA[n], 0,0,0);
    }
  }
  #pragma unroll
  for (int n=0;n<8;n++)
    #pragma unroll
    for (int q=0;q<4;q++){
      int t = wid*16 + kg*4 + q;
      int s = n*16 + fr;
      float v = accA[n][q];
      v = (t > s) ? v : ((t == s) ? diag_l[t] : 0.f);
      accA[n][q] = v;
      Abuf[t*136 + s] = f2b(v);
    }
  __syncthreads();
  // P4a
  {
    #pragma unroll
    for (int j=0;j<2;j++){
      float kkf[8];
      up8(*(const uint4*)(&kkb_l[tq*72 + kh + j*8]), kkf);
      #pragma unroll
      for (int e=0;e<8;e++){
        int k = kh + j*8 + e;
        kkwT_l[k*136 + tq] = f2b(-kkf[e] * __expf(clip30(wsum_l[k] - WC[tq*65+k])));
      }
    }
  }
  __syncthreads();
  // P4b
  {
    f32x4 accC[8];
    #pragma unroll
    for (int n=0;n<8;n++) accC[n] = ZF4;
    #pragma unroll
    for (int ks=0; ks<2; ++ks){
      s16x8 af = *(const s16x8*)(&ka_l[(wid*16 + fr)*72 + ks*32 + kg*8]);
      #pragma unroll
      for (int n=0;n<8;n++){
        s16x8 bf = *(const s16x8*)(&kkb_l[(n*16 + fr)*72 + ks*32 + kg*8]);
        accC[n] = __builtin_amdgcn_mfma_f32_16x16x32_bf16(af, bf, accC[n], 0,0,0);
      }
    }
    #pragma unroll
    for (int n=0;n<8;n++)
      #pragma unroll
      for (int q=0;q<4;q++){
        int t = wid*16 + kg*4 + q;
        int s = n*16 + fr;
        kkcT[s*136 + t] = f2b((t > s) ? accC[n][q] : 0.f);
      }
  }
  __syncthreads();
  // P5a
  {
    const u16* vs = v_g + base + (size_t)tq*2048 + kh;
    #pragma unroll
    for (int j=0;j<2;j++){
      u16 el[8]; unp16(*(const uint4*)(vs + j*8), el);
      #pragma unroll
      for (int e=0;e<8;e++) vT_l[(kh + j*8 + e)*136 + tq] = el[e];
    }
    #pragma unroll
    for (int j=0;j<2;j++){
      u16 el[8]; unp16(*(const uint4*)(&ka_l[tq*72 + kh + j*8]), el);
      #pragma unroll
      for (int e=0;e<8;e++) kaT_l[(kh + j*8 + e)*136 + tq] = el[e];
    }
  }
  // P5b
  {
    f32x4 accP[8];
    #pragma unroll
    for (int n=0;n<8;n++) accP[n] = ZF4;
    #pragma unroll
    for (int ks=0; ks<4; ++ks){
      s16x8 af = *(const s16x8*)(&Abuf[(wid*16 + fr)*136 + ks*32 + kg*8]);
      #pragma unroll
      for (int n=0;n<8;n++){
        s16x8 bf = *(const s16x8*)(&kkcT[(n*16 + fr)*136 + ks*32 + kg*8]);
        accP[n] = __builtin_amdgcn_mfma_f32_16x16x32_bf16(af, bf, accP[n], 0,0,0);
      }
    }
    #pragma unroll
    for (int n=0;n<8;n++)
      #pragma unroll
      for (int q=0;q<4;q++){
        int t = wid*16 + kg*4 + q;
        int s = n*16 + fr;
        float v = accA[n][q] - ((t >= s) ? accP[n][q] : 0.f);
        Abuf[t*136 + s] = f2b(v);
      }
  }
  __syncthreads();
  // P6
  {
    f32x4 accY[4];
    #pragma unroll
    for (int n=0;n<4;n++) accY[n] = ZF4;
    #pragma unroll
    for (int ks=0; ks<4; ++ks){
      s16x8 af = *(const s16x8*)(&Abuf[(wid*16 + fr)*136 + ks*32 + kg*8]);
      #pragma unroll
      for (int n=0;n<4;n++){
        s16x8 bf = *(const s16x8*)(&vT_l[(n*16 + fr)*136 + ks*32 + kg*8]);
        accY[n] = __builtin_amdgcn_mfma_f32_16x16x32_bf16(af, bf, accY[n], 0,0,0);
      }
    }
    #pragma unroll
    for (int n=0;n<4;n++)
      #pragma unroll
      for (int q=0;q<4;q++){
        int t = wid*16 + kg*4 + q;
        int vd = n*16 + fr;
        y1_g[base + (size_t)t*2048 + vd] = f2b(accY[n][q]);
      }
  }
  // P7
  {
    const int isAB = wid >> 2, mrow = (wid & 3) * 16;
    const u16* Amat = isAB ? kkwT_l : kwT_l;
    const u16* Bmat = isAB ? kaT_l  : vT_l;
    f32x4 acc2[4];
    #pragma unroll
    for (int n=0;n<4;n++) acc2[n] = ZF4;
    #pragma unroll
    for (int ks=0; ks<4; ++ks){
      s16x8 af = *(const s16x8*)(&Amat[(mrow + fr)*136 + ks*32 + kg*8]);
      #pragma unroll
      for (int n=0;n<4;n++){
        s16x8 bf = *(const s16x8*)(&Bmat[(n*16 + fr)*136 + ks*32 + kg*8]);
        acc2[n] = __builtin_amdgcn_mfma_f32_16x16x32_bf16(af, bf, acc2[n], 0,0,0);
      }
    }
    u16* kvp = kvab_g + (size_t)cb*8192 + isAB*4096;
    #pragma unroll
    for (int n=0;n<4;n++)
      #pragma unroll
      for (int q=0;q<4;q++){
        int kd = mrow + kg*4 + q, vd = n*16 + fr;
        if (isAB) kvp[vd*64 + kd] = f2b(acc2[n][q]);
        else      kvp[kd*64 + vd] = f2b(acc2[n][q]);
      }
  }
}

// ---------------------------------------------------------------- WKV phase 2: MFMA state scan per (b,h), reg prefetch
__global__ __launch_bounds__(256) void wkv2_k(
   const float* __restrict__ state_in, u16* __restrict__ kvab_g,
   const float* __restrict__ wsA_g, float* __restrict__ out_state)
{
  __shared__ u16 Sb[64][72];
  __shared__ u16 abT[64][72];
  const int tid = threadIdx.x, lane = tid & 63, wid = tid >> 6;
  const int bh = blockIdx.x, b = bh >> 5, h = bh & 31;
  const int fr = lane & 15, kg = lane >> 4;
  const int r0 = wid*16 + kg*4;
  const int vrow = tid >> 2, jc = (tid & 3) * 16;

  f32x4 S[4];
  #pragma unroll
  for (int n=0;n<4;n++)
    #pragma unroll
    for (int q=0;q<4;q++)
      S[n][q] = state_in[(size_t)bh*4096 + (size_t)(r0+q)*64 + n*16+fr];

  uint4 pf_ab0, pf_ab1; u16 pf_kv[16]; float pf_ws[4];
  {
    int cb = b*32 + h;
    const u16* kvp = kvab_g + (size_t)cb*8192;
    pf_ab0 = *(const uint4*)(kvp + 4096 + vrow*64 + jc);
    pf_ab1 = *(const uint4*)(kvp + 4096 + vrow*64 + jc + 8);
    #pragma unroll
    for (int n=0;n<4;n++)
      #pragma unroll
      for (int q=0;q<4;q++)
        pf_kv[n*4+q] = kvp[(r0+q)*64 + n*16+fr];
    #pragma unroll
    for (int n=0;n<4;n++) pf_ws[n] = wsA_g[(size_t)cb*64 + n*16+fr];
  }

  for (int c=0;c<32;c++){
    int cb = (c*2+b)*32 + h;
    *(uint4*)(&abT[vrow][jc])   = pf_ab0;
    *(uint4*)(&abT[vrow][jc+8]) = pf_ab1;
    #pragma unroll
    for (int n=0;n<4;n++)
      #pragma unroll
      for (int q=0;q<4;q++)
        Sb[r0+q][n*16+fr] = f2b(S[n][q]);
    float kvf[16], wsf[4];
    #pragma unroll
    for (int i=0;i<16;i++) kvf[i] = b2f(pf_kv[i]);
    #pragma unroll
    for (int n=0;n<4;n++) wsf[n] = pf_ws[n];
    float* sip = (float*)(kvab_g + (size_t)cb*8192);
    #pragma unroll
    for (int n=0;n<4;n++)
      #pragma unroll
      for (int q=0;q<4;q++)
        sip[(r0+q)*64 + n*16+fr] = S[n][q];
    __syncthreads();
    if (c < 31){
      int cb2 = ((c+1)*2+b)*32 + h;
      const u16* kvp2 = kvab_g + (size_t)cb2*8192;
      pf_ab0 = *(const uint4*)(kvp2 + 4096 + vrow*64 + jc);
      pf_ab1 = *(const uint4*)(kvp2 + 4096 + vrow*64 + jc + 8);
      #pragma unroll
      for (int n=0;n<4;n++)
        #pragma unroll
        for (int q=0;q<4;q++)
          pf_kv[n*4+q] = kvp2[(r0+q)*64 + n*16+fr];
      #pragma unroll
      for (int n=0;n<4;n++) pf_ws[n] = wsA_g[(size_t)cb2*64 + n*16+fr];
    }
    f32x4 acc[4];
    #pragma unroll
    for (int n=0;n<4;n++) acc[n] = ZF4;
    #pragma unroll
    for (int ks=0; ks<2; ++ks){
      s16x8 a = *(const s16x8*)(&Sb[wid*16 + fr][ks*32 + kg*8]);
      #pragma unroll
      for (int n=0;n<4;n++){
        s16x8 bb = *(const s16x8*)(&abT[n*16 + fr][ks*32 + kg*8]);
        acc[n] = __builtin_amdgcn_mfma_f32_16x16x32_bf16(a, bb, acc[n], 0,0,0);
      }
    }
    #pragma unroll
    for (int n=0;n<4;n++)
      #pragma unroll
      for (int q=0;q<4;q++)
        S[n][q] = S[n][q]*wsf[n] + acc[n][q] + kvf[n*4+q];
    __syncthreads();
  }
  #pragma unroll
  for (int n=0;n<4;n++)
    #pragma unroll
    for (int q=0;q<4;q++)
      out_state[(size_t)bh*4096 + (size_t)(r0+q)*64 + n*16+fr] = S[n][q];
}

// ---------------------------------------------------------------- WKV phase 3: y = y1 + rw@S_in, GroupNorm, *g
__global__ __launch_bounds__(256) void wkv3_k(
   const u16* __restrict__ y1_g, const u16* __restrict__ rw_g,
   const u16* __restrict__ kvab_g,
   const u16* __restrict__ g_g, const float* __restrict__ gnw, const float* __restrict__ gnb,
   u16* __restrict__ yf_g)
{
  __shared__ float S_l[64][65];
  __shared__ u16 rw_l[128][72];
  int tid = threadIdx.x;
  int cb = blockIdx.x; int c = cb>>6, b = (cb>>5)&1, h = cb&31;
  size_t base = ((size_t)(b*4096 + c*128))*2048 + h*64;
  const float* sip = (const float*)(kvab_g + (size_t)cb*8192);
  #pragma unroll
  for (int j=0;j<16;j++){ int flat = tid*16+j; S_l[flat>>6][flat&63] = sip[flat]; }
  {
    int t = tid>>1, kh = (tid&1)*32;
    const u16* rs = rw_g + base + (size_t)t*2048 + kh;
    #pragma unroll
    for (int j=0;j<4;j++) *(uint4*)(&rw_l[t][kh+j*8]) = *(const uint4*)(rs + j*8);
  }
  __syncthreads();
  int t = tid>>1, vh = (tid&1)*32;
  float acc[32];
  #pragma unroll
  for (int j=0;j<32;j++) acc[j] = 0.f;
  for (int kf2=0; kf2<64; kf2++){
    float rv = b2f(rw_l[t][kf2]);
    #pragma unroll
    for (int j=0;j<32;j++) acc[j] += rv * S_l[kf2][vh+j];
  }
  float sum=0.f, sq=0.f;
  float yv[32];
  #pragma unroll
  for (int j=0;j<32;j++){
    yv[j] = acc[j] + b2f(y1_g[base + (size_t)t*2048 + vh + j]);
    sum += yv[j]; sq += yv[j]*yv[j];
  }
  sum += __shfl_xor(sum, 1); sq += __shfl_xor(sq, 1);
  float mean = sum * (1.f/64.f);
  float var = sq * (1.f/64.f) - mean*mean;
  float rstd = rsqrtf(fmaxf(var, 0.f) + 6.4e-4f);
  size_t bt = (size_t)(b*4096 + c*128 + t);
  #pragma unroll
  for (int j=0;j<32;j++){
    int ch = h*64 + vh + j;
    float val = (yv[j]-mean)*rstd * gnw[ch] + gnb[ch];
    val *= b2f(g_g[bt*2048 + ch]);
    yf_g[base + (size_t)t*2048 + vh + j] = f2b(val);
  }
}

// ---------------------------------------------------------------- host
#define O_WTR   0ull
#define O_WTK   8388608ull
#define O_WTV   16777216ull
#define O_WTG   25165824ull
#define O_WTO   33554432ull
#define O_W1T   41943040ull
#define O_W2T   42729472ull
#define O_DW1T  43515904ull
#define O_DW2T  43778048ull
#define O_A1T   44040192ull
#define O_A2T   44433408ull
#define O_XXX   44826624ull
#define O_T2    47972352ull
#define O_T3    49020928ull
#define O_WSA   50593792ull
#define O_XMX   51118080ull       /* xmx -> xw -> r */
#define O_A     84672512ull       /* xk -> v -> kvab? no: kvab->V. A: xk -> v */
#define O_I     118226944ull      /* dxprev -> xa -> iclr */
#define O_R     151781376ull      /* xv -> g */
#define O_K     185335808ull      /* xr -> k -> y1 -> yf */
#define O_V     218890240ull      /* xg -> kvab/S_in */
#define WS_NEEDED 252444672ull

extern "C" void kernel_launch(void* const* d_in, const int* in_sizes, int n_in,
                              void* d_out, int out_size, void* d_ws, size_t ws_size,
                              hipStream_t stream)
{
  (void)in_sizes; (void)n_in; (void)out_size;
  if (ws_size < WS_NEEDED) return;
  const float* x     = (const float*)d_in[0];
  const float* shift = (const float*)d_in[1];
  const float* st_in = (const float*)d_in[2];
  const float* maax  = (const float*)d_in[3];
  const float* maas[6] = {(const float*)d_in[4],(const float*)d_in[5],(const float*)d_in[6],
                          (const float*)d_in[7],(const float*)d_in[8],(const float*)d_in[9]};
  const float* w1    = (const float*)d_in[10];
  const float* w2    = (const float*)d_in[11];
  const float* td    = (const float*)d_in[12];
  const float* dw1   = (const float*)d_in[13];
  const float* dw2   = (const float*)d_in[14];
  const float* faaaa = (const float*)d_in[15];
  const float* a0v   = (const float*)d_in[16];
  const float* a1w   = (const float*)d_in[17];
  const float* a2w   = (const float*)d_in[18];
  const float* kkk   = (const float*)d_in[19];
  const float* kka   = (const float*)d_in[20];
  const float* Wr    = (const float*)d_in[21];
  const float* Wk    = (const float*)d_in[22];
  const float* Wv    = (const float*)d_in[23];
  const float* Wg    = (const float*)d_in[24];
  const float* Wo    = (const float*)d_in[25];
  const float* gnw   = (const float*)d_in[26];
  const float* gnb   = (const float*)d_in[27];
  float* out = (float*)d_out;
  char* ws = (char*)d_ws;
  #define WSP(o) ((u16*)(ws + (o)))

  u16 *wtR=WSP(O_WTR), *wtK=WSP(O_WTK), *wtV=WSP(O_WTV), *wtG=WSP(O_WTG), *wtO=WSP(O_WTO);
  u16 *w1t=WSP(O_W1T), *w2t=WSP(O_W2T), *dw1t=WSP(O_DW1T), *dw2t=WSP(O_DW2T), *a1t=WSP(O_A1T), *a2t=WSP(O_A2T);
  u16 *xxx=WSP(O_XXX), *t2b=WSP(O_T2), *t3b=WSP(O_T3);
  u16 *sXMX=WSP(O_XMX), *sA=WSP(O_A), *sI=WSP(O_I), *sR=WSP(O_R), *sK=WSP(O_K), *sV=WSP(O_V);
  u16 *rw = WSP(O_WTR);
  float* wsA = (float*)(ws + O_WSA);
  float* out_xlast = out + 16777216;
  float* out_state = out + 16781312;

  dim3 tb(32,8);
  transpose_k<<<dim3(64,64), tb, 0, stream>>>(Wr, wtR, 2048, 2048);
  transpose_k<<<dim3(64,64), tb, 0, stream>>>(Wk, wtK, 2048, 2048);
  transpose_k<<<dim3(64,64), tb, 0, stream>>>(Wv, wtV, 2048, 2048);
  transpose_k<<<dim3(64,64), tb, 0, stream>>>(Wg, wtG, 2048, 2048);
  transpose_k<<<dim3(64,64), tb, 0, stream>>>(Wo, wtO, 2048, 2048);
  transpose_k<<<dim3(6,64),  tb, 0, stream>>>(w1, w1t, 2048, 192);
  transpose_k<<<dim3(64,6),  tb, 0, stream>>>(w2, w2t, 192, 2048);
  transpose_k<<<dim3(2,64),  tb, 0, stream>>>(dw1, dw1t, 2048, 64);
  transpose_k<<<dim3(64,2),  tb, 0, stream>>>(dw2, dw2t, 64, 2048);
  transpose_k<<<dim3(3,64),  tb, 0, stream>>>(a1w, a1t, 2048, 96);
  transpose_k<<<dim3(64,3),  tb, 0, stream>>>(a2w, a2t, 96, 2048);

  prep_k<<<8192, 256, 0, stream>>>(x, shift, maax, sXMX /*xmx*/, sI /*dxp*/, out_xlast);

  // xxx = tanh(xmx @ w1)
  gemm_thin_k<EPI_TANH><<<dim3(128,3), 256, 0, stream>>>(sXMX, 2048, w1t, 2048, xxx, 192, 192, 2048);
  // all 6 token-shift lerps fused: xw->XMX, xk->A, xv->R, xr->K, xg->V, xa->I(in-place over dxp)
  lerp6_k<<<dim3(64,16), 256, 0, stream>>>(xxx, w2t, x, sI /*dxp*/,
      maas[0], maas[1], maas[2], maas[3], maas[4], maas[5],
      sXMX /*xw*/, sA /*xk*/, sR /*xv*/, sK /*xr*/, sV /*xg*/, sI /*xa*/);
  // t2 = tanh(xw @ dw1) ; t3 = xa @ a1 ; iclr = sigmoid(a0 + t3@a2) -> I (xa dead)
  gemm_thin_k<EPI_TANH><<<dim3(128,1), 256, 0, stream>>>(sXMX, 2048, dw1t, 2048, t2b, 64, 64, 2048);
  gemm_thin_k<EPI_STORE><<<dim3(128,2), 256, 0, stream>>>(sI, 2048, a1t, 2048, t3b, 96, 96, 2048);
  gemm_k<EPI_ICLR,true,true><<<dim3(64,16), 256, 0, stream>>>(t3b, 96, a2t, 96, sI, nullptr, 2048, 8192, 2048, 96, nullptr, nullptr, a0v);
  // big projections: r = xr@Wr -> XMX (xw dead); k = xk@Wk -> K (xr dead); v = xv@Wv -> A (xk dead); g = xg@Wg -> R (xv dead)
  gemm256_k<EPI_STORE><<<dim3(32,8), 512, 0, stream>>>(sK, wtR, sXMX, nullptr, 8192, 2048, 2048);
  gemm256_k<EPI_STORE><<<dim3(32,8), 512, 0, stream>>>(sA, wtK, sK, nullptr, 8192, 2048, 2048);
  gemm256_k<EPI_STORE><<<dim3(32,8), 512, 0, stream>>>(sR, wtV, sA, nullptr, 8192, 2048, 2048);
  gemm256_k<EPI_SILU><<<dim3(32,8), 512, 0, stream>>>(sV, wtG, sR, nullptr, 8192, 2048, 2048);
  // wkv: r=XMX k=K v=A ic=I ; y1 overwrites K ; rw->WTR ; kvab->V (xg dead)
  wkv1_k<<<2048, 512, 0, stream>>>(sXMX, sK, sA, sI, t2b, dw2t, td, faaaa, kkk, kka,
                                   sK, rw, sV, wsA);
  wkv2_k<<<64, 256, 0, stream>>>(st_in, sV, wsA, out_state);
  wkv3_k<<<2048, 256, 0, stream>>>(sK, rw, sV, sR /*g*/, gnw, gnb, sK /*yf in place*/);
  // out = yf @ W_o  (f32 store)
  gemm256_k<EPI_STORE32><<<dim3(32,8), 512, 0, stream>>>(sK, wtO, nullptr, out, 8192, 2048, 2048);
}

// Round 10
// 995.031 us; speedup vs baseline: 2.1050x; 1.0289x over previous
//
#include <hip/hip_runtime.h>

// RWKV7-delta time-mix. f32 in/out, bf16 intermediates + MFMA bf16 16x16x32.
// B=2 T=4096 C=2048 H=32 K=64 CHUNK=128 NC=32.

typedef unsigned short u16;
typedef unsigned int   u32;
typedef __attribute__((ext_vector_type(8))) short s16x8;
typedef __attribute__((ext_vector_type(4))) float f32x4;

#define DEV __device__ __forceinline__

DEV float b2f(u16 v){ return __uint_as_float(((u32)v) << 16); }
DEV u16 f2b(float f){ u32 u = __float_as_uint(f); return (u16)((u + 0x7fffu + ((u >> 16) & 1u)) >> 16); }
DEV float clip30(float x){ return fminf(fmaxf(x, -30.f), 30.f); }
DEV void up8(uint4 v, float* f){
  f[0]=b2f((u16)(v.x&0xffffu)); f[1]=b2f((u16)(v.x>>16));
  f[2]=b2f((u16)(v.y&0xffffu)); f[3]=b2f((u16)(v.y>>16));
  f[4]=b2f((u16)(v.z&0xffffu)); f[5]=b2f((u16)(v.z>>16));
  f[6]=b2f((u16)(v.w&0xffffu)); f[7]=b2f((u16)(v.w>>16));
}
DEV uint4 pk8(const float* f){
  uint4 v;
  v.x = (u32)f2b(f[0]) | ((u32)f2b(f[1])<<16);
  v.y = (u32)f2b(f[2]) | ((u32)f2b(f[3])<<16);
  v.z = (u32)f2b(f[4]) | ((u32)f2b(f[5])<<16);
  v.w = (u32)f2b(f[6]) | ((u32)f2b(f[7])<<16);
  return v;
}
DEV void unp16(uint4 v, u16* o){
  o[0]=(u16)(v.x&0xffffu); o[1]=(u16)(v.x>>16);
  o[2]=(u16)(v.y&0xffffu); o[3]=(u16)(v.y>>16);
  o[4]=(u16)(v.z&0xffffu); o[5]=(u16)(v.z>>16);
  o[6]=(u16)(v.w&0xffffu); o[7]=(u16)(v.w>>16);
}
DEV void gload16(const u16* g, u16* l){
  __builtin_amdgcn_global_load_lds(
      (const __attribute__((address_space(1))) u32*)g,
      (__attribute__((address_space(3))) u32*)l, 16, 0, 0);
}
#define ZF4 ((f32x4){0.f,0.f,0.f,0.f})

// ---------------------------------------------------------------- transpose f32 -> bf16
__global__ void transpose_k(const float* __restrict__ in, u16* __restrict__ out, int R, int C){
  __shared__ float tile[32][33];
  int c0 = blockIdx.x*32, r0 = blockIdx.y*32;
  int tx = threadIdx.x, ty = threadIdx.y; // (32,8)
  #pragma unroll
  for (int j=0;j<4;j++) tile[ty + j*8][tx] = in[(size_t)(r0 + ty + j*8)*C + c0 + tx];
  __syncthreads();
  #pragma unroll
  for (int j=0;j<4;j++) out[(size_t)(c0 + ty + j*8)*R + r0 + tx] = f2b(tile[tx][ty + j*8]);
}

// ---------------------------------------------------------------- prep: xmx bf16, dxprev bf16, x_last f32
__global__ __launch_bounds__(256) void prep_k(const float* __restrict__ x, const float* __restrict__ shift,
    const float* __restrict__ maax, u16* __restrict__ xmx, u16* __restrict__ dxp, float* __restrict__ out_xlast){
  int e8 = (blockIdx.x*256 + threadIdx.x) * 8;
  int row = e8 >> 11, col = e8 & 2047;
  int t = row & 4095, b = row >> 12;
  const float* xp = x + (size_t)row*2048 + col;
  const float* pp = t ? (x + (size_t)(row-1)*2048 + col) : (shift + (size_t)b*2048 + col);
  float xf[8], pf[8], mf[8], of[8], df[8];
  *(float4*)(xf)   = *(const float4*)(xp);
  *(float4*)(xf+4) = *(const float4*)(xp+4);
  *(float4*)(pf)   = *(const float4*)(pp);
  *(float4*)(pf+4) = *(const float4*)(pp+4);
  *(float4*)(mf)   = *(const float4*)(maax + col);
  *(float4*)(mf+4) = *(const float4*)(maax + col + 4);
  #pragma unroll
  for (int j=0;j<8;j++){ df[j] = pf[j]-xf[j]; of[j] = xf[j] + df[j]*mf[j]; }
  *(uint4*)(xmx + (size_t)row*2048 + col) = pk8(of);
  *(uint4*)(dxp + (size_t)row*2048 + col) = pk8(df);
  if (t == 4095){
    *(float4*)(out_xlast + (size_t)b*2048 + col)     = *(const float4*)(xf);
    *(float4*)(out_xlast + (size_t)b*2048 + col + 4) = *(const float4*)(xf+4);
  }
}

// ---------------------------------------------------------------- epilogue ids
enum { EPI_STORE=0, EPI_TANH=1, EPI_SILU=2, EPI_LERP=3, EPI_ICLR=5, EPI_STORE32=6 };

// ---------------------------------------------------------------- fused 6-way token-shift lerp
__global__ __launch_bounds__(256) void lerp6_k(
    const u16* __restrict__ xxx, const u16* __restrict__ w2t,
    const float* __restrict__ x, const u16* __restrict__ dxp,
    const float* __restrict__ ma0, const float* __restrict__ ma1, const float* __restrict__ ma2,
    const float* __restrict__ ma3, const float* __restrict__ ma4, const float* __restrict__ ma5,
    u16* __restrict__ o0, u16* __restrict__ o1, u16* __restrict__ o2,
    u16* __restrict__ o3, u16* __restrict__ o4, u16* __restrict__ o5)
{
  __shared__ u16 As[128][40];
  __shared__ u16 Bs[128][40];
  const int tid = threadIdx.x, lane = tid & 63, wid = tid >> 6;
  const int m0 = blockIdx.x*128, n0 = blockIdx.y*128;
  const int wrow = (wid>>1)*64, wcol = (wid&1)*64;
  const int fr = lane&15, kg = lane>>4;
  const int r_c0 = tid>>2, r_seg = tid&3, r_c1 = r_c0+64;
  const float* maap[6] = {ma0,ma1,ma2,ma3,ma4,ma5};
  u16* outs[6] = {o0,o1,o2,o3,o4,o5};

  float xv_[4][4][4], dxv_[4][4][4];
  #pragma unroll
  for (int m=0;m<4;m++)
    #pragma unroll
    for (int n=0;n<4;n++)
      #pragma unroll
      for (int q=0;q<4;q++){
        int row = m0 + wrow + m*16 + kg*4 + q;
        int col = n0 + wcol + n*16 + fr;
        xv_[m][n][q]  = x[(size_t)row*2048 + col];
        dxv_[m][n][q] = b2f(dxp[(size_t)row*2048 + col]);
      }

  #pragma unroll
  for (int s=0;s<6;s++){
    __syncthreads();
    *(uint4*)(&As[r_c0][r_seg*8]) = *(const uint4*)(xxx + (size_t)(m0+r_c0)*192 + s*32 + r_seg*8);
    *(uint4*)(&As[r_c1][r_seg*8]) = *(const uint4*)(xxx + (size_t)(m0+r_c1)*192 + s*32 + r_seg*8);
    *(uint4*)(&Bs[r_c0][r_seg*8]) = *(const uint4*)(w2t + (size_t)(n0+r_c0)*192 + s*32 + r_seg*8);
    *(uint4*)(&Bs[r_c1][r_seg*8]) = *(const uint4*)(w2t + (size_t)(n0+r_c1)*192 + s*32 + r_seg*8);
    __syncthreads();
    s16x8 a[4], bb[4];
    #pragma unroll
    for (int m=0;m<4;m++) a[m] = *(const s16x8*)(&As[wrow + m*16 + fr][kg*8]);
    #pragma unroll
    for (int n=0;n<4;n++) bb[n] = *(const s16x8*)(&Bs[wcol + n*16 + fr][kg*8]);
    f32x4 acc[4][4];
    #pragma unroll
    for (int m=0;m<4;m++)
      #pragma unroll
      for (int n=0;n<4;n++) acc[m][n] = ZF4;
    #pragma unroll
    for (int m=0;m<4;m++)
      #pragma unroll
      for (int n=0;n<4;n++)
        acc[m][n] = __builtin_amdgcn_mfma_f32_16x16x32_bf16(a[m], bb[n], acc[m][n], 0,0,0);
    #pragma unroll
    for (int n=0;n<4;n++){
      int col = n0 + wcol + n*16 + fr;
      float mv = maap[s][col];
      #pragma unroll
      for (int m=0;m<4;m++)
        #pragma unroll
        for (int q=0;q<4;q++){
          int row = m0 + wrow + m*16 + kg*4 + q;
          outs[s][(size_t)row*2048 + col] = f2b(xv_[m][n][q] + dxv_[m][n][q]*(mv + acc[m][n][q]));
        }
    }
  }
}

// ---------------------------------------------------------------- 256x256 BK=32 counted-vmcnt GEMM (big GEMMs)
// LDS k-slot swizzle: slot' = kg ^ ((row>>1)&3); pre-swizzled GLOBAL source + swizzled read,
// linear LDS dest (rule: both-sides-or-neither with global_load_lds). Kills the 8-way ds_read conflict.
template<int EPI>
__global__ __launch_bounds__(512, 2) void gemm256_k(
    const u16* __restrict__ A, const u16* __restrict__ Bt,
    u16* __restrict__ Cout, float* __restrict__ Cout32,
    int M, int N, int K)
{
  __shared__ __align__(16) u16 lds[4*16384];   // 4 bufs x (A[256][32] + B[256][32]) = 128 KiB
  const int tid = threadIdx.x, lane = tid & 63;
  int bxx = blockIdx.x, byy = blockIdx.y;
  if (gridDim.x == 32 && gridDim.y == 8){
    int bid = byy * 32 + bxx;
    int xcd = bid & 7, idx = bid >> 3;
    bxx = xcd*4 + (idx & 3);
    byy = idx >> 2;
  } else {
    int nwg = gridDim.x * gridDim.y;
    if ((nwg & 7) == 0){
      int bid = byy * gridDim.x + bxx;
      int cpx = nwg >> 3;
      int swz = (bid & 7) * cpx + (bid >> 3);
      bxx = swz % gridDim.x; byy = swz / gridDim.x;
    }
  }
  const int m0 = bxx * 256, n0 = byy * 256;
  const int wid = tid >> 6;
  const int wm = wid >> 2, wn = wid & 3;
  const int fr = lane & 15, kg = lane >> 4;
  const int NT = K >> 5;
  const int chunk0 = __builtin_amdgcn_readfirstlane(wid) * 2;
  const int lr = lane >> 2, lsl = lane & 3;
  const int gswz = (lsl ^ ((lr >> 1) & 3)) << 3;   // pre-swizzled k-offset (elements)
  const int kswz = (kg ^ ((fr >> 1) & 3)) << 3;    // swizzled read k-offset (elements)

  f32x4 acc[8][4];
  #pragma unroll
  for (int m=0;m<8;m++)
    #pragma unroll
    for (int n=0;n<4;n++) acc[m][n] = ZF4;

  auto STAGE = [&](int t){
    u16* ab = lds + (t & 3) * 16384;
    u16* bb = ab + 8192;
    int gc = (t << 5) + gswz;
    #pragma unroll
    for (int i=0;i<2;i++){
      int c = chunk0 + i;
      int r = c*16 + lr;
      gload16(A  + (size_t)(m0 + r)*K + gc, ab + c*512);
      gload16(Bt + (size_t)(n0 + r)*K + gc, bb + c*512);
    }
  };

  STAGE(0); STAGE(1); STAGE(2);
  for (int t=0; t<NT; ++t){
    asm volatile("s_waitcnt vmcnt(8)" ::: "memory");   // tile t landed; t+1,t+2(,t+3) in flight
    __builtin_amdgcn_s_barrier();
    __builtin_amdgcn_sched_barrier(0);
    if (t+3 < NT) STAGE(t+3);
    const u16* ab = lds + (t & 3) * 16384;
    const u16* bb = ab + 8192;
    s16x8 af[8], bf[4];
    #pragma unroll
    for (int m=0;m<8;m++){
      int r = wm*128 + m*16 + fr;
      af[m] = *(const s16x8*)(ab + r*32 + kswz);
    }
    #pragma unroll
    for (int n=0;n<4;n++){
      int r = wn*64 + n*16 + fr;
      bf[n] = *(const s16x8*)(bb + r*32 + kswz);
    }
    __builtin_amdgcn_s_setprio(1);
    #pragma unroll
    for (int m=0;m<8;m++)
      #pragma unroll
      for (int n=0;n<4;n++)
        acc[m][n] = __builtin_amdgcn_mfma_f32_16x16x32_bf16(af[m], bf[n], acc[m][n], 0,0,0);
    __builtin_amdgcn_s_setprio(0);
  }

  #pragma unroll
  for (int n=0;n<4;n++){
    int ccol = n0 + wn*64 + n*16 + fr;
    #pragma unroll
    for (int m=0;m<8;m++){
      #pragma unroll
      for (int q=0;q<4;q++){
        int row = m0 + wm*128 + m*16 + kg*4 + q;
        float v = acc[m][n][q];
        size_t oidx = (size_t)row*N + ccol;
        if constexpr (EPI == EPI_STORE) Cout[oidx] = f2b(v);
        else if constexpr (EPI == EPI_STORE32) Cout32[oidx] = v;
        else if constexpr (EPI == EPI_SILU) Cout[oidx] = f2b(v / (1.f + __expf(-v)));
      }
    }
  }
}

// ---------------------------------------------------------------- generic 128x128 GEMM with fused epilogues
template<int EPI, bool ASYNC, bool SWZ>
__global__ __launch_bounds__(256) void gemm_k(
    const u16* __restrict__ A, int lda,
    const u16* __restrict__ Bt, int ldb,
    u16* __restrict__ Cout, float* __restrict__ Cout32, int ldc,
    int M, int N, int K,
    const float* __restrict__ e_x, const u16* __restrict__ e_dxp, const float* __restrict__ e_vec)
{
  constexpr int LDW = ASYNC ? 32 : 40;
  __shared__ u16 As[128][LDW];
  __shared__ u16 Bs[128][LDW];
  const int tid = threadIdx.x;
  const int lane = tid & 63, wid = tid >> 6;
  int bxx = blockIdx.x, byy = blockIdx.y;
  if constexpr (SWZ){
    int nwg = gridDim.x * gridDim.y;
    if ((nwg & 7) == 0){
      int bid = byy * gridDim.x + bxx;
      int cpx = nwg >> 3;
      int swz = (bid & 7) * cpx + (bid >> 3);
      bxx = swz % gridDim.x; byy = swz / gridDim.x;
    }
  }
  const int m0 = bxx * 128, n0 = byy * 128;
  const int wrow = (wid >> 1) * 64, wcol = (wid & 1) * 64;
  const int fr = lane & 15, kg = lane >> 4;
  const int r_c0 = tid >> 2, r_seg = tid & 3;
  const int r_c1 = r_c0 + 64;

  f32x4 acc[4][4];
  #pragma unroll
  for (int m=0;m<4;m++)
    #pragma unroll
    for (int n=0;n<4;n++) acc[m][n] = ZF4;

  for (int k0 = 0; k0 < K; k0 += 32) {
    __syncthreads();
    if constexpr (ASYNC) {
      const int w4 = __builtin_amdgcn_readfirstlane(wid);
      const int rr = lane >> 2, seg8 = (lane & 3) * 8;
      #pragma unroll
      for (int i=0;i<2;i++){
        int row = w4*32 + i*16 + rr;
        gload16(A  + (size_t)(m0 + row)*lda + k0 + seg8, &As[w4*32 + i*16][0]);
        gload16(Bt + (size_t)(n0 + row)*ldb + k0 + seg8, &Bs[w4*32 + i*16][0]);
      }
    } else {
      uint4 av0 = *(const uint4*)(A + (size_t)(m0 + r_c0)*lda + k0 + r_seg*8);
      uint4 av1 = *(const uint4*)(A + (size_t)(m0 + r_c1)*lda + k0 + r_seg*8);
      *(uint4*)(&As[r_c0][r_seg*8]) = av0;
      *(uint4*)(&As[r_c1][r_seg*8]) = av1;
      uint4 z = make_uint4(0,0,0,0);
      uint4 bv0 = (n0 + r_c0 < N) ? *(const uint4*)(Bt + (size_t)(n0 + r_c0)*ldb + k0 + r_seg*8) : z;
      uint4 bv1 = (n0 + r_c1 < N) ? *(const uint4*)(Bt + (size_t)(n0 + r_c1)*ldb + k0 + r_seg*8) : z;
      *(uint4*)(&Bs[r_c0][r_seg*8]) = bv0;
      *(uint4*)(&Bs[r_c1][r_seg*8]) = bv1;
    }
    __syncthreads();
    s16x8 a[4], bb[4];
    #pragma unroll
    for (int m=0;m<4;m++) a[m] = *(const s16x8*)(&As[wrow + m*16 + fr][kg*8]);
    #pragma unroll
    for (int n=0;n<4;n++) bb[n] = *(const s16x8*)(&Bs[wcol + n*16 + fr][kg*8]);
    #pragma unroll
    for (int m=0;m<4;m++)
      #pragma unroll
      for (int n=0;n<4;n++)
        acc[m][n] = __builtin_amdgcn_mfma_f32_16x16x32_bf16(a[m], bb[n], acc[m][n], 0,0,0);
  }
  #pragma unroll
  for (int n=0;n<4;n++){
    int ccol = n0 + wcol + n*16 + fr;
    if (ccol >= N) continue;
    #pragma unroll
    for (int m=0;m<4;m++){
      #pragma unroll
      for (int q=0;q<4;q++){
        int row = m0 + wrow + m*16 + kg*4 + q;
        float v = acc[m][n][q];
        size_t oidx = (size_t)row*ldc + ccol;
        if constexpr (EPI == EPI_STORE) Cout[oidx] = f2b(v);
        else if constexpr (EPI == EPI_STORE32) Cout32[oidx] = v;
        else if constexpr (EPI == EPI_TANH) Cout[oidx] = f2b(tanhf(v));
        else if constexpr (EPI == EPI_SILU) Cout[oidx] = f2b(v / (1.f + expf(-v)));
        else if constexpr (EPI == EPI_LERP){
          float xv = e_x[(size_t)row*2048 + ccol];
          float dx = b2f(e_dxp[(size_t)row*2048 + ccol]);
          Cout[oidx] = f2b(xv + dx * (e_vec[ccol] + v));
        }
        else if constexpr (EPI == EPI_ICLR) Cout[oidx] = f2b(1.f / (1.f + expf(-(e_vec[ccol] + v))));
      }
    }
  }
}

// ---------------------------------------------------------------- thin GEMM: 64x64 tile, BK=64
template<int EPI>
__global__ __launch_bounds__(256) void gemm_thin_k(
    const u16* __restrict__ A, int lda,
    const u16* __restrict__ Bt, int ldb,
    u16* __restrict__ Cout, int ldc, int N, int K)
{
  __shared__ u16 As[64][72];
  __shared__ u16 Bs[64][72];
  const int tid = threadIdx.x;
  const int lane = tid & 63, wid = tid >> 6;
  const int m0 = blockIdx.x * 64, n0 = blockIdx.y * 64;
  const int wrow = (wid >> 1) * 32, wcol = (wid & 1) * 32;
  const int fr = lane & 15, kg = lane >> 4;
  const int r_c = tid >> 2, r_seg = tid & 3;   // 4 threads/row, 16 elems each

  f32x4 acc[2][2];
  #pragma unroll
  for (int m=0;m<2;m++)
    #pragma unroll
    for (int n=0;n<2;n++) acc[m][n] = ZF4;

  for (int k0 = 0; k0 < K; k0 += 64) {
    __syncthreads();
    {
      const u16* as = A + (size_t)(m0 + r_c)*lda + k0 + r_seg*16;
      *(uint4*)(&As[r_c][r_seg*16])     = *(const uint4*)(as);
      *(uint4*)(&As[r_c][r_seg*16 + 8]) = *(const uint4*)(as + 8);
      uint4 z = make_uint4(0,0,0,0);
      bool ok = (n0 + r_c < N);
      const u16* bs = Bt + (size_t)(n0 + r_c)*ldb + k0 + r_seg*16;
      *(uint4*)(&Bs[r_c][r_seg*16])     = ok ? *(const uint4*)(bs) : z;
      *(uint4*)(&Bs[r_c][r_seg*16 + 8]) = ok ? *(const uint4*)(bs + 8) : z;
    }
    __syncthreads();
    #pragma unroll
    for (int ks=0; ks<2; ++ks){
      s16x8 a[2], bb[2];
      #pragma unroll
      for (int m=0;m<2;m++) a[m] = *(const s16x8*)(&As[wrow + m*16 + fr][ks*32 + kg*8]);
      #pragma unroll
      for (int n=0;n<2;n++) bb[n] = *(const s16x8*)(&Bs[wcol + n*16 + fr][ks*32 + kg*8]);
      #pragma unroll
      for (int m=0;m<2;m++)
        #pragma unroll
        for (int n=0;n<2;n++)
          acc[m][n] = __builtin_amdgcn_mfma_f32_16x16x32_bf16(a[m], bb[n], acc[m][n], 0,0,0);
    }
  }
  #pragma unroll
  for (int n=0;n<2;n++){
    int ccol = n0 + wcol + n*16 + fr;
    if (ccol >= N) continue;
    #pragma unroll
    for (int m=0;m<2;m++){
      #pragma unroll
      for (int q=0;q<4;q++){
        int row = m0 + wrow + m*16 + kg*4 + q;
        float v = acc[m][n][q];
        size_t oidx = (size_t)row*ldc + ccol;
        if constexpr (EPI == EPI_TANH) Cout[oidx] = f2b(tanhf(v));
        else Cout[oidx] = f2b(v);
      }
    }
  }
}

// ---------------------------------------------------------------- WKV phase 1: per chunk-head, 512 threads / 8 waves
// T14: prefetch r/k/ic/v into regs at entry; P2 reuses the same regs (no re-load).
__global__ __launch_bounds__(512, 1) void wkv1_k(
    const u16* __restrict__ r_g, const u16* __restrict__ kraw_g, const u16* __restrict__ v_g,
    const u16* __restrict__ ic_g,
    const u16* __restrict__ t2_g, const u16* __restrict__ dw2t_g, const float* __restrict__ td_g,
    const float* __restrict__ u_g, const float* __restrict__ kkk_g, const float* __restrict__ kka_g,
    u16* __restrict__ y1_g, u16* __restrict__ rw_g,
    u16* __restrict__ kvab_g, float* __restrict__ wsA_g)
{
  __shared__ __align__(16) char arena[162304];
  float* WL   = (float*)(arena);
  float* WC   = (float*)(arena + 34816);
  u16* Abuf   = (u16*)(arena);
  u16* kkcT   = (u16*)(arena + 34816);
  float* diag_l = (float*)(arena + 68096);  // 128
  float* offs_l = diag_l + 128;             // 64
  float* wsum_l = offs_l + 64;              // 64
  float* u_l    = wsum_l + 64;              // 64
  float* kkk_l  = u_l + 64;                 // 64
  float* kka_l  = kkk_l + 64;               // 64
  float* td_l   = kka_l + 64;               // 64 -> ends 70144
  u16* rd_l   = (u16*)(arena + 70144);
  u16* vT_l   = (u16*)(arena + 70144);
  u16* ki_l   = (u16*)(arena + 88576);
  u16* kkwT_l = (u16*)(arena + 88576);
  u16* kwT_l  = (u16*)(arena + 107008);
  u16* ka_l   = (u16*)(arena + 125440);
  u16* kkb_l  = (u16*)(arena + 143872);
  u16* kaT_l  = (u16*)(arena + 143872);

  const int tid = threadIdx.x, lane = tid & 63, wid = tid >> 6;
  const int cb = blockIdx.x;
  const int c = cb >> 6, b = (cb >> 5) & 1, h = cb & 31;
  const size_t base = ((size_t)(b*4096 + c*128)) * 2048 + h*64;
  const int fr = lane & 15, kg = lane >> 4;
  const int tq = tid >> 2, kh = (tid & 3) * 16;

  // T14 prefetch: issue early, consumed at P1/P2/P5a (hidden under P0+scan)
  const u16* g_rs = r_g    + base + (size_t)tq*2048 + kh;
  const u16* g_ks = kraw_g + base + (size_t)tq*2048 + kh;
  const u16* g_is = ic_g   + base + (size_t)tq*2048 + kh;
  const u16* g_vs = v_g    + base + (size_t)tq*2048 + kh;
  uint4 pfr0 = *(const uint4*)(g_rs), pfr1 = *(const uint4*)(g_rs + 8);
  uint4 pfk0 = *(const uint4*)(g_ks), pfk1 = *(const uint4*)(g_ks + 8);
  uint4 pfi0 = *(const uint4*)(g_is), pfi1 = *(const uint4*)(g_is + 8);
  uint4 pfv0 = *(const uint4*)(g_vs), pfv1 = *(const uint4*)(g_vs + 8);

  // P0a
  {
    const u16* t2s = t2_g + (size_t)(b*4096 + c*128 + tq)*64 + kh;
    *(uint4*)(&rd_l[tq*72 + kh])     = *(const uint4*)(t2s);
    *(uint4*)(&rd_l[tq*72 + kh + 8]) = *(const uint4*)(t2s + 8);
    int n = tid >> 3, sg2 = (tid & 7) * 8;
    *(uint4*)(&ki_l[n*72 + sg2]) = *(const uint4*)(dw2t_g + (size_t)(h*64 + n)*64 + sg2);
  }
  if (tid < 64){
    u_l[tid]   = u_g[h*64 + tid];
    kkk_l[tid] = kkk_g[h*64 + tid];
    kka_l[tid] = kka_g[h*64 + tid];
    td_l[tid]  = td_g[h*64 + tid];
  }
  __syncthreads();
  // P0b
  {
    f32x4 accW[4];
    #pragma unroll
    for (int n=0;n<4;n++) accW[n] = ZF4;
    #pragma unroll
    for (int ks=0; ks<2; ++ks){
      s16x8 af = *(const s16x8*)(&rd_l[(wid*16 + fr)*72 + ks*32 + kg*8]);
      #pragma unroll
      for (int n=0;n<4;n++){
        s16x8 bf = *(const s16x8*)(&ki_l[(n*16 + fr)*72 + ks*32 + kg*8]);
        accW[n] = __builtin_amdgcn_mfma_f32_16x16x32_bf16(af, bf, accW[n], 0,0,0);
      }
    }
    #pragma unroll
    for (int n=0;n<4;n++)
      #pragma unroll
      for (int q=0;q<4;q++){
        int t = wid*16 + kg*4 + q;
        int s = n*16 + fr;
        WL[t*65 + s] = -__expf(td_l[s] + accW[n][q]);
      }
  }
  __syncthreads();
  // scan
  for (int j=0;j<8;j++){
    int k = wid*8 + j;
    float v = WL[lane*65 + k];
    #pragma unroll
    for (int d=1; d<64; d<<=1){ float o = __shfl_up(v, d); if (lane >= d) v += o; }
    WC[lane*65 + k] = v;
    float carry = __shfl(v, 63);
    float v2 = WL[(64+lane)*65 + k];
    #pragma unroll
    for (int d=1; d<64; d<<=1){ float o = __shfl_up(v2, d); if (lane >= d) v2 += o; }
    v2 += carry;
    WC[(64+lane)*65 + k] = v2;
    float tot = __shfl(v2, 63);
    if (lane == 0){ offs_l[k] = carry; wsum_l[k] = tot; wsA_g[(size_t)cb*64 + k] = __expf(tot); }
  }
  __syncthreads();
  // P1 (uses prefetched r/k/ic)
  {
    float dpart = 0.f;
    #pragma unroll
    for (int j=0;j<2;j++){
      float rf[8], kf[8], icf[8], rdf[8], kif[8], rwf[8];
      up8(j ? pfr1 : pfr0, rf);
      up8(j ? pfk1 : pfk0, kf);
      up8(j ? pfi1 : pfi0, icf);
      #pragma unroll
      for (int e=0;e<8;e++){
        int k = kh + j*8 + e;
        float kadj = kf[e] * (1.f + (icf[e] - 1.f) * kka_l[k]);
        float wl = WL[tq*65+k], wc = WC[tq*65+k];
        float wcs = wc - wl;
        float off = offs_l[k], wsm = wsum_l[k];
        rdf[e] = rf[e] * __expf(clip30(wcs - off));
        kif[e] = kadj  * __expf(clip30(off - wc));
        rwf[e] = rf[e] * __expf(clip30(wcs));
        kwT_l[k*136 + tq] = f2b(kadj * __expf(clip30(wsm - wc)));
        dpart += rf[e] * u_l[k] * kadj;
      }
      *(uint4*)(&rd_l[tq*72 + kh + j*8]) = pk8(rdf);
      *(uint4*)(&ki_l[tq*72 + kh + j*8]) = pk8(kif);
      *(uint4*)(rw_g + base + (size_t)tq*2048 + kh + j*8) = pk8(rwf);
    }
    dpart += __shfl_xor(dpart, 1);
    dpart += __shfl_xor(dpart, 2);
    if ((tid & 3) == 0) diag_l[tq] = dpart;
  }
  __syncthreads();
  // P2 (reuses prefetched k/ic)
  {
    float kf[16], icf[16], kkraw[16];
    up8(pfk0, kf); up8(pfk1, kf + 8);
    up8(pfi0, icf); up8(pfi1, icf + 8);
    float ss = 0.f;
    #pragma unroll
    for (int e=0;e<16;e++){ kkraw[e] = kf[e]*kkk_l[kh+e]; ss += kkraw[e]*kkraw[e]; }
    ss += __shfl_xor(ss, 1);
    ss += __shfl_xor(ss, 2);
    float rn = 1.f / fmaxf(sqrtf(ss), 1e-12f);
    #pragma unroll
    for (int j=0;j<2;j++){
      float kkb8[8], ka8[8];
      #pragma unroll
      for (int e=0;e<8;e++){
        float kkv = kkraw[j*8+e]*rn;
        kkb8[e] = kkv; ka8[e] = kkv*icf[j*8+e];
      }
      *(uint4*)(&kkb_l[tq*72 + kh + j*8]) = pk8(kkb8);
      *(uint4*)(&ka_l [tq*72 + kh + j*8]) = pk8(ka8);
    }
  }
  __syncthreads();
  // P3
  f32x4 accA[8];
  #pragma unroll
  for (int n=0;n<8;n++) accA[n] = ZF4;
  #pragma unroll
  for (int ks=0; ks<2; ++ks){
    s16x8 af = *(const s16x8*)(&rd_l[(wid*16 + fr)*72 + ks*32 + kg*8]);
    #pragma unroll
    for (int n=0;n<8;n++){
      s16x8 bf = *(const s16x8*)(&ki_l[(n*16 + fr)*72 + ks*32 + kg*8]);
      accA[n] = __builtin_amdgcn_mfma_f32_16x16x32_bf16(af, bf, accA[n], 0,0,0);
    }
  }
  #pragma unroll
  for (int n=0;n<8;n++)
    #pragma unroll
    for (int q=0;q<4;q++){
      int t = wid*16 + kg*4 + q;
      int s = n*16 + fr;
      float v = accA[n][q];
      v = (t > s) ? v : ((t == s) ? diag_l[t] : 0.f);
      accA[n][q] = v;
      Abuf[t*136 + s] = f2b(v);
    }
  __syncthreads();
  // P4a
  {
    #pragma unroll
    for (int j=0;j<2;j++){
      float kkf[8];
      up8(*(const uint4*)(&kkb_l[tq*72 + kh + j*8]), kkf);
      #pragma unroll
      for (int e=0;e<8;e++){
        int k = kh + j*8 + e;
        kkwT_l[k*136 + tq] = f2b(-kkf[e] * __expf(clip30(wsum_l[k] - WC[tq*65+k])));
      }
    }
  }
  __syncthreads();
  // P4b
  {
    f32x4 accC[8];
    #pragma unroll
    for (int n=0;n<8;n++) accC[n] = ZF4;
    #pragma unroll
    for (int ks=0; ks<2; ++ks){
      s16x8 af = *(const s16x8*)(&ka_l[(wid*16 + fr)*72 + ks*32 + kg*8]);
      #pragma unroll
      for (int n=0;n<8;n++){
        s16x8 bf = *(const s16x8*)(&kkb_l[(n*16 + fr)*72 + ks*32 + kg*8]);
        accC[n] = __builtin_amdgcn_mfma_f32_16x16x32_bf16(af, bf, accC[n], 0,0,0);
      }
    }
    #pragma unroll
    for (int n=0;n<8;n++)
      #pragma unroll
      for (int q=0;q<4;q++){
        int t = wid*16 + kg*4 + q;
        int s = n*16 + fr;
        kkcT[s*136 + t] = f2b((t > s) ? accC[n][q] : 0.f);
      }
  }
  __syncthreads();
  // P5a (uses prefetched v)
  {
    u16 el[8];
    unp16(pfv0, el);
    #pragma unroll
    for (int e=0;e<8;e++) vT_l[(kh + e)*136 + tq] = el[e];
    unp16(pfv1, el);
    #pragma unroll
    for (int e=0;e<8;e++) vT_l[(kh + 8 + e)*136 + tq] = el[e];
    #pragma unroll
    for (int j=0;j<2;j++){
      u16 el2[8]; unp16(*(const uint4*)(&ka_l[tq*72 + kh + j*8]), el2);
      #pragma unroll
      for (int e=0;e<8;e++) kaT_l[(kh + j*8 + e)*136 + tq] = el2[e];
    }
  }
  // P5b
  {
    f32x4 accP[8];
    #pragma unroll
    for (int n=0;n<8;n++) accP[n] = ZF4;
    #pragma unroll
    for (int ks=0; ks<4; ++ks){
      s16x8 af = *(const s16x8*)(&Abuf[(wid*16 + fr)*136 + ks*32 + kg*8]);
      #pragma unroll
      for (int n=0;n<8;n++){
        s16x8 bf = *(const s16x8*)(&kkcT[(n*16 + fr)*136 + ks*32 + kg*8]);
        accP[n] = __builtin_amdgcn_mfma_f32_16x16x32_bf16(af, bf, accP[n], 0,0,0);
      }
    }
    #pragma unroll
    for (int n=0;n<8;n++)
      #pragma unroll
      for (int q=0;q<4;q++){
        int t = wid*16 + kg*4 + q;
        int s = n*16 + fr;
        float v = accA[n][q] - ((t >= s) ? accP[n][q] : 0.f);
        Abuf[t*136 + s] = f2b(v);
      }
  }
  __syncthreads();
  // P6
  {
    f32x4 accY[4];
    #pragma unroll
    for (int n=0;n<4;n++) accY[n] = ZF4;
    #pragma unroll
    for (int ks=0; ks<4; ++ks){
      s16x8 af = *(const s16x8*)(&Abuf[(wid*16 + fr)*136 + ks*32 + kg*8]);
      #pragma unroll
      for (int n=0;n<4;n++){
        s16x8 bf = *(const s16x8*)(&vT_l[(n*16 + fr)*136 + ks*32 + kg*8]);
        accY[n] = __builtin_amdgcn_mfma_f32_16x16x32_bf16(af, bf, accY[n], 0,0,0);
      }
    }
    #pragma unroll
    for (int n=0;n<4;n++)
      #pragma unroll
      for (int q=0;q<4;q++){
        int t = wid*16 + kg*4 + q;
        int vd = n*16 + fr;
        y1_g[base + (size_t)t*2048 + vd] = f2b(accY[n][q]);
      }
  }
  // P7
  {
    const int isAB = wid >> 2, mrow = (wid & 3) * 16;
    const u16* Amat = isAB ? kkwT_l : kwT_l;
    const u16* Bmat = isAB ? kaT_l  : vT_l;
    f32x4 acc2[4];
    #pragma unroll
    for (int n=0;n<4;n++) acc2[n] = ZF4;
    #pragma unroll
    for (int ks=0; ks<4; ++ks){
      s16x8 af = *(const s16x8*)(&Amat[(mrow + fr)*136 + ks*32 + kg*8]);
      #pragma unroll
      for (int n=0;n<4;n++){
        s16x8 bf = *(const s16x8*)(&Bmat[(n*16 + fr)*136 + ks*32 + kg*8]);
        acc2[n] = __builtin_amdgcn_mfma_f32_16x16x32_bf16(af, bf, acc2[n], 0,0,0);
      }
    }
    u16* kvp = kvab_g + (size_t)cb*8192 + isAB*4096;
    #pragma unroll
    for (int n=0;n<4;n++)
      #pragma unroll
      for (int q=0;q<4;q++){
        int kd = mrow + kg*4 + q, vd = n*16 + fr;
        if (isAB) kvp[vd*64 + kd] = f2b(acc2[n][q]);
        else      kvp[kd*64 + vd] = f2b(acc2[n][q]);
      }
  }
}

// ---------------------------------------------------------------- WKV phase 2: MFMA state scan per (b,h), reg prefetch
__global__ __launch_bounds__(256) void wkv2_k(
   const float* __restrict__ state_in, u16* __restrict__ kvab_g,
   const float* __restrict__ wsA_g, float* __restrict__ out_state)
{
  __shared__ u16 Sb[64][72];
  __shared__ u16 abT[64][72];
  const int tid = threadIdx.x, lane = tid & 63, wid = tid >> 6;
  const int bh = blockIdx.x, b = bh >> 5, h = bh & 31;
  const int fr = lane & 15, kg = lane >> 4;
  const int r0 = wid*16 + kg*4;
  const int vrow = tid >> 2, jc = (tid & 3) * 16;

  f32x4 S[4];
  #pragma unroll
  for (int n=0;n<4;n++)
    #pragma unroll
    for (int q=0;q<4;q++)
      S[n][q] = state_in[(size_t)bh*4096 + (size_t)(r0+q)*64 + n*16+fr];

  uint4 pf_ab0, pf_ab1; u16 pf_kv[16]; float pf_ws[4];
  {
    int cb = b*32 + h;
    const u16* kvp = kvab_g + (size_t)cb*8192;
    pf_ab0 = *(const uint4*)(kvp + 4096 + vrow*64 + jc);
    pf_ab1 = *(const uint4*)(kvp + 4096 + vrow*64 + jc + 8);
    #pragma unroll
    for (int n=0;n<4;n++)
      #pragma unroll
      for (int q=0;q<4;q++)
        pf_kv[n*4+q] = kvp[(r0+q)*64 + n*16+fr];
    #pragma unroll
    for (int n=0;n<4;n++) pf_ws[n] = wsA_g[(size_t)cb*64 + n*16+fr];
  }

  for (int c=0;c<32;c++){
    int cb = (c*2+b)*32 + h;
    *(uint4*)(&abT[vrow][jc])   = pf_ab0;
    *(uint4*)(&abT[vrow][jc+8]) = pf_ab1;
    #pragma unroll
    for (int n=0;n<4;n++)
      #pragma unroll
      for (int q=0;q<4;q++)
        Sb[r0+q][n*16+fr] = f2b(S[n][q]);
    float kvf[16], wsf[4];
    #pragma unroll
    for (int i=0;i<16;i++) kvf[i] = b2f(pf_kv[i]);
    #pragma unroll
    for (int n=0;n<4;n++) wsf[n] = pf_ws[n];
    float* sip = (float*)(kvab_g + (size_t)cb*8192);
    #pragma unroll
    for (int n=0;n<4;n++)
      #pragma unroll
      for (int q=0;q<4;q++)
        sip[(r0+q)*64 + n*16+fr] = S[n][q];
    __syncthreads();
    if (c < 31){
      int cb2 = ((c+1)*2+b)*32 + h;
      const u16* kvp2 = kvab_g + (size_t)cb2*8192;
      pf_ab0 = *(const uint4*)(kvp2 + 4096 + vrow*64 + jc);
      pf_ab1 = *(const uint4*)(kvp2 + 4096 + vrow*64 + jc + 8);
      #pragma unroll
      for (int n=0;n<4;n++)
        #pragma unroll
        for (int q=0;q<4;q++)
          pf_kv[n*4+q] = kvp2[(r0+q)*64 + n*16+fr];
      #pragma unroll
      for (int n=0;n<4;n++) pf_ws[n] = wsA_g[(size_t)cb2*64 + n*16+fr];
    }
    f32x4 acc[4];
    #pragma unroll
    for (int n=0;n<4;n++) acc[n] = ZF4;
    #pragma unroll
    for (int ks=0; ks<2; ++ks){
      s16x8 a = *(const s16x8*)(&Sb[wid*16 + fr][ks*32 + kg*8]);
      #pragma unroll
      for (int n=0;n<4;n++){
        s16x8 bb = *(const s16x8*)(&abT[n*16 + fr][ks*32 + kg*8]);
        acc[n] = __builtin_amdgcn_mfma_f32_16x16x32_bf16(a, bb, acc[n], 0,0,0);
      }
    }
    #pragma unroll
    for (int n=0;n<4;n++)
      #pragma unroll
      for (int q=0;q<4;q++)
        S[n][q] = S[n][q]*wsf[n] + acc[n][q] + kvf[n*4+q];
    __syncthreads();
  }
  #pragma unroll
  for (int n=0;n<4;n++)
    #pragma unroll
    for (int q=0;q<4;q++)
      out_state[(size_t)bh*4096 + (size_t)(r0+q)*64 + n*16+fr] = S[n][q];
}

// ---------------------------------------------------------------- WKV phase 3: y = y1 + rw@S_in, GroupNorm, *g
__global__ __launch_bounds__(256) void wkv3_k(
   const u16* __restrict__ y1_g, const u16* __restrict__ rw_g,
   const u16* __restrict__ kvab_g,
   const u16* __restrict__ g_g, const float* __restrict__ gnw, const float* __restrict__ gnb,
   u16* __restrict__ yf_g)
{
  __shared__ float S_l[64][65];
  __shared__ u16 rw_l[128][72];
  int tid = threadIdx.x;
  int cb = blockIdx.x; int c = cb>>6, b = (cb>>5)&1, h = cb&31;
  size_t base = ((size_t)(b*4096 + c*128))*2048 + h*64;
  const float* sip = (const float*)(kvab_g + (size_t)cb*8192);
  #pragma unroll
  for (int j=0;j<16;j++){ int flat = tid*16+j; S_l[flat>>6][flat&63] = sip[flat]; }
  {
    int t = tid>>1, kh = (tid&1)*32;
    const u16* rs = rw_g + base + (size_t)t*2048 + kh;
    #pragma unroll
    for (int j=0;j<4;j++) *(uint4*)(&rw_l[t][kh+j*8]) = *(const uint4*)(rs + j*8);
  }
  __syncthreads();
  int t = tid>>1, vh = (tid&1)*32;
  float acc[32];
  #pragma unroll
  for (int j=0;j<32;j++) acc[j] = 0.f;
  for (int kf2=0; kf2<64; kf2++){
    float rv = b2f(rw_l[t][kf2]);
    #pragma unroll
    for (int j=0;j<32;j++) acc[j] += rv * S_l[kf2][vh+j];
  }
  float sum=0.f, sq=0.f;
  float yv[32];
  #pragma unroll
  for (int j=0;j<32;j++){
    yv[j] = acc[j] + b2f(y1_g[base + (size_t)t*2048 + vh + j]);
    sum += yv[j]; sq += yv[j]*yv[j];
  }
  sum += __shfl_xor(sum, 1); sq += __shfl_xor(sq, 1);
  float mean = sum * (1.f/64.f);
  float var = sq * (1.f/64.f) - mean*mean;
  float rstd = rsqrtf(fmaxf(var, 0.f) + 6.4e-4f);
  size_t bt = (size_t)(b*4096 + c*128 + t);
  #pragma unroll
  for (int j=0;j<32;j++){
    int ch = h*64 + vh + j;
    float val = (yv[j]-mean)*rstd * gnw[ch] + gnb[ch];
    val *= b2f(g_g[bt*2048 + ch]);
    yf_g[base + (size_t)t*2048 + vh + j] = f2b(val);
  }
}

// ---------------------------------------------------------------- host
#define O_WTR   0ull
#define O_WTK   8388608ull
#define O_WTV   16777216ull
#define O_WTG   25165824ull
#define O_WTO   33554432ull
#define O_W1T   41943040ull
#define O_W2T   42729472ull
#define O_DW1T  43515904ull
#define O_DW2T  43778048ull
#define O_A1T   44040192ull
#define O_A2T   44433408ull
#define O_XXX   44826624ull
#define O_T2    47972352ull
#define O_T3    49020928ull
#define O_WSA   50593792ull
#define O_XMX   51118080ull       /* xmx -> xw -> r */
#define O_A     84672512ull       /* xk -> v */
#define O_I     118226944ull      /* dxprev -> xa -> iclr */
#define O_R     151781376ull      /* xv -> g */
#define O_K     185335808ull      /* xr -> k -> y1 -> yf */
#define O_V     218890240ull      /* xg -> kvab/S_in */
#define WS_NEEDED 252444672ull

extern "C" void kernel_launch(void* const* d_in, const int* in_sizes, int n_in,
                              void* d_out, int out_size, void* d_ws, size_t ws_size,
                              hipStream_t stream)
{
  (void)in_sizes; (void)n_in; (void)out_size;
  if (ws_size < WS_NEEDED) return;
  const float* x     = (const float*)d_in[0];
  const float* shift = (const float*)d_in[1];
  const float* st_in = (const float*)d_in[2];
  const float* maax  = (const float*)d_in[3];
  const float* maas[6] = {(const float*)d_in[4],(const float*)d_in[5],(const float*)d_in[6],
                          (const float*)d_in[7],(const float*)d_in[8],(const float*)d_in[9]};
  const float* w1    = (const float*)d_in[10];
  const float* w2    = (const float*)d_in[11];
  const float* td    = (const float*)d_in[12];
  const float* dw1   = (const float*)d_in[13];
  const float* dw2   = (const float*)d_in[14];
  const float* faaaa = (const float*)d_in[15];
  const float* a0v   = (const float*)d_in[16];
  const float* a1w   = (const float*)d_in[17];
  const float* a2w   = (const float*)d_in[18];
  const float* kkk   = (const float*)d_in[19];
  const float* kka   = (const float*)d_in[20];
  const float* Wr    = (const float*)d_in[21];
  const float* Wk    = (const float*)d_in[22];
  const float* Wv    = (const float*)d_in[23];
  const float* Wg    = (const float*)d_in[24];
  const float* Wo    = (const float*)d_in[25];
  const float* gnw   = (const float*)d_in[26];
  const float* gnb   = (const float*)d_in[27];
  float* out = (float*)d_out;
  char* ws = (char*)d_ws;
  #define WSP(o) ((u16*)(ws + (o)))

  u16 *wtR=WSP(O_WTR), *wtK=WSP(O_WTK), *wtV=WSP(O_WTV), *wtG=WSP(O_WTG), *wtO=WSP(O_WTO);
  u16 *w1t=WSP(O_W1T), *w2t=WSP(O_W2T), *dw1t=WSP(O_DW1T), *dw2t=WSP(O_DW2T), *a1t=WSP(O_A1T), *a2t=WSP(O_A2T);
  u16 *xxx=WSP(O_XXX), *t2b=WSP(O_T2), *t3b=WSP(O_T3);
  u16 *sXMX=WSP(O_XMX), *sA=WSP(O_A), *sI=WSP(O_I), *sR=WSP(O_R), *sK=WSP(O_K), *sV=WSP(O_V);
  u16 *rw = WSP(O_WTR);
  float* wsA = (float*)(ws + O_WSA);
  float* out_xlast = out + 16777216;
  float* out_state = out + 16781312;

  dim3 tb(32,8);
  transpose_k<<<dim3(64,64), tb, 0, stream>>>(Wr, wtR, 2048, 2048);
  transpose_k<<<dim3(64,64), tb, 0, stream>>>(Wk, wtK, 2048, 2048);
  transpose_k<<<dim3(64,64), tb, 0, stream>>>(Wv, wtV, 2048, 2048);
  transpose_k<<<dim3(64,64), tb, 0, stream>>>(Wg, wtG, 2048, 2048);
  transpose_k<<<dim3(64,64), tb, 0, stream>>>(Wo, wtO, 2048, 2048);
  transpose_k<<<dim3(6,64),  tb, 0, stream>>>(w1, w1t, 2048, 192);
  transpose_k<<<dim3(64,6),  tb, 0, stream>>>(w2, w2t, 192, 2048);
  transpose_k<<<dim3(2,64),  tb, 0, stream>>>(dw1, dw1t, 2048, 64);
  transpose_k<<<dim3(64,2),  tb, 0, stream>>>(dw2, dw2t, 64, 2048);
  transpose_k<<<dim3(3,64),  tb, 0, stream>>>(a1w, a1t, 2048, 96);
  transpose_k<<<dim3(64,3),  tb, 0, stream>>>(a2w, a2t, 96, 2048);

  prep_k<<<8192, 256, 0, stream>>>(x, shift, maax, sXMX /*xmx*/, sI /*dxp*/, out_xlast);

  // xxx = tanh(xmx @ w1)
  gemm_thin_k<EPI_TANH><<<dim3(128,3), 256, 0, stream>>>(sXMX, 2048, w1t, 2048, xxx, 192, 192, 2048);
  // all 6 token-shift lerps fused
  lerp6_k<<<dim3(64,16), 256, 0, stream>>>(xxx, w2t, x, sI /*dxp*/,
      maas[0], maas[1], maas[2], maas[3], maas[4], maas[5],
      sXMX /*xw*/, sA /*xk*/, sR /*xv*/, sK /*xr*/, sV /*xg*/, sI /*xa*/);
  // t2 = tanh(xw @ dw1) ; t3 = xa @ a1 ; iclr = sigmoid(a0 + t3@a2) -> I
  gemm_thin_k<EPI_TANH><<<dim3(128,1), 256, 0, stream>>>(sXMX, 2048, dw1t, 2048, t2b, 64, 64, 2048);
  gemm_thin_k<EPI_STORE><<<dim3(128,2), 256, 0, stream>>>(sI, 2048, a1t, 2048, t3b, 96, 96, 2048);
  gemm_k<EPI_ICLR,true,true><<<dim3(64,16), 256, 0, stream>>>(t3b, 96, a2t, 96, sI, nullptr, 2048, 8192, 2048, 96, nullptr, nullptr, a0v);
  // big projections
  gemm256_k<EPI_STORE><<<dim3(32,8), 512, 0, stream>>>(sK, wtR, sXMX, nullptr, 8192, 2048, 2048);
  gemm256_k<EPI_STORE><<<dim3(32,8), 512, 0, stream>>>(sA, wtK, sK, nullptr, 8192, 2048, 2048);
  gemm256_k<EPI_STORE><<<dim3(32,8), 512, 0, stream>>>(sR, wtV, sA, nullptr, 8192, 2048, 2048);
  gemm256_k<EPI_SILU><<<dim3(32,8), 512, 0, stream>>>(sV, wtG, sR, nullptr, 8192, 2048, 2048);
  // wkv
  wkv1_k<<<2048, 512, 0, stream>>>(sXMX, sK, sA, sI, t2b, dw2t, td, faaaa, kkk, kka,
                                   sK, rw, sV, wsA);
  wkv2_k<<<64, 256, 0, stream>>>(st_in, sV, wsA, out_state);
  wkv3_k<<<2048, 256, 0, stream>>>(sK, rw, sV, sR /*g*/, gnw, gnb, sK /*yf in place*/);
  // out = yf @ W_o  (f32 store)
  gemm256_k<EPI_STORE32><<<dim3(32,8), 512, 0, stream>>>(sK, wtO, nullptr, out, 8192, 2048, 2048);
}

// Round 11
// 970.144 us; speedup vs baseline: 2.1590x; 1.0257x over previous
//
#include <hip/hip_runtime.h>

// RWKV7-delta time-mix. f32 in/out, bf16 intermediates + MFMA bf16 16x16x32.
// B=2 T=4096 C=2048 H=32 K=64 CHUNK=128 NC=32.

typedef unsigned short u16;
typedef unsigned int   u32;
typedef __attribute__((ext_vector_type(8))) short s16x8;
typedef __attribute__((ext_vector_type(4))) float f32x4;

#define DEV __device__ __forceinline__

DEV float b2f(u16 v){ return __uint_as_float(((u32)v) << 16); }
DEV u16 f2b(float f){ u32 u = __float_as_uint(f); return (u16)((u + 0x7fffu + ((u >> 16) & 1u)) >> 16); }
DEV float clip30(float x){ return fminf(fmaxf(x, -30.f), 30.f); }
DEV void up8(uint4 v, float* f){
  f[0]=b2f((u16)(v.x&0xffffu)); f[1]=b2f((u16)(v.x>>16));
  f[2]=b2f((u16)(v.y&0xffffu)); f[3]=b2f((u16)(v.y>>16));
  f[4]=b2f((u16)(v.z&0xffffu)); f[5]=b2f((u16)(v.z>>16));
  f[6]=b2f((u16)(v.w&0xffffu)); f[7]=b2f((u16)(v.w>>16));
}
DEV uint4 pk8(const float* f){
  uint4 v;
  v.x = (u32)f2b(f[0]) | ((u32)f2b(f[1])<<16);
  v.y = (u32)f2b(f[2]) | ((u32)f2b(f[3])<<16);
  v.z = (u32)f2b(f[4]) | ((u32)f2b(f[5])<<16);
  v.w = (u32)f2b(f[6]) | ((u32)f2b(f[7])<<16);
  return v;
}
DEV void unp16(uint4 v, u16* o){
  o[0]=(u16)(v.x&0xffffu); o[1]=(u16)(v.x>>16);
  o[2]=(u16)(v.y&0xffffu); o[3]=(u16)(v.y>>16);
  o[4]=(u16)(v.z&0xffffu); o[5]=(u16)(v.z>>16);
  o[6]=(u16)(v.w&0xffffu); o[7]=(u16)(v.w>>16);
}
DEV void gload16(const u16* g, u16* l){
  __builtin_amdgcn_global_load_lds(
      (const __attribute__((address_space(1))) u32*)g,
      (__attribute__((address_space(3))) u32*)l, 16, 0, 0);
}
#define ZF4 ((f32x4){0.f,0.f,0.f,0.f})

// ---------------------------------------------------------------- transpose f32 -> bf16
__global__ void transpose_k(const float* __restrict__ in, u16* __restrict__ out, int R, int C){
  __shared__ float tile[32][33];
  int c0 = blockIdx.x*32, r0 = blockIdx.y*32;
  int tx = threadIdx.x, ty = threadIdx.y; // (32,8)
  #pragma unroll
  for (int j=0;j<4;j++) tile[ty + j*8][tx] = in[(size_t)(r0 + ty + j*8)*C + c0 + tx];
  __syncthreads();
  #pragma unroll
  for (int j=0;j<4;j++) out[(size_t)(c0 + ty + j*8)*R + r0 + tx] = f2b(tile[tx][ty + j*8]);
}

// batched: 5 square 2048x2048 weight transposes in one launch
__global__ void transpose5_k(const float* __restrict__ w0, const float* __restrict__ w1,
    const float* __restrict__ w2, const float* __restrict__ w3, const float* __restrict__ w4,
    u16* __restrict__ o0, u16* __restrict__ o1, u16* __restrict__ o2,
    u16* __restrict__ o3, u16* __restrict__ o4){
  __shared__ float tile[32][33];
  const float* ins[5] = {w0,w1,w2,w3,w4};
  u16* outs[5] = {o0,o1,o2,o3,o4};
  const float* in = ins[blockIdx.z];
  u16* out = outs[blockIdx.z];
  int c0 = blockIdx.x*32, r0 = blockIdx.y*32;
  int tx = threadIdx.x, ty = threadIdx.y; // (32,8)
  #pragma unroll
  for (int j=0;j<4;j++) tile[ty + j*8][tx] = in[(size_t)(r0 + ty + j*8)*2048 + c0 + tx];
  __syncthreads();
  #pragma unroll
  for (int j=0;j<4;j++) out[(size_t)(c0 + ty + j*8)*2048 + r0 + tx] = f2b(tile[tx][ty + j*8]);
}

// ---------------------------------------------------------------- prep: xmx bf16, dxprev bf16, x_last f32
__global__ __launch_bounds__(256) void prep_k(const float* __restrict__ x, const float* __restrict__ shift,
    const float* __restrict__ maax, u16* __restrict__ xmx, u16* __restrict__ dxp, float* __restrict__ out_xlast){
  int e8 = (blockIdx.x*256 + threadIdx.x) * 8;
  int row = e8 >> 11, col = e8 & 2047;
  int t = row & 4095, b = row >> 12;
  const float* xp = x + (size_t)row*2048 + col;
  const float* pp = t ? (x + (size_t)(row-1)*2048 + col) : (shift + (size_t)b*2048 + col);
  float xf[8], pf[8], mf[8], of[8], df[8];
  *(float4*)(xf)   = *(const float4*)(xp);
  *(float4*)(xf+4) = *(const float4*)(xp+4);
  *(float4*)(pf)   = *(const float4*)(pp);
  *(float4*)(pf+4) = *(const float4*)(pp+4);
  *(float4*)(mf)   = *(const float4*)(maax + col);
  *(float4*)(mf+4) = *(const float4*)(maax + col + 4);
  #pragma unroll
  for (int j=0;j<8;j++){ df[j] = pf[j]-xf[j]; of[j] = xf[j] + df[j]*mf[j]; }
  *(uint4*)(xmx + (size_t)row*2048 + col) = pk8(of);
  *(uint4*)(dxp + (size_t)row*2048 + col) = pk8(df);
  if (t == 4095){
    *(float4*)(out_xlast + (size_t)b*2048 + col)     = *(const float4*)(xf);
    *(float4*)(out_xlast + (size_t)b*2048 + col + 4) = *(const float4*)(xf+4);
  }
}

// ---------------------------------------------------------------- epilogue ids
enum { EPI_STORE=0, EPI_TANH=1, EPI_SILU=2, EPI_LERP=3, EPI_ICLR=5, EPI_STORE32=6 };

// ---------------------------------------------------------------- fused 6-way token-shift lerp
__global__ __launch_bounds__(256) void lerp6_k(
    const u16* __restrict__ xxx, const u16* __restrict__ w2t,
    const float* __restrict__ x, const u16* __restrict__ dxp,
    const float* __restrict__ ma0, const float* __restrict__ ma1, const float* __restrict__ ma2,
    const float* __restrict__ ma3, const float* __restrict__ ma4, const float* __restrict__ ma5,
    u16* __restrict__ o0, u16* __restrict__ o1, u16* __restrict__ o2,
    u16* __restrict__ o3, u16* __restrict__ o4, u16* __restrict__ o5)
{
  __shared__ u16 As[128][40];
  __shared__ u16 Bs[128][40];
  const int tid = threadIdx.x, lane = tid & 63, wid = tid >> 6;
  const int m0 = blockIdx.x*128, n0 = blockIdx.y*128;
  const int wrow = (wid>>1)*64, wcol = (wid&1)*64;
  const int fr = lane&15, kg = lane>>4;
  const int r_c0 = tid>>2, r_seg = tid&3, r_c1 = r_c0+64;
  const float* maap[6] = {ma0,ma1,ma2,ma3,ma4,ma5};
  u16* outs[6] = {o0,o1,o2,o3,o4,o5};

  float xv_[4][4][4], dxv_[4][4][4];
  #pragma unroll
  for (int m=0;m<4;m++)
    #pragma unroll
    for (int n=0;n<4;n++)
      #pragma unroll
      for (int q=0;q<4;q++){
        int row = m0 + wrow + m*16 + kg*4 + q;
        int col = n0 + wcol + n*16 + fr;
        xv_[m][n][q]  = x[(size_t)row*2048 + col];
        dxv_[m][n][q] = b2f(dxp[(size_t)row*2048 + col]);
      }

  #pragma unroll
  for (int s=0;s<6;s++){
    __syncthreads();
    *(uint4*)(&As[r_c0][r_seg*8]) = *(const uint4*)(xxx + (size_t)(m0+r_c0)*192 + s*32 + r_seg*8);
    *(uint4*)(&As[r_c1][r_seg*8]) = *(const uint4*)(xxx + (size_t)(m0+r_c1)*192 + s*32 + r_seg*8);
    *(uint4*)(&Bs[r_c0][r_seg*8]) = *(const uint4*)(w2t + (size_t)(n0+r_c0)*192 + s*32 + r_seg*8);
    *(uint4*)(&Bs[r_c1][r_seg*8]) = *(const uint4*)(w2t + (size_t)(n0+r_c1)*192 + s*32 + r_seg*8);
    __syncthreads();
    s16x8 a[4], bb[4];
    #pragma unroll
    for (int m=0;m<4;m++) a[m] = *(const s16x8*)(&As[wrow + m*16 + fr][kg*8]);
    #pragma unroll
    for (int n=0;n<4;n++) bb[n] = *(const s16x8*)(&Bs[wcol + n*16 + fr][kg*8]);
    f32x4 acc[4][4];
    #pragma unroll
    for (int m=0;m<4;m++)
      #pragma unroll
      for (int n=0;n<4;n++) acc[m][n] = ZF4;
    #pragma unroll
    for (int m=0;m<4;m++)
      #pragma unroll
      for (int n=0;n<4;n++)
        acc[m][n] = __builtin_amdgcn_mfma_f32_16x16x32_bf16(a[m], bb[n], acc[m][n], 0,0,0);
    #pragma unroll
    for (int n=0;n<4;n++){
      int col = n0 + wcol + n*16 + fr;
      float mv = maap[s][col];
      #pragma unroll
      for (int m=0;m<4;m++)
        #pragma unroll
        for (int q=0;q<4;q++){
          int row = m0 + wrow + m*16 + kg*4 + q;
          outs[s][(size_t)row*2048 + col] = f2b(xv_[m][n][q] + dxv_[m][n][q]*(mv + acc[m][n][q]));
        }
    }
  }
}

// ---------------------------------------------------------------- 256x256 BK=32 counted-vmcnt GEMM (big GEMMs)
template<int EPI>
__global__ __launch_bounds__(512, 2) void gemm256_k(
    const u16* __restrict__ A, const u16* __restrict__ Bt,
    u16* __restrict__ Cout, float* __restrict__ Cout32,
    int M, int N, int K)
{
  __shared__ __align__(16) u16 lds[4*16384];   // 4 bufs x (A[256][32] + B[256][32]) = 128 KiB
  const int tid = threadIdx.x, lane = tid & 63;
  int bxx = blockIdx.x, byy = blockIdx.y;
  if (gridDim.x == 32 && gridDim.y == 8){
    int bid = byy * 32 + bxx;
    int xcd = bid & 7, idx = bid >> 3;
    bxx = xcd*4 + (idx & 3);
    byy = idx >> 2;
  } else {
    int nwg = gridDim.x * gridDim.y;
    if ((nwg & 7) == 0){
      int bid = byy * gridDim.x + bxx;
      int cpx = nwg >> 3;
      int swz = (bid & 7) * cpx + (bid >> 3);
      bxx = swz % gridDim.x; byy = swz / gridDim.x;
    }
  }
  const int m0 = bxx * 256, n0 = byy * 256;
  const int wid = tid >> 6;
  const int wm = wid >> 2, wn = wid & 3;
  const int fr = lane & 15, kg = lane >> 4;
  const int NT = K >> 5;
  const int chunk0 = __builtin_amdgcn_readfirstlane(wid) * 2;
  const int lr = lane >> 2, lsl = lane & 3;
  const int gswz = (lsl ^ ((lr >> 1) & 3)) << 3;   // pre-swizzled k-offset (elements)
  const int kswz = (kg ^ ((fr >> 1) & 3)) << 3;    // swizzled read k-offset (elements)

  f32x4 acc[8][4];
  #pragma unroll
  for (int m=0;m<8;m++)
    #pragma unroll
    for (int n=0;n<4;n++) acc[m][n] = ZF4;

  auto STAGE = [&](int t){
    u16* ab = lds + (t & 3) * 16384;
    u16* bb = ab + 8192;
    int gc = (t << 5) + gswz;
    #pragma unroll
    for (int i=0;i<2;i++){
      int c = chunk0 + i;
      int r = c*16 + lr;
      gload16(A  + (size_t)(m0 + r)*K + gc, ab + c*512);
      gload16(Bt + (size_t)(n0 + r)*K + gc, bb + c*512);
    }
  };

  STAGE(0); STAGE(1); STAGE(2);
  for (int t=0; t<NT; ++t){
    asm volatile("s_waitcnt vmcnt(8)" ::: "memory");
    __builtin_amdgcn_s_barrier();
    __builtin_amdgcn_sched_barrier(0);
    if (t+3 < NT) STAGE(t+3);
    const u16* ab = lds + (t & 3) * 16384;
    const u16* bb = ab + 8192;
    s16x8 af[8], bf[4];
    #pragma unroll
    for (int m=0;m<8;m++){
      int r = wm*128 + m*16 + fr;
      af[m] = *(const s16x8*)(ab + r*32 + kswz);
    }
    #pragma unroll
    for (int n=0;n<4;n++){
      int r = wn*64 + n*16 + fr;
      bf[n] = *(const s16x8*)(bb + r*32 + kswz);
    }
    __builtin_amdgcn_s_setprio(1);
    #pragma unroll
    for (int m=0;m<8;m++)
      #pragma unroll
      for (int n=0;n<4;n++)
        acc[m][n] = __builtin_amdgcn_mfma_f32_16x16x32_bf16(af[m], bf[n], acc[m][n], 0,0,0);
    __builtin_amdgcn_s_setprio(0);
  }

  #pragma unroll
  for (int n=0;n<4;n++){
    int ccol = n0 + wn*64 + n*16 + fr;
    #pragma unroll
    for (int m=0;m<8;m++){
      #pragma unroll
      for (int q=0;q<4;q++){
        int row = m0 + wm*128 + m*16 + kg*4 + q;
        float v = acc[m][n][q];
        size_t oidx = (size_t)row*N + ccol;
        if constexpr (EPI == EPI_STORE) Cout[oidx] = f2b(v);
        else if constexpr (EPI == EPI_STORE32) Cout32[oidx] = v;
        else if constexpr (EPI == EPI_SILU) Cout[oidx] = f2b(v / (1.f + __expf(-v)));
      }
    }
  }
}

// ---------------------------------------------------------------- generic 128x128 GEMM with fused epilogues
template<int EPI, bool ASYNC, bool SWZ>
__global__ __launch_bounds__(256) void gemm_k(
    const u16* __restrict__ A, int lda,
    const u16* __restrict__ Bt, int ldb,
    u16* __restrict__ Cout, float* __restrict__ Cout32, int ldc,
    int M, int N, int K,
    const float* __restrict__ e_x, const u16* __restrict__ e_dxp, const float* __restrict__ e_vec)
{
  constexpr int LDW = ASYNC ? 32 : 40;
  __shared__ u16 As[128][LDW];
  __shared__ u16 Bs[128][LDW];
  const int tid = threadIdx.x;
  const int lane = tid & 63, wid = tid >> 6;
  int bxx = blockIdx.x, byy = blockIdx.y;
  if constexpr (SWZ){
    int nwg = gridDim.x * gridDim.y;
    if ((nwg & 7) == 0){
      int bid = byy * gridDim.x + bxx;
      int cpx = nwg >> 3;
      int swz = (bid & 7) * cpx + (bid >> 3);
      bxx = swz % gridDim.x; byy = swz / gridDim.x;
    }
  }
  const int m0 = bxx * 128, n0 = byy * 128;
  const int wrow = (wid >> 1) * 64, wcol = (wid & 1) * 64;
  const int fr = lane & 15, kg = lane >> 4;
  const int r_c0 = tid >> 2, r_seg = tid & 3;
  const int r_c1 = r_c0 + 64;

  f32x4 acc[4][4];
  #pragma unroll
  for (int m=0;m<4;m++)
    #pragma unroll
    for (int n=0;n<4;n++) acc[m][n] = ZF4;

  for (int k0 = 0; k0 < K; k0 += 32) {
    __syncthreads();
    if constexpr (ASYNC) {
      const int w4 = __builtin_amdgcn_readfirstlane(wid);
      const int rr = lane >> 2, seg8 = (lane & 3) * 8;
      #pragma unroll
      for (int i=0;i<2;i++){
        int row = w4*32 + i*16 + rr;
        gload16(A  + (size_t)(m0 + row)*lda + k0 + seg8, &As[w4*32 + i*16][0]);
        gload16(Bt + (size_t)(n0 + row)*ldb + k0 + seg8, &Bs[w4*32 + i*16][0]);
      }
    } else {
      uint4 av0 = *(const uint4*)(A + (size_t)(m0 + r_c0)*lda + k0 + r_seg*8);
      uint4 av1 = *(const uint4*)(A + (size_t)(m0 + r_c1)*lda + k0 + r_seg*8);
      *(uint4*)(&As[r_c0][r_seg*8]) = av0;
      *(uint4*)(&As[r_c1][r_seg*8]) = av1;
      uint4 z = make_uint4(0,0,0,0);
      uint4 bv0 = (n0 + r_c0 < N) ? *(const uint4*)(Bt + (size_t)(n0 + r_c0)*ldb + k0 + r_seg*8) : z;
      uint4 bv1 = (n0 + r_c1 < N) ? *(const uint4*)(Bt + (size_t)(n0 + r_c1)*ldb + k0 + r_seg*8) : z;
      *(uint4*)(&Bs[r_c0][r_seg*8]) = bv0;
      *(uint4*)(&Bs[r_c1][r_seg*8]) = bv1;
    }
    __syncthreads();
    s16x8 a[4], bb[4];
    #pragma unroll
    for (int m=0;m<4;m++) a[m] = *(const s16x8*)(&As[wrow + m*16 + fr][kg*8]);
    #pragma unroll
    for (int n=0;n<4;n++) bb[n] = *(const s16x8*)(&Bs[wcol + n*16 + fr][kg*8]);
    #pragma unroll
    for (int m=0;m<4;m++)
      #pragma unroll
      for (int n=0;n<4;n++)
        acc[m][n] = __builtin_amdgcn_mfma_f32_16x16x32_bf16(a[m], bb[n], acc[m][n], 0,0,0);
  }
  #pragma unroll
  for (int n=0;n<4;n++){
    int ccol = n0 + wcol + n*16 + fr;
    if (ccol >= N) continue;
    #pragma unroll
    for (int m=0;m<4;m++){
      #pragma unroll
      for (int q=0;q<4;q++){
        int row = m0 + wrow + m*16 + kg*4 + q;
        float v = acc[m][n][q];
        size_t oidx = (size_t)row*ldc + ccol;
        if constexpr (EPI == EPI_STORE) Cout[oidx] = f2b(v);
        else if constexpr (EPI == EPI_STORE32) Cout32[oidx] = v;
        else if constexpr (EPI == EPI_TANH) Cout[oidx] = f2b(tanhf(v));
        else if constexpr (EPI == EPI_SILU) Cout[oidx] = f2b(v / (1.f + expf(-v)));
        else if constexpr (EPI == EPI_LERP){
          float xv = e_x[(size_t)row*2048 + ccol];
          float dx = b2f(e_dxp[(size_t)row*2048 + ccol]);
          Cout[oidx] = f2b(xv + dx * (e_vec[ccol] + v));
        }
        else if constexpr (EPI == EPI_ICLR) Cout[oidx] = f2b(1.f / (1.f + expf(-(e_vec[ccol] + v))));
      }
    }
  }
}

// ---------------------------------------------------------------- thin GEMM: 64x64 tile, BK=64
template<int EPI>
__global__ __launch_bounds__(256) void gemm_thin_k(
    const u16* __restrict__ A, int lda,
    const u16* __restrict__ Bt, int ldb,
    u16* __restrict__ Cout, int ldc, int N, int K)
{
  __shared__ u16 As[64][72];
  __shared__ u16 Bs[64][72];
  const int tid = threadIdx.x;
  const int lane = tid & 63, wid = tid >> 6;
  const int m0 = blockIdx.x * 64, n0 = blockIdx.y * 64;
  const int wrow = (wid >> 1) * 32, wcol = (wid & 1) * 32;
  const int fr = lane & 15, kg = lane >> 4;
  const int r_c = tid >> 2, r_seg = tid & 3;

  f32x4 acc[2][2];
  #pragma unroll
  for (int m=0;m<2;m++)
    #pragma unroll
    for (int n=0;n<2;n++) acc[m][n] = ZF4;

  for (int k0 = 0; k0 < K; k0 += 64) {
    __syncthreads();
    {
      const u16* as = A + (size_t)(m0 + r_c)*lda + k0 + r_seg*16;
      *(uint4*)(&As[r_c][r_seg*16])     = *(const uint4*)(as);
      *(uint4*)(&As[r_c][r_seg*16 + 8]) = *(const uint4*)(as + 8);
      uint4 z = make_uint4(0,0,0,0);
      bool ok = (n0 + r_c < N);
      const u16* bs = Bt + (size_t)(n0 + r_c)*ldb + k0 + r_seg*16;
      *(uint4*)(&Bs[r_c][r_seg*16])     = ok ? *(const uint4*)(bs) : z;
      *(uint4*)(&Bs[r_c][r_seg*16 + 8]) = ok ? *(const uint4*)(bs + 8) : z;
    }
    __syncthreads();
    #pragma unroll
    for (int ks=0; ks<2; ++ks){
      s16x8 a[2], bb[2];
      #pragma unroll
      for (int m=0;m<2;m++) a[m] = *(const s16x8*)(&As[wrow + m*16 + fr][ks*32 + kg*8]);
      #pragma unroll
      for (int n=0;n<2;n++) bb[n] = *(const s16x8*)(&Bs[wcol + n*16 + fr][ks*32 + kg*8]);
      #pragma unroll
      for (int m=0;m<2;m++)
        #pragma unroll
        for (int n=0;n<2;n++)
          acc[m][n] = __builtin_amdgcn_mfma_f32_16x16x32_bf16(a[m], bb[n], acc[m][n], 0,0,0);
    }
  }
  #pragma unroll
  for (int n=0;n<2;n++){
    int ccol = n0 + wcol + n*16 + fr;
    if (ccol >= N) continue;
    #pragma unroll
    for (int m=0;m<2;m++){
      #pragma unroll
      for (int q=0;q<4;q++){
        int row = m0 + wrow + m*16 + kg*4 + q;
        float v = acc[m][n][q];
        size_t oidx = (size_t)row*ldc + ccol;
        if constexpr (EPI == EPI_TANH) Cout[oidx] = f2b(tanhf(v));
        else Cout[oidx] = f2b(v);
      }
    }
  }
}

// ---------------------------------------------------------------- WKV phase 1: per chunk-head, 512 threads / 8 waves
__global__ __launch_bounds__(512, 1) void wkv1_k(
    const u16* __restrict__ r_g, const u16* __restrict__ kraw_g, const u16* __restrict__ v_g,
    const u16* __restrict__ ic_g,
    const u16* __restrict__ t2_g, const u16* __restrict__ dw2t_g, const float* __restrict__ td_g,
    const float* __restrict__ u_g, const float* __restrict__ kkk_g, const float* __restrict__ kka_g,
    u16* __restrict__ y1_g, u16* __restrict__ rw_g,
    u16* __restrict__ kvab_g, float* __restrict__ wsA_g)
{
  __shared__ __align__(16) char arena[162304];
  float* WL   = (float*)(arena);
  float* WC   = (float*)(arena + 34816);
  u16* Abuf   = (u16*)(arena);
  u16* kkcT   = (u16*)(arena + 34816);
  float* diag_l = (float*)(arena + 68096);  // 128
  float* offs_l = diag_l + 128;             // 64
  float* wsum_l = offs_l + 64;              // 64
  float* u_l    = wsum_l + 64;              // 64
  float* kkk_l  = u_l + 64;                 // 64
  float* kka_l  = kkk_l + 64;               // 64
  float* td_l   = kka_l + 64;               // 64 -> ends 70144
  u16* rd_l   = (u16*)(arena + 70144);
  u16* vT_l   = (u16*)(arena + 70144);
  u16* ki_l   = (u16*)(arena + 88576);
  u16* kkwT_l = (u16*)(arena + 88576);
  u16* kwT_l  = (u16*)(arena + 107008);
  u16* ka_l   = (u16*)(arena + 125440);
  u16* kkb_l  = (u16*)(arena + 143872);
  u16* kaT_l  = (u16*)(arena + 143872);

  const int tid = threadIdx.x, lane = tid & 63, wid = tid >> 6;
  const int cb = blockIdx.x;
  const int c = cb >> 6, b = (cb >> 5) & 1, h = cb & 31;
  const size_t base = ((size_t)(b*4096 + c*128)) * 2048 + h*64;
  const int fr = lane & 15, kg = lane >> 4;
  const int tq = tid >> 2, kh = (tid & 3) * 16;

  // P0a
  {
    const u16* t2s = t2_g + (size_t)(b*4096 + c*128 + tq)*64 + kh;
    *(uint4*)(&rd_l[tq*72 + kh])     = *(const uint4*)(t2s);
    *(uint4*)(&rd_l[tq*72 + kh + 8]) = *(const uint4*)(t2s + 8);
    int n = tid >> 3, sg2 = (tid & 7) * 8;
    *(uint4*)(&ki_l[n*72 + sg2]) = *(const uint4*)(dw2t_g + (size_t)(h*64 + n)*64 + sg2);
  }
  if (tid < 64){
    u_l[tid]   = u_g[h*64 + tid];
    kkk_l[tid] = kkk_g[h*64 + tid];
    kka_l[tid] = kka_g[h*64 + tid];
    td_l[tid]  = td_g[h*64 + tid];
  }
  __syncthreads();
  // P0b
  {
    f32x4 accW[4];
    #pragma unroll
    for (int n=0;n<4;n++) accW[n] = ZF4;
    #pragma unroll
    for (int ks=0; ks<2; ++ks){
      s16x8 af = *(const s16x8*)(&rd_l[(wid*16 + fr)*72 + ks*32 + kg*8]);
      #pragma unroll
      for (int n=0;n<4;n++){
        s16x8 bf = *(const s16x8*)(&ki_l[(n*16 + fr)*72 + ks*32 + kg*8]);
        accW[n] = __builtin_amdgcn_mfma_f32_16x16x32_bf16(af, bf, accW[n], 0,0,0);
      }
    }
    #pragma unroll
    for (int n=0;n<4;n++)
      #pragma unroll
      for (int q=0;q<4;q++){
        int t = wid*16 + kg*4 + q;
        int s = n*16 + fr;
        WL[t*65 + s] = -__expf(td_l[s] + accW[n][q]);
      }
  }
  __syncthreads();
  // scan
  for (int j=0;j<8;j++){
    int k = wid*8 + j;
    float v = WL[lane*65 + k];
    #pragma unroll
    for (int d=1; d<64; d<<=1){ float o = __shfl_up(v, d); if (lane >= d) v += o; }
    WC[lane*65 + k] = v;
    float carry = __shfl(v, 63);
    float v2 = WL[(64+lane)*65 + k];
    #pragma unroll
    for (int d=1; d<64; d<<=1){ float o = __shfl_up(v2, d); if (lane >= d) v2 += o; }
    v2 += carry;
    WC[(64+lane)*65 + k] = v2;
    float tot = __shfl(v2, 63);
    if (lane == 0){ offs_l[k] = carry; wsum_l[k] = tot; wsA_g[(size_t)cb*64 + k] = __expf(tot); }
  }
  __syncthreads();
  // P1
  {
    const u16* rs  = r_g    + base + (size_t)tq*2048 + kh;
    const u16* ks_ = kraw_g + base + (size_t)tq*2048 + kh;
    const u16* is_ = ic_g   + base + (size_t)tq*2048 + kh;
    float dpart = 0.f;
    #pragma unroll
    for (int j=0;j<2;j++){
      float rf[8], kf[8], icf[8], rdf[8], kif[8], rwf[8];
      up8(*(const uint4*)(rs + j*8), rf);
      up8(*(const uint4*)(ks_ + j*8), kf);
      up8(*(const uint4*)(is_ + j*8), icf);
      #pragma unroll
      for (int e=0;e<8;e++){
        int k = kh + j*8 + e;
        float kadj = kf[e] * (1.f + (icf[e] - 1.f) * kka_l[k]);
        float wl = WL[tq*65+k], wc = WC[tq*65+k];
        float wcs = wc - wl;
        float off = offs_l[k], wsm = wsum_l[k];
        rdf[e] = rf[e] * __expf(clip30(wcs - off));
        kif[e] = kadj  * __expf(clip30(off - wc));
        rwf[e] = rf[e] * __expf(clip30(wcs));
        kwT_l[k*136 + tq] = f2b(kadj * __expf(clip30(wsm - wc)));
        dpart += rf[e] * u_l[k] * kadj;
      }
      *(uint4*)(&rd_l[tq*72 + kh + j*8]) = pk8(rdf);
      *(uint4*)(&ki_l[tq*72 + kh + j*8]) = pk8(kif);
      *(uint4*)(rw_g + base + (size_t)tq*2048 + kh + j*8) = pk8(rwf);
    }
    dpart += __shfl_xor(dpart, 1);
    dpart += __shfl_xor(dpart, 2);
    if ((tid & 3) == 0) diag_l[tq] = dpart;
  }
  __syncthreads();
  // P2
  {
    const u16* ks_ = kraw_g + base + (size_t)tq*2048 + kh;
    const u16* is_ = ic_g   + base + (size_t)tq*2048 + kh;
    float kf[16], icf[16], kkraw[16];
    #pragma unroll
    for (int j=0;j<2;j++){
      up8(*(const uint4*)(ks_ + j*8), kf + j*8);
      up8(*(const uint4*)(is_ + j*8), icf + j*8);
    }
    float ss = 0.f;
    #pragma unroll
    for (int e=0;e<16;e++){ kkraw[e] = kf[e]*kkk_l[kh+e]; ss += kkraw[e]*kkraw[e]; }
    ss += __shfl_xor(ss, 1);
    ss += __shfl_xor(ss, 2);
    float rn = 1.f / fmaxf(sqrtf(ss), 1e-12f);
    #pragma unroll
    for (int j=0;j<2;j++){
      float kkb8[8], ka8[8];
      #pragma unroll
      for (int e=0;e<8;e++){
        float kkv = kkraw[j*8+e]*rn;
        kkb8[e] = kkv; ka8[e] = kkv*icf[j*8+e];
      }
      *(uint4*)(&kkb_l[tq*72 + kh + j*8]) = pk8(kkb8);
      *(uint4*)(&ka_l [tq*72 + kh + j*8]) = pk8(ka8);
    }
  }
  __syncthreads();
  // P3
  f32x4 accA[8];
  #pragma unroll
  for (int n=0;n<8;n++) accA[n] = ZF4;
  #pragma unroll
  for (int ks=0; ks<2; ++ks){
    s16x8 af = *(const s16x8*)(&rd_l[(wid*16 + fr)*72 + ks*32 + kg*8]);
    #pragma unroll
    for (int n=0;n<8;n++){
      s16x8 bf = *(const s16x8*)(&ki_l[(n*16 + fr)*72 + ks*32 + kg*8]);
      accA[n] = __builtin_amdgcn_mfma_f32_16x16x32_bf16(af, bf, accA[n], 0,0,0);
    }
  }
  #pragma unroll
  for (int n=0;n<8;n++)
    #pragma unroll
    for (int q=0;q<4;q++){
      int t = wid*16 + kg*4 + q;
      int s = n*16 + fr;
      float v = accA[n][q];
      v = (t > s) ? v : ((t == s) ? diag_l[t] : 0.f);
      accA[n][q] = v;
      Abuf[t*136 + s] = f2b(v);
    }
  __syncthreads();
  // P4a
  {
    #pragma unroll
    for (int j=0;j<2;j++){
      float kkf[8];
      up8(*(const uint4*)(&kkb_l[tq*72 + kh + j*8]), kkf);
      #pragma unroll
      for (int e=0;e<8;e++){
        int k = kh + j*8 + e;
        kkwT_l[k*136 + tq] = f2b(-kkf[e] * __expf(clip30(wsum_l[k] - WC[tq*65+k])));
      }
    }
  }
  __syncthreads();
  // P4b
  {
    f32x4 accC[8];
    #pragma unroll
    for (int n=0;n<8;n++) accC[n] = ZF4;
    #pragma unroll
    for (int ks=0; ks<2; ++ks){
      s16x8 af = *(const s16x8*)(&ka_l[(wid*16 + fr)*72 + ks*32 + kg*8]);
      #pragma unroll
      for (int n=0;n<8;n++){
        s16x8 bf = *(const s16x8*)(&kkb_l[(n*16 + fr)*72 + ks*32 + kg*8]);
        accC[n] = __builtin_amdgcn_mfma_f32_16x16x32_bf16(af, bf, accC[n], 0,0,0);
      }
    }
    #pragma unroll
    for (int n=0;n<8;n++)
      #pragma unroll
      for (int q=0;q<4;q++){
        int t = wid*16 + kg*4 + q;
        int s = n*16 + fr;
        kkcT[s*136 + t] = f2b((t > s) ? accC[n][q] : 0.f);
      }
  }
  __syncthreads();
  // P5a
  {
    const u16* vs = v_g + base + (size_t)tq*2048 + kh;
    #pragma unroll
    for (int j=0;j<2;j++){
      u16 el[8]; unp16(*(const uint4*)(vs + j*8), el);
      #pragma unroll
      for (int e=0;e<8;e++) vT_l[(kh + j*8 + e)*136 + tq] = el[e];
    }
    #pragma unroll
    for (int j=0;j<2;j++){
      u16 el2[8]; unp16(*(const uint4*)(&ka_l[tq*72 + kh + j*8]), el2);
      #pragma unroll
      for (int e=0;e<8;e++) kaT_l[(kh + j*8 + e)*136 + tq] = el2[e];
    }
  }
  // P5b
  {
    f32x4 accP[8];
    #pragma unroll
    for (int n=0;n<8;n++) accP[n] = ZF4;
    #pragma unroll
    for (int ks=0; ks<4; ++ks){
      s16x8 af = *(const s16x8*)(&Abuf[(wid*16 + fr)*136 + ks*32 + kg*8]);
      #pragma unroll
      for (int n=0;n<8;n++){
        s16x8 bf = *(const s16x8*)(&kkcT[(n*16 + fr)*136 + ks*32 + kg*8]);
        accP[n] = __builtin_amdgcn_mfma_f32_16x16x32_bf16(af, bf, accP[n], 0,0,0);
      }
    }
    #pragma unroll
    for (int n=0;n<8;n++)
      #pragma unroll
      for (int q=0;q<4;q++){
        int t = wid*16 + kg*4 + q;
        int s = n*16 + fr;
        float v = accA[n][q] - ((t >= s) ? accP[n][q] : 0.f);
        Abuf[t*136 + s] = f2b(v);
      }
  }
  __syncthreads();
  // P6
  {
    f32x4 accY[4];
    #pragma unroll
    for (int n=0;n<4;n++) accY[n] = ZF4;
    #pragma unroll
    for (int ks=0; ks<4; ++ks){
      s16x8 af = *(const s16x8*)(&Abuf[(wid*16 + fr)*136 + ks*32 + kg*8]);
      #pragma unroll
      for (int n=0;n<4;n++){
        s16x8 bf = *(const s16x8*)(&vT_l[(n*16 + fr)*136 + ks*32 + kg*8]);
        accY[n] = __builtin_amdgcn_mfma_f32_16x16x32_bf16(af, bf, accY[n], 0,0,0);
      }
    }
    #pragma unroll
    for (int n=0;n<4;n++)
      #pragma unroll
      for (int q=0;q<4;q++){
        int t = wid*16 + kg*4 + q;
        int vd = n*16 + fr;
        y1_g[base + (size_t)t*2048 + vd] = f2b(accY[n][q]);
      }
  }
  // P7
  {
    const int isAB = wid >> 2, mrow = (wid & 3) * 16;
    const u16* Amat = isAB ? kkwT_l : kwT_l;
    const u16* Bmat = isAB ? kaT_l  : vT_l;
    f32x4 acc2[4];
    #pragma unroll
    for (int n=0;n<4;n++) acc2[n] = ZF4;
    #pragma unroll
    for (int ks=0; ks<4; ++ks){
      s16x8 af = *(const s16x8*)(&Amat[(mrow + fr)*136 + ks*32 + kg*8]);
      #pragma unroll
      for (int n=0;n<4;n++){
        s16x8 bf = *(const s16x8*)(&Bmat[(n*16 + fr)*136 + ks*32 + kg*8]);
        acc2[n] = __builtin_amdgcn_mfma_f32_16x16x32_bf16(af, bf, acc2[n], 0,0,0);
      }
    }
    u16* kvp = kvab_g + (size_t)cb*8192 + isAB*4096;
    #pragma unroll
    for (int n=0;n<4;n++)
      #pragma unroll
      for (int q=0;q<4;q++){
        int kd = mrow + kg*4 + q, vd = n*16 + fr;
        if (isAB) kvp[vd*64 + kd] = f2b(acc2[n][q]);
        else      kvp[kd*64 + vd] = f2b(acc2[n][q]);
      }
  }
}

// ---------------------------------------------------------------- WKV phase 2: MFMA state scan, 4-way row split
// grid = 64 (b,h) x 4 row-groups; each block owns 16 rows of S. S_in -> separate buffer (sin_g).
__global__ __launch_bounds__(256) void wkv2_k(
   const float* __restrict__ state_in, const u16* __restrict__ kvab_g,
   const float* __restrict__ wsA_g, float* __restrict__ sin_g, float* __restrict__ out_state)
{
  __shared__ u16 Sb[16][72];
  __shared__ u16 abT[64][72];
  const int tid = threadIdx.x, lane = tid & 63, wid = tid >> 6;  // wid = v-frag (16 cols)
  const int blk = blockIdx.x;
  const int bh = blk >> 2, rg = blk & 3;
  const int b = bh >> 5, h = bh & 31;
  const int fr = lane & 15, kg = lane >> 4;
  const int lrow = kg*4;                 // local row base
  const int grow = rg*16 + lrow;         // global S row base
  const int vcol = wid*16 + fr;
  const int vrow = tid >> 2, jc = (tid & 3) * 16;

  f32x4 S;
  #pragma unroll
  for (int q=0;q<4;q++)
    S[q] = state_in[(size_t)bh*4096 + (size_t)(grow+q)*64 + vcol];

  uint4 pf_ab0, pf_ab1; u16 pf_kv[4]; float pf_ws;
  {
    int cb = b*32 + h;
    const u16* kvp = kvab_g + (size_t)cb*8192;
    pf_ab0 = *(const uint4*)(kvp + 4096 + vrow*64 + jc);
    pf_ab1 = *(const uint4*)(kvp + 4096 + vrow*64 + jc + 8);
    #pragma unroll
    for (int q=0;q<4;q++) pf_kv[q] = kvp[(grow+q)*64 + vcol];
    pf_ws = wsA_g[(size_t)cb*64 + vcol];
  }

  for (int c=0;c<32;c++){
    int cb = (c*2+b)*32 + h;
    *(uint4*)(&abT[vrow][jc])   = pf_ab0;
    *(uint4*)(&abT[vrow][jc+8]) = pf_ab1;
    #pragma unroll
    for (int q=0;q<4;q++) Sb[lrow+q][vcol] = f2b(S[q]);
    float kvf[4];
    #pragma unroll
    for (int q=0;q<4;q++) kvf[q] = b2f(pf_kv[q]);
    float wsf = pf_ws;
    // entry state for wkv3 (separate buffer; kvab untouched)
    float* sip = sin_g + (size_t)cb*4096;
    #pragma unroll
    for (int q=0;q<4;q++) sip[(size_t)(grow+q)*64 + vcol] = S[q];
    __syncthreads();
    if (c < 31){
      int cb2 = ((c+1)*2+b)*32 + h;
      const u16* kvp2 = kvab_g + (size_t)cb2*8192;
      pf_ab0 = *(const uint4*)(kvp2 + 4096 + vrow*64 + jc);
      pf_ab1 = *(const uint4*)(kvp2 + 4096 + vrow*64 + jc + 8);
      #pragma unroll
      for (int q=0;q<4;q++) pf_kv[q] = kvp2[(grow+q)*64 + vcol];
      pf_ws = wsA_g[(size_t)cb2*64 + vcol];
    }
    f32x4 acc = ZF4;
    #pragma unroll
    for (int ks=0; ks<2; ++ks){
      s16x8 a  = *(const s16x8*)(&Sb[fr][ks*32 + kg*8]);
      s16x8 bb = *(const s16x8*)(&abT[wid*16 + fr][ks*32 + kg*8]);
      acc = __builtin_amdgcn_mfma_f32_16x16x32_bf16(a, bb, acc, 0,0,0);
    }
    #pragma unroll
    for (int q=0;q<4;q++)
      S[q] = S[q]*wsf + acc[q] + kvf[q];
    __syncthreads();
  }
  #pragma unroll
  for (int q=0;q<4;q++)
    out_state[(size_t)bh*4096 + (size_t)(grow+q)*64 + vcol] = S[q];
}

// ---------------------------------------------------------------- WKV phase 3: y = y1 + rw@S_in, GroupNorm, *g
__global__ __launch_bounds__(256) void wkv3_k(
   const u16* __restrict__ y1_g, const u16* __restrict__ rw_g,
   const float* __restrict__ sin_g,
   const u16* __restrict__ g_g, const float* __restrict__ gnw, const float* __restrict__ gnb,
   u16* __restrict__ yf_g)
{
  __shared__ float S_l[64][65];
  __shared__ u16 rw_l[128][72];
  int tid = threadIdx.x;
  int cb = blockIdx.x; int c = cb>>6, b = (cb>>5)&1, h = cb&31;
  size_t base = ((size_t)(b*4096 + c*128))*2048 + h*64;
  const float* sip = sin_g + (size_t)cb*4096;
  #pragma unroll
  for (int j=0;j<16;j++){ int flat = tid*16+j; S_l[flat>>6][flat&63] = sip[flat]; }
  {
    int t = tid>>1, kh = (tid&1)*32;
    const u16* rs = rw_g + base + (size_t)t*2048 + kh;
    #pragma unroll
    for (int j=0;j<4;j++) *(uint4*)(&rw_l[t][kh+j*8]) = *(const uint4*)(rs + j*8);
  }
  __syncthreads();
  int t = tid>>1, vh = (tid&1)*32;
  float acc[32];
  #pragma unroll
  for (int j=0;j<32;j++) acc[j] = 0.f;
  for (int kf2=0; kf2<64; kf2++){
    float rv = b2f(rw_l[t][kf2]);
    #pragma unroll
    for (int j=0;j<32;j++) acc[j] += rv * S_l[kf2][vh+j];
  }
  float sum=0.f, sq=0.f;
  float yv[32];
  #pragma unroll
  for (int j=0;j<32;j++){
    yv[j] = acc[j] + b2f(y1_g[base + (size_t)t*2048 + vh + j]);
    sum += yv[j]; sq += yv[j]*yv[j];
  }
  sum += __shfl_xor(sum, 1); sq += __shfl_xor(sq, 1);
  float mean = sum * (1.f/64.f);
  float var = sq * (1.f/64.f) - mean*mean;
  float rstd = rsqrtf(fmaxf(var, 0.f) + 6.4e-4f);
  size_t bt = (size_t)(b*4096 + c*128 + t);
  #pragma unroll
  for (int j=0;j<32;j++){
    int ch = h*64 + vh + j;
    float val = (yv[j]-mean)*rstd * gnw[ch] + gnb[ch];
    val *= b2f(g_g[bt*2048 + ch]);
    yf_g[base + (size_t)t*2048 + vh + j] = f2b(val);
  }
}

// ---------------------------------------------------------------- host
#define O_WTR   0ull
#define O_WTK   8388608ull
#define O_WTV   16777216ull
#define O_WTG   25165824ull
#define O_WTO   33554432ull
#define O_W1T   41943040ull
#define O_W2T   42729472ull
#define O_DW1T  43515904ull
#define O_DW2T  43778048ull
#define O_A1T   44040192ull
#define O_A2T   44433408ull
#define O_XXX   44826624ull
#define O_T2    47972352ull
#define O_T3    49020928ull
#define O_WSA   50593792ull
#define O_XMX   51118080ull       /* xmx -> xw -> r -> S_in(f32) */
#define O_A     84672512ull       /* xk -> v */
#define O_I     118226944ull      /* dxprev -> xa -> iclr */
#define O_R     151781376ull      /* xv -> g */
#define O_K     185335808ull      /* xr -> k -> y1 -> yf */
#define O_V     218890240ull      /* xg -> kvab */
#define WS_NEEDED 252444672ull

extern "C" void kernel_launch(void* const* d_in, const int* in_sizes, int n_in,
                              void* d_out, int out_size, void* d_ws, size_t ws_size,
                              hipStream_t stream)
{
  (void)in_sizes; (void)n_in; (void)out_size;
  if (ws_size < WS_NEEDED) return;
  const float* x     = (const float*)d_in[0];
  const float* shift = (const float*)d_in[1];
  const float* st_in = (const float*)d_in[2];
  const float* maax  = (const float*)d_in[3];
  const float* maas[6] = {(const float*)d_in[4],(const float*)d_in[5],(const float*)d_in[6],
                          (const float*)d_in[7],(const float*)d_in[8],(const float*)d_in[9]};
  const float* w1    = (const float*)d_in[10];
  const float* w2    = (const float*)d_in[11];
  const float* td    = (const float*)d_in[12];
  const float* dw1   = (const float*)d_in[13];
  const float* dw2   = (const float*)d_in[14];
  const float* faaaa = (const float*)d_in[15];
  const float* a0v   = (const float*)d_in[16];
  const float* a1w   = (const float*)d_in[17];
  const float* a2w   = (const float*)d_in[18];
  const float* kkk   = (const float*)d_in[19];
  const float* kka   = (const float*)d_in[20];
  const float* Wr    = (const float*)d_in[21];
  const float* Wk    = (const float*)d_in[22];
  const float* Wv    = (const float*)d_in[23];
  const float* Wg    = (const float*)d_in[24];
  const float* Wo    = (const float*)d_in[25];
  const float* gnw   = (const float*)d_in[26];
  const float* gnb   = (const float*)d_in[27];
  float* out = (float*)d_out;
  char* ws = (char*)d_ws;
  #define WSP(o) ((u16*)(ws + (o)))

  u16 *wtR=WSP(O_WTR), *wtK=WSP(O_WTK), *wtV=WSP(O_WTV), *wtG=WSP(O_WTG), *wtO=WSP(O_WTO);
  u16 *w1t=WSP(O_W1T), *w2t=WSP(O_W2T), *dw1t=WSP(O_DW1T), *dw2t=WSP(O_DW2T), *a1t=WSP(O_A1T), *a2t=WSP(O_A2T);
  u16 *xxx=WSP(O_XXX), *t2b=WSP(O_T2), *t3b=WSP(O_T3);
  u16 *sXMX=WSP(O_XMX), *sA=WSP(O_A), *sI=WSP(O_I), *sR=WSP(O_R), *sK=WSP(O_K), *sV=WSP(O_V);
  u16 *rw = WSP(O_WTR);
  float* sinF = (float*)(ws + O_XMX);   // S_in f32, reuses dead r region after wkv1
  float* wsA = (float*)(ws + O_WSA);
  float* out_xlast = out + 16777216;
  float* out_state = out + 16781312;

  dim3 tb(32,8);
  transpose5_k<<<dim3(64,64,5), tb, 0, stream>>>(Wr, Wk, Wv, Wg, Wo, wtR, wtK, wtV, wtG, wtO);
  transpose_k<<<dim3(6,64),  tb, 0, stream>>>(w1, w1t, 2048, 192);
  transpose_k<<<dim3(64,6),  tb, 0, stream>>>(w2, w2t, 192, 2048);
  transpose_k<<<dim3(2,64),  tb, 0, stream>>>(dw1, dw1t, 2048, 64);
  transpose_k<<<dim3(64,2),  tb, 0, stream>>>(dw2, dw2t, 64, 2048);
  transpose_k<<<dim3(3,64),  tb, 0, stream>>>(a1w, a1t, 2048, 96);
  transpose_k<<<dim3(64,3),  tb, 0, stream>>>(a2w, a2t, 96, 2048);

  prep_k<<<8192, 256, 0, stream>>>(x, shift, maax, sXMX /*xmx*/, sI /*dxp*/, out_xlast);

  // xxx = tanh(xmx @ w1)
  gemm_thin_k<EPI_TANH><<<dim3(128,3), 256, 0, stream>>>(sXMX, 2048, w1t, 2048, xxx, 192, 192, 2048);
  // all 6 token-shift lerps fused
  lerp6_k<<<dim3(64,16), 256, 0, stream>>>(xxx, w2t, x, sI /*dxp*/,
      maas[0], maas[1], maas[2], maas[3], maas[4], maas[5],
      sXMX /*xw*/, sA /*xk*/, sR /*xv*/, sK /*xr*/, sV /*xg*/, sI /*xa*/);
  // t2 = tanh(xw @ dw1) ; t3 = xa @ a1 ; iclr = sigmoid(a0 + t3@a2) -> I
  gemm_thin_k<EPI_TANH><<<dim3(128,1), 256, 0, stream>>>(sXMX, 2048, dw1t, 2048, t2b, 64, 64, 2048);
  gemm_thin_k<EPI_STORE><<<dim3(128,2), 256, 0, stream>>>(sI, 2048, a1t, 2048, t3b, 96, 96, 2048);
  gemm_k<EPI_ICLR,true,true><<<dim3(64,16), 256, 0, stream>>>(t3b, 96, a2t, 96, sI, nullptr, 2048, 8192, 2048, 96, nullptr, nullptr, a0v);
  // big projections: r->XMX, k->K, v->A, g->R
  gemm256_k<EPI_STORE><<<dim3(32,8), 512, 0, stream>>>(sK, wtR, sXMX, nullptr, 8192, 2048, 2048);
  gemm256_k<EPI_STORE><<<dim3(32,8), 512, 0, stream>>>(sA, wtK, sK, nullptr, 8192, 2048, 2048);
  gemm256_k<EPI_STORE><<<dim3(32,8), 512, 0, stream>>>(sR, wtV, sA, nullptr, 8192, 2048, 2048);
  gemm256_k<EPI_SILU><<<dim3(32,8), 512, 0, stream>>>(sV, wtG, sR, nullptr, 8192, 2048, 2048);
  // wkv
  wkv1_k<<<2048, 512, 0, stream>>>(sXMX, sK, sA, sI, t2b, dw2t, td, faaaa, kkk, kka,
                                   sK, rw, sV, wsA);
  wkv2_k<<<256, 256, 0, stream>>>(st_in, sV, wsA, sinF, out_state);
  wkv3_k<<<2048, 256, 0, stream>>>(sK, rw, sinF, sR /*g*/, gnw, gnb, sK /*yf in place*/);
  // out = yf @ W_o  (f32 store)
  gemm256_k<EPI_STORE32><<<dim3(32,8), 512, 0, stream>>>(sK, wtO, nullptr, out, 8192, 2048, 2048);
}

// Round 12
// 938.205 us; speedup vs baseline: 2.2325x; 1.0340x over previous
//
#include <hip/hip_runtime.h>

// RWKV7-delta time-mix. f32 in/out, bf16 intermediates + MFMA bf16 16x16x32.
// B=2 T=4096 C=2048 H=32 K=64 CHUNK=128 NC=32.

typedef unsigned short u16;
typedef unsigned int   u32;
typedef __attribute__((ext_vector_type(8))) short s16x8;
typedef __attribute__((ext_vector_type(4))) float f32x4;

#define DEV __device__ __forceinline__

DEV float b2f(u16 v){ return __uint_as_float(((u32)v) << 16); }
DEV u16 f2b(float f){ u32 u = __float_as_uint(f); return (u16)((u + 0x7fffu + ((u >> 16) & 1u)) >> 16); }
DEV float clip30(float x){ return fminf(fmaxf(x, -30.f), 30.f); }
DEV void up8(uint4 v, float* f){
  f[0]=b2f((u16)(v.x&0xffffu)); f[1]=b2f((u16)(v.x>>16));
  f[2]=b2f((u16)(v.y&0xffffu)); f[3]=b2f((u16)(v.y>>16));
  f[4]=b2f((u16)(v.z&0xffffu)); f[5]=b2f((u16)(v.z>>16));
  f[6]=b2f((u16)(v.w&0xffffu)); f[7]=b2f((u16)(v.w>>16));
}
DEV uint4 pk8(const float* f){
  uint4 v;
  v.x = (u32)f2b(f[0]) | ((u32)f2b(f[1])<<16);
  v.y = (u32)f2b(f[2]) | ((u32)f2b(f[3])<<16);
  v.z = (u32)f2b(f[4]) | ((u32)f2b(f[5])<<16);
  v.w = (u32)f2b(f[6]) | ((u32)f2b(f[7])<<16);
  return v;
}
DEV void unp16(uint4 v, u16* o){
  o[0]=(u16)(v.x&0xffffu); o[1]=(u16)(v.x>>16);
  o[2]=(u16)(v.y&0xffffu); o[3]=(u16)(v.y>>16);
  o[4]=(u16)(v.z&0xffffu); o[5]=(u16)(v.z>>16);
  o[6]=(u16)(v.w&0xffffu); o[7]=(u16)(v.w>>16);
}
DEV void gload16(const u16* g, u16* l){
  __builtin_amdgcn_global_load_lds(
      (const __attribute__((address_space(1))) u32*)g,
      (__attribute__((address_space(3))) u32*)l, 16, 0, 0);
}
#define ZF4 ((f32x4){0.f,0.f,0.f,0.f})

// ---------------------------------------------------------------- batched: 5 square 2048x2048 weight transposes
__global__ void transpose5_k(const float* __restrict__ w0, const float* __restrict__ w1,
    const float* __restrict__ w2, const float* __restrict__ w3, const float* __restrict__ w4,
    u16* __restrict__ o0, u16* __restrict__ o1, u16* __restrict__ o2,
    u16* __restrict__ o3, u16* __restrict__ o4){
  __shared__ float tile[32][33];
  const float* ins[5] = {w0,w1,w2,w3,w4};
  u16* outs[5] = {o0,o1,o2,o3,o4};
  const float* in = ins[blockIdx.z];
  u16* out = outs[blockIdx.z];
  int c0 = blockIdx.x*32, r0 = blockIdx.y*32;
  int tx = threadIdx.x, ty = threadIdx.y; // (32,8)
  #pragma unroll
  for (int j=0;j<4;j++) tile[ty + j*8][tx] = in[(size_t)(r0 + ty + j*8)*2048 + c0 + tx];
  __syncthreads();
  #pragma unroll
  for (int j=0;j<4;j++) out[(size_t)(c0 + ty + j*8)*2048 + r0 + tx] = f2b(tile[tx][ty + j*8]);
}

// batched: 6 small transposes (w1, w2, dw1, dw2, a1, a2) in one launch
__global__ void transpose6_k(
    const float* __restrict__ i0, const float* __restrict__ i1, const float* __restrict__ i2,
    const float* __restrict__ i3, const float* __restrict__ i4, const float* __restrict__ i5,
    u16* __restrict__ o0, u16* __restrict__ o1, u16* __restrict__ o2,
    u16* __restrict__ o3, u16* __restrict__ o4, u16* __restrict__ o5){
  __shared__ float tile[32][33];
  const float* ins[6] = {i0,i1,i2,i3,i4,i5};
  u16* outs[6] = {o0,o1,o2,o3,o4,o5};
  const int Rs[6] = {2048, 192, 2048, 64, 2048, 96};
  const int Cs[6] = {192, 2048, 64, 2048, 96, 2048};
  int z = blockIdx.z;
  int R = Rs[z], C = Cs[z];
  int c0 = blockIdx.x*32, r0 = blockIdx.y*32;
  if (c0 >= C || r0 >= R) return;
  const float* in = ins[z];
  u16* out = outs[z];
  int tx = threadIdx.x, ty = threadIdx.y; // (32,8)
  #pragma unroll
  for (int j=0;j<4;j++) tile[ty + j*8][tx] = in[(size_t)(r0 + ty + j*8)*C + c0 + tx];
  __syncthreads();
  #pragma unroll
  for (int j=0;j<4;j++) out[(size_t)(c0 + ty + j*8)*R + r0 + tx] = f2b(tile[tx][ty + j*8]);
}

// ---------------------------------------------------------------- prep: xmx bf16, dxprev bf16, x_last f32
__global__ __launch_bounds__(256) void prep_k(const float* __restrict__ x, const float* __restrict__ shift,
    const float* __restrict__ maax, u16* __restrict__ xmx, u16* __restrict__ dxp, float* __restrict__ out_xlast){
  int e8 = (blockIdx.x*256 + threadIdx.x) * 8;
  int row = e8 >> 11, col = e8 & 2047;
  int t = row & 4095, b = row >> 12;
  const float* xp = x + (size_t)row*2048 + col;
  const float* pp = t ? (x + (size_t)(row-1)*2048 + col) : (shift + (size_t)b*2048 + col);
  float xf[8], pf[8], mf[8], of[8], df[8];
  *(float4*)(xf)   = *(const float4*)(xp);
  *(float4*)(xf+4) = *(const float4*)(xp+4);
  *(float4*)(pf)   = *(const float4*)(pp);
  *(float4*)(pf+4) = *(const float4*)(pp+4);
  *(float4*)(mf)   = *(const float4*)(maax + col);
  *(float4*)(mf+4) = *(const float4*)(maax + col + 4);
  #pragma unroll
  for (int j=0;j<8;j++){ df[j] = pf[j]-xf[j]; of[j] = xf[j] + df[j]*mf[j]; }
  *(uint4*)(xmx + (size_t)row*2048 + col) = pk8(of);
  *(uint4*)(dxp + (size_t)row*2048 + col) = pk8(df);
  if (t == 4095){
    *(float4*)(out_xlast + (size_t)b*2048 + col)     = *(const float4*)(xf);
    *(float4*)(out_xlast + (size_t)b*2048 + col + 4) = *(const float4*)(xf+4);
  }
}

// ---------------------------------------------------------------- epilogue ids
enum { EPI_STORE=0, EPI_TANH=1, EPI_SILU=2, EPI_LERP=3, EPI_ICLR=5, EPI_STORE32=6 };

// ---------------------------------------------------------------- fused 6-way token-shift lerp
__global__ __launch_bounds__(256) void lerp6_k(
    const u16* __restrict__ xxx, const u16* __restrict__ w2t,
    const float* __restrict__ x, const u16* __restrict__ dxp,
    const float* __restrict__ ma0, const float* __restrict__ ma1, const float* __restrict__ ma2,
    const float* __restrict__ ma3, const float* __restrict__ ma4, const float* __restrict__ ma5,
    u16* __restrict__ o0, u16* __restrict__ o1, u16* __restrict__ o2,
    u16* __restrict__ o3, u16* __restrict__ o4, u16* __restrict__ o5)
{
  __shared__ u16 As[128][40];
  __shared__ u16 Bs[128][40];
  const int tid = threadIdx.x, lane = tid & 63, wid = tid >> 6;
  const int m0 = blockIdx.x*128, n0 = blockIdx.y*128;
  const int wrow = (wid>>1)*64, wcol = (wid&1)*64;
  const int fr = lane&15, kg = lane>>4;
  const int r_c0 = tid>>2, r_seg = tid&3, r_c1 = r_c0+64;
  const float* maap[6] = {ma0,ma1,ma2,ma3,ma4,ma5};
  u16* outs[6] = {o0,o1,o2,o3,o4,o5};

  float xv_[4][4][4], dxv_[4][4][4];
  #pragma unroll
  for (int m=0;m<4;m++)
    #pragma unroll
    for (int n=0;n<4;n++)
      #pragma unroll
      for (int q=0;q<4;q++){
        int row = m0 + wrow + m*16 + kg*4 + q;
        int col = n0 + wcol + n*16 + fr;
        xv_[m][n][q]  = x[(size_t)row*2048 + col];
        dxv_[m][n][q] = b2f(dxp[(size_t)row*2048 + col]);
      }

  #pragma unroll
  for (int s=0;s<6;s++){
    __syncthreads();
    *(uint4*)(&As[r_c0][r_seg*8]) = *(const uint4*)(xxx + (size_t)(m0+r_c0)*192 + s*32 + r_seg*8);
    *(uint4*)(&As[r_c1][r_seg*8]) = *(const uint4*)(xxx + (size_t)(m0+r_c1)*192 + s*32 + r_seg*8);
    *(uint4*)(&Bs[r_c0][r_seg*8]) = *(const uint4*)(w2t + (size_t)(n0+r_c0)*192 + s*32 + r_seg*8);
    *(uint4*)(&Bs[r_c1][r_seg*8]) = *(const uint4*)(w2t + (size_t)(n0+r_c1)*192 + s*32 + r_seg*8);
    __syncthreads();
    s16x8 a[4], bb[4];
    #pragma unroll
    for (int m=0;m<4;m++) a[m] = *(const s16x8*)(&As[wrow + m*16 + fr][kg*8]);
    #pragma unroll
    for (int n=0;n<4;n++) bb[n] = *(const s16x8*)(&Bs[wcol + n*16 + fr][kg*8]);
    f32x4 acc[4][4];
    #pragma unroll
    for (int m=0;m<4;m++)
      #pragma unroll
      for (int n=0;n<4;n++) acc[m][n] = ZF4;
    #pragma unroll
    for (int m=0;m<4;m++)
      #pragma unroll
      for (int n=0;n<4;n++)
        acc[m][n] = __builtin_amdgcn_mfma_f32_16x16x32_bf16(a[m], bb[n], acc[m][n], 0,0,0);
    #pragma unroll
    for (int n=0;n<4;n++){
      int col = n0 + wcol + n*16 + fr;
      float mv = maap[s][col];
      #pragma unroll
      for (int m=0;m<4;m++)
        #pragma unroll
        for (int q=0;q<4;q++){
          int row = m0 + wrow + m*16 + kg*4 + q;
          outs[s][(size_t)row*2048 + col] = f2b(xv_[m][n][q] + dxv_[m][n][q]*(mv + acc[m][n][q]));
        }
    }
  }
}

// ---------------------------------------------------------------- 256x256 BK=32 counted-vmcnt GEMM (big GEMMs)
// Epilogue vmcnt ladder fixes latent tail race: at t=NT-2/NT-1 fewer stages are
// outstanding, so vmcnt(8) would pass without guaranteeing tile t landed.
template<int EPI>
__global__ __launch_bounds__(512, 2) void gemm256_k(
    const u16* __restrict__ A, const u16* __restrict__ Bt,
    u16* __restrict__ Cout, float* __restrict__ Cout32,
    int M, int N, int K)
{
  __shared__ __align__(16) u16 lds[4*16384];   // 4 bufs x (A[256][32] + B[256][32]) = 128 KiB
  const int tid = threadIdx.x, lane = tid & 63;
  int bxx = blockIdx.x, byy = blockIdx.y;
  if (gridDim.x == 32 && gridDim.y == 8){
    int bid = byy * 32 + bxx;
    int xcd = bid & 7, idx = bid >> 3;
    bxx = xcd*4 + (idx & 3);
    byy = idx >> 2;
  } else {
    int nwg = gridDim.x * gridDim.y;
    if ((nwg & 7) == 0){
      int bid = byy * gridDim.x + bxx;
      int cpx = nwg >> 3;
      int swz = (bid & 7) * cpx + (bid >> 3);
      bxx = swz % gridDim.x; byy = swz / gridDim.x;
    }
  }
  const int m0 = bxx * 256, n0 = byy * 256;
  const int wid = tid >> 6;
  const int wm = wid >> 2, wn = wid & 3;
  const int fr = lane & 15, kg = lane >> 4;
  const int NT = K >> 5;
  const int chunk0 = __builtin_amdgcn_readfirstlane(wid) * 2;
  const int lr = lane >> 2, lsl = lane & 3;
  const int gswz = (lsl ^ ((lr >> 1) & 3)) << 3;   // pre-swizzled k-offset (elements)
  const int kswz = (kg ^ ((fr >> 1) & 3)) << 3;    // swizzled read k-offset (elements)

  f32x4 acc[8][4];
  #pragma unroll
  for (int m=0;m<8;m++)
    #pragma unroll
    for (int n=0;n<4;n++) acc[m][n] = ZF4;

  auto STAGE = [&](int t){
    u16* ab = lds + (t & 3) * 16384;
    u16* bb = ab + 8192;
    int gc = (t << 5) + gswz;
    #pragma unroll
    for (int i=0;i<2;i++){
      int c = chunk0 + i;
      int r = c*16 + lr;
      gload16(A  + (size_t)(m0 + r)*K + gc, ab + c*512);
      gload16(Bt + (size_t)(n0 + r)*K + gc, bb + c*512);
    }
  };

  STAGE(0); STAGE(1); STAGE(2);
  for (int t=0; t<NT; ++t){
    if (t+2 < NT)      { asm volatile("s_waitcnt vmcnt(8)" ::: "memory"); }
    else if (t+1 < NT) { asm volatile("s_waitcnt vmcnt(4)" ::: "memory"); }
    else               { asm volatile("s_waitcnt vmcnt(0)" ::: "memory"); }
    __builtin_amdgcn_s_barrier();
    __builtin_amdgcn_sched_barrier(0);
    if (t+3 < NT) STAGE(t+3);
    const u16* ab = lds + (t & 3) * 16384;
    const u16* bb = ab + 8192;
    s16x8 af[8], bf[4];
    #pragma unroll
    for (int m=0;m<8;m++){
      int r = wm*128 + m*16 + fr;
      af[m] = *(const s16x8*)(ab + r*32 + kswz);
    }
    #pragma unroll
    for (int n=0;n<4;n++){
      int r = wn*64 + n*16 + fr;
      bf[n] = *(const s16x8*)(bb + r*32 + kswz);
    }
    __builtin_amdgcn_s_setprio(1);
    #pragma unroll
    for (int m=0;m<8;m++)
      #pragma unroll
      for (int n=0;n<4;n++)
        acc[m][n] = __builtin_amdgcn_mfma_f32_16x16x32_bf16(af[m], bf[n], acc[m][n], 0,0,0);
    __builtin_amdgcn_s_setprio(0);
  }

  #pragma unroll
  for (int n=0;n<4;n++){
    int ccol = n0 + wn*64 + n*16 + fr;
    #pragma unroll
    for (int m=0;m<8;m++){
      #pragma unroll
      for (int q=0;q<4;q++){
        int row = m0 + wm*128 + m*16 + kg*4 + q;
        float v = acc[m][n][q];
        size_t oidx = (size_t)row*N + ccol;
        if constexpr (EPI == EPI_STORE) Cout[oidx] = f2b(v);
        else if constexpr (EPI == EPI_STORE32) Cout32[oidx] = v;
        else if constexpr (EPI == EPI_SILU) Cout[oidx] = f2b(v / (1.f + __expf(-v)));
      }
    }
  }
}

// ---------------------------------------------------------------- generic 128x128 GEMM with fused epilogues
template<int EPI, bool ASYNC, bool SWZ>
__global__ __launch_bounds__(256) void gemm_k(
    const u16* __restrict__ A, int lda,
    const u16* __restrict__ Bt, int ldb,
    u16* __restrict__ Cout, float* __restrict__ Cout32, int ldc,
    int M, int N, int K,
    const float* __restrict__ e_x, const u16* __restrict__ e_dxp, const float* __restrict__ e_vec)
{
  constexpr int LDW = ASYNC ? 32 : 40;
  __shared__ u16 As[128][LDW];
  __shared__ u16 Bs[128][LDW];
  const int tid = threadIdx.x;
  const int lane = tid & 63, wid = tid >> 6;
  int bxx = blockIdx.x, byy = blockIdx.y;
  if constexpr (SWZ){
    int nwg = gridDim.x * gridDim.y;
    if ((nwg & 7) == 0){
      int bid = byy * gridDim.x + bxx;
      int cpx = nwg >> 3;
      int swz = (bid & 7) * cpx + (bid >> 3);
      bxx = swz % gridDim.x; byy = swz / gridDim.x;
    }
  }
  const int m0 = bxx * 128, n0 = byy * 128;
  const int wrow = (wid >> 1) * 64, wcol = (wid & 1) * 64;
  const int fr = lane & 15, kg = lane >> 4;
  const int r_c0 = tid >> 2, r_seg = tid & 3;
  const int r_c1 = r_c0 + 64;

  f32x4 acc[4][4];
  #pragma unroll
  for (int m=0;m<4;m++)
    #pragma unroll
    for (int n=0;n<4;n++) acc[m][n] = ZF4;

  for (int k0 = 0; k0 < K; k0 += 32) {
    __syncthreads();
    if constexpr (ASYNC) {
      const int w4 = __builtin_amdgcn_readfirstlane(wid);
      const int rr = lane >> 2, seg8 = (lane & 3) * 8;
      #pragma unroll
      for (int i=0;i<2;i++){
        int row = w4*32 + i*16 + rr;
        gload16(A  + (size_t)(m0 + row)*lda + k0 + seg8, &As[w4*32 + i*16][0]);
        gload16(Bt + (size_t)(n0 + row)*ldb + k0 + seg8, &Bs[w4*32 + i*16][0]);
      }
    } else {
      uint4 av0 = *(const uint4*)(A + (size_t)(m0 + r_c0)*lda + k0 + r_seg*8);
      uint4 av1 = *(const uint4*)(A + (size_t)(m0 + r_c1)*lda + k0 + r_seg*8);
      *(uint4*)(&As[r_c0][r_seg*8]) = av0;
      *(uint4*)(&As[r_c1][r_seg*8]) = av1;
      uint4 z = make_uint4(0,0,0,0);
      uint4 bv0 = (n0 + r_c0 < N) ? *(const uint4*)(Bt + (size_t)(n0 + r_c0)*ldb + k0 + r_seg*8) : z;
      uint4 bv1 = (n0 + r_c1 < N) ? *(const uint4*)(Bt + (size_t)(n0 + r_c1)*ldb + k0 + r_seg*8) : z;
      *(uint4*)(&Bs[r_c0][r_seg*8]) = bv0;
      *(uint4*)(&Bs[r_c1][r_seg*8]) = bv1;
    }
    __syncthreads();
    s16x8 a[4], bb[4];
    #pragma unroll
    for (int m=0;m<4;m++) a[m] = *(const s16x8*)(&As[wrow + m*16 + fr][kg*8]);
    #pragma unroll
    for (int n=0;n<4;n++) bb[n] = *(const s16x8*)(&Bs[wcol + n*16 + fr][kg*8]);
    #pragma unroll
    for (int m=0;m<4;m++)
      #pragma unroll
      for (int n=0;n<4;n++)
        acc[m][n] = __builtin_amdgcn_mfma_f32_16x16x32_bf16(a[m], bb[n], acc[m][n], 0,0,0);
  }
  #pragma unroll
  for (int n=0;n<4;n++){
    int ccol = n0 + wcol + n*16 + fr;
    if (ccol >= N) continue;
    #pragma unroll
    for (int m=0;m<4;m++){
      #pragma unroll
      for (int q=0;q<4;q++){
        int row = m0 + wrow + m*16 + kg*4 + q;
        float v = acc[m][n][q];
        size_t oidx = (size_t)row*ldc + ccol;
        if constexpr (EPI == EPI_STORE) Cout[oidx] = f2b(v);
        else if constexpr (EPI == EPI_STORE32) Cout32[oidx] = v;
        else if constexpr (EPI == EPI_TANH) Cout[oidx] = f2b(tanhf(v));
        else if constexpr (EPI == EPI_SILU) Cout[oidx] = f2b(v / (1.f + expf(-v)));
        else if constexpr (EPI == EPI_LERP){
          float xv = e_x[(size_t)row*2048 + ccol];
          float dx = b2f(e_dxp[(size_t)row*2048 + ccol]);
          Cout[oidx] = f2b(xv + dx * (e_vec[ccol] + v));
        }
        else if constexpr (EPI == EPI_ICLR) Cout[oidx] = f2b(1.f / (1.f + expf(-(e_vec[ccol] + v))));
      }
    }
  }
}

// ---------------------------------------------------------------- paired thin GEMMs: z=0 (tanh) and z=1 (store)
__global__ __launch_bounds__(256) void thin2_k(
    const u16* __restrict__ A0, const u16* __restrict__ Bt0, u16* __restrict__ C0, int N0,
    const u16* __restrict__ A1, const u16* __restrict__ Bt1, u16* __restrict__ C1, int N1,
    int K)
{
  const u16* A  = blockIdx.z ? A1 : A0;
  const u16* Bt = blockIdx.z ? Bt1 : Bt0;
  u16* Cout     = blockIdx.z ? C1 : C0;
  const int N   = blockIdx.z ? N1 : N0;
  const int ldc = N;
  const bool do_tanh = (blockIdx.z == 0);
  const int m0 = blockIdx.x * 64, n0 = blockIdx.y * 64;
  if (n0 >= N) return;

  __shared__ u16 As[64][72];
  __shared__ u16 Bs[64][72];
  const int tid = threadIdx.x;
  const int lane = tid & 63, wid = tid >> 6;
  const int wrow = (wid >> 1) * 32, wcol = (wid & 1) * 32;
  const int fr = lane & 15, kg = lane >> 4;
  const int r_c = tid >> 2, r_seg = tid & 3;

  f32x4 acc[2][2];
  #pragma unroll
  for (int m=0;m<2;m++)
    #pragma unroll
    for (int n=0;n<2;n++) acc[m][n] = ZF4;

  for (int k0 = 0; k0 < K; k0 += 64) {
    __syncthreads();
    {
      const u16* as = A + (size_t)(m0 + r_c)*K + k0 + r_seg*16;
      *(uint4*)(&As[r_c][r_seg*16])     = *(const uint4*)(as);
      *(uint4*)(&As[r_c][r_seg*16 + 8]) = *(const uint4*)(as + 8);
      uint4 z = make_uint4(0,0,0,0);
      bool ok = (n0 + r_c < N);
      const u16* bs = Bt + (size_t)(n0 + r_c)*K + k0 + r_seg*16;
      *(uint4*)(&Bs[r_c][r_seg*16])     = ok ? *(const uint4*)(bs) : z;
      *(uint4*)(&Bs[r_c][r_seg*16 + 8]) = ok ? *(const uint4*)(bs + 8) : z;
    }
    __syncthreads();
    #pragma unroll
    for (int ks=0; ks<2; ++ks){
      s16x8 a[2], bb[2];
      #pragma unroll
      for (int m=0;m<2;m++) a[m] = *(const s16x8*)(&As[wrow + m*16 + fr][ks*32 + kg*8]);
      #pragma unroll
      for (int n=0;n<2;n++) bb[n] = *(const s16x8*)(&Bs[wcol + n*16 + fr][ks*32 + kg*8]);
      #pragma unroll
      for (int m=0;m<2;m++)
        #pragma unroll
        for (int n=0;n<2;n++)
          acc[m][n] = __builtin_amdgcn_mfma_f32_16x16x32_bf16(a[m], bb[n], acc[m][n], 0,0,0);
    }
  }
  #pragma unroll
  for (int n=0;n<2;n++){
    int ccol = n0 + wcol + n*16 + fr;
    if (ccol >= N) continue;
    #pragma unroll
    for (int m=0;m<2;m++){
      #pragma unroll
      for (int q=0;q<4;q++){
        int row = m0 + wrow + m*16 + kg*4 + q;
        float v = acc[m][n][q];
        Cout[(size_t)row*ldc + ccol] = f2b(do_tanh ? tanhf(v) : v);
      }
    }
  }
}

// ---------------------------------------------------------------- thin GEMM: 64x64 tile, BK=64
template<int EPI>
__global__ __launch_bounds__(256) void gemm_thin_k(
    const u16* __restrict__ A, int lda,
    const u16* __restrict__ Bt, int ldb,
    u16* __restrict__ Cout, int ldc, int N, int K)
{
  __shared__ u16 As[64][72];
  __shared__ u16 Bs[64][72];
  const int tid = threadIdx.x;
  const int lane = tid & 63, wid = tid >> 6;
  const int m0 = blockIdx.x * 64, n0 = blockIdx.y * 64;
  const int wrow = (wid >> 1) * 32, wcol = (wid & 1) * 32;
  const int fr = lane & 15, kg = lane >> 4;
  const int r_c = tid >> 2, r_seg = tid & 3;

  f32x4 acc[2][2];
  #pragma unroll
  for (int m=0;m<2;m++)
    #pragma unroll
    for (int n=0;n<2;n++) acc[m][n] = ZF4;

  for (int k0 = 0; k0 < K; k0 += 64) {
    __syncthreads();
    {
      const u16* as = A + (size_t)(m0 + r_c)*lda + k0 + r_seg*16;
      *(uint4*)(&As[r_c][r_seg*16])     = *(const uint4*)(as);
      *(uint4*)(&As[r_c][r_seg*16 + 8]) = *(const uint4*)(as + 8);
      uint4 z = make_uint4(0,0,0,0);
      bool ok = (n0 + r_c < N);
      const u16* bs = Bt + (size_t)(n0 + r_c)*ldb + k0 + r_seg*16;
      *(uint4*)(&Bs[r_c][r_seg*16])     = ok ? *(const uint4*)(bs) : z;
      *(uint4*)(&Bs[r_c][r_seg*16 + 8]) = ok ? *(const uint4*)(bs + 8) : z;
    }
    __syncthreads();
    #pragma unroll
    for (int ks=0; ks<2; ++ks){
      s16x8 a[2], bb[2];
      #pragma unroll
      for (int m=0;m<2;m++) a[m] = *(const s16x8*)(&As[wrow + m*16 + fr][ks*32 + kg*8]);
      #pragma unroll
      for (int n=0;n<2;n++) bb[n] = *(const s16x8*)(&Bs[wcol + n*16 + fr][ks*32 + kg*8]);
      #pragma unroll
      for (int m=0;m<2;m++)
        #pragma unroll
        for (int n=0;n<2;n++)
          acc[m][n] = __builtin_amdgcn_mfma_f32_16x16x32_bf16(a[m], bb[n], acc[m][n], 0,0,0);
    }
  }
  #pragma unroll
  for (int n=0;n<2;n++){
    int ccol = n0 + wcol + n*16 + fr;
    if (ccol >= N) continue;
    #pragma unroll
    for (int m=0;m<2;m++){
      #pragma unroll
      for (int q=0;q<4;q++){
        int row = m0 + wrow + m*16 + kg*4 + q;
        float v = acc[m][n][q];
        size_t oidx = (size_t)row*ldc + ccol;
        if constexpr (EPI == EPI_TANH) Cout[oidx] = f2b(tanhf(v));
        else Cout[oidx] = f2b(v);
      }
    }
  }
}

// ---------------------------------------------------------------- WKV phase 1: per chunk-head, 512 threads / 8 waves
__global__ __launch_bounds__(512, 1) void wkv1_k(
    const u16* __restrict__ r_g, const u16* __restrict__ kraw_g, const u16* __restrict__ v_g,
    const u16* __restrict__ ic_g,
    const u16* __restrict__ t2_g, const u16* __restrict__ dw2t_g, const float* __restrict__ td_g,
    const float* __restrict__ u_g, const float* __restrict__ kkk_g, const float* __restrict__ kka_g,
    u16* __restrict__ y1_g, u16* __restrict__ rw_g,
    u16* __restrict__ kvab_g, float* __restrict__ wsA_g)
{
  __shared__ __align__(16) char arena[162304];
  float* WL   = (float*)(arena);
  float* WC   = (float*)(arena + 34816);
  u16* Abuf   = (u16*)(arena);
  u16* kkcT   = (u16*)(arena + 34816);
  float* diag_l = (float*)(arena + 68096);  // 128
  float* offs_l = diag_l + 128;             // 64
  float* wsum_l = offs_l + 64;              // 64
  float* u_l    = wsum_l + 64;              // 64
  float* kkk_l  = u_l + 64;                 // 64
  float* kka_l  = kkk_l + 64;               // 64
  float* td_l   = kka_l + 64;               // 64 -> ends 70144
  u16* rd_l   = (u16*)(arena + 70144);
  u16* vT_l   = (u16*)(arena + 70144);
  u16* ki_l   = (u16*)(arena + 88576);
  u16* kkwT_l = (u16*)(arena + 88576);
  u16* kwT_l  = (u16*)(arena + 107008);
  u16* ka_l   = (u16*)(arena + 125440);
  u16* kkb_l  = (u16*)(arena + 143872);
  u16* kaT_l  = (u16*)(arena + 143872);

  const int tid = threadIdx.x, lane = tid & 63, wid = tid >> 6;
  const int cb = blockIdx.x;
  const int c = cb >> 6, b = (cb >> 5) & 1, h = cb & 31;
  const size_t base = ((size_t)(b*4096 + c*128)) * 2048 + h*64;
  const int fr = lane & 15, kg = lane >> 4;
  const int tq = tid >> 2, kh = (tid & 3) * 16;

  // P0a
  {
    const u16* t2s = t2_g + (size_t)(b*4096 + c*128 + tq)*64 + kh;
    *(uint4*)(&rd_l[tq*72 + kh])     = *(const uint4*)(t2s);
    *(uint4*)(&rd_l[tq*72 + kh + 8]) = *(const uint4*)(t2s + 8);
    int n = tid >> 3, sg2 = (tid & 7) * 8;
    *(uint4*)(&ki_l[n*72 + sg2]) = *(const uint4*)(dw2t_g + (size_t)(h*64 + n)*64 + sg2);
  }
  if (tid < 64){
    u_l[tid]   = u_g[h*64 + tid];
    kkk_l[tid] = kkk_g[h*64 + tid];
    kka_l[tid] = kka_g[h*64 + tid];
    td_l[tid]  = td_g[h*64 + tid];
  }
  __syncthreads();
  // P0b
  {
    f32x4 accW[4];
    #pragma unroll
    for (int n=0;n<4;n++) accW[n] = ZF4;
    #pragma unroll
    for (int ks=0; ks<2; ++ks){
      s16x8 af = *(const s16x8*)(&rd_l[(wid*16 + fr)*72 + ks*32 + kg*8]);
      #pragma unroll
      for (int n=0;n<4;n++){
        s16x8 bf = *(const s16x8*)(&ki_l[(n*16 + fr)*72 + ks*32 + kg*8]);
        accW[n] = __builtin_amdgcn_mfma_f32_16x16x32_bf16(af, bf, accW[n], 0,0,0);
      }
    }
    #pragma unroll
    for (int n=0;n<4;n++)
      #pragma unroll
      for (int q=0;q<4;q++){
        int t = wid*16 + kg*4 + q;
        int s = n*16 + fr;
        WL[t*65 + s] = -__expf(td_l[s] + accW[n][q]);
      }
  }
  __syncthreads();
  // scan
  for (int j=0;j<8;j++){
    int k = wid*8 + j;
    float v = WL[lane*65 + k];
    #pragma unroll
    for (int d=1; d<64; d<<=1){ float o = __shfl_up(v, d); if (lane >= d) v += o; }
    WC[lane*65 + k] = v;
    float carry = __shfl(v, 63);
    float v2 = WL[(64+lane)*65 + k];
    #pragma unroll
    for (int d=1; d<64; d<<=1){ float o = __shfl_up(v2, d); if (lane >= d) v2 += o; }
    v2 += carry;
    WC[(64+lane)*65 + k] = v2;
    float tot = __shfl(v2, 63);
    if (lane == 0){ offs_l[k] = carry; wsum_l[k] = tot; wsA_g[(size_t)cb*64 + k] = __expf(tot); }
  }
  __syncthreads();
  // P1
  {
    const u16* rs  = r_g    + base + (size_t)tq*2048 + kh;
    const u16* ks_ = kraw_g + base + (size_t)tq*2048 + kh;
    const u16* is_ = ic_g   + base + (size_t)tq*2048 + kh;
    float dpart = 0.f;
    #pragma unroll
    for (int j=0;j<2;j++){
      float rf[8], kf[8], icf[8], rdf[8], kif[8], rwf[8];
      up8(*(const uint4*)(rs + j*8), rf);
      up8(*(const uint4*)(ks_ + j*8), kf);
      up8(*(const uint4*)(is_ + j*8), icf);
      #pragma unroll
      for (int e=0;e<8;e++){
        int k = kh + j*8 + e;
        float kadj = kf[e] * (1.f + (icf[e] - 1.f) * kka_l[k]);
        float wl = WL[tq*65+k], wc = WC[tq*65+k];
        float wcs = wc - wl;
        float off = offs_l[k], wsm = wsum_l[k];
        rdf[e] = rf[e] * __expf(clip30(wcs - off));
        kif[e] = kadj  * __expf(clip30(off - wc));
        rwf[e] = rf[e] * __expf(clip30(wcs));
        kwT_l[k*136 + tq] = f2b(kadj * __expf(clip30(wsm - wc)));
        dpart += rf[e] * u_l[k] * kadj;
      }
      *(uint4*)(&rd_l[tq*72 + kh + j*8]) = pk8(rdf);
      *(uint4*)(&ki_l[tq*72 + kh + j*8]) = pk8(kif);
      *(uint4*)(rw_g + base + (size_t)tq*2048 + kh + j*8) = pk8(rwf);
    }
    dpart += __shfl_xor(dpart, 1);
    dpart += __shfl_xor(dpart, 2);
    if ((tid & 3) == 0) diag_l[tq] = dpart;
  }
  __syncthreads();
  // P2
  {
    const u16* ks_ = kraw_g + base + (size_t)tq*2048 + kh;
    const u16* is_ = ic_g   + base + (size_t)tq*2048 + kh;
    float kf[16], icf[16], kkraw[16];
    #pragma unroll
    for (int j=0;j<2;j++){
      up8(*(const uint4*)(ks_ + j*8), kf + j*8);
      up8(*(const uint4*)(is_ + j*8), icf + j*8);
    }
    float ss = 0.f;
    #pragma unroll
    for (int e=0;e<16;e++){ kkraw[e] = kf[e]*kkk_l[kh+e]; ss += kkraw[e]*kkraw[e]; }
    ss += __shfl_xor(ss, 1);
    ss += __shfl_xor(ss, 2);
    float rn = 1.f / fmaxf(sqrtf(ss), 1e-12f);
    #pragma unroll
    for (int j=0;j<2;j++){
      float kkb8[8], ka8[8];
      #pragma unroll
      for (int e=0;e<8;e++){
        float kkv = kkraw[j*8+e]*rn;
        kkb8[e] = kkv; ka8[e] = kkv*icf[j*8+e];
      }
      *(uint4*)(&kkb_l[tq*72 + kh + j*8]) = pk8(kkb8);
      *(uint4*)(&ka_l [tq*72 + kh + j*8]) = pk8(ka8);
    }
  }
  __syncthreads();
  // P3
  f32x4 accA[8];
  #pragma unroll
  for (int n=0;n<8;n++) accA[n] = ZF4;
  #pragma unroll
  for (int ks=0; ks<2; ++ks){
    s16x8 af = *(const s16x8*)(&rd_l[(wid*16 + fr)*72 + ks*32 + kg*8]);
    #pragma unroll
    for (int n=0;n<8;n++){
      s16x8 bf = *(const s16x8*)(&ki_l[(n*16 + fr)*72 + ks*32 + kg*8]);
      accA[n] = __builtin_amdgcn_mfma_f32_16x16x32_bf16(af, bf, accA[n], 0,0,0);
    }
  }
  #pragma unroll
  for (int n=0;n<8;n++)
    #pragma unroll
    for (int q=0;q<4;q++){
      int t = wid*16 + kg*4 + q;
      int s = n*16 + fr;
      float v = accA[n][q];
      v = (t > s) ? v : ((t == s) ? diag_l[t] : 0.f);
      accA[n][q] = v;
      Abuf[t*136 + s] = f2b(v);
    }
  __syncthreads();
  // P4a
  {
    #pragma unroll
    for (int j=0;j<2;j++){
      float kkf[8];
      up8(*(const uint4*)(&kkb_l[tq*72 + kh + j*8]), kkf);
      #pragma unroll
      for (int e=0;e<8;e++){
        int k = kh + j*8 + e;
        kkwT_l[k*136 + tq] = f2b(-kkf[e] * __expf(clip30(wsum_l[k] - WC[tq*65+k])));
      }
    }
  }
  __syncthreads();
  // P4b
  {
    f32x4 accC[8];
    #pragma unroll
    for (int n=0;n<8;n++) accC[n] = ZF4;
    #pragma unroll
    for (int ks=0; ks<2; ++ks){
      s16x8 af = *(const s16x8*)(&ka_l[(wid*16 + fr)*72 + ks*32 + kg*8]);
      #pragma unroll
      for (int n=0;n<8;n++){
        s16x8 bf = *(const s16x8*)(&kkb_l[(n*16 + fr)*72 + ks*32 + kg*8]);
        accC[n] = __builtin_amdgcn_mfma_f32_16x16x32_bf16(af, bf, accC[n], 0,0,0);
      }
    }
    #pragma unroll
    for (int n=0;n<8;n++)
      #pragma unroll
      for (int q=0;q<4;q++){
        int t = wid*16 + kg*4 + q;
        int s = n*16 + fr;
        kkcT[s*136 + t] = f2b((t > s) ? accC[n][q] : 0.f);
      }
  }
  __syncthreads();
  // P5a
  {
    const u16* vs = v_g + base + (size_t)tq*2048 + kh;
    #pragma unroll
    for (int j=0;j<2;j++){
      u16 el[8]; unp16(*(const uint4*)(vs + j*8), el);
      #pragma unroll
      for (int e=0;e<8;e++) vT_l[(kh + j*8 + e)*136 + tq] = el[e];
    }
    #pragma unroll
    for (int j=0;j<2;j++){
      u16 el2[8]; unp16(*(const uint4*)(&ka_l[tq*72 + kh + j*8]), el2);
      #pragma unroll
      for (int e=0;e<8;e++) kaT_l[(kh + j*8 + e)*136 + tq] = el2[e];
    }
  }
  // P5b
  {
    f32x4 accP[8];
    #pragma unroll
    for (int n=0;n<8;n++) accP[n] = ZF4;
    #pragma unroll
    for (int ks=0; ks<4; ++ks){
      s16x8 af = *(const s16x8*)(&Abuf[(wid*16 + fr)*136 + ks*32 + kg*8]);
      #pragma unroll
      for (int n=0;n<8;n++){
        s16x8 bf = *(const s16x8*)(&kkcT[(n*16 + fr)*136 + ks*32 + kg*8]);
        accP[n] = __builtin_amdgcn_mfma_f32_16x16x32_bf16(af, bf, accP[n], 0,0,0);
      }
    }
    #pragma unroll
    for (int n=0;n<8;n++)
      #pragma unroll
      for (int q=0;q<4;q++){
        int t = wid*16 + kg*4 + q;
        int s = n*16 + fr;
        float v = accA[n][q] - ((t >= s) ? accP[n][q] : 0.f);
        Abuf[t*136 + s] = f2b(v);
      }
  }
  __syncthreads();
  // P6
  {
    f32x4 accY[4];
    #pragma unroll
    for (int n=0;n<4;n++) accY[n] = ZF4;
    #pragma unroll
    for (int ks=0; ks<4; ++ks){
      s16x8 af = *(const s16x8*)(&Abuf[(wid*16 + fr)*136 + ks*32 + kg*8]);
      #pragma unroll
      for (int n=0;n<4;n++){
        s16x8 bf = *(const s16x8*)(&vT_l[(n*16 + fr)*136 + ks*32 + kg*8]);
        accY[n] = __builtin_amdgcn_mfma_f32_16x16x32_bf16(af, bf, accY[n], 0,0,0);
      }
    }
    #pragma unroll
    for (int n=0;n<4;n++)
      #pragma unroll
      for (int q=0;q<4;q++){
        int t = wid*16 + kg*4 + q;
        int vd = n*16 + fr;
        y1_g[base + (size_t)t*2048 + vd] = f2b(accY[n][q]);
      }
  }
  // P7
  {
    const int isAB = wid >> 2, mrow = (wid & 3) * 16;
    const u16* Amat = isAB ? kkwT_l : kwT_l;
    const u16* Bmat = isAB ? kaT_l  : vT_l;
    f32x4 acc2[4];
    #pragma unroll
    for (int n=0;n<4;n++) acc2[n] = ZF4;
    #pragma unroll
    for (int ks=0; ks<4; ++ks){
      s16x8 af = *(const s16x8*)(&Amat[(mrow + fr)*136 + ks*32 + kg*8]);
      #pragma unroll
      for (int n=0;n<4;n++){
        s16x8 bf = *(const s16x8*)(&Bmat[(n*16 + fr)*136 + ks*32 + kg*8]);
        acc2[n] = __builtin_amdgcn_mfma_f32_16x16x32_bf16(af, bf, acc2[n], 0,0,0);
      }
    }
    u16* kvp = kvab_g + (size_t)cb*8192 + isAB*4096;
    #pragma unroll
    for (int n=0;n<4;n++)
      #pragma unroll
      for (int q=0;q<4;q++){
        int kd = mrow + kg*4 + q, vd = n*16 + fr;
        if (isAB) kvp[vd*64 + kd] = f2b(acc2[n][q]);
        else      kvp[kd*64 + vd] = f2b(acc2[n][q]);
      }
  }
}

// ---------------------------------------------------------------- WKV phase 2: MFMA state scan, 4-way row split
__global__ __launch_bounds__(256) void wkv2_k(
   const float* __restrict__ state_in, const u16* __restrict__ kvab_g,
   const float* __restrict__ wsA_g, float* __restrict__ sin_g, float* __restrict__ out_state)
{
  __shared__ u16 Sb[16][72];
  __shared__ u16 abT[64][72];
  const int tid = threadIdx.x, lane = tid & 63, wid = tid >> 6;
  const int blk = blockIdx.x;
  const int bh = blk >> 2, rg = blk & 3;
  const int b = bh >> 5, h = bh & 31;
  const int fr = lane & 15, kg = lane >> 4;
  const int lrow = kg*4;
  const int grow = rg*16 + lrow;
  const int vcol = wid*16 + fr;
  const int vrow = tid >> 2, jc = (tid & 3) * 16;

  f32x4 S;
  #pragma unroll
  for (int q=0;q<4;q++)
    S[q] = state_in[(size_t)bh*4096 + (size_t)(grow+q)*64 + vcol];

  uint4 pf_ab0, pf_ab1; u16 pf_kv[4]; float pf_ws;
  {
    int cb = b*32 + h;
    const u16* kvp = kvab_g + (size_t)cb*8192;
    pf_ab0 = *(const uint4*)(kvp + 4096 + vrow*64 + jc);
    pf_ab1 = *(const uint4*)(kvp + 4096 + vrow*64 + jc + 8);
    #pragma unroll
    for (int q=0;q<4;q++) pf_kv[q] = kvp[(grow+q)*64 + vcol];
    pf_ws = wsA_g[(size_t)cb*64 + vcol];
  }

  for (int c=0;c<32;c++){
    int cb = (c*2+b)*32 + h;
    *(uint4*)(&abT[vrow][jc])   = pf_ab0;
    *(uint4*)(&abT[vrow][jc+8]) = pf_ab1;
    #pragma unroll
    for (int q=0;q<4;q++) Sb[lrow+q][vcol] = f2b(S[q]);
    float kvf[4];
    #pragma unroll
    for (int q=0;q<4;q++) kvf[q] = b2f(pf_kv[q]);
    float wsf = pf_ws;
    float* sip = sin_g + (size_t)cb*4096;
    #pragma unroll
    for (int q=0;q<4;q++) sip[(size_t)(grow+q)*64 + vcol] = S[q];
    __syncthreads();
    if (c < 31){
      int cb2 = ((c+1)*2+b)*32 + h;
      const u16* kvp2 = kvab_g + (size_t)cb2*8192;
      pf_ab0 = *(const uint4*)(kvp2 + 4096 + vrow*64 + jc);
      pf_ab1 = *(const uint4*)(kvp2 + 4096 + vrow*64 + jc + 8);
      #pragma unroll
      for (int q=0;q<4;q++) pf_kv[q] = kvp2[(grow+q)*64 + vcol];
      pf_ws = wsA_g[(size_t)cb2*64 + vcol];
    }
    f32x4 acc = ZF4;
    #pragma unroll
    for (int ks=0; ks<2; ++ks){
      s16x8 a  = *(const s16x8*)(&Sb[fr][ks*32 + kg*8]);
      s16x8 bb = *(const s16x8*)(&abT[wid*16 + fr][ks*32 + kg*8]);
      acc = __builtin_amdgcn_mfma_f32_16x16x32_bf16(a, bb, acc, 0,0,0);
    }
    #pragma unroll
    for (int q=0;q<4;q++)
      S[q] = S[q]*wsf + acc[q] + kvf[q];
    __syncthreads();
  }
  #pragma unroll
  for (int q=0;q<4;q++)
    out_state[(size_t)bh*4096 + (size_t)(grow+q)*64 + vcol] = S[q];
}

// ---------------------------------------------------------------- WKV phase 3: y = y1 + rw@S_in, GroupNorm, *g
__global__ __launch_bounds__(256) void wkv3_k(
   const u16* __restrict__ y1_g, const u16* __restrict__ rw_g,
   const float* __restrict__ sin_g,
   const u16* __restrict__ g_g, const float* __restrict__ gnw, const float* __restrict__ gnb,
   u16* __restrict__ yf_g)
{
  __shared__ float S_l[64][65];
  __shared__ u16 rw_l[128][72];
  int tid = threadIdx.x;
  int cb = blockIdx.x; int c = cb>>6, b = (cb>>5)&1, h = cb&31;
  size_t base = ((size_t)(b*4096 + c*128))*2048 + h*64;
  const float* sip = sin_g + (size_t)cb*4096;
  #pragma unroll
  for (int j=0;j<16;j++){ int flat = tid*16+j; S_l[flat>>6][flat&63] = sip[flat]; }
  {
    int t = tid>>1, kh = (tid&1)*32;
    const u16* rs = rw_g + base + (size_t)t*2048 + kh;
    #pragma unroll
    for (int j=0;j<4;j++) *(uint4*)(&rw_l[t][kh+j*8]) = *(const uint4*)(rs + j*8);
  }
  __syncthreads();
  int t = tid>>1, vh = (tid&1)*32;
  float acc[32];
  #pragma unroll
  for (int j=0;j<32;j++) acc[j] = 0.f;
  for (int kf2=0; kf2<64; kf2++){
    float rv = b2f(rw_l[t][kf2]);
    #pragma unroll
    for (int j=0;j<32;j++) acc[j] += rv * S_l[kf2][vh+j];
  }
  float sum=0.f, sq=0.f;
  float yv[32];
  #pragma unroll
  for (int j=0;j<32;j++){
    yv[j] = acc[j] + b2f(y1_g[base + (size_t)t*2048 + vh + j]);
    sum += yv[j]; sq += yv[j]*yv[j];
  }
  sum += __shfl_xor(sum, 1); sq += __shfl_xor(sq, 1);
  float mean = sum * (1.f/64.f);
  float var = sq * (1.f/64.f) - mean*mean;
  float rstd = rsqrtf(fmaxf(var, 0.f) + 6.4e-4f);
  size_t bt = (size_t)(b*4096 + c*128 + t);
  #pragma unroll
  for (int j=0;j<32;j++){
    int ch = h*64 + vh + j;
    float val = (yv[j]-mean)*rstd * gnw[ch] + gnb[ch];
    val *= b2f(g_g[bt*2048 + ch]);
    yf_g[base + (size_t)t*2048 + vh + j] = f2b(val);
  }
}

// ---------------------------------------------------------------- host
#define O_WTR   0ull
#define O_WTK   8388608ull
#define O_WTV   16777216ull
#define O_WTG   25165824ull
#define O_WTO   33554432ull
#define O_W1T   41943040ull
#define O_W2T   42729472ull
#define O_DW1T  43515904ull
#define O_DW2T  43778048ull
#define O_A1T   44040192ull
#define O_A2T   44433408ull
#define O_XXX   44826624ull
#define O_T2    47972352ull
#define O_T3    49020928ull
#define O_WSA   50593792ull
#define O_XMX   51118080ull       /* xmx -> xw -> r -> S_in(f32) */
#define O_A     84672512ull       /* xk -> v */
#define O_I     118226944ull      /* dxprev -> xa -> iclr */
#define O_R     151781376ull      /* xv -> g */
#define O_K     185335808ull      /* xr -> k -> y1 -> yf */
#define O_V     218890240ull      /* xg -> kvab */
#define WS_NEEDED 252444672ull

extern "C" void kernel_launch(void* const* d_in, const int* in_sizes, int n_in,
                              void* d_out, int out_size, void* d_ws, size_t ws_size,
                              hipStream_t stream)
{
  (void)in_sizes; (void)n_in; (void)out_size;
  if (ws_size < WS_NEEDED) return;
  const float* x     = (const float*)d_in[0];
  const float* shift = (const float*)d_in[1];
  const float* st_in = (const float*)d_in[2];
  const float* maax  = (const float*)d_in[3];
  const float* maas[6] = {(const float*)d_in[4],(const float*)d_in[5],(const float*)d_in[6],
                          (const float*)d_in[7],(const float*)d_in[8],(const float*)d_in[9]};
  const float* w1    = (const float*)d_in[10];
  const float* w2    = (const float*)d_in[11];
  const float* td    = (const float*)d_in[12];
  const float* dw1   = (const float*)d_in[13];
  const float* dw2   = (const float*)d_in[14];
  const float* faaaa = (const float*)d_in[15];
  const float* a0v   = (const float*)d_in[16];
  const float* a1w   = (const float*)d_in[17];
  const float* a2w   = (const float*)d_in[18];
  const float* kkk   = (const float*)d_in[19];
  const float* kka   = (const float*)d_in[20];
  const float* Wr    = (const float*)d_in[21];
  const float* Wk    = (const float*)d_in[22];
  const float* Wv    = (const float*)d_in[23];
  const float* Wg    = (const float*)d_in[24];
  const float* Wo    = (const float*)d_in[25];
  const float* gnw   = (const float*)d_in[26];
  const float* gnb   = (const float*)d_in[27];
  float* out = (float*)d_out;
  char* ws = (char*)d_ws;
  #define WSP(o) ((u16*)(ws + (o)))

  u16 *wtR=WSP(O_WTR), *wtK=WSP(O_WTK), *wtV=WSP(O_WTV), *wtG=WSP(O_WTG), *wtO=WSP(O_WTO);
  u16 *w1t=WSP(O_W1T), *w2t=WSP(O_W2T), *dw1t=WSP(O_DW1T), *dw2t=WSP(O_DW2T), *a1t=WSP(O_A1T), *a2t=WSP(O_A2T);
  u16 *xxx=WSP(O_XXX), *t2b=WSP(O_T2), *t3b=WSP(O_T3);
  u16 *sXMX=WSP(O_XMX), *sA=WSP(O_A), *sI=WSP(O_I), *sR=WSP(O_R), *sK=WSP(O_K), *sV=WSP(O_V);
  u16 *rw = WSP(O_WTR);
  float* sinF = (float*)(ws + O_XMX);
  float* wsA = (float*)(ws + O_WSA);
  float* out_xlast = out + 16777216;
  float* out_state = out + 16781312;

  dim3 tb(32,8);
  transpose5_k<<<dim3(64,64,5), tb, 0, stream>>>(Wr, Wk, Wv, Wg, Wo, wtR, wtK, wtV, wtG, wtO);
  transpose6_k<<<dim3(64,64,6), tb, 0, stream>>>(w1, w2, dw1, dw2, a1w, a2w,
                                                 w1t, w2t, dw1t, dw2t, a1t, a2t);

  prep_k<<<8192, 256, 0, stream>>>(x, shift, maax, sXMX /*xmx*/, sI /*dxp*/, out_xlast);

  // xxx = tanh(xmx @ w1)
  gemm_thin_k<EPI_TANH><<<dim3(128,3), 256, 0, stream>>>(sXMX, 2048, w1t, 2048, xxx, 192, 192, 2048);
  // all 6 token-shift lerps fused
  lerp6_k<<<dim3(64,16), 256, 0, stream>>>(xxx, w2t, x, sI /*dxp*/,
      maas[0], maas[1], maas[2], maas[3], maas[4], maas[5],
      sXMX /*xw*/, sA /*xk*/, sR /*xv*/, sK /*xr*/, sV /*xg*/, sI /*xa*/);
  // t2 = tanh(xw @ dw1) and t3 = xa @ a1 (paired, independent)
  thin2_k<<<dim3(128,2,2), 256, 0, stream>>>(sXMX, dw1t, t2b, 64, sI, a1t, t3b, 96, 2048);
  // iclr = sigmoid(a0 + t3@a2) -> I
  gemm_k<EPI_ICLR,true,true><<<dim3(64,16), 256, 0, stream>>>(t3b, 96, a2t, 96, sI, nullptr, 2048, 8192, 2048, 96, nullptr, nullptr, a0v);
  // big projections: r->XMX, k->K, v->A, g->R (strict chain, sequential)
  gemm256_k<EPI_STORE><<<dim3(32,8), 512, 0, stream>>>(sK, wtR, sXMX, nullptr, 8192, 2048, 2048);
  gemm256_k<EPI_STORE><<<dim3(32,8), 512, 0, stream>>>(sA, wtK, sK, nullptr, 8192, 2048, 2048);
  gemm256_k<EPI_STORE><<<dim3(32,8), 512, 0, stream>>>(sR, wtV, sA, nullptr, 8192, 2048, 2048);
  gemm256_k<EPI_SILU><<<dim3(32,8), 512, 0, stream>>>(sV, wtG, sR, nullptr, 8192, 2048, 2048);
  // wkv
  wkv1_k<<<2048, 512, 0, stream>>>(sXMX, sK, sA, sI, t2b, dw2t, td, faaaa, kkk, kka,
                                   sK, rw, sV, wsA);
  wkv2_k<<<256, 256, 0, stream>>>(st_in, sV, wsA, sinF, out_state);
  wkv3_k<<<2048, 256, 0, stream>>>(sK, rw, sinF, sR /*g*/, gnw, gnb, sK /*yf in place*/);
  // out = yf @ W_o  (f32 store)
  gemm256_k<EPI_STORE32><<<dim3(32,8), 512, 0, stream>>>(sK, wtO, nullptr, out, 8192, 2048, 2048);
}